// Round 12
// baseline (677.450 us; speedup 1.0000x reference)
//
#include <hip/hip_runtime.h>
#include <math.h>

#define TN 8192          // total nodes (B*N)
#define KNN 9
#define NPG 1024         // nodes per graph
#define TK (TN*KNN)      // 73728 edge rows
#define CPCL 12          // cap per (node,chunk), local (8 chunks of 128)
#define NCHG 32          // global chunks (of 256 candidates)
#define CPCG 16          // cap per (node,chunk), global

// ---------------- helpers ----------------
__device__ __forceinline__ float sqnorm(float4 v){
  return fmaf(v.x,v.x,fmaf(v.y,v.y,fmaf(v.z,v.z,v.w*v.w)));
}
__device__ __forceinline__ float pairdist(float4 a, float sqa, float4 b, float sqb){
  float dot = fmaf(a.x,b.x,fmaf(a.y,b.y,fmaf(a.z,b.z,a.w*b.w)));
  return sqa + sqb - 2.0f*dot;
}
__device__ __forceinline__ void chain9(float (&bd)[9], float d){
  float t=d;
  #pragma unroll
  for(int p=0;p<9;p++){
    float lo=fminf(bd[p],t);
    t=fmaxf(bd[p],t);
    bd[p]=lo;
  }
}
__device__ __forceinline__ void insert9(float (&bd)[9], int (&bi)[9], float d, int id){
  if(d < bd[8]){
    float td=d; int ti=id;
    #pragma unroll
    for(int p=0;p<9;p++){
      bool sw = (td < bd[p]);
      float nbd = sw ? td : bd[p];
      int   nbi = sw ? ti : bi[p];
      float ntd = sw ? bd[p] : td;
      int   nti = sw ? bi[p] : ti;
      bd[p]=nbd; bi[p]=nbi; td=ntd; ti=nti;
    }
  }
}

// ---------------- kNN: local (per-graph) ----------------
__global__ __launch_bounds__(256) void k_part_local(const float4* __restrict__ x, float* __restrict__ pd){
  __shared__ float4 sx[128]; __shared__ float ssq[128];
  int nb = blockIdx.x >> 3, chunk = blockIdx.x & 7;
  int g = nb >> 2;
  int cbase = g*NPG + chunk*128;
  if(threadIdx.x < 128){
    float4 v = x[cbase + threadIdx.x];
    sx[threadIdx.x]=v; ssq[threadIdx.x]=sqnorm(v);
  }
  __syncthreads();
  int node = nb*256 + threadIdx.x;
  float4 xi = x[node]; float sqi = sqnorm(xi);
  float bdA[9], bdB[9];
  #pragma unroll
  for(int q=0;q<9;q++){bdA[q]=1e30f;bdB[q]=1e30f;}
  for(int j=0;j<128;j+=2){
    chain9(bdA, pairdist(xi,sqi,sx[j],ssq[j]));
    chain9(bdB, pairdist(xi,sqi,sx[j+1],ssq[j+1]));
  }
  #pragma unroll
  for(int q=0;q<9;q++) chain9(bdA, bdB[q]);
  #pragma unroll
  for(int q=0;q<9;q++) pd[(size_t)(chunk*9+q)*TN + node]=bdA[q];
}

__global__ __launch_bounds__(256) void k_thresh_local(const float* __restrict__ pd,
      float* __restrict__ tl){
  int node = blockIdx.x*256 + threadIdx.x;
  float bd[9];
  #pragma unroll
  for(int q=0;q<9;q++) bd[q]=1e30f;
  for(int m=0;m<72;m++) chain9(bd, pd[(size_t)m*TN + node]);
  float t = bd[8];
  tl[node] = t + fabsf(t)*1e-5f + 1e-12f;
}

__global__ __launch_bounds__(256) void k_collect_local(const float4* __restrict__ x,
      const float* __restrict__ tl, unsigned char* __restrict__ cnt8,
      unsigned short* __restrict__ list){
  __shared__ float4 sx[128]; __shared__ float ssq[128];
  int nb = blockIdx.x >> 3, chunk = blockIdx.x & 7;
  int g = nb >> 2;
  int cbase = g*NPG + chunk*128;
  if(threadIdx.x < 128){
    float4 v = x[cbase + threadIdx.x];
    sx[threadIdx.x]=v; ssq[threadIdx.x]=sqnorm(v);
  }
  __syncthreads();
  int node = nb*256 + threadIdx.x;
  float4 xi = x[node];
  float m2x=-2.0f*xi.x, m2y=-2.0f*xi.y, m2z=-2.0f*xi.z, m2w=-2.0f*xi.w;
  float tadj = tl[node] - sqnorm(xi);
  int cnt = 0;
  unsigned short* lst = list + ((size_t)node*8 + chunk)*CPCL;
  for(int j=0;j<128;j+=4){
    float4 v0=sx[j], v1=sx[j+1], v2=sx[j+2], v3=sx[j+3];
    float q0=ssq[j], q1=ssq[j+1], q2=ssq[j+2], q3=ssq[j+3];
    float s0=fmaf(v0.x,m2x,fmaf(v0.y,m2y,fmaf(v0.z,m2z,fmaf(v0.w,m2w,q0))));
    float s1=fmaf(v1.x,m2x,fmaf(v1.y,m2y,fmaf(v1.z,m2z,fmaf(v1.w,m2w,q1))));
    float s2=fmaf(v2.x,m2x,fmaf(v2.y,m2y,fmaf(v2.z,m2z,fmaf(v2.w,m2w,q2))));
    float s3=fmaf(v3.x,m2x,fmaf(v3.y,m2y,fmaf(v3.z,m2z,fmaf(v3.w,m2w,q3))));
    if(s0<=tadj){ if(cnt<CPCL) lst[cnt]=(unsigned short)(cbase+j  ); cnt++; }
    if(s1<=tadj){ if(cnt<CPCL) lst[cnt]=(unsigned short)(cbase+j+1); cnt++; }
    if(s2<=tadj){ if(cnt<CPCL) lst[cnt]=(unsigned short)(cbase+j+2); cnt++; }
    if(s3<=tadj){ if(cnt<CPCL) lst[cnt]=(unsigned short)(cbase+j+3); cnt++; }
  }
  cnt8[(size_t)node*8 + chunk] = (unsigned char)(cnt > 255 ? 255 : cnt);
}

// 8 threads per node: sub handles 1 chunk; LDS merge of 8 partial top-9s
__global__ __launch_bounds__(256) void k_refine_local(const float4* __restrict__ x,
      const unsigned char* __restrict__ cnt8, const unsigned short* __restrict__ list,
      int* __restrict__ out){
  __shared__ float sval[32][73];
  __shared__ int   sidx[32][73];
  __shared__ int   sovf[32];
  int slot = threadIdx.x >> 3, sub = threadIdx.x & 7;
  int node = blockIdx.x*32 + slot;
  if(sub==0) sovf[slot]=0;
  __syncthreads();
  float4 xi = x[node]; float sqi = sqnorm(xi);
  float bd[9]; int bi[9];
  #pragma unroll
  for(int q=0;q<9;q++){bd[q]=1e30f; bi[q]=node;}
  int ch = sub;
  int c = cnt8[(size_t)node*8 + ch];
  if(c > CPCL) sovf[slot]=1;
  int n = c < CPCL ? c : CPCL;
  const unsigned short* lst = list + ((size_t)node*8 + ch)*CPCL;
  for(int m=0;m<n;m++){
    int j = lst[m]; float4 v = x[j];
    insert9(bd,bi, pairdist(xi,sqi,v,sqnorm(v)), j);
  }
  #pragma unroll
  for(int q=0;q<9;q++){ sval[slot][sub*9+q]=bd[q]; sidx[slot][sub*9+q]=bi[q]; }
  __syncthreads();
  if(sub==0){
    for(int m=9;m<72;m++) insert9(bd,bi, sval[slot][m], sidx[slot][m]);
    if(sovf[slot]){
      #pragma unroll
      for(int q=0;q<9;q++){bd[q]=1e30f; bi[q]=node;}
      int gbase = node & ~(NPG-1);
      for(int j=gbase;j<gbase+NPG;j++){
        float4 v = x[j];
        insert9(bd,bi, pairdist(xi,sqi,v,sqnorm(v)), j);
      }
    }
    #pragma unroll
    for(int q=0;q<9;q++) out[(size_t)node*9+q]=bi[q];
  }
}

// ---------------- kNN: global (two problems: xl, xs) ----------------
__global__ __launch_bounds__(256) void k_part_sub(const float4* __restrict__ xa,
      const float4* __restrict__ xb, float* __restrict__ pd){
  const float4* x = blockIdx.y ? xb : xa;
  __shared__ float4 sx[256]; __shared__ float ssq[256];
  int nb = blockIdx.x >> 3, chunk = blockIdx.x & 7;
  {
    int j = (chunk*256 + threadIdx.x)*4;
    float4 v = x[j];
    sx[threadIdx.x]=v; ssq[threadIdx.x]=sqnorm(v);
  }
  __syncthreads();
  int node = nb*256 + threadIdx.x;
  float4 xi = x[node]; float sqi = sqnorm(xi);
  float bdA[9], bdB[9];
  #pragma unroll
  for(int q=0;q<9;q++){bdA[q]=1e30f;bdB[q]=1e30f;}
  for(int j=0;j<256;j+=2){
    chain9(bdA, pairdist(xi,sqi,sx[j],ssq[j]));
    chain9(bdB, pairdist(xi,sqi,sx[j+1],ssq[j+1]));
  }
  #pragma unroll
  for(int q=0;q<9;q++) chain9(bdA, bdB[q]);
  int pn = blockIdx.y*TN + node;
  #pragma unroll
  for(int q=0;q<9;q++) pd[(size_t)(chunk*9+q)*2*TN + pn]=bdA[q];
}

__global__ __launch_bounds__(256) void k_thresh_sub(const float* __restrict__ pd,
      float* __restrict__ tg){
  int pn = blockIdx.x*256 + threadIdx.x;   // < 2*TN
  float bd[9];
  #pragma unroll
  for(int q=0;q<9;q++) bd[q]=1e30f;
  for(int m=0;m<72;m++) chain9(bd, pd[(size_t)m*2*TN + pn]);
  float t = bd[8];
  tg[pn] = t + fabsf(t)*1e-5f + 1e-12f;
}

// 2 nodes/thread, 32 chunks of 256 cands: grid (16*32, 2) = 1024 blocks
__global__ __launch_bounds__(256) void k_collect_glob(const float4* __restrict__ xa,
      const float4* __restrict__ xb, const float* __restrict__ tg,
      unsigned char* __restrict__ cnt8, unsigned short* __restrict__ list){
  const float4* x = blockIdx.y ? xb : xa;
  __shared__ float4 sx[256];
  __shared__ float4 ssq4[64];
  int nb = blockIdx.x >> 5, chunk = blockIdx.x & 31;
  int cbase = chunk*256;
  {
    float4 v = x[cbase+threadIdx.x];
    sx[threadIdx.x]=v; ((float*)ssq4)[threadIdx.x]=sqnorm(v);
  }
  __syncthreads();
  int node0 = nb*512 + threadIdx.x;
  int node1 = node0 + 256;
  int pn0 = blockIdx.y*TN + node0;
  int pn1 = pn0 + 256;
  float4 xi0 = x[node0], xi1 = x[node1];
  float a0x=-2.0f*xi0.x, a0y=-2.0f*xi0.y, a0z=-2.0f*xi0.z, a0w=-2.0f*xi0.w;
  float a1x=-2.0f*xi1.x, a1y=-2.0f*xi1.y, a1z=-2.0f*xi1.z, a1w=-2.0f*xi1.w;
  float t0 = tg[pn0] - sqnorm(xi0);
  float t1 = tg[pn1] - sqnorm(xi1);
  int c0 = 0, c1 = 0;
  unsigned short* l0 = list + ((size_t)pn0*NCHG + chunk)*CPCG;
  unsigned short* l1 = list + ((size_t)pn1*NCHG + chunk)*CPCG;
  for(int j=0;j<256;j+=4){
    float4 v0=sx[j], v1=sx[j+1], v2=sx[j+2], v3=sx[j+3];
    float4 qv = ssq4[j>>2];
    float s00=fmaf(v0.x,a0x,fmaf(v0.y,a0y,fmaf(v0.z,a0z,fmaf(v0.w,a0w,qv.x))));
    float s01=fmaf(v1.x,a0x,fmaf(v1.y,a0y,fmaf(v1.z,a0z,fmaf(v1.w,a0w,qv.y))));
    float s02=fmaf(v2.x,a0x,fmaf(v2.y,a0y,fmaf(v2.z,a0z,fmaf(v2.w,a0w,qv.z))));
    float s03=fmaf(v3.x,a0x,fmaf(v3.y,a0y,fmaf(v3.z,a0z,fmaf(v3.w,a0w,qv.w))));
    float s10=fmaf(v0.x,a1x,fmaf(v0.y,a1y,fmaf(v0.z,a1z,fmaf(v0.w,a1w,qv.x))));
    float s11=fmaf(v1.x,a1x,fmaf(v1.y,a1y,fmaf(v1.z,a1z,fmaf(v1.w,a1w,qv.y))));
    float s12=fmaf(v2.x,a1x,fmaf(v2.y,a1y,fmaf(v2.z,a1z,fmaf(v2.w,a1w,qv.z))));
    float s13=fmaf(v3.x,a1x,fmaf(v3.y,a1y,fmaf(v3.z,a1z,fmaf(v3.w,a1w,qv.w))));
    if(s00<=t0){ if(c0<CPCG) l0[c0]=(unsigned short)(cbase+j  ); c0++; }
    if(s01<=t0){ if(c0<CPCG) l0[c0]=(unsigned short)(cbase+j+1); c0++; }
    if(s02<=t0){ if(c0<CPCG) l0[c0]=(unsigned short)(cbase+j+2); c0++; }
    if(s03<=t0){ if(c0<CPCG) l0[c0]=(unsigned short)(cbase+j+3); c0++; }
    if(s10<=t1){ if(c1<CPCG) l1[c1]=(unsigned short)(cbase+j  ); c1++; }
    if(s11<=t1){ if(c1<CPCG) l1[c1]=(unsigned short)(cbase+j+1); c1++; }
    if(s12<=t1){ if(c1<CPCG) l1[c1]=(unsigned short)(cbase+j+2); c1++; }
    if(s13<=t1){ if(c1<CPCG) l1[c1]=(unsigned short)(cbase+j+3); c1++; }
  }
  cnt8[(size_t)pn0*NCHG + chunk] = (unsigned char)(c0 > 255 ? 255 : c0);
  cnt8[(size_t)pn1*NCHG + chunk] = (unsigned char)(c1 > 255 ? 255 : c1);
}

// 8 threads per node: sub handles 4 chunks; LDS merge of 8 partial top-9s
__global__ __launch_bounds__(256) void k_refine_glob(const float4* __restrict__ xa,
      const float4* __restrict__ xb, const unsigned char* __restrict__ cnt8,
      const unsigned short* __restrict__ list, int* __restrict__ outl, int* __restrict__ outs){
  __shared__ float sval[32][73];
  __shared__ int   sidx[32][73];
  __shared__ int   sovf[32];
  int slot = threadIdx.x >> 3, sub = threadIdx.x & 7;
  int pn = blockIdx.x*32 + slot;          // < 2*TN; grid = 512
  int prob = blockIdx.x >> 8;             // uniform per block
  int node = pn & (TN-1);
  const float4* x = prob ? xb : xa;
  if(sub==0) sovf[slot]=0;
  __syncthreads();
  float4 xi = x[node]; float sqi = sqnorm(xi);
  float bd[9]; int bi[9];
  #pragma unroll
  for(int q=0;q<9;q++){bd[q]=1e30f; bi[q]=node;}
  bool ovf=false;
  for(int ch=sub*4; ch<sub*4+4; ch++){
    int c = cnt8[(size_t)pn*NCHG + ch];
    if(c > CPCG) ovf=true;
    int n = c < CPCG ? c : CPCG;
    const unsigned short* lst = list + ((size_t)pn*NCHG + ch)*CPCG;
    for(int m=0;m<n;m++){
      int j = lst[m]; float4 v = x[j];
      insert9(bd,bi, pairdist(xi,sqi,v,sqnorm(v)), j);
    }
  }
  if(ovf) sovf[slot]=1;
  #pragma unroll
  for(int q=0;q<9;q++){ sval[slot][sub*9+q]=bd[q]; sidx[slot][sub*9+q]=bi[q]; }
  __syncthreads();
  if(sub==0){
    for(int m=9;m<72;m++) insert9(bd,bi, sval[slot][m], sidx[slot][m]);
    if(sovf[slot]){
      #pragma unroll
      for(int q=0;q<9;q++){bd[q]=1e30f; bi[q]=node;}
      for(int j=0;j<TN;j++){
        float4 v = x[j];
        insert9(bd,bi, pairdist(xi,sqi,v,sqnorm(v)), j);
      }
    }
    int* o = prob ? outs : outl;
    #pragma unroll
    for(int q=0;q<9;q++) o[(size_t)node*9+q]=bi[q];
  }
}

// ---------------- conv1: moment-based BN, fused recompute (no Y materialization) ----------------
__global__ __launch_bounds__(256) void k_mom8(const float4* __restrict__ x,
      const int* __restrict__ idx, float* __restrict__ mpart){
  __shared__ float sa[256][9];
  int t = threadIdx.x;
  int e = blockIdx.x*256 + t;
  int i = e/KNN; int j = idx[e];
  float4 xi = x[i], xj = x[j];
  sa[t][0]=xi.x; sa[t][1]=xi.y; sa[t][2]=xi.z; sa[t][3]=xi.w;
  sa[t][4]=xj.x-xi.x; sa[t][5]=xj.y-xi.y; sa[t][6]=xj.z-xi.z; sa[t][7]=xj.w-xi.w;
  __syncthreads();
  if(t < 44){
    float s=0.f;
    if(t<8){
      for(int e2=0;e2<256;e2++) s += sa[e2][t];
    } else {
      int f=t-8, p=0, q=0, acc=0;
      for(p=0;p<8;p++){ int cnt=8-p; if(f<acc+cnt){ q=p+(f-acc); break;} acc+=cnt; }
      for(int e2=0;e2<256;e2++) s += sa[e2][p]*sa[e2][q];
    }
    mpart[blockIdx.x*44+t]=s;
  }
}

__global__ void k_bn1q(const float* __restrict__ mpart, const float* __restrict__ W1,
      const float* __restrict__ g, const float* __restrict__ be,
      float* __restrict__ scale, float* __restrict__ shift){
  __shared__ double mom[44];
  int t = threadIdx.x;   // 128
  if(t<44){ double s=0; for(int b=0;b<288;b++) s+=(double)mpart[b*44+t]; mom[t]=s; }
  __syncthreads();
  double m[8], w[8];
  #pragma unroll
  for(int p=0;p<8;p++){ m[p]=mom[p]/(double)TK; w[p]=(double)W1[p*128+t]; }
  double q=0.0; int f=8;
  for(int p=0;p<8;p++)
    for(int qq=p;qq<8;qq++){
      double cov = mom[f]/(double)TK - m[p]*m[qq];
      q += (p==qq?1.0:2.0)*w[p]*w[qq]*cov;
      f++;
    }
  if(q<0) q=0;
  double sc = (double)g[t]/sqrt(q+1e-5);
  double mu=0; for(int p=0;p<8;p++) mu += m[p]*w[p];
  scale[t]=(float)sc;
  shift[t]=(float)((double)be[t] - mu*sc);
}

// SYRK v2: 4 passes of 64 edges; stride-10 group layout (row stride 160 floats)
// -> zj reads conflict-free, zi reads broadcast; LDS ~48KB -> 3 blocks/CU
__global__ __launch_bounds__(256) void k_syrk128(const float4* __restrict__ x,
      const int* __restrict__ idx, const float* __restrict__ W1,
      const float* __restrict__ sc1, const float* __restrict__ sh1,
      float* __restrict__ mpartM){
  __shared__ float sa[64][9];
  __shared__ float sW1[8*128];
  __shared__ float sZ[64*160];      // group g (8 floats) of row e at e*160 + g*10
  __shared__ float ssum[128];
  const int tid = threadIdx.x;
  if(tid<256) ((float4*)sW1)[tid] = ((const float4*)W1)[tid];
  if(tid<128) ssum[tid]=0.f;
  const int zc4 = tid & 31, ze0 = tid >> 5;     // z-compute: chunk zc4 (0..31), rows ze0+8k
  const int zg = zc4 >> 1, zh = zc4 & 1;        // group, half
  const int gi = tid >> 4, gj = tid & 15;       // syrk tile (8x8) indices
  const int i0 = gi*8, j0 = gj*8;
  float acc[8][8];
  #pragma unroll
  for(int a=0;a<8;a++)
    #pragma unroll
    for(int b=0;b<8;b++) acc[a][b]=0.f;
  float ls[4]={0,0,0,0};
  float4 scv = ((const float4*)sc1)[zc4];
  float4 shv = ((const float4*)sh1)[zc4];
  for(int pass=0;pass<4;pass++){
    __syncthreads();
    if(tid<64){
      int e = blockIdx.x*256 + pass*64 + tid;
      int i = e/KNN; int j = idx[e];
      float4 xi = x[i], xj = x[j];
      sa[tid][0]=xi.x; sa[tid][1]=xi.y; sa[tid][2]=xi.z; sa[tid][3]=xi.w;
      sa[tid][4]=xj.x-xi.x; sa[tid][5]=xj.y-xi.y; sa[tid][6]=xj.z-xi.z; sa[tid][7]=xj.w-xi.w;
    }
    __syncthreads();
    for(int e=ze0; e<64; e+=8){
      float4 y = make_float4(0.f,0.f,0.f,0.f);
      #pragma unroll
      for(int k=0;k<8;k++){
        float a = sa[e][k];
        float4 wv = *(const float4*)(sW1 + k*128 + zc4*4);
        y.x=fmaf(a,wv.x,y.x); y.y=fmaf(a,wv.y,y.y);
        y.z=fmaf(a,wv.z,y.z); y.w=fmaf(a,wv.w,y.w);
      }
      float4 z;
      z.x = fmaxf(fmaf(scv.x,y.x,shv.x),0.f);
      z.y = fmaxf(fmaf(scv.y,y.y,shv.y),0.f);
      z.z = fmaxf(fmaf(scv.z,y.z,shv.z),0.f);
      z.w = fmaxf(fmaf(scv.w,y.w,shv.w),0.f);
      *(float4*)(sZ + e*160 + zg*10 + zh*4) = z;
      ls[0]+=z.x; ls[1]+=z.y; ls[2]+=z.z; ls[3]+=z.w;
    }
    __syncthreads();
    #pragma unroll 2
    for(int e=0;e<64;e++){
      const float* rz = sZ + e*160;
      float4 zi0 = *(const float4*)(rz + gi*10);
      float4 zi1 = *(const float4*)(rz + gi*10 + 4);
      float4 zj0 = *(const float4*)(rz + gj*10);
      float4 zj1 = *(const float4*)(rz + gj*10 + 4);
      float zi[8] = {zi0.x,zi0.y,zi0.z,zi0.w,zi1.x,zi1.y,zi1.z,zi1.w};
      float zj[8] = {zj0.x,zj0.y,zj0.z,zj0.w,zj1.x,zj1.y,zj1.z,zj1.w};
      #pragma unroll
      for(int a=0;a<8;a++)
        #pragma unroll
        for(int b=0;b<8;b++) acc[a][b]=fmaf(zi[a],zj[b],acc[a][b]);
    }
  }
  #pragma unroll
  for(int c=0;c<4;c++) atomicAdd(&ssum[zc4*4+c], ls[c]);
  float* mp = mpartM + (size_t)blockIdx.x*16512;
  #pragma unroll
  for(int a=0;a<8;a++){
    *(float4*)(mp + (i0+a)*128 + j0)     = make_float4(acc[a][0],acc[a][1],acc[a][2],acc[a][3]);
    *(float4*)(mp + (i0+a)*128 + j0 + 4) = make_float4(acc[a][4],acc[a][5],acc[a][6],acc[a][7]);
  }
  __syncthreads();
  if(tid<128) mp[16384+tid] = ssum[tid];
}

__global__ __launch_bounds__(256) void k_redM(const float* __restrict__ mpartM,
      double* __restrict__ Md){
  int ch = blockIdx.x*256 + threadIdx.x;
  if(ch >= 16512) return;
  double s=0;
  for(int b=0;b<288;b++) s += (double)mpartM[(size_t)b*16512 + ch];
  Md[ch]=s;
}

__global__ void k_bn2q(const double* __restrict__ Md, const float* __restrict__ W2,
      const float* __restrict__ g, const float* __restrict__ be,
      float* __restrict__ scale, float* __restrict__ shift){
  __shared__ double redq[128], redt[128];
  __shared__ float sw[128];
  int c = blockIdx.x, t = threadIdx.x;   // 128 threads
  sw[t] = W2[t*128+c];
  __syncthreads();
  double zb = Md[16384+t]/(double)TK;
  double inner=0;
  for(int j=0;j<128;j++) inner += Md[t*128+j]*(double)sw[j];
  redq[t] = (double)sw[t]*(inner/(double)TK);
  redt[t] = (double)sw[t]*zb;
  __syncthreads();
  for(int s=64;s>0;s>>=1){
    if(t<s){ redq[t]+=redq[t+s]; redt[t]+=redt[t+s]; }
    __syncthreads();
  }
  if(t==0){
    double var = redq[0] - redt[0]*redt[0];
    if(var<0) var=0;
    double sc = (double)g[c]/sqrt(var+1e-5);
    scale[c]=(float)sc;
    shift[c]=(float)((double)be[c] - redt[0]*sc);
  }
}

// fused: gather A (8 nodes, 72 edges) -> z1 recompute -> GEMM x W2 (global, broadcast)
// -> BN2+ReLU -> mean over 9 -> Zb[node][128]
__global__ __launch_bounds__(256) void k_midagg(const float4* __restrict__ x,
      const int* __restrict__ idx, const float* __restrict__ W1,
      const float* __restrict__ sc1, const float* __restrict__ sh1,
      const float* __restrict__ W2, const float* __restrict__ sc2,
      const float* __restrict__ sh2, float* __restrict__ Zb){
  __shared__ float sa[72][9];
  __shared__ float sW1[8*128];
  __shared__ float sZ[72*132];
  const int tid = threadIdx.x;
  const int node0 = blockIdx.x*8;
  if(tid<256) ((float4*)sW1)[tid] = ((const float4*)W1)[tid];
  if(tid<72){
    int e = blockIdx.x*72 + tid;
    int i = e/KNN; int j = idx[e];
    float4 xi = x[i], xj = x[j];
    sa[tid][0]=xi.x; sa[tid][1]=xi.y; sa[tid][2]=xi.z; sa[tid][3]=xi.w;
    sa[tid][4]=xj.x-xi.x; sa[tid][5]=xj.y-xi.y; sa[tid][6]=xj.z-xi.z; sa[tid][7]=xj.w-xi.w;
  }
  __syncthreads();
  for(int f=tid; f<2304; f+=256){
    int e = f>>5, c4 = f&31;
    float4 scv = ((const float4*)sc1)[c4];
    float4 shv = ((const float4*)sh1)[c4];
    float4 y = make_float4(0.f,0.f,0.f,0.f);
    #pragma unroll
    for(int k=0;k<8;k++){
      float a = sa[e][k];
      float4 wv = *(const float4*)(sW1 + k*128 + c4*4);
      y.x=fmaf(a,wv.x,y.x); y.y=fmaf(a,wv.y,y.y);
      y.z=fmaf(a,wv.z,y.z); y.w=fmaf(a,wv.w,y.w);
    }
    float4 z;
    z.x = fmaxf(fmaf(scv.x,y.x,shv.x),0.f);
    z.y = fmaxf(fmaf(scv.y,y.y,shv.y),0.f);
    z.z = fmaxf(fmaf(scv.z,y.z,shv.z),0.f);
    z.w = fmaxf(fmaf(scv.w,y.w,shv.w),0.f);
    *(float4*)(sZ + e*132 + c4*4) = z;
  }
  __syncthreads();
  const int tc = tid & 31, tr = tid >> 5;  // node tr, cols tc*4
  float acc[9][4];
  #pragma unroll
  for(int s=0;s<9;s++)
    #pragma unroll
    for(int e=0;e<4;e++) acc[s][e]=0.f;
  #pragma unroll 2
  for(int k4=0;k4<32;k4++){
    float4 av[9];
    #pragma unroll
    for(int s=0;s<9;s++) av[s] = *(const float4*)(sZ + (tr*9+s)*132 + k4*4);
    #pragma unroll
    for(int kk=0;kk<4;kk++){
      float4 bv = *(const float4*)(W2 + (size_t)(k4*4+kk)*128 + tc*4);
      #pragma unroll
      for(int s=0;s<9;s++){
        float a = (kk==0)?av[s].x:(kk==1)?av[s].y:(kk==2)?av[s].z:av[s].w;
        acc[s][0]=fmaf(a,bv.x,acc[s][0]);
        acc[s][1]=fmaf(a,bv.y,acc[s][1]);
        acc[s][2]=fmaf(a,bv.z,acc[s][2]);
        acc[s][3]=fmaf(a,bv.w,acc[s][3]);
      }
    }
  }
  float4 scv = ((const float4*)sc2)[tc];
  float4 shv = ((const float4*)sh2)[tc];
  float4 sum = make_float4(0.f,0.f,0.f,0.f);
  #pragma unroll
  for(int s=0;s<9;s++){
    sum.x += fmaxf(fmaf(scv.x,acc[s][0],shv.x),0.f);
    sum.y += fmaxf(fmaf(scv.y,acc[s][1],shv.y),0.f);
    sum.z += fmaxf(fmaf(scv.z,acc[s][2],shv.z),0.f);
    sum.w += fmaxf(fmaf(scv.w,acc[s][3],shv.w),0.f);
  }
  sum.x*=(1.f/9.f); sum.y*=(1.f/9.f); sum.z*=(1.f/9.f); sum.w*=(1.f/9.f);
  *(float4*)(Zb + (size_t)(node0+tr)*128 + tc*4) = sum;
}

// plain GEMM x1 = Zb[8192,128] @ W3[128,128] + b3
__global__ __launch_bounds__(256) void k_gemm128(const float* __restrict__ A,
      const float* __restrict__ W, const float* __restrict__ bias,
      float* __restrict__ out){
  __shared__ float sZ[64*132];
  const int tid = threadIdx.x;
  const int row0 = blockIdx.x*64;
  for(int e=tid; e<64*32; e+=256){
    int r = e>>5, c4 = e&31;
    ((float4*)(sZ + r*132))[c4] = ((const float4*)(A + (size_t)(row0+r)*128))[c4];
  }
  __syncthreads();
  const int tc = tid & 31, tr = tid >> 5;  // cols tc*4, rows tr+rr*8
  float acc[8][4];
  #pragma unroll
  for(int rr=0;rr<8;rr++)
    #pragma unroll
    for(int e=0;e<4;e++) acc[rr][e]=0.f;
  #pragma unroll 4
  for(int k4=0;k4<32;k4++){
    float4 av[8];
    #pragma unroll
    for(int rr=0;rr<8;rr++) av[rr] = *(const float4*)(sZ + (tr+rr*8)*132 + k4*4);
    #pragma unroll
    for(int kk=0;kk<4;kk++){
      float4 bv = *(const float4*)(W + (size_t)(k4*4+kk)*128 + tc*4);
      #pragma unroll
      for(int rr=0;rr<8;rr++){
        float a = (kk==0)?av[rr].x:(kk==1)?av[rr].y:(kk==2)?av[rr].z:av[rr].w;
        acc[rr][0]=fmaf(a,bv.x,acc[rr][0]);
        acc[rr][1]=fmaf(a,bv.y,acc[rr][1]);
        acc[rr][2]=fmaf(a,bv.z,acc[rr][2]);
        acc[rr][3]=fmaf(a,bv.w,acc[rr][3]);
      }
    }
  }
  float4 breg = *(const float4*)(bias + tc*4);
  #pragma unroll
  for(int rr=0;rr<8;rr++){
    int r = row0 + tr + rr*8;
    float4 vals;
    vals.x = acc[rr][0]+breg.x;
    vals.y = acc[rr][1]+breg.y;
    vals.z = acc[rr][2]+breg.z;
    vals.w = acc[rr][3]+breg.w;
    *(float4*)(out + (size_t)r*128 + tc*4) = vals;
  }
}

// ---------------- conv3 (unchanged) ----------------
__global__ __launch_bounds__(256) void k_l1d(const float4* __restrict__ xa,
        const float4* __restrict__ xb, const int* __restrict__ ia,
        const int* __restrict__ ib, const float* __restrict__ W,
        const float* __restrict__ bias, float* __restrict__ Ybase,
        float* __restrict__ pstat){
  constexpr int NOUT = 64;
  __shared__ float sA[64][9];
  __shared__ float sW[8*NOUT];
  __shared__ float ssum[NOUT], ssq2[NOUT];
  const int by = blockIdx.y;
  const float4* x = by ? xb : xa;
  const int* idx = by ? ib : ia;
  float* Y = Ybase + (size_t)by*TK*NOUT;
  const int tid = threadIdx.x;
  const int row0 = blockIdx.x*64;
  if(tid < 64){
    int r = row0 + tid;
    int i = r/KNN;
    int j = idx[r];
    float4 xi = x[i], xj = x[j];
    sA[tid][0]=xi.x; sA[tid][1]=xi.y; sA[tid][2]=xi.z; sA[tid][3]=xi.w;
    sA[tid][4]=xj.x-xi.x; sA[tid][5]=xj.y-xi.y; sA[tid][6]=xj.z-xi.z; sA[tid][7]=xj.w-xi.w;
  }
  for(int e=tid; e<8*NOUT/4; e+=256) ((float4*)sW)[e] = ((const float4*)W)[e];
  if(tid < NOUT){ ssum[tid]=0.f; ssq2[tid]=0.f; }
  __syncthreads();
  const int tc = tid & 15, tr = tid >> 4;
  float acc[4][4];
  #pragma unroll
  for(int rr=0;rr<4;rr++)
    #pragma unroll
    for(int cc=0;cc<4;cc++) acc[rr][cc]=0.f;
  #pragma unroll
  for(int k=0;k<8;k++){
    float a[4];
    #pragma unroll
    for(int rr=0;rr<4;rr++) a[rr]=sA[tr*4+rr][k];
    #pragma unroll
    for(int cc=0;cc<4;cc++){
      float bv = sW[k*NOUT + tc*4 + cc];
      #pragma unroll
      for(int rr=0;rr<4;rr++) acc[rr][cc]=fmaf(a[rr],bv,acc[rr][cc]);
    }
  }
  float breg[4];
  #pragma unroll
  for(int cc=0;cc<4;cc++) breg[cc]=bias[tc*4+cc];
  float ls[4], lq[4];
  #pragma unroll
  for(int cc=0;cc<4;cc++){ls[cc]=0.f;lq[cc]=0.f;}
  #pragma unroll
  for(int rr=0;rr<4;rr++){
    int r = row0 + tr*4 + rr;
    float vals[4];
    #pragma unroll
    for(int u=0;u<4;u++){
      float val = acc[rr][u] + breg[u];
      vals[u]=val; ls[u]+=val; lq[u]+=val*val;
    }
    *(float4*)(Y + (size_t)r*NOUT + tc*4) = make_float4(vals[0],vals[1],vals[2],vals[3]);
  }
  #pragma unroll
  for(int cc=0;cc<4;cc++){
    atomicAdd(&ssum[tc*4+cc], ls[cc]);
    atomicAdd(&ssq2[tc*4+cc], lq[cc]);
  }
  __syncthreads();
  if(tid < NOUT){
    size_t pb = ((size_t)by*1152 + blockIdx.x)*2*NOUT;
    pstat[pb + tid] = ssum[tid];
    pstat[pb + NOUT + tid] = ssq2[tid];
  }
}

__global__ __launch_bounds__(256) void k_psum(const float* __restrict__ pstat,
      double* __restrict__ pp, int nblk, int twoC){
  size_t base = (size_t)blockIdx.y*nblk*twoC;
  int per = (nblk+7)/8;
  int b0 = blockIdx.x*per;
  int b1 = b0+per; if(b1>nblk) b1=nblk;
  for(int e=threadIdx.x; e<twoC; e+=256){
    double s=0;
    for(int b=b0;b<b1;b++) s += (double)pstat[base + (size_t)b*twoC + e];
    pp[((size_t)blockIdx.y*8 + blockIdx.x)*twoC + e] = s;
  }
}

__global__ void k_finalized(const double* __restrict__ pp,
     const float* __restrict__ g, const float* __restrict__ be,
     float* __restrict__ scale, float* __restrict__ shift, double M){
  int prob = threadIdx.x >> 6, c = threadIdx.x & 63;
  double S=0,Q=0;
  for(int b=0;b<8;b++){
    S+=pp[((size_t)prob*8+b)*128 + c];
    Q+=pp[((size_t)prob*8+b)*128 + 64 + c];
  }
  double mu = S/M;
  double var = Q/M - mu*mu;
  if(var < 0) var = 0;
  double sc = (double)g[c] / sqrt(var + 1e-5);
  scale[prob*64+c] = (float)sc;
  shift[prob*64+c] = (float)((double)be[c] - mu*sc);
}

__global__ __launch_bounds__(512,4) void k_mid64d(float* __restrict__ Ybase,
        const float* __restrict__ W, const float* __restrict__ bias,
        const float* __restrict__ scale2, const float* __restrict__ shift2,
        float* __restrict__ pstat){
  constexpr int C = 64;
  constexpr int CPAD = 68;
  __shared__ float sZ[128*CPAD];
  __shared__ float sW[64*C];
  __shared__ float ssum[C], ssq2[C];
  const int by = blockIdx.y;
  float* Y = Ybase + (size_t)by*TK*C;
  const float* scale = scale2 + by*C;
  const float* shift = shift2 + by*C;
  const int tid = threadIdx.x;
  const int row0 = blockIdx.x*128;
  for(int e=tid; e<128*16; e+=512){
    int r = e>>4, c4 = e&15;
    float4 v = ((const float4*)(Y + (size_t)(row0+r)*C))[c4];
    float4 sc = ((const float4*)scale)[c4];
    float4 sh = ((const float4*)shift)[c4];
    v.x = fmaxf(fmaf(sc.x,v.x,sh.x), 0.f);
    v.y = fmaxf(fmaf(sc.y,v.y,sh.y), 0.f);
    v.z = fmaxf(fmaf(sc.z,v.z,sh.z), 0.f);
    v.w = fmaxf(fmaf(sc.w,v.w,sh.w), 0.f);
    ((float4*)(sZ + r*CPAD))[c4] = v;
  }
  for(int e=tid; e<64*C/4; e+=512) ((float4*)sW)[e] = ((const float4*)W)[e];
  if(tid < C){ ssum[tid]=0.f; ssq2[tid]=0.f; }
  __syncthreads();
  const int tc = tid & 15, tr = tid >> 4;   // cols tc*4, rows tr+rr*32
  float acc[4][4];
  #pragma unroll
  for(int rr=0;rr<4;rr++)
    #pragma unroll
    for(int e=0;e<4;e++) acc[rr][e]=0.f;
  #pragma unroll 4
  for(int k4=0;k4<16;k4++){
    float4 av[4];
    #pragma unroll
    for(int rr=0;rr<4;rr++) av[rr] = *(const float4*)(sZ + (tr+rr*32)*CPAD + k4*4);
    #pragma unroll
    for(int kk=0;kk<4;kk++){
      float4 bv = *(const float4*)(sW + (k4*4+kk)*C + tc*4);
      #pragma unroll
      for(int rr=0;rr<4;rr++){
        float a = (kk==0)?av[rr].x:(kk==1)?av[rr].y:(kk==2)?av[rr].z:av[rr].w;
        acc[rr][0]=fmaf(a,bv.x,acc[rr][0]);
        acc[rr][1]=fmaf(a,bv.y,acc[rr][1]);
        acc[rr][2]=fmaf(a,bv.z,acc[rr][2]);
        acc[rr][3]=fmaf(a,bv.w,acc[rr][3]);
      }
    }
  }
  float4 breg = *(const float4*)(bias + tc*4);
  float ls[4]={0,0,0,0}, lq[4]={0,0,0,0};
  #pragma unroll
  for(int rr=0;rr<4;rr++){
    int r = row0 + tr + rr*32;
    float4 vals;
    vals.x = acc[rr][0]+breg.x;
    vals.y = acc[rr][1]+breg.y;
    vals.z = acc[rr][2]+breg.z;
    vals.w = acc[rr][3]+breg.w;
    ls[0]+=vals.x; lq[0]+=vals.x*vals.x;
    ls[1]+=vals.y; lq[1]+=vals.y*vals.y;
    ls[2]+=vals.z; lq[2]+=vals.z*vals.z;
    ls[3]+=vals.w; lq[3]+=vals.w*vals.w;
    *(float4*)(Y + (size_t)r*C + tc*4) = vals;
  }
  #pragma unroll
  for(int e=0;e<4;e++){
    atomicAdd(&ssum[tc*4+e], ls[e]);
    atomicAdd(&ssq2[tc*4+e], lq[e]);
  }
  __syncthreads();
  if(tid < C){
    size_t pb = ((size_t)by*576 + blockIdx.x)*2*C;
    pstat[pb + tid] = ssum[tid];
    pstat[pb + C + tid] = ssq2[tid];
  }
}

__global__ __launch_bounds__(256) void k_agg_gemmd(const float* __restrict__ Ybase,
      const float* __restrict__ scale2, const float* __restrict__ shift2,
      const float* __restrict__ W, const float* __restrict__ bias,
      float* __restrict__ outl, float* __restrict__ outs){
  constexpr int KIN=64, NOUT=16;
  constexpr int CPAD = KIN+4;
  __shared__ float sZ[64*CPAD];
  __shared__ float sW[KIN*NOUT];
  const int by = blockIdx.y;
  const float* Y = Ybase + (size_t)by*TK*KIN;
  const float* scale = scale2 + by*KIN;
  const float* shift = shift2 + by*KIN;
  float* out = by ? outs : outl;
  const int tid = threadIdx.x;
  const int node0 = blockIdx.x*64;
  for(int e=tid; e<64*KIN/4; e+=256){
    int r = e/(KIN/4), c4 = e%(KIN/4);
    float4 sc = ((const float4*)scale)[c4];
    float4 sh = ((const float4*)shift)[c4];
    const float4* src = (const float4*)(Y + (size_t)(node0+r)*KNN*KIN) + c4;
    float4 s = make_float4(0.f,0.f,0.f,0.f);
    #pragma unroll
    for(int j=0;j<KNN;j++){
      float4 v = src[(size_t)j*(KIN/4)];
      s.x += fmaxf(fmaf(sc.x,v.x,sh.x),0.f);
      s.y += fmaxf(fmaf(sc.y,v.y,sh.y),0.f);
      s.z += fmaxf(fmaf(sc.z,v.z,sh.z),0.f);
      s.w += fmaxf(fmaf(sc.w,v.w,sh.w),0.f);
    }
    s.x*=(1.f/9.f); s.y*=(1.f/9.f); s.z*=(1.f/9.f); s.w*=(1.f/9.f);
    ((float4*)(sZ + r*CPAD))[c4] = s;
  }
  for(int e=tid; e<KIN*NOUT/4; e+=256) ((float4*)sW)[e] = ((const float4*)W)[e];
  __syncthreads();
  const int tc = tid & 15, tr = tid >> 4;
  float acc[4] = {0.f,0.f,0.f,0.f};
  for(int k4=0;k4<KIN/4;k4++){
    float4 av[4];
    #pragma unroll
    for(int rr=0;rr<4;rr++) av[rr] = *(const float4*)(sZ + (tr+rr*16)*CPAD + k4*4);
    #pragma unroll
    for(int kk=0;kk<4;kk++){
      float bv = sW[(k4*4+kk)*NOUT + tc];
      #pragma unroll
      for(int rr=0;rr<4;rr++){
        float a = (kk==0)?av[rr].x:(kk==1)?av[rr].y:(kk==2)?av[rr].z:av[rr].w;
        acc[rr]=fmaf(a,bv,acc[rr]);
      }
    }
  }
  #pragma unroll
  for(int rr=0;rr<4;rr++){
    int r = node0 + tr + rr*16;
    out[(size_t)r*NOUT + tc] = acc[rr] + bias[tc];
  }
}

// ---------------- head MLP 128->64->32->1, block-tiled (32 rows/block) ----------------
__global__ __launch_bounds__(256) void k_head(const float* __restrict__ x1,
    const float* __restrict__ W1, const float* __restrict__ b1,
    const float* __restrict__ W2, const float* __restrict__ b2,
    const float* __restrict__ W3, const float* __restrict__ b3,
    float* __restrict__ h, float* __restrict__ pstat){
  __shared__ float sA[32*132];
  __shared__ float sW1[128*64];
  __shared__ float o1[32*68];
  __shared__ float sW2[64*32];
  __shared__ float o2[32*33];
  __shared__ float sb1[64], sb2[32], sW3v[32];
  __shared__ float rs[32], rq[32];
  const int tid = threadIdx.x;
  const int row0 = blockIdx.x*32;
  for(int e=tid; e<32*32; e+=256){
    int r = e>>5, c4 = e&31;
    ((float4*)(sA + r*132))[c4] = ((const float4*)(x1 + (size_t)(row0+r)*128))[c4];
  }
  for(int e=tid; e<128*64/4; e+=256) ((float4*)sW1)[e] = ((const float4*)W1)[e];
  for(int e=tid; e<64*32/4; e+=256)  ((float4*)sW2)[e] = ((const float4*)W2)[e];
  if(tid < 64) sb1[tid]=b1[tid];
  if(tid < 32){ sb2[tid]=b2[tid]; sW3v[tid]=W3[tid]; }
  __syncthreads();
  const int tc = tid & 15, tr = tid >> 4;
  float a1[2][4];
  #pragma unroll
  for(int rr=0;rr<2;rr++)
    #pragma unroll
    for(int e=0;e<4;e++) a1[rr][e]=0.f;
  for(int k4=0;k4<32;k4++){
    float4 av0 = *(const float4*)(sA + (tr*2  )*132 + k4*4);
    float4 av1 = *(const float4*)(sA + (tr*2+1)*132 + k4*4);
    #pragma unroll
    for(int kk=0;kk<4;kk++){
      float4 bv = *(const float4*)(sW1 + (k4*4+kk)*64 + tc*4);
      float p0 = (kk==0)?av0.x:(kk==1)?av0.y:(kk==2)?av0.z:av0.w;
      float p1 = (kk==0)?av1.x:(kk==1)?av1.y:(kk==2)?av1.z:av1.w;
      a1[0][0]=fmaf(p0,bv.x,a1[0][0]); a1[0][1]=fmaf(p0,bv.y,a1[0][1]);
      a1[0][2]=fmaf(p0,bv.z,a1[0][2]); a1[0][3]=fmaf(p0,bv.w,a1[0][3]);
      a1[1][0]=fmaf(p1,bv.x,a1[1][0]); a1[1][1]=fmaf(p1,bv.y,a1[1][1]);
      a1[1][2]=fmaf(p1,bv.z,a1[1][2]); a1[1][3]=fmaf(p1,bv.w,a1[1][3]);
    }
  }
  #pragma unroll
  for(int rr=0;rr<2;rr++)
    #pragma unroll
    for(int e=0;e<4;e++)
      o1[(tr*2+rr)*68 + tc*4+e] = fmaxf(a1[rr][e]+sb1[tc*4+e], 0.f);
  __syncthreads();
  float a2[2][2] = {{0.f,0.f},{0.f,0.f}};
  for(int k=0;k<64;k++){
    float w0 = sW2[k*32 + tc*2], w1 = sW2[k*32 + tc*2+1];
    float v0 = o1[(tr*2  )*68 + k];
    float v1 = o1[(tr*2+1)*68 + k];
    a2[0][0]=fmaf(v0,w0,a2[0][0]); a2[0][1]=fmaf(v0,w1,a2[0][1]);
    a2[1][0]=fmaf(v1,w0,a2[1][0]); a2[1][1]=fmaf(v1,w1,a2[1][1]);
  }
  #pragma unroll
  for(int rr=0;rr<2;rr++)
    #pragma unroll
    for(int cc=0;cc<2;cc++)
      o2[(tr*2+rr)*33 + tc*2+cc] = fmaxf(a2[rr][cc]+sb2[tc*2+cc], 0.f);
  __syncthreads();
  if(tid < 32){
    float hv = b3[0];
    #pragma unroll
    for(int k=0;k<32;k++) hv = fmaf(o2[tid*33+k], sW3v[k], hv);
    h[row0+tid]=hv;
    rs[tid]=hv; rq[tid]=hv*hv;
  }
  __syncthreads();
  if(tid==0){
    float S=0.f, Q=0.f;
    #pragma unroll
    for(int i=0;i<32;i++){ S+=rs[i]; Q+=rq[i]; }
    pstat[blockIdx.x*2]=S; pstat[blockIdx.x*2+1]=Q;
  }
}

__global__ __launch_bounds__(256) void k_fin_h(const float* __restrict__ pstat,
      float* __restrict__ hpar){
  __shared__ double sS[256], sQ[256];
  int t = threadIdx.x;
  sS[t] = (double)pstat[2*t]; sQ[t] = (double)pstat[2*t+1];
  __syncthreads();
  for(int s=128;s>0;s>>=1){
    if(t<s){ sS[t]+=sS[t+s]; sQ[t]+=sQ[t+s]; }
    __syncthreads();
  }
  if(t==0){
    double mu = sS[0]/8192.0;
    double var = (sQ[0] - 8192.0*mu*mu)/8191.0;   // ddof=1
    double sd = (var > 0) ? sqrt(var) : 0.0;
    hpar[0]=(float)mu;
    hpar[1]=(float)(1.0/(sd + 1e-5));
  }
}

__global__ __launch_bounds__(256) void k_gate(const float* __restrict__ h,
      const float* __restrict__ hpar, const float4* __restrict__ x,
      float4* __restrict__ xl, float4* __restrict__ xs){
  int i = blockIdx.x*256 + threadIdx.x;
  float z = (h[i]-hpar[0])*hpar[1];
  float o = 1.0f/(1.0f+expf(-z));
  float om = 1.0f - o;
  float4 v = x[i];
  xl[i] = make_float4(o*v.x, o*v.y, o*v.z, o*v.w);
  xs[i] = make_float4(om*v.x, om*v.y, om*v.z, om*v.w);
}

// ---------------- final: per-graph max pool (16ch x 2) + linear [32]->1 ----------------
__global__ __launch_bounds__(256) void k_final(const float* __restrict__ xlf,
      const float* __restrict__ xsf, const float* __restrict__ W,
      const float* __restrict__ b, float* __restrict__ out){
  __shared__ float red[32][8];
  int g = blockIdx.x;
  int c = threadIdx.x & 31;
  int chunk = threadIdx.x >> 5;
  const float* src = (c < 16) ? xlf : xsf;
  int ch = (c < 16) ? c : c-16;
  float m = -1e30f;
  for(int n=chunk*128; n<chunk*128+128; n++)
    m = fmaxf(m, src[((size_t)g*1024+n)*16 + ch]);
  red[c][chunk]=m;
  __syncthreads();
  if(threadIdx.x < 32){
    float mm = red[threadIdx.x][0];
    #pragma unroll
    for(int p=1;p<8;p++) mm = fmaxf(mm, red[threadIdx.x][p]);
    red[threadIdx.x][0]=mm;
  }
  __syncthreads();
  if(threadIdx.x == 0){
    float acc = b[0];
    for(int cc=0;cc<32;cc++) acc = fmaf(red[cc][0], W[cc], acc);
    out[g]=acc;
  }
}

// ---------------- launch ----------------
extern "C" void kernel_launch(void* const* d_in, const int* in_sizes, int n_in,
                              void* d_out, int out_size, void* d_ws, size_t ws_size,
                              hipStream_t stream){
  const float* x    =(const float*)d_in[0];
  const float* c1W1 =(const float*)d_in[1];
  const float* c1g1 =(const float*)d_in[3];
  const float* c1be1=(const float*)d_in[4];
  const float* c1W2 =(const float*)d_in[5];
  const float* c1g2 =(const float*)d_in[7];
  const float* c1be2=(const float*)d_in[8];
  const float* c1W3 =(const float*)d_in[9];
  const float* c1b3 =(const float*)d_in[10];
  const float* c3W1 =(const float*)d_in[11];
  const float* c3b1 =(const float*)d_in[12];
  const float* c3g1 =(const float*)d_in[13];
  const float* c3be1=(const float*)d_in[14];
  const float* c3W2 =(const float*)d_in[15];
  const float* c3b2 =(const float*)d_in[16];
  const float* c3g2 =(const float*)d_in[17];
  const float* c3be2=(const float*)d_in[18];
  const float* c3W3 =(const float*)d_in[19];
  const float* c3b3 =(const float*)d_in[20];
  const float* hW1  =(const float*)d_in[21];
  const float* hb1  =(const float*)d_in[22];
  const float* hW2  =(const float*)d_in[23];
  const float* hb2  =(const float*)d_in[24];
  const float* hW3  =(const float*)d_in[25];
  const float* hb3  =(const float*)d_in[26];
  const float* l2W  =(const float*)d_in[27];
  const float* l2b  =(const float*)d_in[28];
  (void)in_sizes; (void)n_in; (void)out_size; (void)ws_size;

  char* wsb=(char*)d_ws;
  size_t off=0;
  auto alloc=[&](size_t bytes)->char*{
    char* p = wsb + off;
    off = (off + bytes + 255) & ~(size_t)255;
    return p;
  };
  float* Y    =(float*)alloc((size_t)TK*128*4);   // conv3 activations / overlays (mpartM, listg)
  float* x1   =(float*)alloc((size_t)TN*128*4);
  float* Zb   =(float*)alloc((size_t)TN*128*4);
  int*   idx1 =(int*)  alloc((size_t)TK*4);
  int*   idxl =(int*)  alloc((size_t)TK*4);
  int*   idxs =(int*)  alloc((size_t)TK*4);
  float* pd   =(float*)alloc((size_t)2*TN*72*4);
  float* h    =(float*)alloc((size_t)TN*4);
  float* xl   =(float*)alloc((size_t)TN*16);
  float* xs   =(float*)alloc((size_t)TN*16);
  float* xlf  =(float*)alloc((size_t)TN*16*4);
  float* xsf  =(float*)alloc((size_t)TN*16*4);
  float* pstat=(float*)alloc((size_t)2304*128*4);
  double* pp  =(double*)alloc((size_t)16*256*8);
  double* Md  =(double*)alloc((size_t)16512*8);
  float* mp44 =(float*)alloc((size_t)288*44*4);
  float* tl   =(float*)alloc((size_t)TN*4);
  float* tg   =(float*)alloc((size_t)2*TN*4);
  unsigned char* cnt8l=(unsigned char*)alloc((size_t)TN*8);
  unsigned char* cnt8g=(unsigned char*)alloc((size_t)2*TN*NCHG);
  float* bnp  =(float*)alloc(1024*4);
  float* hpar =(float*)alloc(64);

  float* sc1=bnp,      *sh1=bnp+128, *sc2=bnp+256, *sh2=bnp+384;
  float* scA=bnp+512,  *shA=bnp+640, *scB=bnp+768, *shB=bnp+896;  // conv3: [prob][64]
  unsigned short* listl=(unsigned short*)Y;   // Y region dead during kNN phases
  unsigned short* listg=(unsigned short*)Y;
  float* mpartM = Y;                          // Y region dead during conv1 moments

  // ---- conv1 kNN (per-graph) ----
  k_part_local  <<<256,256,0,stream>>>((const float4*)x, pd);
  k_thresh_local<<<32, 256,0,stream>>>(pd, tl);
  k_collect_local<<<256,256,0,stream>>>((const float4*)x, tl, cnt8l, listl);
  k_refine_local<<<TN/32,256,0,stream>>>((const float4*)x, cnt8l, listl, idx1);
  // ---- conv1 (moment-based, no Y materialization) ----
  k_mom8<<<288,256,0,stream>>>((const float4*)x, idx1, mp44);
  k_bn1q<<<1,128,0,stream>>>(mp44, c1W1, c1g1, c1be1, sc1, sh1);
  k_syrk128<<<288,256,0,stream>>>((const float4*)x, idx1, c1W1, sc1, sh1, mpartM);
  k_redM<<<65,256,0,stream>>>(mpartM, Md);
  k_bn2q<<<128,128,0,stream>>>(Md, c1W2, c1g2, c1be2, sc2, sh2);
  k_midagg<<<1024,256,0,stream>>>((const float4*)x, idx1, c1W1, sc1, sh1, c1W2, sc2, sh2, Zb);
  k_gemm128<<<TN/64,256,0,stream>>>(Zb, c1W3, c1b3, x1);
  // ---- head + gate ----
  k_head<<<TN/32,256,0,stream>>>(x1,hW1,hb1,hW2,hb2,hW3,hb3,h,pstat);
  k_fin_h<<<1,256,0,stream>>>(pstat,hpar);
  k_gate<<<32,256,0,stream>>>(h,hpar,(const float4*)x,(float4*)xl,(float4*)xs);
  // ---- global kNN for xl & xs ----
  k_part_sub   <<<dim3(256,2),256,0,stream>>>((const float4*)xl,(const float4*)xs,pd);
  k_thresh_sub <<<64,256,0,stream>>>(pd,tg);
  k_collect_glob<<<dim3(512,2),256,0,stream>>>((const float4*)xl,(const float4*)xs,tg,cnt8g,listg);
  k_refine_glob<<<2*TN/32,256,0,stream>>>((const float4*)xl,(const float4*)xs,cnt8g,listg,idxl,idxs);
  // ---- conv3 on xl & xs (dual dispatches, unchanged) ----
  k_l1d<<<dim3(1152,2),256,0,stream>>>((const float4*)xl,(const float4*)xs,idxl,idxs,c3W1,c3b1,Y,pstat);
  k_psum<<<dim3(8,2),256,0,stream>>>(pstat, pp, 1152, 128);
  k_finalized<<<1,128,0,stream>>>(pp,c3g1,c3be1,scA,shA,(double)TK);
  k_mid64d<<<dim3(576,2),512,0,stream>>>(Y, c3W2, c3b2, scA, shA, pstat);
  k_psum<<<dim3(8,2),256,0,stream>>>(pstat, pp, 576, 128);
  k_finalized<<<1,128,0,stream>>>(pp,c3g2,c3be2,scB,shB,(double)TK);
  k_agg_gemmd<<<dim3(TN/64,2),256,0,stream>>>(Y, scB, shB, c3W3, c3b3, xlf, xsf);
  // ---- final pooling + linear ----
  k_final<<<8,256,0,stream>>>(xlf,xsf,l2W,l2b,(float*)d_out);
}

// Round 13
// 497.903 us; speedup vs baseline: 1.3606x; 1.3606x over previous
//
#include <hip/hip_runtime.h>
#include <math.h>

#define TN 8192          // total nodes (B*N)
#define KNN 9
#define NPG 1024         // nodes per graph
#define TK (TN*KNN)      // 73728 edge rows
#define CPCL 12          // cap per (node,chunk), local (8 chunks of 128)
#define NCHG 32          // global chunks (of 256 candidates)
#define CPCG 16          // cap per (node,chunk), global

// ---------------- helpers ----------------
__device__ __forceinline__ float sqnorm(float4 v){
  return fmaf(v.x,v.x,fmaf(v.y,v.y,fmaf(v.z,v.z,v.w*v.w)));
}
__device__ __forceinline__ float pairdist(float4 a, float sqa, float4 b, float sqb){
  float dot = fmaf(a.x,b.x,fmaf(a.y,b.y,fmaf(a.z,b.z,a.w*b.w)));
  return sqa + sqb - 2.0f*dot;
}
__device__ __forceinline__ void chain9(float (&bd)[9], float d){
  float t=d;
  #pragma unroll
  for(int p=0;p<9;p++){
    float lo=fminf(bd[p],t);
    t=fmaxf(bd[p],t);
    bd[p]=lo;
  }
}
__device__ __forceinline__ void insert9(float (&bd)[9], int (&bi)[9], float d, int id){
  if(d < bd[8]){
    float td=d; int ti=id;
    #pragma unroll
    for(int p=0;p<9;p++){
      bool sw = (td < bd[p]);
      float nbd = sw ? td : bd[p];
      int   nbi = sw ? ti : bi[p];
      float ntd = sw ? bd[p] : td;
      int   nti = sw ? bi[p] : ti;
      bd[p]=nbd; bi[p]=nbi; td=ntd; ti=nti;
    }
  }
}

// ---------------- kNN: local (per-graph) ----------------
__global__ __launch_bounds__(256) void k_part_local(const float4* __restrict__ x, float* __restrict__ pd){
  __shared__ float4 sx[128]; __shared__ float ssq[128];
  int nb = blockIdx.x >> 3, chunk = blockIdx.x & 7;
  int g = nb >> 2;
  int cbase = g*NPG + chunk*128;
  if(threadIdx.x < 128){
    float4 v = x[cbase + threadIdx.x];
    sx[threadIdx.x]=v; ssq[threadIdx.x]=sqnorm(v);
  }
  __syncthreads();
  int node = nb*256 + threadIdx.x;
  float4 xi = x[node]; float sqi = sqnorm(xi);
  float bdA[9], bdB[9];
  #pragma unroll
  for(int q=0;q<9;q++){bdA[q]=1e30f;bdB[q]=1e30f;}
  for(int j=0;j<128;j+=2){
    chain9(bdA, pairdist(xi,sqi,sx[j],ssq[j]));
    chain9(bdB, pairdist(xi,sqi,sx[j+1],ssq[j+1]));
  }
  #pragma unroll
  for(int q=0;q<9;q++) chain9(bdA, bdB[q]);
  #pragma unroll
  for(int q=0;q<9;q++) pd[(size_t)(chunk*9+q)*TN + node]=bdA[q];
}

__global__ __launch_bounds__(256) void k_thresh_local(const float* __restrict__ pd,
      float* __restrict__ tl){
  int node = blockIdx.x*256 + threadIdx.x;
  float bd[9];
  #pragma unroll
  for(int q=0;q<9;q++) bd[q]=1e30f;
  for(int m=0;m<72;m++) chain9(bd, pd[(size_t)m*TN + node]);
  float t = bd[8];
  tl[node] = t + fabsf(t)*1e-5f + 1e-12f;
}

__global__ __launch_bounds__(256) void k_collect_local(const float4* __restrict__ x,
      const float* __restrict__ tl, unsigned char* __restrict__ cnt8,
      unsigned short* __restrict__ list){
  __shared__ float4 sx[128]; __shared__ float ssq[128];
  int nb = blockIdx.x >> 3, chunk = blockIdx.x & 7;
  int g = nb >> 2;
  int cbase = g*NPG + chunk*128;
  if(threadIdx.x < 128){
    float4 v = x[cbase + threadIdx.x];
    sx[threadIdx.x]=v; ssq[threadIdx.x]=sqnorm(v);
  }
  __syncthreads();
  int node = nb*256 + threadIdx.x;
  float4 xi = x[node];
  float m2x=-2.0f*xi.x, m2y=-2.0f*xi.y, m2z=-2.0f*xi.z, m2w=-2.0f*xi.w;
  float tadj = tl[node] - sqnorm(xi);
  int cnt = 0;
  unsigned short* lst = list + ((size_t)node*8 + chunk)*CPCL;
  for(int j=0;j<128;j+=4){
    float4 v0=sx[j], v1=sx[j+1], v2=sx[j+2], v3=sx[j+3];
    float q0=ssq[j], q1=ssq[j+1], q2=ssq[j+2], q3=ssq[j+3];
    float s0=fmaf(v0.x,m2x,fmaf(v0.y,m2y,fmaf(v0.z,m2z,fmaf(v0.w,m2w,q0))));
    float s1=fmaf(v1.x,m2x,fmaf(v1.y,m2y,fmaf(v1.z,m2z,fmaf(v1.w,m2w,q1))));
    float s2=fmaf(v2.x,m2x,fmaf(v2.y,m2y,fmaf(v2.z,m2z,fmaf(v2.w,m2w,q2))));
    float s3=fmaf(v3.x,m2x,fmaf(v3.y,m2y,fmaf(v3.z,m2z,fmaf(v3.w,m2w,q3))));
    if(s0<=tadj){ if(cnt<CPCL) lst[cnt]=(unsigned short)(cbase+j  ); cnt++; }
    if(s1<=tadj){ if(cnt<CPCL) lst[cnt]=(unsigned short)(cbase+j+1); cnt++; }
    if(s2<=tadj){ if(cnt<CPCL) lst[cnt]=(unsigned short)(cbase+j+2); cnt++; }
    if(s3<=tadj){ if(cnt<CPCL) lst[cnt]=(unsigned short)(cbase+j+3); cnt++; }
  }
  cnt8[(size_t)node*8 + chunk] = (unsigned char)(cnt > 255 ? 255 : cnt);
}

// 8 threads per node: sub handles 1 chunk; LDS merge of 8 partial top-9s
__global__ __launch_bounds__(256) void k_refine_local(const float4* __restrict__ x,
      const unsigned char* __restrict__ cnt8, const unsigned short* __restrict__ list,
      int* __restrict__ out){
  __shared__ float sval[32][73];
  __shared__ int   sidx[32][73];
  __shared__ int   sovf[32];
  int slot = threadIdx.x >> 3, sub = threadIdx.x & 7;
  int node = blockIdx.x*32 + slot;
  if(sub==0) sovf[slot]=0;
  __syncthreads();
  float4 xi = x[node]; float sqi = sqnorm(xi);
  float bd[9]; int bi[9];
  #pragma unroll
  for(int q=0;q<9;q++){bd[q]=1e30f; bi[q]=node;}
  int ch = sub;
  int c = cnt8[(size_t)node*8 + ch];
  if(c > CPCL) sovf[slot]=1;
  int n = c < CPCL ? c : CPCL;
  const unsigned short* lst = list + ((size_t)node*8 + ch)*CPCL;
  for(int m=0;m<n;m++){
    int j = lst[m]; float4 v = x[j];
    insert9(bd,bi, pairdist(xi,sqi,v,sqnorm(v)), j);
  }
  #pragma unroll
  for(int q=0;q<9;q++){ sval[slot][sub*9+q]=bd[q]; sidx[slot][sub*9+q]=bi[q]; }
  __syncthreads();
  if(sub==0){
    for(int m=9;m<72;m++) insert9(bd,bi, sval[slot][m], sidx[slot][m]);
    if(sovf[slot]){
      #pragma unroll
      for(int q=0;q<9;q++){bd[q]=1e30f; bi[q]=node;}
      int gbase = node & ~(NPG-1);
      for(int j=gbase;j<gbase+NPG;j++){
        float4 v = x[j];
        insert9(bd,bi, pairdist(xi,sqi,v,sqnorm(v)), j);
      }
    }
    #pragma unroll
    for(int q=0;q<9;q++) out[(size_t)node*9+q]=bi[q];
  }
}

// ---------------- kNN: global (two problems: xl, xs) ----------------
__global__ __launch_bounds__(256) void k_part_sub(const float4* __restrict__ xa,
      const float4* __restrict__ xb, float* __restrict__ pd){
  const float4* x = blockIdx.y ? xb : xa;
  __shared__ float4 sx[256]; __shared__ float ssq[256];
  int nb = blockIdx.x >> 3, chunk = blockIdx.x & 7;
  {
    int j = (chunk*256 + threadIdx.x)*4;
    float4 v = x[j];
    sx[threadIdx.x]=v; ssq[threadIdx.x]=sqnorm(v);
  }
  __syncthreads();
  int node = nb*256 + threadIdx.x;
  float4 xi = x[node]; float sqi = sqnorm(xi);
  float bdA[9], bdB[9];
  #pragma unroll
  for(int q=0;q<9;q++){bdA[q]=1e30f;bdB[q]=1e30f;}
  for(int j=0;j<256;j+=2){
    chain9(bdA, pairdist(xi,sqi,sx[j],ssq[j]));
    chain9(bdB, pairdist(xi,sqi,sx[j+1],ssq[j+1]));
  }
  #pragma unroll
  for(int q=0;q<9;q++) chain9(bdA, bdB[q]);
  int pn = blockIdx.y*TN + node;
  #pragma unroll
  for(int q=0;q<9;q++) pd[(size_t)(chunk*9+q)*2*TN + pn]=bdA[q];
}

__global__ __launch_bounds__(256) void k_thresh_sub(const float* __restrict__ pd,
      float* __restrict__ tg){
  int pn = blockIdx.x*256 + threadIdx.x;   // < 2*TN
  float bd[9];
  #pragma unroll
  for(int q=0;q<9;q++) bd[q]=1e30f;
  for(int m=0;m<72;m++) chain9(bd, pd[(size_t)m*2*TN + pn]);
  float t = bd[8];
  tg[pn] = t + fabsf(t)*1e-5f + 1e-12f;
}

// 2 nodes/thread, 32 chunks of 256 cands: grid (16*32, 2) = 1024 blocks
__global__ __launch_bounds__(256) void k_collect_glob(const float4* __restrict__ xa,
      const float4* __restrict__ xb, const float* __restrict__ tg,
      unsigned char* __restrict__ cnt8, unsigned short* __restrict__ list){
  const float4* x = blockIdx.y ? xb : xa;
  __shared__ float4 sx[256];
  __shared__ float4 ssq4[64];
  int nb = blockIdx.x >> 5, chunk = blockIdx.x & 31;
  int cbase = chunk*256;
  {
    float4 v = x[cbase+threadIdx.x];
    sx[threadIdx.x]=v; ((float*)ssq4)[threadIdx.x]=sqnorm(v);
  }
  __syncthreads();
  int node0 = nb*512 + threadIdx.x;
  int node1 = node0 + 256;
  int pn0 = blockIdx.y*TN + node0;
  int pn1 = pn0 + 256;
  float4 xi0 = x[node0], xi1 = x[node1];
  float a0x=-2.0f*xi0.x, a0y=-2.0f*xi0.y, a0z=-2.0f*xi0.z, a0w=-2.0f*xi0.w;
  float a1x=-2.0f*xi1.x, a1y=-2.0f*xi1.y, a1z=-2.0f*xi1.z, a1w=-2.0f*xi1.w;
  float t0 = tg[pn0] - sqnorm(xi0);
  float t1 = tg[pn1] - sqnorm(xi1);
  int c0 = 0, c1 = 0;
  unsigned short* l0 = list + ((size_t)pn0*NCHG + chunk)*CPCG;
  unsigned short* l1 = list + ((size_t)pn1*NCHG + chunk)*CPCG;
  for(int j=0;j<256;j+=4){
    float4 v0=sx[j], v1=sx[j+1], v2=sx[j+2], v3=sx[j+3];
    float4 qv = ssq4[j>>2];
    float s00=fmaf(v0.x,a0x,fmaf(v0.y,a0y,fmaf(v0.z,a0z,fmaf(v0.w,a0w,qv.x))));
    float s01=fmaf(v1.x,a0x,fmaf(v1.y,a0y,fmaf(v1.z,a0z,fmaf(v1.w,a0w,qv.y))));
    float s02=fmaf(v2.x,a0x,fmaf(v2.y,a0y,fmaf(v2.z,a0z,fmaf(v2.w,a0w,qv.z))));
    float s03=fmaf(v3.x,a0x,fmaf(v3.y,a0y,fmaf(v3.z,a0z,fmaf(v3.w,a0w,qv.w))));
    float s10=fmaf(v0.x,a1x,fmaf(v0.y,a1y,fmaf(v0.z,a1z,fmaf(v0.w,a1w,qv.x))));
    float s11=fmaf(v1.x,a1x,fmaf(v1.y,a1y,fmaf(v1.z,a1z,fmaf(v1.w,a1w,qv.y))));
    float s12=fmaf(v2.x,a1x,fmaf(v2.y,a1y,fmaf(v2.z,a1z,fmaf(v2.w,a1w,qv.z))));
    float s13=fmaf(v3.x,a1x,fmaf(v3.y,a1y,fmaf(v3.z,a1z,fmaf(v3.w,a1w,qv.w))));
    if(s00<=t0){ if(c0<CPCG) l0[c0]=(unsigned short)(cbase+j  ); c0++; }
    if(s01<=t0){ if(c0<CPCG) l0[c0]=(unsigned short)(cbase+j+1); c0++; }
    if(s02<=t0){ if(c0<CPCG) l0[c0]=(unsigned short)(cbase+j+2); c0++; }
    if(s03<=t0){ if(c0<CPCG) l0[c0]=(unsigned short)(cbase+j+3); c0++; }
    if(s10<=t1){ if(c1<CPCG) l1[c1]=(unsigned short)(cbase+j  ); c1++; }
    if(s11<=t1){ if(c1<CPCG) l1[c1]=(unsigned short)(cbase+j+1); c1++; }
    if(s12<=t1){ if(c1<CPCG) l1[c1]=(unsigned short)(cbase+j+2); c1++; }
    if(s13<=t1){ if(c1<CPCG) l1[c1]=(unsigned short)(cbase+j+3); c1++; }
  }
  cnt8[(size_t)pn0*NCHG + chunk] = (unsigned char)(c0 > 255 ? 255 : c0);
  cnt8[(size_t)pn1*NCHG + chunk] = (unsigned char)(c1 > 255 ? 255 : c1);
}

// 8 threads per node: sub handles 4 chunks; LDS merge of 8 partial top-9s
__global__ __launch_bounds__(256) void k_refine_glob(const float4* __restrict__ xa,
      const float4* __restrict__ xb, const unsigned char* __restrict__ cnt8,
      const unsigned short* __restrict__ list, int* __restrict__ outl, int* __restrict__ outs){
  __shared__ float sval[32][73];
  __shared__ int   sidx[32][73];
  __shared__ int   sovf[32];
  int slot = threadIdx.x >> 3, sub = threadIdx.x & 7;
  int pn = blockIdx.x*32 + slot;          // < 2*TN; grid = 512
  int prob = blockIdx.x >> 8;             // uniform per block
  int node = pn & (TN-1);
  const float4* x = prob ? xb : xa;
  if(sub==0) sovf[slot]=0;
  __syncthreads();
  float4 xi = x[node]; float sqi = sqnorm(xi);
  float bd[9]; int bi[9];
  #pragma unroll
  for(int q=0;q<9;q++){bd[q]=1e30f; bi[q]=node;}
  bool ovf=false;
  for(int ch=sub*4; ch<sub*4+4; ch++){
    int c = cnt8[(size_t)pn*NCHG + ch];
    if(c > CPCG) ovf=true;
    int n = c < CPCG ? c : CPCG;
    const unsigned short* lst = list + ((size_t)pn*NCHG + ch)*CPCG;
    for(int m=0;m<n;m++){
      int j = lst[m]; float4 v = x[j];
      insert9(bd,bi, pairdist(xi,sqi,v,sqnorm(v)), j);
    }
  }
  if(ovf) sovf[slot]=1;
  #pragma unroll
  for(int q=0;q<9;q++){ sval[slot][sub*9+q]=bd[q]; sidx[slot][sub*9+q]=bi[q]; }
  __syncthreads();
  if(sub==0){
    for(int m=9;m<72;m++) insert9(bd,bi, sval[slot][m], sidx[slot][m]);
    if(sovf[slot]){
      #pragma unroll
      for(int q=0;q<9;q++){bd[q]=1e30f; bi[q]=node;}
      for(int j=0;j<TN;j++){
        float4 v = x[j];
        insert9(bd,bi, pairdist(xi,sqi,v,sqnorm(v)), j);
      }
    }
    int* o = prob ? outs : outl;
    #pragma unroll
    for(int q=0;q<9;q++) o[(size_t)node*9+q]=bi[q];
  }
}

// ---------------- conv1: moment-based BN, fused recompute (no Y materialization) ----------------
__global__ __launch_bounds__(256) void k_mom8(const float4* __restrict__ x,
      const int* __restrict__ idx, float* __restrict__ mpart){
  __shared__ float sa[256][9];
  int t = threadIdx.x;
  int e = blockIdx.x*256 + t;
  int i = e/KNN; int j = idx[e];
  float4 xi = x[i], xj = x[j];
  sa[t][0]=xi.x; sa[t][1]=xi.y; sa[t][2]=xi.z; sa[t][3]=xi.w;
  sa[t][4]=xj.x-xi.x; sa[t][5]=xj.y-xi.y; sa[t][6]=xj.z-xi.z; sa[t][7]=xj.w-xi.w;
  __syncthreads();
  if(t < 44){
    float s=0.f;
    if(t<8){
      for(int e2=0;e2<256;e2++) s += sa[e2][t];
    } else {
      int f=t-8, p=0, q=0, acc=0;
      for(p=0;p<8;p++){ int cnt=8-p; if(f<acc+cnt){ q=p+(f-acc); break;} acc+=cnt; }
      for(int e2=0;e2<256;e2++) s += sa[e2][p]*sa[e2][q];
    }
    mpart[blockIdx.x*44+t]=s;
  }
}

__global__ void k_bn1q(const float* __restrict__ mpart, const float* __restrict__ W1,
      const float* __restrict__ g, const float* __restrict__ be,
      float* __restrict__ scale, float* __restrict__ shift){
  __shared__ double mom[44];
  int t = threadIdx.x;   // 128
  if(t<44){ double s=0; for(int b=0;b<288;b++) s+=(double)mpart[b*44+t]; mom[t]=s; }
  __syncthreads();
  double m[8], w[8];
  #pragma unroll
  for(int p=0;p<8;p++){ m[p]=mom[p]/(double)TK; w[p]=(double)W1[p*128+t]; }
  double q=0.0; int f=8;
  for(int p=0;p<8;p++)
    for(int qq=p;qq<8;qq++){
      double cov = mom[f]/(double)TK - m[p]*m[qq];
      q += (p==qq?1.0:2.0)*w[p]*w[qq]*cov;
      f++;
    }
  if(q<0) q=0;
  double sc = (double)g[t]/sqrt(q+1e-5);
  double mu=0; for(int p=0;p<8;p++) mu += m[p]*w[p];
  scale[t]=(float)sc;
  shift[t]=(float)((double)be[t] - mu*sc);
}

// SYRK v3: 4 passes of 64 edges; R11-proven aligned stride-132 layout; LDS ~41KB -> 3 blocks/CU
__global__ __launch_bounds__(256) void k_syrk128(const float4* __restrict__ x,
      const int* __restrict__ idx, const float* __restrict__ W1,
      const float* __restrict__ sc1, const float* __restrict__ sh1,
      float* __restrict__ mpartM){
  __shared__ float sa[64][9];
  __shared__ float sW1[8*128];
  __shared__ float sZ[64*132];
  __shared__ float ssum[128];
  const int tid = threadIdx.x;
  ((float4*)sW1)[tid] = ((const float4*)W1)[tid];
  if(tid<128) ssum[tid]=0.f;
  const int zc4 = tid & 31, ze0 = tid >> 5;     // z-compute mapping
  const int i0 = (tid>>4)*8, j0 = (tid&15)*8;   // syrk mapping
  float acc[8][8];
  #pragma unroll
  for(int a=0;a<8;a++)
    #pragma unroll
    for(int b=0;b<8;b++) acc[a][b]=0.f;
  float ls[4]={0,0,0,0};
  float4 scv = ((const float4*)sc1)[zc4];
  float4 shv = ((const float4*)sh1)[zc4];
  for(int pass=0;pass<4;pass++){
    __syncthreads();
    if(tid<64){
      int e = blockIdx.x*256 + pass*64 + tid;
      int i = e/KNN; int j = idx[e];
      float4 xi = x[i], xj = x[j];
      sa[tid][0]=xi.x; sa[tid][1]=xi.y; sa[tid][2]=xi.z; sa[tid][3]=xi.w;
      sa[tid][4]=xj.x-xi.x; sa[tid][5]=xj.y-xi.y; sa[tid][6]=xj.z-xi.z; sa[tid][7]=xj.w-xi.w;
    }
    __syncthreads();
    for(int e=ze0; e<64; e+=8){
      float4 y = make_float4(0.f,0.f,0.f,0.f);
      #pragma unroll
      for(int k=0;k<8;k++){
        float a = sa[e][k];
        float4 wv = *(const float4*)(sW1 + k*128 + zc4*4);
        y.x=fmaf(a,wv.x,y.x); y.y=fmaf(a,wv.y,y.y);
        y.z=fmaf(a,wv.z,y.z); y.w=fmaf(a,wv.w,y.w);
      }
      float4 z;
      z.x = fmaxf(fmaf(scv.x,y.x,shv.x),0.f);
      z.y = fmaxf(fmaf(scv.y,y.y,shv.y),0.f);
      z.z = fmaxf(fmaf(scv.z,y.z,shv.z),0.f);
      z.w = fmaxf(fmaf(scv.w,y.w,shv.w),0.f);
      *(float4*)(sZ + e*132 + zc4*4) = z;
      ls[0]+=z.x; ls[1]+=z.y; ls[2]+=z.z; ls[3]+=z.w;
    }
    __syncthreads();
    #pragma unroll 2
    for(int e=0;e<64;e++){
      const float* rz = sZ + e*132;
      float4 zi0 = *(const float4*)(rz + i0);
      float4 zi1 = *(const float4*)(rz + i0 + 4);
      float4 zj0 = *(const float4*)(rz + j0);
      float4 zj1 = *(const float4*)(rz + j0 + 4);
      float zi[8] = {zi0.x,zi0.y,zi0.z,zi0.w,zi1.x,zi1.y,zi1.z,zi1.w};
      float zj[8] = {zj0.x,zj0.y,zj0.z,zj0.w,zj1.x,zj1.y,zj1.z,zj1.w};
      #pragma unroll
      for(int a=0;a<8;a++)
        #pragma unroll
        for(int b=0;b<8;b++) acc[a][b]=fmaf(zi[a],zj[b],acc[a][b]);
    }
  }
  #pragma unroll
  for(int c=0;c<4;c++) atomicAdd(&ssum[zc4*4+c], ls[c]);
  float* mp = mpartM + (size_t)blockIdx.x*16512;
  #pragma unroll
  for(int a=0;a<8;a++){
    *(float4*)(mp + (i0+a)*128 + j0)     = make_float4(acc[a][0],acc[a][1],acc[a][2],acc[a][3]);
    *(float4*)(mp + (i0+a)*128 + j0 + 4) = make_float4(acc[a][4],acc[a][5],acc[a][6],acc[a][7]);
  }
  __syncthreads();
  if(tid<128) mp[16384+tid] = ssum[tid];
}

__global__ __launch_bounds__(256) void k_redM(const float* __restrict__ mpartM,
      double* __restrict__ Md){
  int ch = blockIdx.x*256 + threadIdx.x;
  if(ch >= 16512) return;
  double s=0;
  for(int b=0;b<288;b++) s += (double)mpartM[(size_t)b*16512 + ch];
  Md[ch]=s;
}

__global__ void k_bn2q(const double* __restrict__ Md, const float* __restrict__ W2,
      const float* __restrict__ g, const float* __restrict__ be,
      float* __restrict__ scale, float* __restrict__ shift){
  __shared__ double redq[128], redt[128];
  __shared__ float sw[128];
  int c = blockIdx.x, t = threadIdx.x;   // 128 threads
  sw[t] = W2[t*128+c];
  __syncthreads();
  double zb = Md[16384+t]/(double)TK;
  double inner=0;
  for(int j=0;j<128;j++) inner += Md[t*128+j]*(double)sw[j];
  redq[t] = (double)sw[t]*(inner/(double)TK);
  redt[t] = (double)sw[t]*zb;
  __syncthreads();
  for(int s=64;s>0;s>>=1){
    if(t<s){ redq[t]+=redq[t+s]; redt[t]+=redt[t+s]; }
    __syncthreads();
  }
  if(t==0){
    double var = redq[0] - redt[0]*redt[0];
    if(var<0) var=0;
    double sc = (double)g[c]/sqrt(var+1e-5);
    scale[c]=(float)sc;
    shift[c]=(float)((double)be[c] - redt[0]*sc);
  }
}

// fused: gather A (8 nodes, 72 edges) -> z1 recompute -> GEMM x W2 (global, broadcast)
// -> BN2+ReLU -> mean over 9 -> Zb[node][128]
__global__ __launch_bounds__(256) void k_midagg(const float4* __restrict__ x,
      const int* __restrict__ idx, const float* __restrict__ W1,
      const float* __restrict__ sc1, const float* __restrict__ sh1,
      const float* __restrict__ W2, const float* __restrict__ sc2,
      const float* __restrict__ sh2, float* __restrict__ Zb){
  __shared__ float sa[72][9];
  __shared__ float sW1[8*128];
  __shared__ float sZ[72*132];
  const int tid = threadIdx.x;
  const int node0 = blockIdx.x*8;
  if(tid<256) ((float4*)sW1)[tid] = ((const float4*)W1)[tid];
  if(tid<72){
    int e = blockIdx.x*72 + tid;
    int i = e/KNN; int j = idx[e];
    float4 xi = x[i], xj = x[j];
    sa[tid][0]=xi.x; sa[tid][1]=xi.y; sa[tid][2]=xi.z; sa[tid][3]=xi.w;
    sa[tid][4]=xj.x-xi.x; sa[tid][5]=xj.y-xi.y; sa[tid][6]=xj.z-xi.z; sa[tid][7]=xj.w-xi.w;
  }
  __syncthreads();
  for(int f=tid; f<2304; f+=256){
    int e = f>>5, c4 = f&31;
    float4 scv = ((const float4*)sc1)[c4];
    float4 shv = ((const float4*)sh1)[c4];
    float4 y = make_float4(0.f,0.f,0.f,0.f);
    #pragma unroll
    for(int k=0;k<8;k++){
      float a = sa[e][k];
      float4 wv = *(const float4*)(sW1 + k*128 + c4*4);
      y.x=fmaf(a,wv.x,y.x); y.y=fmaf(a,wv.y,y.y);
      y.z=fmaf(a,wv.z,y.z); y.w=fmaf(a,wv.w,y.w);
    }
    float4 z;
    z.x = fmaxf(fmaf(scv.x,y.x,shv.x),0.f);
    z.y = fmaxf(fmaf(scv.y,y.y,shv.y),0.f);
    z.z = fmaxf(fmaf(scv.z,y.z,shv.z),0.f);
    z.w = fmaxf(fmaf(scv.w,y.w,shv.w),0.f);
    *(float4*)(sZ + e*132 + c4*4) = z;
  }
  __syncthreads();
  const int tc = tid & 31, tr = tid >> 5;  // node tr, cols tc*4
  float acc[9][4];
  #pragma unroll
  for(int s=0;s<9;s++)
    #pragma unroll
    for(int e=0;e<4;e++) acc[s][e]=0.f;
  #pragma unroll 2
  for(int k4=0;k4<32;k4++){
    float4 av[9];
    #pragma unroll
    for(int s=0;s<9;s++) av[s] = *(const float4*)(sZ + (tr*9+s)*132 + k4*4);
    #pragma unroll
    for(int kk=0;kk<4;kk++){
      float4 bv = *(const float4*)(W2 + (size_t)(k4*4+kk)*128 + tc*4);
      #pragma unroll
      for(int s=0;s<9;s++){
        float a = (kk==0)?av[s].x:(kk==1)?av[s].y:(kk==2)?av[s].z:av[s].w;
        acc[s][0]=fmaf(a,bv.x,acc[s][0]);
        acc[s][1]=fmaf(a,bv.y,acc[s][1]);
        acc[s][2]=fmaf(a,bv.z,acc[s][2]);
        acc[s][3]=fmaf(a,bv.w,acc[s][3]);
      }
    }
  }
  float4 scv = ((const float4*)sc2)[tc];
  float4 shv = ((const float4*)sh2)[tc];
  float4 sum = make_float4(0.f,0.f,0.f,0.f);
  #pragma unroll
  for(int s=0;s<9;s++){
    sum.x += fmaxf(fmaf(scv.x,acc[s][0],shv.x),0.f);
    sum.y += fmaxf(fmaf(scv.y,acc[s][1],shv.y),0.f);
    sum.z += fmaxf(fmaf(scv.z,acc[s][2],shv.z),0.f);
    sum.w += fmaxf(fmaf(scv.w,acc[s][3],shv.w),0.f);
  }
  sum.x*=(1.f/9.f); sum.y*=(1.f/9.f); sum.z*=(1.f/9.f); sum.w*=(1.f/9.f);
  *(float4*)(Zb + (size_t)(node0+tr)*128 + tc*4) = sum;
}

// plain GEMM x1 = Zb[8192,128] @ W3[128,128] + b3
__global__ __launch_bounds__(256) void k_gemm128(const float* __restrict__ A,
      const float* __restrict__ W, const float* __restrict__ bias,
      float* __restrict__ out){
  __shared__ float sZ[64*132];
  const int tid = threadIdx.x;
  const int row0 = blockIdx.x*64;
  for(int e=tid; e<64*32; e+=256){
    int r = e>>5, c4 = e&31;
    ((float4*)(sZ + r*132))[c4] = ((const float4*)(A + (size_t)(row0+r)*128))[c4];
  }
  __syncthreads();
  const int tc = tid & 31, tr = tid >> 5;  // cols tc*4, rows tr+rr*8
  float acc[8][4];
  #pragma unroll
  for(int rr=0;rr<8;rr++)
    #pragma unroll
    for(int e=0;e<4;e++) acc[rr][e]=0.f;
  #pragma unroll 4
  for(int k4=0;k4<32;k4++){
    float4 av[8];
    #pragma unroll
    for(int rr=0;rr<8;rr++) av[rr] = *(const float4*)(sZ + (tr+rr*8)*132 + k4*4);
    #pragma unroll
    for(int kk=0;kk<4;kk++){
      float4 bv = *(const float4*)(W + (size_t)(k4*4+kk)*128 + tc*4);
      #pragma unroll
      for(int rr=0;rr<8;rr++){
        float a = (kk==0)?av[rr].x:(kk==1)?av[rr].y:(kk==2)?av[rr].z:av[rr].w;
        acc[rr][0]=fmaf(a,bv.x,acc[rr][0]);
        acc[rr][1]=fmaf(a,bv.y,acc[rr][1]);
        acc[rr][2]=fmaf(a,bv.z,acc[rr][2]);
        acc[rr][3]=fmaf(a,bv.w,acc[rr][3]);
      }
    }
  }
  float4 breg = *(const float4*)(bias + tc*4);
  #pragma unroll
  for(int rr=0;rr<8;rr++){
    int r = row0 + tr + rr*8;
    float4 vals;
    vals.x = acc[rr][0]+breg.x;
    vals.y = acc[rr][1]+breg.y;
    vals.z = acc[rr][2]+breg.z;
    vals.w = acc[rr][3]+breg.w;
    *(float4*)(out + (size_t)r*128 + tc*4) = vals;
  }
}

// ---------------- conv3 (unchanged) ----------------
__global__ __launch_bounds__(256) void k_l1d(const float4* __restrict__ xa,
        const float4* __restrict__ xb, const int* __restrict__ ia,
        const int* __restrict__ ib, const float* __restrict__ W,
        const float* __restrict__ bias, float* __restrict__ Ybase,
        float* __restrict__ pstat){
  constexpr int NOUT = 64;
  __shared__ float sA[64][9];
  __shared__ float sW[8*NOUT];
  __shared__ float ssum[NOUT], ssq2[NOUT];
  const int by = blockIdx.y;
  const float4* x = by ? xb : xa;
  const int* idx = by ? ib : ia;
  float* Y = Ybase + (size_t)by*TK*NOUT;
  const int tid = threadIdx.x;
  const int row0 = blockIdx.x*64;
  if(tid < 64){
    int r = row0 + tid;
    int i = r/KNN;
    int j = idx[r];
    float4 xi = x[i], xj = x[j];
    sA[tid][0]=xi.x; sA[tid][1]=xi.y; sA[tid][2]=xi.z; sA[tid][3]=xi.w;
    sA[tid][4]=xj.x-xi.x; sA[tid][5]=xj.y-xi.y; sA[tid][6]=xj.z-xi.z; sA[tid][7]=xj.w-xi.w;
  }
  for(int e=tid; e<8*NOUT/4; e+=256) ((float4*)sW)[e] = ((const float4*)W)[e];
  if(tid < NOUT){ ssum[tid]=0.f; ssq2[tid]=0.f; }
  __syncthreads();
  const int tc = tid & 15, tr = tid >> 4;
  float acc[4][4];
  #pragma unroll
  for(int rr=0;rr<4;rr++)
    #pragma unroll
    for(int cc=0;cc<4;cc++) acc[rr][cc]=0.f;
  #pragma unroll
  for(int k=0;k<8;k++){
    float a[4];
    #pragma unroll
    for(int rr=0;rr<4;rr++) a[rr]=sA[tr*4+rr][k];
    #pragma unroll
    for(int cc=0;cc<4;cc++){
      float bv = sW[k*NOUT + tc*4 + cc];
      #pragma unroll
      for(int rr=0;rr<4;rr++) acc[rr][cc]=fmaf(a[rr],bv,acc[rr][cc]);
    }
  }
  float breg[4];
  #pragma unroll
  for(int cc=0;cc<4;cc++) breg[cc]=bias[tc*4+cc];
  float ls[4], lq[4];
  #pragma unroll
  for(int cc=0;cc<4;cc++){ls[cc]=0.f;lq[cc]=0.f;}
  #pragma unroll
  for(int rr=0;rr<4;rr++){
    int r = row0 + tr*4 + rr;
    float vals[4];
    #pragma unroll
    for(int u=0;u<4;u++){
      float val = acc[rr][u] + breg[u];
      vals[u]=val; ls[u]+=val; lq[u]+=val*val;
    }
    *(float4*)(Y + (size_t)r*NOUT + tc*4) = make_float4(vals[0],vals[1],vals[2],vals[3]);
  }
  #pragma unroll
  for(int cc=0;cc<4;cc++){
    atomicAdd(&ssum[tc*4+cc], ls[cc]);
    atomicAdd(&ssq2[tc*4+cc], lq[cc]);
  }
  __syncthreads();
  if(tid < NOUT){
    size_t pb = ((size_t)by*1152 + blockIdx.x)*2*NOUT;
    pstat[pb + tid] = ssum[tid];
    pstat[pb + NOUT + tid] = ssq2[tid];
  }
}

__global__ __launch_bounds__(256) void k_psum(const float* __restrict__ pstat,
      double* __restrict__ pp, int nblk, int twoC){
  size_t base = (size_t)blockIdx.y*nblk*twoC;
  int per = (nblk+7)/8;
  int b0 = blockIdx.x*per;
  int b1 = b0+per; if(b1>nblk) b1=nblk;
  for(int e=threadIdx.x; e<twoC; e+=256){
    double s=0;
    for(int b=b0;b<b1;b++) s += (double)pstat[base + (size_t)b*twoC + e];
    pp[((size_t)blockIdx.y*8 + blockIdx.x)*twoC + e] = s;
  }
}

__global__ void k_finalized(const double* __restrict__ pp,
     const float* __restrict__ g, const float* __restrict__ be,
     float* __restrict__ scale, float* __restrict__ shift, double M){
  int prob = threadIdx.x >> 6, c = threadIdx.x & 63;
  double S=0,Q=0;
  for(int b=0;b<8;b++){
    S+=pp[((size_t)prob*8+b)*128 + c];
    Q+=pp[((size_t)prob*8+b)*128 + 64 + c];
  }
  double mu = S/M;
  double var = Q/M - mu*mu;
  if(var < 0) var = 0;
  double sc = (double)g[c] / sqrt(var + 1e-5);
  scale[prob*64+c] = (float)sc;
  shift[prob*64+c] = (float)((double)be[c] - mu*sc);
}

__global__ __launch_bounds__(512,4) void k_mid64d(float* __restrict__ Ybase,
        const float* __restrict__ W, const float* __restrict__ bias,
        const float* __restrict__ scale2, const float* __restrict__ shift2,
        float* __restrict__ pstat){
  constexpr int C = 64;
  constexpr int CPAD = 68;
  __shared__ float sZ[128*CPAD];
  __shared__ float sW[64*C];
  __shared__ float ssum[C], ssq2[C];
  const int by = blockIdx.y;
  float* Y = Ybase + (size_t)by*TK*C;
  const float* scale = scale2 + by*C;
  const float* shift = shift2 + by*C;
  const int tid = threadIdx.x;
  const int row0 = blockIdx.x*128;
  for(int e=tid; e<128*16; e+=512){
    int r = e>>4, c4 = e&15;
    float4 v = ((const float4*)(Y + (size_t)(row0+r)*C))[c4];
    float4 sc = ((const float4*)scale)[c4];
    float4 sh = ((const float4*)shift)[c4];
    v.x = fmaxf(fmaf(sc.x,v.x,sh.x), 0.f);
    v.y = fmaxf(fmaf(sc.y,v.y,sh.y), 0.f);
    v.z = fmaxf(fmaf(sc.z,v.z,sh.z), 0.f);
    v.w = fmaxf(fmaf(sc.w,v.w,sh.w), 0.f);
    ((float4*)(sZ + r*CPAD))[c4] = v;
  }
  for(int e=tid; e<64*C/4; e+=512) ((float4*)sW)[e] = ((const float4*)W)[e];
  if(tid < C){ ssum[tid]=0.f; ssq2[tid]=0.f; }
  __syncthreads();
  const int tc = tid & 15, tr = tid >> 4;   // cols tc*4, rows tr+rr*32
  float acc[4][4];
  #pragma unroll
  for(int rr=0;rr<4;rr++)
    #pragma unroll
    for(int e=0;e<4;e++) acc[rr][e]=0.f;
  #pragma unroll 4
  for(int k4=0;k4<16;k4++){
    float4 av[4];
    #pragma unroll
    for(int rr=0;rr<4;rr++) av[rr] = *(const float4*)(sZ + (tr+rr*32)*CPAD + k4*4);
    #pragma unroll
    for(int kk=0;kk<4;kk++){
      float4 bv = *(const float4*)(sW + (k4*4+kk)*C + tc*4);
      #pragma unroll
      for(int rr=0;rr<4;rr++){
        float a = (kk==0)?av[rr].x:(kk==1)?av[rr].y:(kk==2)?av[rr].z:av[rr].w;
        acc[rr][0]=fmaf(a,bv.x,acc[rr][0]);
        acc[rr][1]=fmaf(a,bv.y,acc[rr][1]);
        acc[rr][2]=fmaf(a,bv.z,acc[rr][2]);
        acc[rr][3]=fmaf(a,bv.w,acc[rr][3]);
      }
    }
  }
  float4 breg = *(const float4*)(bias + tc*4);
  float ls[4]={0,0,0,0}, lq[4]={0,0,0,0};
  #pragma unroll
  for(int rr=0;rr<4;rr++){
    int r = row0 + tr + rr*32;
    float4 vals;
    vals.x = acc[rr][0]+breg.x;
    vals.y = acc[rr][1]+breg.y;
    vals.z = acc[rr][2]+breg.z;
    vals.w = acc[rr][3]+breg.w;
    ls[0]+=vals.x; lq[0]+=vals.x*vals.x;
    ls[1]+=vals.y; lq[1]+=vals.y*vals.y;
    ls[2]+=vals.z; lq[2]+=vals.z*vals.z;
    ls[3]+=vals.w; lq[3]+=vals.w*vals.w;
    *(float4*)(Y + (size_t)r*C + tc*4) = vals;
  }
  #pragma unroll
  for(int e=0;e<4;e++){
    atomicAdd(&ssum[tc*4+e], ls[e]);
    atomicAdd(&ssq2[tc*4+e], lq[e]);
  }
  __syncthreads();
  if(tid < C){
    size_t pb = ((size_t)by*576 + blockIdx.x)*2*C;
    pstat[pb + tid] = ssum[tid];
    pstat[pb + C + tid] = ssq2[tid];
  }
}

__global__ __launch_bounds__(256) void k_agg_gemmd(const float* __restrict__ Ybase,
      const float* __restrict__ scale2, const float* __restrict__ shift2,
      const float* __restrict__ W, const float* __restrict__ bias,
      float* __restrict__ outl, float* __restrict__ outs){
  constexpr int KIN=64, NOUT=16;
  constexpr int CPAD = KIN+4;
  __shared__ float sZ[64*CPAD];
  __shared__ float sW[KIN*NOUT];
  const int by = blockIdx.y;
  const float* Y = Ybase + (size_t)by*TK*KIN;
  const float* scale = scale2 + by*KIN;
  const float* shift = shift2 + by*KIN;
  float* out = by ? outs : outl;
  const int tid = threadIdx.x;
  const int node0 = blockIdx.x*64;
  for(int e=tid; e<64*KIN/4; e+=256){
    int r = e/(KIN/4), c4 = e%(KIN/4);
    float4 sc = ((const float4*)scale)[c4];
    float4 sh = ((const float4*)shift)[c4];
    const float4* src = (const float4*)(Y + (size_t)(node0+r)*KNN*KIN) + c4;
    float4 s = make_float4(0.f,0.f,0.f,0.f);
    #pragma unroll
    for(int j=0;j<KNN;j++){
      float4 v = src[(size_t)j*(KIN/4)];
      s.x += fmaxf(fmaf(sc.x,v.x,sh.x),0.f);
      s.y += fmaxf(fmaf(sc.y,v.y,sh.y),0.f);
      s.z += fmaxf(fmaf(sc.z,v.z,sh.z),0.f);
      s.w += fmaxf(fmaf(sc.w,v.w,sh.w),0.f);
    }
    s.x*=(1.f/9.f); s.y*=(1.f/9.f); s.z*=(1.f/9.f); s.w*=(1.f/9.f);
    ((float4*)(sZ + r*CPAD))[c4] = s;
  }
  for(int e=tid; e<KIN*NOUT/4; e+=256) ((float4*)sW)[e] = ((const float4*)W)[e];
  __syncthreads();
  const int tc = tid & 15, tr = tid >> 4;
  float acc[4] = {0.f,0.f,0.f,0.f};
  for(int k4=0;k4<KIN/4;k4++){
    float4 av[4];
    #pragma unroll
    for(int rr=0;rr<4;rr++) av[rr] = *(const float4*)(sZ + (tr+rr*16)*CPAD + k4*4);
    #pragma unroll
    for(int kk=0;kk<4;kk++){
      float bv = sW[(k4*4+kk)*NOUT + tc];
      #pragma unroll
      for(int rr=0;rr<4;rr++){
        float a = (kk==0)?av[rr].x:(kk==1)?av[rr].y:(kk==2)?av[rr].z:av[rr].w;
        acc[rr]=fmaf(a,bv,acc[rr]);
      }
    }
  }
  #pragma unroll
  for(int rr=0;rr<4;rr++){
    int r = node0 + tr + rr*16;
    out[(size_t)r*NOUT + tc] = acc[rr] + bias[tc];
  }
}

// ---------------- head MLP 128->64->32->1, block-tiled (32 rows/block) ----------------
__global__ __launch_bounds__(256) void k_head(const float* __restrict__ x1,
    const float* __restrict__ W1, const float* __restrict__ b1,
    const float* __restrict__ W2, const float* __restrict__ b2,
    const float* __restrict__ W3, const float* __restrict__ b3,
    float* __restrict__ h, float* __restrict__ pstat){
  __shared__ float sA[32*132];
  __shared__ float sW1[128*64];
  __shared__ float o1[32*68];
  __shared__ float sW2[64*32];
  __shared__ float o2[32*33];
  __shared__ float sb1[64], sb2[32], sW3v[32];
  __shared__ float rs[32], rq[32];
  const int tid = threadIdx.x;
  const int row0 = blockIdx.x*32;
  for(int e=tid; e<32*32; e+=256){
    int r = e>>5, c4 = e&31;
    ((float4*)(sA + r*132))[c4] = ((const float4*)(x1 + (size_t)(row0+r)*128))[c4];
  }
  for(int e=tid; e<128*64/4; e+=256) ((float4*)sW1)[e] = ((const float4*)W1)[e];
  for(int e=tid; e<64*32/4; e+=256)  ((float4*)sW2)[e] = ((const float4*)W2)[e];
  if(tid < 64) sb1[tid]=b1[tid];
  if(tid < 32){ sb2[tid]=b2[tid]; sW3v[tid]=W3[tid]; }
  __syncthreads();
  const int tc = tid & 15, tr = tid >> 4;
  float a1[2][4];
  #pragma unroll
  for(int rr=0;rr<2;rr++)
    #pragma unroll
    for(int e=0;e<4;e++) a1[rr][e]=0.f;
  for(int k4=0;k4<32;k4++){
    float4 av0 = *(const float4*)(sA + (tr*2  )*132 + k4*4);
    float4 av1 = *(const float4*)(sA + (tr*2+1)*132 + k4*4);
    #pragma unroll
    for(int kk=0;kk<4;kk++){
      float4 bv = *(const float4*)(sW1 + (k4*4+kk)*64 + tc*4);
      float p0 = (kk==0)?av0.x:(kk==1)?av0.y:(kk==2)?av0.z:av0.w;
      float p1 = (kk==0)?av1.x:(kk==1)?av1.y:(kk==2)?av1.z:av1.w;
      a1[0][0]=fmaf(p0,bv.x,a1[0][0]); a1[0][1]=fmaf(p0,bv.y,a1[0][1]);
      a1[0][2]=fmaf(p0,bv.z,a1[0][2]); a1[0][3]=fmaf(p0,bv.w,a1[0][3]);
      a1[1][0]=fmaf(p1,bv.x,a1[1][0]); a1[1][1]=fmaf(p1,bv.y,a1[1][1]);
      a1[1][2]=fmaf(p1,bv.z,a1[1][2]); a1[1][3]=fmaf(p1,bv.w,a1[1][3]);
    }
  }
  #pragma unroll
  for(int rr=0;rr<2;rr++)
    #pragma unroll
    for(int e=0;e<4;e++)
      o1[(tr*2+rr)*68 + tc*4+e] = fmaxf(a1[rr][e]+sb1[tc*4+e], 0.f);
  __syncthreads();
  float a2[2][2] = {{0.f,0.f},{0.f,0.f}};
  for(int k=0;k<64;k++){
    float w0 = sW2[k*32 + tc*2], w1 = sW2[k*32 + tc*2+1];
    float v0 = o1[(tr*2  )*68 + k];
    float v1 = o1[(tr*2+1)*68 + k];
    a2[0][0]=fmaf(v0,w0,a2[0][0]); a2[0][1]=fmaf(v0,w1,a2[0][1]);
    a2[1][0]=fmaf(v1,w0,a2[1][0]); a2[1][1]=fmaf(v1,w1,a2[1][1]);
  }
  #pragma unroll
  for(int rr=0;rr<2;rr++)
    #pragma unroll
    for(int cc=0;cc<2;cc++)
      o2[(tr*2+rr)*33 + tc*2+cc] = fmaxf(a2[rr][cc]+sb2[tc*2+cc], 0.f);
  __syncthreads();
  if(tid < 32){
    float hv = b3[0];
    #pragma unroll
    for(int k=0;k<32;k++) hv = fmaf(o2[tid*33+k], sW3v[k], hv);
    h[row0+tid]=hv;
    rs[tid]=hv; rq[tid]=hv*hv;
  }
  __syncthreads();
  if(tid==0){
    float S=0.f, Q=0.f;
    #pragma unroll
    for(int i=0;i<32;i++){ S+=rs[i]; Q+=rq[i]; }
    pstat[blockIdx.x*2]=S; pstat[blockIdx.x*2+1]=Q;
  }
}

__global__ __launch_bounds__(256) void k_fin_h(const float* __restrict__ pstat,
      float* __restrict__ hpar){
  __shared__ double sS[256], sQ[256];
  int t = threadIdx.x;
  sS[t] = (double)pstat[2*t]; sQ[t] = (double)pstat[2*t+1];
  __syncthreads();
  for(int s=128;s>0;s>>=1){
    if(t<s){ sS[t]+=sS[t+s]; sQ[t]+=sQ[t+s]; }
    __syncthreads();
  }
  if(t==0){
    double mu = sS[0]/8192.0;
    double var = (sQ[0] - 8192.0*mu*mu)/8191.0;   // ddof=1
    double sd = (var > 0) ? sqrt(var) : 0.0;
    hpar[0]=(float)mu;
    hpar[1]=(float)(1.0/(sd + 1e-5));
  }
}

__global__ __launch_bounds__(256) void k_gate(const float* __restrict__ h,
      const float* __restrict__ hpar, const float4* __restrict__ x,
      float4* __restrict__ xl, float4* __restrict__ xs){
  int i = blockIdx.x*256 + threadIdx.x;
  float z = (h[i]-hpar[0])*hpar[1];
  float o = 1.0f/(1.0f+expf(-z));
  float om = 1.0f - o;
  float4 v = x[i];
  xl[i] = make_float4(o*v.x, o*v.y, o*v.z, o*v.w);
  xs[i] = make_float4(om*v.x, om*v.y, om*v.z, om*v.w);
}

// ---------------- final: per-graph max pool (16ch x 2) + linear [32]->1 ----------------
__global__ __launch_bounds__(256) void k_final(const float* __restrict__ xlf,
      const float* __restrict__ xsf, const float* __restrict__ W,
      const float* __restrict__ b, float* __restrict__ out){
  __shared__ float red[32][8];
  int g = blockIdx.x;
  int c = threadIdx.x & 31;
  int chunk = threadIdx.x >> 5;
  const float* src = (c < 16) ? xlf : xsf;
  int ch = (c < 16) ? c : c-16;
  float m = -1e30f;
  for(int n=chunk*128; n<chunk*128+128; n++)
    m = fmaxf(m, src[((size_t)g*1024+n)*16 + ch]);
  red[c][chunk]=m;
  __syncthreads();
  if(threadIdx.x < 32){
    float mm = red[threadIdx.x][0];
    #pragma unroll
    for(int p=1;p<8;p++) mm = fmaxf(mm, red[threadIdx.x][p]);
    red[threadIdx.x][0]=mm;
  }
  __syncthreads();
  if(threadIdx.x == 0){
    float acc = b[0];
    for(int cc=0;cc<32;cc++) acc = fmaf(red[cc][0], W[cc], acc);
    out[g]=acc;
  }
}

// ---------------- launch ----------------
extern "C" void kernel_launch(void* const* d_in, const int* in_sizes, int n_in,
                              void* d_out, int out_size, void* d_ws, size_t ws_size,
                              hipStream_t stream){
  const float* x    =(const float*)d_in[0];
  const float* c1W1 =(const float*)d_in[1];
  const float* c1g1 =(const float*)d_in[3];
  const float* c1be1=(const float*)d_in[4];
  const float* c1W2 =(const float*)d_in[5];
  const float* c1g2 =(const float*)d_in[7];
  const float* c1be2=(const float*)d_in[8];
  const float* c1W3 =(const float*)d_in[9];
  const float* c1b3 =(const float*)d_in[10];
  const float* c3W1 =(const float*)d_in[11];
  const float* c3b1 =(const float*)d_in[12];
  const float* c3g1 =(const float*)d_in[13];
  const float* c3be1=(const float*)d_in[14];
  const float* c3W2 =(const float*)d_in[15];
  const float* c3b2 =(const float*)d_in[16];
  const float* c3g2 =(const float*)d_in[17];
  const float* c3be2=(const float*)d_in[18];
  const float* c3W3 =(const float*)d_in[19];
  const float* c3b3 =(const float*)d_in[20];
  const float* hW1  =(const float*)d_in[21];
  const float* hb1  =(const float*)d_in[22];
  const float* hW2  =(const float*)d_in[23];
  const float* hb2  =(const float*)d_in[24];
  const float* hW3  =(const float*)d_in[25];
  const float* hb3  =(const float*)d_in[26];
  const float* l2W  =(const float*)d_in[27];
  const float* l2b  =(const float*)d_in[28];
  (void)in_sizes; (void)n_in; (void)out_size; (void)ws_size;

  char* wsb=(char*)d_ws;
  size_t off=0;
  auto alloc=[&](size_t bytes)->char*{
    char* p = wsb + off;
    off = (off + bytes + 255) & ~(size_t)255;
    return p;
  };
  float* Y    =(float*)alloc((size_t)TK*128*4);   // conv3 activations / overlays (mpartM, listg)
  float* x1   =(float*)alloc((size_t)TN*128*4);
  float* Zb   =(float*)alloc((size_t)TN*128*4);
  int*   idx1 =(int*)  alloc((size_t)TK*4);
  int*   idxl =(int*)  alloc((size_t)TK*4);
  int*   idxs =(int*)  alloc((size_t)TK*4);
  float* pd   =(float*)alloc((size_t)2*TN*72*4);
  float* h    =(float*)alloc((size_t)TN*4);
  float* xl   =(float*)alloc((size_t)TN*16);
  float* xs   =(float*)alloc((size_t)TN*16);
  float* xlf  =(float*)alloc((size_t)TN*16*4);
  float* xsf  =(float*)alloc((size_t)TN*16*4);
  float* pstat=(float*)alloc((size_t)2304*128*4);
  double* pp  =(double*)alloc((size_t)16*256*8);
  double* Md  =(double*)alloc((size_t)16512*8);
  float* mp44 =(float*)alloc((size_t)288*44*4);
  float* tl   =(float*)alloc((size_t)TN*4);
  float* tg   =(float*)alloc((size_t)2*TN*4);
  unsigned char* cnt8l=(unsigned char*)alloc((size_t)TN*8);
  unsigned char* cnt8g=(unsigned char*)alloc((size_t)2*TN*NCHG);
  float* bnp  =(float*)alloc(1024*4);
  float* hpar =(float*)alloc(64);

  float* sc1=bnp,      *sh1=bnp+128, *sc2=bnp+256, *sh2=bnp+384;
  float* scA=bnp+512,  *shA=bnp+640, *scB=bnp+768, *shB=bnp+896;  // conv3: [prob][64]
  unsigned short* listl=(unsigned short*)Y;   // Y region dead during kNN phases
  unsigned short* listg=(unsigned short*)Y;
  float* mpartM = Y;                          // Y region dead during conv1 moments

  // ---- conv1 kNN (per-graph) ----
  k_part_local  <<<256,256,0,stream>>>((const float4*)x, pd);
  k_thresh_local<<<32, 256,0,stream>>>(pd, tl);
  k_collect_local<<<256,256,0,stream>>>((const float4*)x, tl, cnt8l, listl);
  k_refine_local<<<TN/32,256,0,stream>>>((const float4*)x, cnt8l, listl, idx1);
  // ---- conv1 (moment-based, no Y materialization) ----
  k_mom8<<<288,256,0,stream>>>((const float4*)x, idx1, mp44);
  k_bn1q<<<1,128,0,stream>>>(mp44, c1W1, c1g1, c1be1, sc1, sh1);
  k_syrk128<<<288,256,0,stream>>>((const float4*)x, idx1, c1W1, sc1, sh1, mpartM);
  k_redM<<<65,256,0,stream>>>(mpartM, Md);
  k_bn2q<<<128,128,0,stream>>>(Md, c1W2, c1g2, c1be2, sc2, sh2);
  k_midagg<<<1024,256,0,stream>>>((const float4*)x, idx1, c1W1, sc1, sh1, c1W2, sc2, sh2, Zb);
  k_gemm128<<<TN/64,256,0,stream>>>(Zb, c1W3, c1b3, x1);
  // ---- head + gate ----
  k_head<<<TN/32,256,0,stream>>>(x1,hW1,hb1,hW2,hb2,hW3,hb3,h,pstat);
  k_fin_h<<<1,256,0,stream>>>(pstat,hpar);
  k_gate<<<32,256,0,stream>>>(h,hpar,(const float4*)x,(float4*)xl,(float4*)xs);
  // ---- global kNN for xl & xs ----
  k_part_sub   <<<dim3(256,2),256,0,stream>>>((const float4*)xl,(const float4*)xs,pd);
  k_thresh_sub <<<64,256,0,stream>>>(pd,tg);
  k_collect_glob<<<dim3(512,2),256,0,stream>>>((const float4*)xl,(const float4*)xs,tg,cnt8g,listg);
  k_refine_glob<<<2*TN/32,256,0,stream>>>((const float4*)xl,(const float4*)xs,cnt8g,listg,idxl,idxs);
  // ---- conv3 on xl & xs (dual dispatches, unchanged) ----
  k_l1d<<<dim3(1152,2),256,0,stream>>>((const float4*)xl,(const float4*)xs,idxl,idxs,c3W1,c3b1,Y,pstat);
  k_psum<<<dim3(8,2),256,0,stream>>>(pstat, pp, 1152, 128);
  k_finalized<<<1,128,0,stream>>>(pp,c3g1,c3be1,scA,shA,(double)TK);
  k_mid64d<<<dim3(576,2),512,0,stream>>>(Y, c3W2, c3b2, scA, shA, pstat);
  k_psum<<<dim3(8,2),256,0,stream>>>(pstat, pp, 576, 128);
  k_finalized<<<1,128,0,stream>>>(pp,c3g2,c3be2,scB,shB,(double)TK);
  k_agg_gemmd<<<dim3(TN/64,2),256,0,stream>>>(Y, scB, shB, c3W3, c3b3, xlf, xsf);
  // ---- final pooling + linear ----
  k_final<<<8,256,0,stream>>>(xlf,xsf,l2W,l2b,(float*)d_out);
}

// Round 14
// 450.745 us; speedup vs baseline: 1.5030x; 1.1046x over previous
//
#include <hip/hip_runtime.h>
#include <math.h>

#define TN 8192          // total nodes (B*N)
#define KNN 9
#define NPG 1024         // nodes per graph
#define TK (TN*KNN)      // 73728 edge rows
#define CPCL 12          // cap per (node,chunk), local (8 chunks of 128)
#define NCHG 32          // global chunks (of 256 candidates)
#define CPCG 16          // cap per (node,chunk), global

// ---------------- helpers ----------------
__device__ __forceinline__ float sqnorm(float4 v){
  return fmaf(v.x,v.x,fmaf(v.y,v.y,fmaf(v.z,v.z,v.w*v.w)));
}
__device__ __forceinline__ float pairdist(float4 a, float sqa, float4 b, float sqb){
  float dot = fmaf(a.x,b.x,fmaf(a.y,b.y,fmaf(a.z,b.z,a.w*b.w)));
  return sqa + sqb - 2.0f*dot;
}
__device__ __forceinline__ void chain9(float (&bd)[9], float d){
  float t=d;
  #pragma unroll
  for(int p=0;p<9;p++){
    float lo=fminf(bd[p],t);
    t=fmaxf(bd[p],t);
    bd[p]=lo;
  }
}
__device__ __forceinline__ void insert9(float (&bd)[9], int (&bi)[9], float d, int id){
  if(d < bd[8]){
    float td=d; int ti=id;
    #pragma unroll
    for(int p=0;p<9;p++){
      bool sw = (td < bd[p]);
      float nbd = sw ? td : bd[p];
      int   nbi = sw ? ti : bi[p];
      float ntd = sw ? bd[p] : td;
      int   nti = sw ? bi[p] : ti;
      bd[p]=nbd; bi[p]=nbi; td=ntd; ti=nti;
    }
  }
}

// ---------------- kNN: local (per-graph) ----------------
__global__ __launch_bounds__(256) void k_part_local(const float4* __restrict__ x, float* __restrict__ pd){
  __shared__ float4 sx[128]; __shared__ float ssq[128];
  int nb = blockIdx.x >> 3, chunk = blockIdx.x & 7;
  int g = nb >> 2;
  int cbase = g*NPG + chunk*128;
  if(threadIdx.x < 128){
    float4 v = x[cbase + threadIdx.x];
    sx[threadIdx.x]=v; ssq[threadIdx.x]=sqnorm(v);
  }
  __syncthreads();
  int node = nb*256 + threadIdx.x;
  float4 xi = x[node]; float sqi = sqnorm(xi);
  float bdA[9], bdB[9];
  #pragma unroll
  for(int q=0;q<9;q++){bdA[q]=1e30f;bdB[q]=1e30f;}
  for(int j=0;j<128;j+=2){
    chain9(bdA, pairdist(xi,sqi,sx[j],ssq[j]));
    chain9(bdB, pairdist(xi,sqi,sx[j+1],ssq[j+1]));
  }
  #pragma unroll
  for(int q=0;q<9;q++) chain9(bdA, bdB[q]);
  #pragma unroll
  for(int q=0;q<9;q++) pd[(size_t)(chunk*9+q)*TN + node]=bdA[q];
}

__global__ __launch_bounds__(256) void k_thresh_local(const float* __restrict__ pd,
      float* __restrict__ tl){
  int node = blockIdx.x*256 + threadIdx.x;
  float bd[9];
  #pragma unroll
  for(int q=0;q<9;q++) bd[q]=1e30f;
  for(int m=0;m<72;m++) chain9(bd, pd[(size_t)m*TN + node]);
  float t = bd[8];
  tl[node] = t + fabsf(t)*1e-5f + 1e-12f;
}

__global__ __launch_bounds__(256) void k_collect_local(const float4* __restrict__ x,
      const float* __restrict__ tl, unsigned char* __restrict__ cnt8,
      unsigned short* __restrict__ list){
  __shared__ float4 sx[128]; __shared__ float ssq[128];
  int nb = blockIdx.x >> 3, chunk = blockIdx.x & 7;
  int g = nb >> 2;
  int cbase = g*NPG + chunk*128;
  if(threadIdx.x < 128){
    float4 v = x[cbase + threadIdx.x];
    sx[threadIdx.x]=v; ssq[threadIdx.x]=sqnorm(v);
  }
  __syncthreads();
  int node = nb*256 + threadIdx.x;
  float4 xi = x[node];
  float m2x=-2.0f*xi.x, m2y=-2.0f*xi.y, m2z=-2.0f*xi.z, m2w=-2.0f*xi.w;
  float tadj = tl[node] - sqnorm(xi);
  int cnt = 0;
  unsigned short* lst = list + ((size_t)node*8 + chunk)*CPCL;
  for(int j=0;j<128;j+=4){
    float4 v0=sx[j], v1=sx[j+1], v2=sx[j+2], v3=sx[j+3];
    float q0=ssq[j], q1=ssq[j+1], q2=ssq[j+2], q3=ssq[j+3];
    float s0=fmaf(v0.x,m2x,fmaf(v0.y,m2y,fmaf(v0.z,m2z,fmaf(v0.w,m2w,q0))));
    float s1=fmaf(v1.x,m2x,fmaf(v1.y,m2y,fmaf(v1.z,m2z,fmaf(v1.w,m2w,q1))));
    float s2=fmaf(v2.x,m2x,fmaf(v2.y,m2y,fmaf(v2.z,m2z,fmaf(v2.w,m2w,q2))));
    float s3=fmaf(v3.x,m2x,fmaf(v3.y,m2y,fmaf(v3.z,m2z,fmaf(v3.w,m2w,q3))));
    if(s0<=tadj){ if(cnt<CPCL) lst[cnt]=(unsigned short)(cbase+j  ); cnt++; }
    if(s1<=tadj){ if(cnt<CPCL) lst[cnt]=(unsigned short)(cbase+j+1); cnt++; }
    if(s2<=tadj){ if(cnt<CPCL) lst[cnt]=(unsigned short)(cbase+j+2); cnt++; }
    if(s3<=tadj){ if(cnt<CPCL) lst[cnt]=(unsigned short)(cbase+j+3); cnt++; }
  }
  cnt8[(size_t)node*8 + chunk] = (unsigned char)(cnt > 255 ? 255 : cnt);
}

// 8 threads per node: sub handles 1 chunk; LDS merge of 8 partial top-9s
__global__ __launch_bounds__(256) void k_refine_local(const float4* __restrict__ x,
      const unsigned char* __restrict__ cnt8, const unsigned short* __restrict__ list,
      int* __restrict__ out){
  __shared__ float sval[32][73];
  __shared__ int   sidx[32][73];
  __shared__ int   sovf[32];
  int slot = threadIdx.x >> 3, sub = threadIdx.x & 7;
  int node = blockIdx.x*32 + slot;
  if(sub==0) sovf[slot]=0;
  __syncthreads();
  float4 xi = x[node]; float sqi = sqnorm(xi);
  float bd[9]; int bi[9];
  #pragma unroll
  for(int q=0;q<9;q++){bd[q]=1e30f; bi[q]=node;}
  int ch = sub;
  int c = cnt8[(size_t)node*8 + ch];
  if(c > CPCL) sovf[slot]=1;
  int n = c < CPCL ? c : CPCL;
  const unsigned short* lst = list + ((size_t)node*8 + ch)*CPCL;
  for(int m=0;m<n;m++){
    int j = lst[m]; float4 v = x[j];
    insert9(bd,bi, pairdist(xi,sqi,v,sqnorm(v)), j);
  }
  #pragma unroll
  for(int q=0;q<9;q++){ sval[slot][sub*9+q]=bd[q]; sidx[slot][sub*9+q]=bi[q]; }
  __syncthreads();
  if(sub==0){
    for(int m=9;m<72;m++) insert9(bd,bi, sval[slot][m], sidx[slot][m]);
    if(sovf[slot]){
      #pragma unroll
      for(int q=0;q<9;q++){bd[q]=1e30f; bi[q]=node;}
      int gbase = node & ~(NPG-1);
      for(int j=gbase;j<gbase+NPG;j++){
        float4 v = x[j];
        insert9(bd,bi, pairdist(xi,sqi,v,sqnorm(v)), j);
      }
    }
    #pragma unroll
    for(int q=0;q<9;q++) out[(size_t)node*9+q]=bi[q];
  }
}

// ---------------- kNN: global (two problems: xl, xs) ----------------
__global__ __launch_bounds__(256) void k_part_sub(const float4* __restrict__ xa,
      const float4* __restrict__ xb, float* __restrict__ pd){
  const float4* x = blockIdx.y ? xb : xa;
  __shared__ float4 sx[256]; __shared__ float ssq[256];
  int nb = blockIdx.x >> 3, chunk = blockIdx.x & 7;
  {
    int j = (chunk*256 + threadIdx.x)*4;
    float4 v = x[j];
    sx[threadIdx.x]=v; ssq[threadIdx.x]=sqnorm(v);
  }
  __syncthreads();
  int node = nb*256 + threadIdx.x;
  float4 xi = x[node]; float sqi = sqnorm(xi);
  float bdA[9], bdB[9];
  #pragma unroll
  for(int q=0;q<9;q++){bdA[q]=1e30f;bdB[q]=1e30f;}
  for(int j=0;j<256;j+=2){
    chain9(bdA, pairdist(xi,sqi,sx[j],ssq[j]));
    chain9(bdB, pairdist(xi,sqi,sx[j+1],ssq[j+1]));
  }
  #pragma unroll
  for(int q=0;q<9;q++) chain9(bdA, bdB[q]);
  int pn = blockIdx.y*TN + node;
  #pragma unroll
  for(int q=0;q<9;q++) pd[(size_t)(chunk*9+q)*2*TN + pn]=bdA[q];
}

__global__ __launch_bounds__(256) void k_thresh_sub(const float* __restrict__ pd,
      float* __restrict__ tg){
  int pn = blockIdx.x*256 + threadIdx.x;   // < 2*TN
  float bd[9];
  #pragma unroll
  for(int q=0;q<9;q++) bd[q]=1e30f;
  for(int m=0;m<72;m++) chain9(bd, pd[(size_t)m*2*TN + pn]);
  float t = bd[8];
  tg[pn] = t + fabsf(t)*1e-5f + 1e-12f;
}

// 2 nodes/thread, 32 chunks of 256 cands: grid (16*32, 2) = 1024 blocks
__global__ __launch_bounds__(256) void k_collect_glob(const float4* __restrict__ xa,
      const float4* __restrict__ xb, const float* __restrict__ tg,
      unsigned char* __restrict__ cnt8, unsigned short* __restrict__ list){
  const float4* x = blockIdx.y ? xb : xa;
  __shared__ float4 sx[256];
  __shared__ float4 ssq4[64];
  int nb = blockIdx.x >> 5, chunk = blockIdx.x & 31;
  int cbase = chunk*256;
  {
    float4 v = x[cbase+threadIdx.x];
    sx[threadIdx.x]=v; ((float*)ssq4)[threadIdx.x]=sqnorm(v);
  }
  __syncthreads();
  int node0 = nb*512 + threadIdx.x;
  int node1 = node0 + 256;
  int pn0 = blockIdx.y*TN + node0;
  int pn1 = pn0 + 256;
  float4 xi0 = x[node0], xi1 = x[node1];
  float a0x=-2.0f*xi0.x, a0y=-2.0f*xi0.y, a0z=-2.0f*xi0.z, a0w=-2.0f*xi0.w;
  float a1x=-2.0f*xi1.x, a1y=-2.0f*xi1.y, a1z=-2.0f*xi1.z, a1w=-2.0f*xi1.w;
  float t0 = tg[pn0] - sqnorm(xi0);
  float t1 = tg[pn1] - sqnorm(xi1);
  int c0 = 0, c1 = 0;
  unsigned short* l0 = list + ((size_t)pn0*NCHG + chunk)*CPCG;
  unsigned short* l1 = list + ((size_t)pn1*NCHG + chunk)*CPCG;
  for(int j=0;j<256;j+=4){
    float4 v0=sx[j], v1=sx[j+1], v2=sx[j+2], v3=sx[j+3];
    float4 qv = ssq4[j>>2];
    float s00=fmaf(v0.x,a0x,fmaf(v0.y,a0y,fmaf(v0.z,a0z,fmaf(v0.w,a0w,qv.x))));
    float s01=fmaf(v1.x,a0x,fmaf(v1.y,a0y,fmaf(v1.z,a0z,fmaf(v1.w,a0w,qv.y))));
    float s02=fmaf(v2.x,a0x,fmaf(v2.y,a0y,fmaf(v2.z,a0z,fmaf(v2.w,a0w,qv.z))));
    float s03=fmaf(v3.x,a0x,fmaf(v3.y,a0y,fmaf(v3.z,a0z,fmaf(v3.w,a0w,qv.w))));
    float s10=fmaf(v0.x,a1x,fmaf(v0.y,a1y,fmaf(v0.z,a1z,fmaf(v0.w,a1w,qv.x))));
    float s11=fmaf(v1.x,a1x,fmaf(v1.y,a1y,fmaf(v1.z,a1z,fmaf(v1.w,a1w,qv.y))));
    float s12=fmaf(v2.x,a1x,fmaf(v2.y,a1y,fmaf(v2.z,a1z,fmaf(v2.w,a1w,qv.z))));
    float s13=fmaf(v3.x,a1x,fmaf(v3.y,a1y,fmaf(v3.z,a1z,fmaf(v3.w,a1w,qv.w))));
    if(s00<=t0){ if(c0<CPCG) l0[c0]=(unsigned short)(cbase+j  ); c0++; }
    if(s01<=t0){ if(c0<CPCG) l0[c0]=(unsigned short)(cbase+j+1); c0++; }
    if(s02<=t0){ if(c0<CPCG) l0[c0]=(unsigned short)(cbase+j+2); c0++; }
    if(s03<=t0){ if(c0<CPCG) l0[c0]=(unsigned short)(cbase+j+3); c0++; }
    if(s10<=t1){ if(c1<CPCG) l1[c1]=(unsigned short)(cbase+j  ); c1++; }
    if(s11<=t1){ if(c1<CPCG) l1[c1]=(unsigned short)(cbase+j+1); c1++; }
    if(s12<=t1){ if(c1<CPCG) l1[c1]=(unsigned short)(cbase+j+2); c1++; }
    if(s13<=t1){ if(c1<CPCG) l1[c1]=(unsigned short)(cbase+j+3); c1++; }
  }
  cnt8[(size_t)pn0*NCHG + chunk] = (unsigned char)(c0 > 255 ? 255 : c0);
  cnt8[(size_t)pn1*NCHG + chunk] = (unsigned char)(c1 > 255 ? 255 : c1);
}

// 8 threads per node: sub handles 4 chunks; LDS merge of 8 partial top-9s
__global__ __launch_bounds__(256) void k_refine_glob(const float4* __restrict__ xa,
      const float4* __restrict__ xb, const unsigned char* __restrict__ cnt8,
      const unsigned short* __restrict__ list, int* __restrict__ outl, int* __restrict__ outs){
  __shared__ float sval[32][73];
  __shared__ int   sidx[32][73];
  __shared__ int   sovf[32];
  int slot = threadIdx.x >> 3, sub = threadIdx.x & 7;
  int pn = blockIdx.x*32 + slot;          // < 2*TN; grid = 512
  int prob = blockIdx.x >> 8;             // uniform per block
  int node = pn & (TN-1);
  const float4* x = prob ? xb : xa;
  if(sub==0) sovf[slot]=0;
  __syncthreads();
  float4 xi = x[node]; float sqi = sqnorm(xi);
  float bd[9]; int bi[9];
  #pragma unroll
  for(int q=0;q<9;q++){bd[q]=1e30f; bi[q]=node;}
  bool ovf=false;
  for(int ch=sub*4; ch<sub*4+4; ch++){
    int c = cnt8[(size_t)pn*NCHG + ch];
    if(c > CPCG) ovf=true;
    int n = c < CPCG ? c : CPCG;
    const unsigned short* lst = list + ((size_t)pn*NCHG + ch)*CPCG;
    for(int m=0;m<n;m++){
      int j = lst[m]; float4 v = x[j];
      insert9(bd,bi, pairdist(xi,sqi,v,sqnorm(v)), j);
    }
  }
  if(ovf) sovf[slot]=1;
  #pragma unroll
  for(int q=0;q<9;q++){ sval[slot][sub*9+q]=bd[q]; sidx[slot][sub*9+q]=bi[q]; }
  __syncthreads();
  if(sub==0){
    for(int m=9;m<72;m++) insert9(bd,bi, sval[slot][m], sidx[slot][m]);
    if(sovf[slot]){
      #pragma unroll
      for(int q=0;q<9;q++){bd[q]=1e30f; bi[q]=node;}
      for(int j=0;j<TN;j++){
        float4 v = x[j];
        insert9(bd,bi, pairdist(xi,sqi,v,sqnorm(v)), j);
      }
    }
    int* o = prob ? outs : outl;
    #pragma unroll
    for(int q=0;q<9;q++) o[(size_t)node*9+q]=bi[q];
  }
}

// ---------------- conv1: moment-based BN, fused recompute (no Y materialization) ----------------
__global__ __launch_bounds__(256) void k_mom8(const float4* __restrict__ x,
      const int* __restrict__ idx, float* __restrict__ mpart){
  __shared__ float sa[256][9];
  int t = threadIdx.x;
  int e = blockIdx.x*256 + t;
  int i = e/KNN; int j = idx[e];
  float4 xi = x[i], xj = x[j];
  sa[t][0]=xi.x; sa[t][1]=xi.y; sa[t][2]=xi.z; sa[t][3]=xi.w;
  sa[t][4]=xj.x-xi.x; sa[t][5]=xj.y-xi.y; sa[t][6]=xj.z-xi.z; sa[t][7]=xj.w-xi.w;
  __syncthreads();
  if(t < 44){
    float s=0.f;
    if(t<8){
      for(int e2=0;e2<256;e2++) s += sa[e2][t];
    } else {
      int f=t-8, p=0, q=0, acc=0;
      for(p=0;p<8;p++){ int cnt=8-p; if(f<acc+cnt){ q=p+(f-acc); break;} acc+=cnt; }
      for(int e2=0;e2<256;e2++) s += sa[e2][p]*sa[e2][q];
    }
    mpart[blockIdx.x*44+t]=s;
  }
}

__global__ void k_bn1q(const float* __restrict__ mpart, const float* __restrict__ W1,
      const float* __restrict__ g, const float* __restrict__ be,
      float* __restrict__ scale, float* __restrict__ shift){
  __shared__ double mom[44];
  int t = threadIdx.x;   // 128
  if(t<44){ double s=0; for(int b=0;b<288;b++) s+=(double)mpart[b*44+t]; mom[t]=s; }
  __syncthreads();
  double m[8], w[8];
  #pragma unroll
  for(int p=0;p<8;p++){ m[p]=mom[p]/(double)TK; w[p]=(double)W1[p*128+t]; }
  double q=0.0; int f=8;
  for(int p=0;p<8;p++)
    for(int qq=p;qq<8;qq++){
      double cov = mom[f]/(double)TK - m[p]*m[qq];
      q += (p==qq?1.0:2.0)*w[p]*w[qq]*cov;
      f++;
    }
  if(q<0) q=0;
  double sc = (double)g[t]/sqrt(q+1e-5);
  double mu=0; for(int p=0;p<8;p++) mu += m[p]*w[p];
  scale[t]=(float)sc;
  shift[t]=(float)((double)be[t] - mu*sc);
}

// SYRK: 4 passes of 64 edges; aligned stride-132 layout
__global__ __launch_bounds__(256) void k_syrk128(const float4* __restrict__ x,
      const int* __restrict__ idx, const float* __restrict__ W1,
      const float* __restrict__ sc1, const float* __restrict__ sh1,
      float* __restrict__ mpartM){
  __shared__ float sa[64][9];
  __shared__ float sW1[8*128];
  __shared__ float sZ[64*132];
  __shared__ float ssum[128];
  const int tid = threadIdx.x;
  ((float4*)sW1)[tid] = ((const float4*)W1)[tid];
  if(tid<128) ssum[tid]=0.f;
  const int zc4 = tid & 31, ze0 = tid >> 5;     // z-compute mapping
  const int i0 = (tid>>4)*8, j0 = (tid&15)*8;   // syrk mapping
  float acc[8][8];
  #pragma unroll
  for(int a=0;a<8;a++)
    #pragma unroll
    for(int b=0;b<8;b++) acc[a][b]=0.f;
  float ls[4]={0,0,0,0};
  float4 scv = ((const float4*)sc1)[zc4];
  float4 shv = ((const float4*)sh1)[zc4];
  for(int pass=0;pass<4;pass++){
    __syncthreads();
    if(tid<64){
      int e = blockIdx.x*256 + pass*64 + tid;
      int i = e/KNN; int j = idx[e];
      float4 xi = x[i], xj = x[j];
      sa[tid][0]=xi.x; sa[tid][1]=xi.y; sa[tid][2]=xi.z; sa[tid][3]=xi.w;
      sa[tid][4]=xj.x-xi.x; sa[tid][5]=xj.y-xi.y; sa[tid][6]=xj.z-xi.z; sa[tid][7]=xj.w-xi.w;
    }
    __syncthreads();
    for(int e=ze0; e<64; e+=8){
      float4 y = make_float4(0.f,0.f,0.f,0.f);
      #pragma unroll
      for(int k=0;k<8;k++){
        float a = sa[e][k];
        float4 wv = *(const float4*)(sW1 + k*128 + zc4*4);
        y.x=fmaf(a,wv.x,y.x); y.y=fmaf(a,wv.y,y.y);
        y.z=fmaf(a,wv.z,y.z); y.w=fmaf(a,wv.w,y.w);
      }
      float4 z;
      z.x = fmaxf(fmaf(scv.x,y.x,shv.x),0.f);
      z.y = fmaxf(fmaf(scv.y,y.y,shv.y),0.f);
      z.z = fmaxf(fmaf(scv.z,y.z,shv.z),0.f);
      z.w = fmaxf(fmaf(scv.w,y.w,shv.w),0.f);
      *(float4*)(sZ + e*132 + zc4*4) = z;
      ls[0]+=z.x; ls[1]+=z.y; ls[2]+=z.z; ls[3]+=z.w;
    }
    __syncthreads();
    #pragma unroll 2
    for(int e=0;e<64;e++){
      const float* rz = sZ + e*132;
      float4 zi0 = *(const float4*)(rz + i0);
      float4 zi1 = *(const float4*)(rz + i0 + 4);
      float4 zj0 = *(const float4*)(rz + j0);
      float4 zj1 = *(const float4*)(rz + j0 + 4);
      float zi[8] = {zi0.x,zi0.y,zi0.z,zi0.w,zi1.x,zi1.y,zi1.z,zi1.w};
      float zj[8] = {zj0.x,zj0.y,zj0.z,zj0.w,zj1.x,zj1.y,zj1.z,zj1.w};
      #pragma unroll
      for(int a=0;a<8;a++)
        #pragma unroll
        for(int b=0;b<8;b++) acc[a][b]=fmaf(zi[a],zj[b],acc[a][b]);
    }
  }
  #pragma unroll
  for(int c=0;c<4;c++) atomicAdd(&ssum[zc4*4+c], ls[c]);
  float* mp = mpartM + (size_t)blockIdx.x*16512;
  #pragma unroll
  for(int a=0;a<8;a++){
    *(float4*)(mp + (i0+a)*128 + j0)     = make_float4(acc[a][0],acc[a][1],acc[a][2],acc[a][3]);
    *(float4*)(mp + (i0+a)*128 + j0 + 4) = make_float4(acc[a][4],acc[a][5],acc[a][6],acc[a][7]);
  }
  __syncthreads();
  if(tid<128) mp[16384+tid] = ssum[tid];
}

__global__ __launch_bounds__(256) void k_redM(const float* __restrict__ mpartM,
      double* __restrict__ Md){
  int ch = blockIdx.x*256 + threadIdx.x;
  if(ch >= 16512) return;
  double s=0;
  for(int b=0;b<288;b++) s += (double)mpartM[(size_t)b*16512 + ch];
  Md[ch]=s;
}

__global__ void k_bn2q(const double* __restrict__ Md, const float* __restrict__ W2,
      const float* __restrict__ g, const float* __restrict__ be,
      float* __restrict__ scale, float* __restrict__ shift){
  __shared__ double redq[128], redt[128];
  __shared__ float sw[128];
  int c = blockIdx.x, t = threadIdx.x;   // 128 threads
  sw[t] = W2[t*128+c];
  __syncthreads();
  double zb = Md[16384+t]/(double)TK;
  double inner=0;
  for(int j=0;j<128;j++) inner += Md[t*128+j]*(double)sw[j];
  redq[t] = (double)sw[t]*(inner/(double)TK);
  redt[t] = (double)sw[t]*zb;
  __syncthreads();
  for(int s=64;s>0;s>>=1){
    if(t<s){ redq[t]+=redq[t+s]; redt[t]+=redt[t+s]; }
    __syncthreads();
  }
  if(t==0){
    double var = redq[0] - redt[0]*redt[0];
    if(var<0) var=0;
    double sc = (double)g[c]/sqrt(var+1e-5);
    scale[c]=(float)sc;
    shift[c]=(float)((double)be[c] - redt[0]*sc);
  }
}

// fused: gather A (8 nodes, 72 edges) -> z1 recompute -> GEMM x W2 (global, broadcast)
// -> BN2+ReLU -> mean over 9 -> Zb[node][128]
__global__ __launch_bounds__(256) void k_midagg(const float4* __restrict__ x,
      const int* __restrict__ idx, const float* __restrict__ W1,
      const float* __restrict__ sc1, const float* __restrict__ sh1,
      const float* __restrict__ W2, const float* __restrict__ sc2,
      const float* __restrict__ sh2, float* __restrict__ Zb){
  __shared__ float sa[72][9];
  __shared__ float sW1[8*128];
  __shared__ float sZ[72*132];
  const int tid = threadIdx.x;
  const int node0 = blockIdx.x*8;
  if(tid<256) ((float4*)sW1)[tid] = ((const float4*)W1)[tid];
  if(tid<72){
    int e = blockIdx.x*72 + tid;
    int i = e/KNN; int j = idx[e];
    float4 xi = x[i], xj = x[j];
    sa[tid][0]=xi.x; sa[tid][1]=xi.y; sa[tid][2]=xi.z; sa[tid][3]=xi.w;
    sa[tid][4]=xj.x-xi.x; sa[tid][5]=xj.y-xi.y; sa[tid][6]=xj.z-xi.z; sa[tid][7]=xj.w-xi.w;
  }
  __syncthreads();
  for(int f=tid; f<2304; f+=256){
    int e = f>>5, c4 = f&31;
    float4 scv = ((const float4*)sc1)[c4];
    float4 shv = ((const float4*)sh1)[c4];
    float4 y = make_float4(0.f,0.f,0.f,0.f);
    #pragma unroll
    for(int k=0;k<8;k++){
      float a = sa[e][k];
      float4 wv = *(const float4*)(sW1 + k*128 + c4*4);
      y.x=fmaf(a,wv.x,y.x); y.y=fmaf(a,wv.y,y.y);
      y.z=fmaf(a,wv.z,y.z); y.w=fmaf(a,wv.w,y.w);
    }
    float4 z;
    z.x = fmaxf(fmaf(scv.x,y.x,shv.x),0.f);
    z.y = fmaxf(fmaf(scv.y,y.y,shv.y),0.f);
    z.z = fmaxf(fmaf(scv.z,y.z,shv.z),0.f);
    z.w = fmaxf(fmaf(scv.w,y.w,shv.w),0.f);
    *(float4*)(sZ + e*132 + c4*4) = z;
  }
  __syncthreads();
  const int tc = tid & 31, tr = tid >> 5;  // node tr, cols tc*4
  float acc[9][4];
  #pragma unroll
  for(int s=0;s<9;s++)
    #pragma unroll
    for(int e=0;e<4;e++) acc[s][e]=0.f;
  #pragma unroll 2
  for(int k4=0;k4<32;k4++){
    float4 av[9];
    #pragma unroll
    for(int s=0;s<9;s++) av[s] = *(const float4*)(sZ + (tr*9+s)*132 + k4*4);
    #pragma unroll
    for(int kk=0;kk<4;kk++){
      float4 bv = *(const float4*)(W2 + (size_t)(k4*4+kk)*128 + tc*4);
      #pragma unroll
      for(int s=0;s<9;s++){
        float a = (kk==0)?av[s].x:(kk==1)?av[s].y:(kk==2)?av[s].z:av[s].w;
        acc[s][0]=fmaf(a,bv.x,acc[s][0]);
        acc[s][1]=fmaf(a,bv.y,acc[s][1]);
        acc[s][2]=fmaf(a,bv.z,acc[s][2]);
        acc[s][3]=fmaf(a,bv.w,acc[s][3]);
      }
    }
  }
  float4 scv = ((const float4*)sc2)[tc];
  float4 shv = ((const float4*)sh2)[tc];
  float4 sum = make_float4(0.f,0.f,0.f,0.f);
  #pragma unroll
  for(int s=0;s<9;s++){
    sum.x += fmaxf(fmaf(scv.x,acc[s][0],shv.x),0.f);
    sum.y += fmaxf(fmaf(scv.y,acc[s][1],shv.y),0.f);
    sum.z += fmaxf(fmaf(scv.z,acc[s][2],shv.z),0.f);
    sum.w += fmaxf(fmaf(scv.w,acc[s][3],shv.w),0.f);
  }
  sum.x*=(1.f/9.f); sum.y*=(1.f/9.f); sum.z*=(1.f/9.f); sum.w*=(1.f/9.f);
  *(float4*)(Zb + (size_t)(node0+tr)*128 + tc*4) = sum;
}

// plain GEMM x1 = Zb[8192,128] @ W3[128,128] + b3
__global__ __launch_bounds__(256) void k_gemm128(const float* __restrict__ A,
      const float* __restrict__ W, const float* __restrict__ bias,
      float* __restrict__ out){
  __shared__ float sZ[64*132];
  const int tid = threadIdx.x;
  const int row0 = blockIdx.x*64;
  for(int e=tid; e<64*32; e+=256){
    int r = e>>5, c4 = e&31;
    ((float4*)(sZ + r*132))[c4] = ((const float4*)(A + (size_t)(row0+r)*128))[c4];
  }
  __syncthreads();
  const int tc = tid & 31, tr = tid >> 5;  // cols tc*4, rows tr+rr*8
  float acc[8][4];
  #pragma unroll
  for(int rr=0;rr<8;rr++)
    #pragma unroll
    for(int e=0;e<4;e++) acc[rr][e]=0.f;
  #pragma unroll 4
  for(int k4=0;k4<32;k4++){
    float4 av[8];
    #pragma unroll
    for(int rr=0;rr<8;rr++) av[rr] = *(const float4*)(sZ + (tr+rr*8)*132 + k4*4);
    #pragma unroll
    for(int kk=0;kk<4;kk++){
      float4 bv = *(const float4*)(W + (size_t)(k4*4+kk)*128 + tc*4);
      #pragma unroll
      for(int rr=0;rr<8;rr++){
        float a = (kk==0)?av[rr].x:(kk==1)?av[rr].y:(kk==2)?av[rr].z:av[rr].w;
        acc[rr][0]=fmaf(a,bv.x,acc[rr][0]);
        acc[rr][1]=fmaf(a,bv.y,acc[rr][1]);
        acc[rr][2]=fmaf(a,bv.z,acc[rr][2]);
        acc[rr][3]=fmaf(a,bv.w,acc[rr][3]);
      }
    }
  }
  float4 breg = *(const float4*)(bias + tc*4);
  #pragma unroll
  for(int rr=0;rr<8;rr++){
    int r = row0 + tr + rr*8;
    float4 vals;
    vals.x = acc[rr][0]+breg.x;
    vals.y = acc[rr][1]+breg.y;
    vals.z = acc[rr][2]+breg.z;
    vals.w = acc[rr][3]+breg.w;
    *(float4*)(out + (size_t)r*128 + tc*4) = vals;
  }
}

// ---------------- conv3 NEW: moment-based, dual problems ----------------
__global__ __launch_bounds__(256) void k_mom8d(const float4* __restrict__ xa,
      const float4* __restrict__ xb, const int* __restrict__ ia,
      const int* __restrict__ ib, float* __restrict__ mpart){
  __shared__ float sa[256][9];
  const int prob = blockIdx.y;
  const float4* x = prob ? xb : xa;
  const int* idx = prob ? ib : ia;
  int t = threadIdx.x;
  int e = blockIdx.x*256 + t;
  int i = e/KNN; int j = idx[e];
  float4 xi = x[i], xj = x[j];
  sa[t][0]=xi.x; sa[t][1]=xi.y; sa[t][2]=xi.z; sa[t][3]=xi.w;
  sa[t][4]=xj.x-xi.x; sa[t][5]=xj.y-xi.y; sa[t][6]=xj.z-xi.z; sa[t][7]=xj.w-xi.w;
  __syncthreads();
  if(t < 44){
    float s=0.f;
    if(t<8){
      for(int e2=0;e2<256;e2++) s += sa[e2][t];
    } else {
      int f=t-8, p=0, q=0, acc=0;
      for(p=0;p<8;p++){ int cnt=8-p; if(f<acc+cnt){ q=p+(f-acc); break;} acc+=cnt; }
      for(int e2=0;e2<256;e2++) s += sa[e2][p]*sa[e2][q];
    }
    mpart[((size_t)prob*288 + blockIdx.x)*44 + t]=s;
  }
}

// 128 threads = 2 probs x 64 ch; W1 is 8x64
__global__ void k_bn1qd(const float* __restrict__ mpart, const float* __restrict__ W1,
      const float* __restrict__ g, const float* __restrict__ be,
      float* __restrict__ scale, float* __restrict__ shift){
  __shared__ double mom[2][44];
  int t = threadIdx.x;   // 128
  if(t<88){
    int pr=t/44, m=t%44;
    double s=0; for(int b=0;b<288;b++) s+=(double)mpart[((size_t)pr*288+b)*44+m];
    mom[pr][m]=s;
  }
  __syncthreads();
  int prob = t>>6, c = t&63;
  double m[8], w[8];
  #pragma unroll
  for(int p=0;p<8;p++){ m[p]=mom[prob][p]/(double)TK; w[p]=(double)W1[p*64+c]; }
  double q=0.0; int f=8;
  for(int p=0;p<8;p++)
    for(int qq=p;qq<8;qq++){
      double cov = mom[prob][f]/(double)TK - m[p]*m[qq];
      q += (p==qq?1.0:2.0)*w[p]*w[qq]*cov;
      f++;
    }
  if(q<0) q=0;
  double sc = (double)g[c]/sqrt(q+1e-5);
  double mu=0; for(int p=0;p<8;p++) mu += m[p]*w[p];
  scale[prob*64+c]=(float)sc;
  shift[prob*64+c]=(float)((double)be[c] - mu*sc);
}

// SYRK 64-d dual: per block 256 edges (4 passes of 64), M64 + colsum -> mpartM[(prob*288+b)*4160]
__global__ __launch_bounds__(256) void k_syrk64d(const float4* __restrict__ xa,
      const float4* __restrict__ xb, const int* __restrict__ ia,
      const int* __restrict__ ib, const float* __restrict__ W1,
      const float* __restrict__ sc0, const float* __restrict__ sh0,
      float* __restrict__ mpartM){
  __shared__ float sa[64][9];
  __shared__ float sW1[8*64];
  __shared__ float sZ[64*68];
  __shared__ float ssum[64];
  const int prob = blockIdx.y;
  const float4* x = prob ? xb : xa;
  const int* idx = prob ? ib : ia;
  const float* sc1 = sc0 + prob*64;
  const float* sh1 = sh0 + prob*64;
  const int tid = threadIdx.x;
  if(tid<128) ((float4*)sW1)[tid] = ((const float4*)W1)[tid];
  if(tid<64) ssum[tid]=0.f;
  const int zc4 = tid & 15, ze0 = tid >> 4;     // z chunk (16x4=64ch), rows ze0+16k
  const int i0 = (tid>>4)*4, j0 = (tid&15)*4;   // syrk 4x4 tile
  float acc[4][4];
  #pragma unroll
  for(int a=0;a<4;a++)
    #pragma unroll
    for(int b=0;b<4;b++) acc[a][b]=0.f;
  float ls[4]={0,0,0,0};
  float4 scv = ((const float4*)sc1)[zc4];
  float4 shv = ((const float4*)sh1)[zc4];
  for(int pass=0;pass<4;pass++){
    __syncthreads();
    if(tid<64){
      int e = blockIdx.x*256 + pass*64 + tid;
      int i = e/KNN; int j = idx[e];
      float4 xi = x[i], xj = x[j];
      sa[tid][0]=xi.x; sa[tid][1]=xi.y; sa[tid][2]=xi.z; sa[tid][3]=xi.w;
      sa[tid][4]=xj.x-xi.x; sa[tid][5]=xj.y-xi.y; sa[tid][6]=xj.z-xi.z; sa[tid][7]=xj.w-xi.w;
    }
    __syncthreads();
    for(int e=ze0; e<64; e+=16){
      float4 y = make_float4(0.f,0.f,0.f,0.f);
      #pragma unroll
      for(int k=0;k<8;k++){
        float a = sa[e][k];
        float4 wv = *(const float4*)(sW1 + k*64 + zc4*4);
        y.x=fmaf(a,wv.x,y.x); y.y=fmaf(a,wv.y,y.y);
        y.z=fmaf(a,wv.z,y.z); y.w=fmaf(a,wv.w,y.w);
      }
      float4 z;
      z.x = fmaxf(fmaf(scv.x,y.x,shv.x),0.f);
      z.y = fmaxf(fmaf(scv.y,y.y,shv.y),0.f);
      z.z = fmaxf(fmaf(scv.z,y.z,shv.z),0.f);
      z.w = fmaxf(fmaf(scv.w,y.w,shv.w),0.f);
      *(float4*)(sZ + e*68 + zc4*4) = z;
      ls[0]+=z.x; ls[1]+=z.y; ls[2]+=z.z; ls[3]+=z.w;
    }
    __syncthreads();
    #pragma unroll 4
    for(int e=0;e<64;e++){
      const float* rz = sZ + e*68;
      float4 zi4 = *(const float4*)(rz + i0);
      float4 zj4 = *(const float4*)(rz + j0);
      float zi[4]={zi4.x,zi4.y,zi4.z,zi4.w};
      float zj[4]={zj4.x,zj4.y,zj4.z,zj4.w};
      #pragma unroll
      for(int a=0;a<4;a++)
        #pragma unroll
        for(int b=0;b<4;b++) acc[a][b]=fmaf(zi[a],zj[b],acc[a][b]);
    }
  }
  #pragma unroll
  for(int c=0;c<4;c++) atomicAdd(&ssum[zc4*4+c], ls[c]);
  float* mp = mpartM + ((size_t)prob*288 + blockIdx.x)*4160;
  #pragma unroll
  for(int a=0;a<4;a++)
    *(float4*)(mp + (i0+a)*64 + j0) = make_float4(acc[a][0],acc[a][1],acc[a][2],acc[a][3]);
  __syncthreads();
  if(tid<64) mp[4096+tid] = ssum[tid];
}

__global__ __launch_bounds__(256) void k_redMd(const float* __restrict__ mpartM,
      double* __restrict__ Md){
  int ch = blockIdx.x*256 + threadIdx.x;
  if(ch >= 8320) return;
  int prob = ch / 4160, c = ch % 4160;
  double s=0;
  for(int b=0;b<288;b++) s += (double)mpartM[((size_t)prob*288+b)*4160 + c];
  Md[(size_t)prob*4160 + c]=s;
}

// grid (64, 2); 64 threads; W2 is 64x64
__global__ void k_bn2qd(const double* __restrict__ Md, const float* __restrict__ W2,
      const float* __restrict__ g, const float* __restrict__ be,
      float* __restrict__ scale, float* __restrict__ shift){
  __shared__ double redq[64], redt[64];
  __shared__ float sw[64];
  int c = blockIdx.x, prob = blockIdx.y, t = threadIdx.x;   // 64 threads
  const double* md = Md + (size_t)prob*4160;
  sw[t] = W2[t*64+c];
  __syncthreads();
  double zb = md[4096+t]/(double)TK;
  double inner=0;
  for(int j=0;j<64;j++) inner += md[t*64+j]*(double)sw[j];
  redq[t] = (double)sw[t]*(inner/(double)TK);
  redt[t] = (double)sw[t]*zb;
  __syncthreads();
  for(int s=32;s>0;s>>=1){
    if(t<s){ redq[t]+=redq[t+s]; redt[t]+=redt[t+s]; }
    __syncthreads();
  }
  if(t==0){
    double var = redq[0] - redt[0]*redt[0];
    if(var<0) var=0;
    double sc = (double)g[c]/sqrt(var+1e-5);
    scale[prob*64+c]=(float)sc;
    shift[prob*64+c]=(float)((double)be[c] - redt[0]*sc);
  }
}

// fused conv3 mid+agg: 16 nodes / 144 edges per block; grid (512, 2)
__global__ __launch_bounds__(256) void k_midagg64d(const float4* __restrict__ xa,
      const float4* __restrict__ xb, const int* __restrict__ ia,
      const int* __restrict__ ib, const float* __restrict__ W1,
      const float* __restrict__ sc0, const float* __restrict__ sh0,
      const float* __restrict__ W2, const float* __restrict__ sc20,
      const float* __restrict__ sh20, float* __restrict__ Zb64){
  __shared__ float sa[144][9];
  __shared__ float sW1[8*64];
  __shared__ float sZ[144*68];
  const int prob = blockIdx.y;
  const float4* x = prob ? xb : xa;
  const int* idx = prob ? ib : ia;
  const float* sc1 = sc0 + prob*64;
  const float* sh1 = sh0 + prob*64;
  const float* sc2 = sc20 + prob*64;
  const float* sh2 = sh20 + prob*64;
  const int tid = threadIdx.x;
  const int node0 = blockIdx.x*16;
  if(tid<128) ((float4*)sW1)[tid] = ((const float4*)W1)[tid];
  if(tid<144){
    int e = blockIdx.x*144 + tid;
    int i = e/KNN; int j = idx[e];
    float4 xi = x[i], xj = x[j];
    sa[tid][0]=xi.x; sa[tid][1]=xi.y; sa[tid][2]=xi.z; sa[tid][3]=xi.w;
    sa[tid][4]=xj.x-xi.x; sa[tid][5]=xj.y-xi.y; sa[tid][6]=xj.z-xi.z; sa[tid][7]=xj.w-xi.w;
  }
  __syncthreads();
  // z1 recompute: 144 edges x 16 chunks of 4
  for(int f=tid; f<144*16; f+=256){
    int e = f>>4, c4 = f&15;
    float4 scv = ((const float4*)sc1)[c4];
    float4 shv = ((const float4*)sh1)[c4];
    float4 y = make_float4(0.f,0.f,0.f,0.f);
    #pragma unroll
    for(int k=0;k<8;k++){
      float a = sa[e][k];
      float4 wv = *(const float4*)(sW1 + k*64 + c4*4);
      y.x=fmaf(a,wv.x,y.x); y.y=fmaf(a,wv.y,y.y);
      y.z=fmaf(a,wv.z,y.z); y.w=fmaf(a,wv.w,y.w);
    }
    float4 z;
    z.x = fmaxf(fmaf(scv.x,y.x,shv.x),0.f);
    z.y = fmaxf(fmaf(scv.y,y.y,shv.y),0.f);
    z.z = fmaxf(fmaf(scv.z,y.z,shv.z),0.f);
    z.w = fmaxf(fmaf(scv.w,y.w,shv.w),0.f);
    *(float4*)(sZ + e*68 + c4*4) = z;
  }
  __syncthreads();
  // GEMM x W2 + BN2 + ReLU + mean9 -> Zb64
  const int cg = tid & 15, nd = tid >> 4;   // node nd (16), cols cg*4
  float acc[9][4];
  #pragma unroll
  for(int s=0;s<9;s++)
    #pragma unroll
    for(int e=0;e<4;e++) acc[s][e]=0.f;
  #pragma unroll 2
  for(int k4=0;k4<16;k4++){
    float4 av[9];
    #pragma unroll
    for(int s=0;s<9;s++) av[s] = *(const float4*)(sZ + (nd*9+s)*68 + k4*4);
    #pragma unroll
    for(int kk=0;kk<4;kk++){
      float4 bv = *(const float4*)(W2 + (size_t)(k4*4+kk)*64 + cg*4);
      #pragma unroll
      for(int s=0;s<9;s++){
        float a = (kk==0)?av[s].x:(kk==1)?av[s].y:(kk==2)?av[s].z:av[s].w;
        acc[s][0]=fmaf(a,bv.x,acc[s][0]);
        acc[s][1]=fmaf(a,bv.y,acc[s][1]);
        acc[s][2]=fmaf(a,bv.z,acc[s][2]);
        acc[s][3]=fmaf(a,bv.w,acc[s][3]);
      }
    }
  }
  float4 scv = ((const float4*)sc2)[cg];
  float4 shv = ((const float4*)sh2)[cg];
  float4 sum = make_float4(0.f,0.f,0.f,0.f);
  #pragma unroll
  for(int s=0;s<9;s++){
    sum.x += fmaxf(fmaf(scv.x,acc[s][0],shv.x),0.f);
    sum.y += fmaxf(fmaf(scv.y,acc[s][1],shv.y),0.f);
    sum.z += fmaxf(fmaf(scv.z,acc[s][2],shv.z),0.f);
    sum.w += fmaxf(fmaf(scv.w,acc[s][3],shv.w),0.f);
  }
  sum.x*=(1.f/9.f); sum.y*=(1.f/9.f); sum.z*=(1.f/9.f); sum.w*=(1.f/9.f);
  *(float4*)(Zb64 + ((size_t)prob*TN + node0+nd)*64 + cg*4) = sum;
}

// Zb64 @ W3[64,16] + b3 -> xlf/xsf; grid (TN/64, 2)
__global__ __launch_bounds__(256) void k_gemm16d(const float* __restrict__ Zb64,
      const float* __restrict__ W, const float* __restrict__ bias,
      float* __restrict__ outl, float* __restrict__ outs){
  __shared__ float sZ[64*68];
  __shared__ float sW[64*16];
  const int prob = blockIdx.y;
  const float* A = Zb64 + (size_t)prob*TN*64;
  float* out = prob ? outs : outl;
  const int tid = threadIdx.x;
  const int row0 = blockIdx.x*64;
  for(int e=tid; e<64*16; e+=256){
    int r = e>>4, c4 = e&15;
    ((float4*)(sZ + r*68))[c4] = ((const float4*)(A + (size_t)(row0+r)*64))[c4];
  }
  ((float4*)sW)[tid] = ((const float4*)W)[tid];
  __syncthreads();
  const int tc = tid & 15, tr = tid >> 4;   // col tc, rows tr+rr*16
  float acc[4] = {0.f,0.f,0.f,0.f};
  #pragma unroll 4
  for(int k4=0;k4<16;k4++){
    float4 av[4];
    #pragma unroll
    for(int rr=0;rr<4;rr++) av[rr] = *(const float4*)(sZ + (tr+rr*16)*68 + k4*4);
    #pragma unroll
    for(int kk=0;kk<4;kk++){
      float bv = sW[(k4*4+kk)*16 + tc];
      #pragma unroll
      for(int rr=0;rr<4;rr++){
        float a = (kk==0)?av[rr].x:(kk==1)?av[rr].y:(kk==2)?av[rr].z:av[rr].w;
        acc[rr]=fmaf(a,bv,acc[rr]);
      }
    }
  }
  #pragma unroll
  for(int rr=0;rr<4;rr++){
    int r = row0 + tr + rr*16;
    out[(size_t)r*16 + tc] = acc[rr] + bias[tc];
  }
}

// ---------------- head MLP 128->64->32->1, block-tiled (32 rows/block) ----------------
__global__ __launch_bounds__(256) void k_head(const float* __restrict__ x1,
    const float* __restrict__ W1, const float* __restrict__ b1,
    const float* __restrict__ W2, const float* __restrict__ b2,
    const float* __restrict__ W3, const float* __restrict__ b3,
    float* __restrict__ h, float* __restrict__ pstat){
  __shared__ float sA[32*132];
  __shared__ float sW1[128*64];
  __shared__ float o1[32*68];
  __shared__ float sW2[64*32];
  __shared__ float o2[32*33];
  __shared__ float sb1[64], sb2[32], sW3v[32];
  __shared__ float rs[32], rq[32];
  const int tid = threadIdx.x;
  const int row0 = blockIdx.x*32;
  for(int e=tid; e<32*32; e+=256){
    int r = e>>5, c4 = e&31;
    ((float4*)(sA + r*132))[c4] = ((const float4*)(x1 + (size_t)(row0+r)*128))[c4];
  }
  for(int e=tid; e<128*64/4; e+=256) ((float4*)sW1)[e] = ((const float4*)W1)[e];
  for(int e=tid; e<64*32/4; e+=256)  ((float4*)sW2)[e] = ((const float4*)W2)[e];
  if(tid < 64) sb1[tid]=b1[tid];
  if(tid < 32){ sb2[tid]=b2[tid]; sW3v[tid]=W3[tid]; }
  __syncthreads();
  const int tc = tid & 15, tr = tid >> 4;
  float a1[2][4];
  #pragma unroll
  for(int rr=0;rr<2;rr++)
    #pragma unroll
    for(int e=0;e<4;e++) a1[rr][e]=0.f;
  for(int k4=0;k4<32;k4++){
    float4 av0 = *(const float4*)(sA + (tr*2  )*132 + k4*4);
    float4 av1 = *(const float4*)(sA + (tr*2+1)*132 + k4*4);
    #pragma unroll
    for(int kk=0;kk<4;kk++){
      float4 bv = *(const float4*)(sW1 + (k4*4+kk)*64 + tc*4);
      float p0 = (kk==0)?av0.x:(kk==1)?av0.y:(kk==2)?av0.z:av0.w;
      float p1 = (kk==0)?av1.x:(kk==1)?av1.y:(kk==2)?av1.z:av1.w;
      a1[0][0]=fmaf(p0,bv.x,a1[0][0]); a1[0][1]=fmaf(p0,bv.y,a1[0][1]);
      a1[0][2]=fmaf(p0,bv.z,a1[0][2]); a1[0][3]=fmaf(p0,bv.w,a1[0][3]);
      a1[1][0]=fmaf(p1,bv.x,a1[1][0]); a1[1][1]=fmaf(p1,bv.y,a1[1][1]);
      a1[1][2]=fmaf(p1,bv.z,a1[1][2]); a1[1][3]=fmaf(p1,bv.w,a1[1][3]);
    }
  }
  #pragma unroll
  for(int rr=0;rr<2;rr++)
    #pragma unroll
    for(int e=0;e<4;e++)
      o1[(tr*2+rr)*68 + tc*4+e] = fmaxf(a1[rr][e]+sb1[tc*4+e], 0.f);
  __syncthreads();
  float a2[2][2] = {{0.f,0.f},{0.f,0.f}};
  for(int k=0;k<64;k++){
    float w0 = sW2[k*32 + tc*2], w1 = sW2[k*32 + tc*2+1];
    float v0 = o1[(tr*2  )*68 + k];
    float v1 = o1[(tr*2+1)*68 + k];
    a2[0][0]=fmaf(v0,w0,a2[0][0]); a2[0][1]=fmaf(v0,w1,a2[0][1]);
    a2[1][0]=fmaf(v1,w0,a2[1][0]); a2[1][1]=fmaf(v1,w1,a2[1][1]);
  }
  #pragma unroll
  for(int rr=0;rr<2;rr++)
    #pragma unroll
    for(int cc=0;cc<2;cc++)
      o2[(tr*2+rr)*33 + tc*2+cc] = fmaxf(a2[rr][cc]+sb2[tc*2+cc], 0.f);
  __syncthreads();
  if(tid < 32){
    float hv = b3[0];
    #pragma unroll
    for(int k=0;k<32;k++) hv = fmaf(o2[tid*33+k], sW3v[k], hv);
    h[row0+tid]=hv;
    rs[tid]=hv; rq[tid]=hv*hv;
  }
  __syncthreads();
  if(tid==0){
    float S=0.f, Q=0.f;
    #pragma unroll
    for(int i=0;i<32;i++){ S+=rs[i]; Q+=rq[i]; }
    pstat[blockIdx.x*2]=S; pstat[blockIdx.x*2+1]=Q;
  }
}

__global__ __launch_bounds__(256) void k_fin_h(const float* __restrict__ pstat,
      float* __restrict__ hpar){
  __shared__ double sS[256], sQ[256];
  int t = threadIdx.x;
  sS[t] = (double)pstat[2*t]; sQ[t] = (double)pstat[2*t+1];
  __syncthreads();
  for(int s=128;s>0;s>>=1){
    if(t<s){ sS[t]+=sS[t+s]; sQ[t]+=sQ[t+s]; }
    __syncthreads();
  }
  if(t==0){
    double mu = sS[0]/8192.0;
    double var = (sQ[0] - 8192.0*mu*mu)/8191.0;   // ddof=1
    double sd = (var > 0) ? sqrt(var) : 0.0;
    hpar[0]=(float)mu;
    hpar[1]=(float)(1.0/(sd + 1e-5));
  }
}

__global__ __launch_bounds__(256) void k_gate(const float* __restrict__ h,
      const float* __restrict__ hpar, const float4* __restrict__ x,
      float4* __restrict__ xl, float4* __restrict__ xs){
  int i = blockIdx.x*256 + threadIdx.x;
  float z = (h[i]-hpar[0])*hpar[1];
  float o = 1.0f/(1.0f+expf(-z));
  float om = 1.0f - o;
  float4 v = x[i];
  xl[i] = make_float4(o*v.x, o*v.y, o*v.z, o*v.w);
  xs[i] = make_float4(om*v.x, om*v.y, om*v.z, om*v.w);
}

// ---------------- final: per-graph max pool (16ch x 2) + linear [32]->1 ----------------
__global__ __launch_bounds__(256) void k_final(const float* __restrict__ xlf,
      const float* __restrict__ xsf, const float* __restrict__ W,
      const float* __restrict__ b, float* __restrict__ out){
  __shared__ float red[32][8];
  int g = blockIdx.x;
  int c = threadIdx.x & 31;
  int chunk = threadIdx.x >> 5;
  const float* src = (c < 16) ? xlf : xsf;
  int ch = (c < 16) ? c : c-16;
  float m = -1e30f;
  for(int n=chunk*128; n<chunk*128+128; n++)
    m = fmaxf(m, src[((size_t)g*1024+n)*16 + ch]);
  red[c][chunk]=m;
  __syncthreads();
  if(threadIdx.x < 32){
    float mm = red[threadIdx.x][0];
    #pragma unroll
    for(int p=1;p<8;p++) mm = fmaxf(mm, red[threadIdx.x][p]);
    red[threadIdx.x][0]=mm;
  }
  __syncthreads();
  if(threadIdx.x == 0){
    float acc = b[0];
    for(int cc=0;cc<32;cc++) acc = fmaf(red[cc][0], W[cc], acc);
    out[g]=acc;
  }
}

// ---------------- launch ----------------
extern "C" void kernel_launch(void* const* d_in, const int* in_sizes, int n_in,
                              void* d_out, int out_size, void* d_ws, size_t ws_size,
                              hipStream_t stream){
  const float* x    =(const float*)d_in[0];
  const float* c1W1 =(const float*)d_in[1];
  const float* c1g1 =(const float*)d_in[3];
  const float* c1be1=(const float*)d_in[4];
  const float* c1W2 =(const float*)d_in[5];
  const float* c1g2 =(const float*)d_in[7];
  const float* c1be2=(const float*)d_in[8];
  const float* c1W3 =(const float*)d_in[9];
  const float* c1b3 =(const float*)d_in[10];
  const float* c3W1 =(const float*)d_in[11];
  const float* c3g1 =(const float*)d_in[13];
  const float* c3be1=(const float*)d_in[14];
  const float* c3W2 =(const float*)d_in[15];
  const float* c3g2 =(const float*)d_in[17];
  const float* c3be2=(const float*)d_in[18];
  const float* c3W3 =(const float*)d_in[19];
  const float* c3b3 =(const float*)d_in[20];
  const float* hW1  =(const float*)d_in[21];
  const float* hb1  =(const float*)d_in[22];
  const float* hW2  =(const float*)d_in[23];
  const float* hb2  =(const float*)d_in[24];
  const float* hW3  =(const float*)d_in[25];
  const float* hb3  =(const float*)d_in[26];
  const float* l2W  =(const float*)d_in[27];
  const float* l2b  =(const float*)d_in[28];
  (void)in_sizes; (void)n_in; (void)out_size; (void)ws_size;

  char* wsb=(char*)d_ws;
  size_t off=0;
  auto alloc=[&](size_t bytes)->char*{
    char* p = wsb + off;
    off = (off + bytes + 255) & ~(size_t)255;
    return p;
  };
  float* Y    =(float*)alloc((size_t)TK*128*4);   // overlay: lists, mpartM (conv1+conv3)
  float* x1   =(float*)alloc((size_t)TN*128*4);
  float* Zb   =(float*)alloc((size_t)TN*128*4);   // conv1 Zb / conv3 Zb64 (dual)
  int*   idx1 =(int*)  alloc((size_t)TK*4);
  int*   idxl =(int*)  alloc((size_t)TK*4);
  int*   idxs =(int*)  alloc((size_t)TK*4);
  float* pd   =(float*)alloc((size_t)2*TN*72*4);
  float* h    =(float*)alloc((size_t)TN*4);
  float* xl   =(float*)alloc((size_t)TN*16);
  float* xs   =(float*)alloc((size_t)TN*16);
  float* xlf  =(float*)alloc((size_t)TN*16*4);
  float* xsf  =(float*)alloc((size_t)TN*16*4);
  float* pstat=(float*)alloc((size_t)512*4);
  double* Md  =(double*)alloc((size_t)16512*8);
  double* Mdd =(double*)alloc((size_t)8320*8);
  float* mp44 =(float*)alloc((size_t)288*44*4);
  float* mp44d=(float*)alloc((size_t)2*288*44*4);
  float* tl   =(float*)alloc((size_t)TN*4);
  float* tg   =(float*)alloc((size_t)2*TN*4);
  unsigned char* cnt8l=(unsigned char*)alloc((size_t)TN*8);
  unsigned char* cnt8g=(unsigned char*)alloc((size_t)2*TN*NCHG);
  float* bnp  =(float*)alloc(1024*4);
  float* hpar =(float*)alloc(64);

  float* sc1=bnp,      *sh1=bnp+128, *sc2=bnp+256, *sh2=bnp+384;
  float* scA=bnp+512,  *shA=bnp+640, *scB=bnp+768, *shB=bnp+896;  // conv3: [prob][64]
  unsigned short* listl=(unsigned short*)Y;   // Y region dead during kNN phases
  unsigned short* listg=(unsigned short*)Y;
  float* mpartM = Y;                          // conv1 moments overlay
  float* mpartMd = Y;                         // conv3 moments overlay (disjoint in time)

  // ---- conv1 kNN (per-graph) ----
  k_part_local  <<<256,256,0,stream>>>((const float4*)x, pd);
  k_thresh_local<<<32, 256,0,stream>>>(pd, tl);
  k_collect_local<<<256,256,0,stream>>>((const float4*)x, tl, cnt8l, listl);
  k_refine_local<<<TN/32,256,0,stream>>>((const float4*)x, cnt8l, listl, idx1);
  // ---- conv1 (moment-based, no Y materialization) ----
  k_mom8<<<288,256,0,stream>>>((const float4*)x, idx1, mp44);
  k_bn1q<<<1,128,0,stream>>>(mp44, c1W1, c1g1, c1be1, sc1, sh1);
  k_syrk128<<<288,256,0,stream>>>((const float4*)x, idx1, c1W1, sc1, sh1, mpartM);
  k_redM<<<65,256,0,stream>>>(mpartM, Md);
  k_bn2q<<<128,128,0,stream>>>(Md, c1W2, c1g2, c1be2, sc2, sh2);
  k_midagg<<<1024,256,0,stream>>>((const float4*)x, idx1, c1W1, sc1, sh1, c1W2, sc2, sh2, Zb);
  k_gemm128<<<TN/64,256,0,stream>>>(Zb, c1W3, c1b3, x1);
  // ---- head + gate ----
  k_head<<<TN/32,256,0,stream>>>(x1,hW1,hb1,hW2,hb2,hW3,hb3,h,pstat);
  k_fin_h<<<1,256,0,stream>>>(pstat,hpar);
  k_gate<<<32,256,0,stream>>>(h,hpar,(const float4*)x,(float4*)xl,(float4*)xs);
  // ---- global kNN for xl & xs ----
  k_part_sub   <<<dim3(256,2),256,0,stream>>>((const float4*)xl,(const float4*)xs,pd);
  k_thresh_sub <<<64,256,0,stream>>>(pd,tg);
  k_collect_glob<<<dim3(512,2),256,0,stream>>>((const float4*)xl,(const float4*)xs,tg,cnt8g,listg);
  k_refine_glob<<<2*TN/32,256,0,stream>>>((const float4*)xl,(const float4*)xs,cnt8g,listg,idxl,idxs);
  // ---- conv3 on xl & xs (moment-based, dual) ----
  k_mom8d<<<dim3(288,2),256,0,stream>>>((const float4*)xl,(const float4*)xs,idxl,idxs,mp44d);
  k_bn1qd<<<1,128,0,stream>>>(mp44d, c3W1, c3g1, c3be1, scA, shA);
  k_syrk64d<<<dim3(288,2),256,0,stream>>>((const float4*)xl,(const float4*)xs,idxl,idxs,c3W1,scA,shA,mpartMd);
  k_redMd<<<33,256,0,stream>>>(mpartMd, Mdd);
  k_bn2qd<<<dim3(64,2),64,0,stream>>>(Mdd, c3W2, c3g2, c3be2, scB, shB);
  k_midagg64d<<<dim3(512,2),256,0,stream>>>((const float4*)xl,(const float4*)xs,idxl,idxs,
      c3W1, scA, shA, c3W2, scB, shB, Zb);
  k_gemm16d<<<dim3(TN/64,2),256,0,stream>>>(Zb, c3W3, c3b3, xlf, xsf);
  // ---- final pooling + linear ----
  k_final<<<8,256,0,stream>>>(xlf,xsf,l2W,l2b,(float*)d_out);
}

// Round 15
// 430.128 us; speedup vs baseline: 1.5750x; 1.0479x over previous
//
#include <hip/hip_runtime.h>
#include <math.h>

#define TN 8192          // total nodes (B*N)
#define KNN 9
#define NPG 1024         // nodes per graph
#define TK (TN*KNN)      // 73728 edge rows
#define CPCL 12          // cap per (node,chunk), local (8 chunks of 128)
#define NCHG 32          // global chunks (of 256 candidates)
#define CPCG 16          // cap per (node,chunk), global

// ---------------- helpers ----------------
__device__ __forceinline__ float sqnorm(float4 v){
  return fmaf(v.x,v.x,fmaf(v.y,v.y,fmaf(v.z,v.z,v.w*v.w)));
}
__device__ __forceinline__ float pairdist(float4 a, float sqa, float4 b, float sqb){
  float dot = fmaf(a.x,b.x,fmaf(a.y,b.y,fmaf(a.z,b.z,a.w*b.w)));
  return sqa + sqb - 2.0f*dot;
}
__device__ __forceinline__ void chain9(float (&bd)[9], float d){
  float t=d;
  #pragma unroll
  for(int p=0;p<9;p++){
    float lo=fminf(bd[p],t);
    t=fmaxf(bd[p],t);
    bd[p]=lo;
  }
}
__device__ __forceinline__ void insert9(float (&bd)[9], int (&bi)[9], float d, int id){
  if(d < bd[8]){
    float td=d; int ti=id;
    #pragma unroll
    for(int p=0;p<9;p++){
      bool sw = (td < bd[p]);
      float nbd = sw ? td : bd[p];
      int   nbi = sw ? ti : bi[p];
      float ntd = sw ? bd[p] : td;
      int   nti = sw ? bi[p] : ti;
      bd[p]=nbd; bi[p]=nbi; td=ntd; ti=nti;
    }
  }
}

// ---------------- kNN: local (per-graph) ----------------
__global__ __launch_bounds__(256) void k_part_local(const float4* __restrict__ x, float* __restrict__ pd){
  __shared__ float4 sx[128]; __shared__ float ssq[128];
  int nb = blockIdx.x >> 3, chunk = blockIdx.x & 7;
  int g = nb >> 2;
  int cbase = g*NPG + chunk*128;
  if(threadIdx.x < 128){
    float4 v = x[cbase + threadIdx.x];
    sx[threadIdx.x]=v; ssq[threadIdx.x]=sqnorm(v);
  }
  __syncthreads();
  int node = nb*256 + threadIdx.x;
  float4 xi = x[node]; float sqi = sqnorm(xi);
  float bdA[9], bdB[9];
  #pragma unroll
  for(int q=0;q<9;q++){bdA[q]=1e30f;bdB[q]=1e30f;}
  for(int j=0;j<128;j+=2){
    chain9(bdA, pairdist(xi,sqi,sx[j],ssq[j]));
    chain9(bdB, pairdist(xi,sqi,sx[j+1],ssq[j+1]));
  }
  #pragma unroll
  for(int q=0;q<9;q++) chain9(bdA, bdB[q]);
  #pragma unroll
  for(int q=0;q<9;q++) pd[(size_t)(chunk*9+q)*TN + node]=bdA[q];
}

__global__ __launch_bounds__(256) void k_thresh_local(const float* __restrict__ pd,
      float* __restrict__ tl){
  int node = blockIdx.x*256 + threadIdx.x;
  float bd[9];
  #pragma unroll
  for(int q=0;q<9;q++) bd[q]=1e30f;
  for(int m=0;m<72;m++) chain9(bd, pd[(size_t)m*TN + node]);
  float t = bd[8];
  tl[node] = t + fabsf(t)*1e-5f + 1e-12f;
}

__global__ __launch_bounds__(256) void k_collect_local(const float4* __restrict__ x,
      const float* __restrict__ tl, unsigned char* __restrict__ cnt8,
      unsigned short* __restrict__ list){
  __shared__ float4 sx[128]; __shared__ float ssq[128];
  int nb = blockIdx.x >> 3, chunk = blockIdx.x & 7;
  int g = nb >> 2;
  int cbase = g*NPG + chunk*128;
  if(threadIdx.x < 128){
    float4 v = x[cbase + threadIdx.x];
    sx[threadIdx.x]=v; ssq[threadIdx.x]=sqnorm(v);
  }
  __syncthreads();
  int node = nb*256 + threadIdx.x;
  float4 xi = x[node];
  float m2x=-2.0f*xi.x, m2y=-2.0f*xi.y, m2z=-2.0f*xi.z, m2w=-2.0f*xi.w;
  float tadj = tl[node] - sqnorm(xi);
  int cnt = 0;
  unsigned short* lst = list + ((size_t)node*8 + chunk)*CPCL;
  for(int j=0;j<128;j+=4){
    float4 v0=sx[j], v1=sx[j+1], v2=sx[j+2], v3=sx[j+3];
    float q0=ssq[j], q1=ssq[j+1], q2=ssq[j+2], q3=ssq[j+3];
    float s0=fmaf(v0.x,m2x,fmaf(v0.y,m2y,fmaf(v0.z,m2z,fmaf(v0.w,m2w,q0))));
    float s1=fmaf(v1.x,m2x,fmaf(v1.y,m2y,fmaf(v1.z,m2z,fmaf(v1.w,m2w,q1))));
    float s2=fmaf(v2.x,m2x,fmaf(v2.y,m2y,fmaf(v2.z,m2z,fmaf(v2.w,m2w,q2))));
    float s3=fmaf(v3.x,m2x,fmaf(v3.y,m2y,fmaf(v3.z,m2z,fmaf(v3.w,m2w,q3))));
    if(s0<=tadj){ if(cnt<CPCL) lst[cnt]=(unsigned short)(cbase+j  ); cnt++; }
    if(s1<=tadj){ if(cnt<CPCL) lst[cnt]=(unsigned short)(cbase+j+1); cnt++; }
    if(s2<=tadj){ if(cnt<CPCL) lst[cnt]=(unsigned short)(cbase+j+2); cnt++; }
    if(s3<=tadj){ if(cnt<CPCL) lst[cnt]=(unsigned short)(cbase+j+3); cnt++; }
  }
  cnt8[(size_t)node*8 + chunk] = (unsigned char)(cnt > 255 ? 255 : cnt);
}

// 8 threads per node: sub handles 1 chunk; LDS merge of 8 partial top-9s
__global__ __launch_bounds__(256) void k_refine_local(const float4* __restrict__ x,
      const unsigned char* __restrict__ cnt8, const unsigned short* __restrict__ list,
      int* __restrict__ out){
  __shared__ float sval[32][73];
  __shared__ int   sidx[32][73];
  __shared__ int   sovf[32];
  int slot = threadIdx.x >> 3, sub = threadIdx.x & 7;
  int node = blockIdx.x*32 + slot;
  if(sub==0) sovf[slot]=0;
  __syncthreads();
  float4 xi = x[node]; float sqi = sqnorm(xi);
  float bd[9]; int bi[9];
  #pragma unroll
  for(int q=0;q<9;q++){bd[q]=1e30f; bi[q]=node;}
  int ch = sub;
  int c = cnt8[(size_t)node*8 + ch];
  if(c > CPCL) sovf[slot]=1;
  int n = c < CPCL ? c : CPCL;
  const unsigned short* lst = list + ((size_t)node*8 + ch)*CPCL;
  for(int m=0;m<n;m++){
    int j = lst[m]; float4 v = x[j];
    insert9(bd,bi, pairdist(xi,sqi,v,sqnorm(v)), j);
  }
  #pragma unroll
  for(int q=0;q<9;q++){ sval[slot][sub*9+q]=bd[q]; sidx[slot][sub*9+q]=bi[q]; }
  __syncthreads();
  if(sub==0){
    for(int m=9;m<72;m++) insert9(bd,bi, sval[slot][m], sidx[slot][m]);
    if(sovf[slot]){
      #pragma unroll
      for(int q=0;q<9;q++){bd[q]=1e30f; bi[q]=node;}
      int gbase = node & ~(NPG-1);
      for(int j=gbase;j<gbase+NPG;j++){
        float4 v = x[j];
        insert9(bd,bi, pairdist(xi,sqi,v,sqnorm(v)), j);
      }
    }
    #pragma unroll
    for(int q=0;q<9;q++) out[(size_t)node*9+q]=bi[q];
  }
}

// ---------------- kNN: global (two problems: xl, xs) ----------------
__global__ __launch_bounds__(256) void k_part_sub(const float4* __restrict__ xa,
      const float4* __restrict__ xb, float* __restrict__ pd){
  const float4* x = blockIdx.y ? xb : xa;
  __shared__ float4 sx[256]; __shared__ float ssq[256];
  int nb = blockIdx.x >> 3, chunk = blockIdx.x & 7;
  {
    int j = (chunk*256 + threadIdx.x)*4;
    float4 v = x[j];
    sx[threadIdx.x]=v; ssq[threadIdx.x]=sqnorm(v);
  }
  __syncthreads();
  int node = nb*256 + threadIdx.x;
  float4 xi = x[node]; float sqi = sqnorm(xi);
  float bdA[9], bdB[9];
  #pragma unroll
  for(int q=0;q<9;q++){bdA[q]=1e30f;bdB[q]=1e30f;}
  for(int j=0;j<256;j+=2){
    chain9(bdA, pairdist(xi,sqi,sx[j],ssq[j]));
    chain9(bdB, pairdist(xi,sqi,sx[j+1],ssq[j+1]));
  }
  #pragma unroll
  for(int q=0;q<9;q++) chain9(bdA, bdB[q]);
  int pn = blockIdx.y*TN + node;
  #pragma unroll
  for(int q=0;q<9;q++) pd[(size_t)(chunk*9+q)*2*TN + pn]=bdA[q];
}

__global__ __launch_bounds__(256) void k_thresh_sub(const float* __restrict__ pd,
      float* __restrict__ tg){
  int pn = blockIdx.x*256 + threadIdx.x;   // < 2*TN
  float bd[9];
  #pragma unroll
  for(int q=0;q<9;q++) bd[q]=1e30f;
  for(int m=0;m<72;m++) chain9(bd, pd[(size_t)m*2*TN + pn]);
  float t = bd[8];
  tg[pn] = t + fabsf(t)*1e-5f + 1e-12f;
}

// 2 nodes/thread, 32 chunks of 256 cands: grid (16*32, 2) = 1024 blocks
__global__ __launch_bounds__(256) void k_collect_glob(const float4* __restrict__ xa,
      const float4* __restrict__ xb, const float* __restrict__ tg,
      unsigned char* __restrict__ cnt8, unsigned short* __restrict__ list){
  const float4* x = blockIdx.y ? xb : xa;
  __shared__ float4 sx[256];
  __shared__ float4 ssq4[64];
  int nb = blockIdx.x >> 5, chunk = blockIdx.x & 31;
  int cbase = chunk*256;
  {
    float4 v = x[cbase+threadIdx.x];
    sx[threadIdx.x]=v; ((float*)ssq4)[threadIdx.x]=sqnorm(v);
  }
  __syncthreads();
  int node0 = nb*512 + threadIdx.x;
  int node1 = node0 + 256;
  int pn0 = blockIdx.y*TN + node0;
  int pn1 = pn0 + 256;
  float4 xi0 = x[node0], xi1 = x[node1];
  float a0x=-2.0f*xi0.x, a0y=-2.0f*xi0.y, a0z=-2.0f*xi0.z, a0w=-2.0f*xi0.w;
  float a1x=-2.0f*xi1.x, a1y=-2.0f*xi1.y, a1z=-2.0f*xi1.z, a1w=-2.0f*xi1.w;
  float t0 = tg[pn0] - sqnorm(xi0);
  float t1 = tg[pn1] - sqnorm(xi1);
  int c0 = 0, c1 = 0;
  unsigned short* l0 = list + ((size_t)pn0*NCHG + chunk)*CPCG;
  unsigned short* l1 = list + ((size_t)pn1*NCHG + chunk)*CPCG;
  for(int j=0;j<256;j+=4){
    float4 v0=sx[j], v1=sx[j+1], v2=sx[j+2], v3=sx[j+3];
    float4 qv = ssq4[j>>2];
    float s00=fmaf(v0.x,a0x,fmaf(v0.y,a0y,fmaf(v0.z,a0z,fmaf(v0.w,a0w,qv.x))));
    float s01=fmaf(v1.x,a0x,fmaf(v1.y,a0y,fmaf(v1.z,a0z,fmaf(v1.w,a0w,qv.y))));
    float s02=fmaf(v2.x,a0x,fmaf(v2.y,a0y,fmaf(v2.z,a0z,fmaf(v2.w,a0w,qv.z))));
    float s03=fmaf(v3.x,a0x,fmaf(v3.y,a0y,fmaf(v3.z,a0z,fmaf(v3.w,a0w,qv.w))));
    float s10=fmaf(v0.x,a1x,fmaf(v0.y,a1y,fmaf(v0.z,a1z,fmaf(v0.w,a1w,qv.x))));
    float s11=fmaf(v1.x,a1x,fmaf(v1.y,a1y,fmaf(v1.z,a1z,fmaf(v1.w,a1w,qv.y))));
    float s12=fmaf(v2.x,a1x,fmaf(v2.y,a1y,fmaf(v2.z,a1z,fmaf(v2.w,a1w,qv.z))));
    float s13=fmaf(v3.x,a1x,fmaf(v3.y,a1y,fmaf(v3.z,a1z,fmaf(v3.w,a1w,qv.w))));
    if(s00<=t0){ if(c0<CPCG) l0[c0]=(unsigned short)(cbase+j  ); c0++; }
    if(s01<=t0){ if(c0<CPCG) l0[c0]=(unsigned short)(cbase+j+1); c0++; }
    if(s02<=t0){ if(c0<CPCG) l0[c0]=(unsigned short)(cbase+j+2); c0++; }
    if(s03<=t0){ if(c0<CPCG) l0[c0]=(unsigned short)(cbase+j+3); c0++; }
    if(s10<=t1){ if(c1<CPCG) l1[c1]=(unsigned short)(cbase+j  ); c1++; }
    if(s11<=t1){ if(c1<CPCG) l1[c1]=(unsigned short)(cbase+j+1); c1++; }
    if(s12<=t1){ if(c1<CPCG) l1[c1]=(unsigned short)(cbase+j+2); c1++; }
    if(s13<=t1){ if(c1<CPCG) l1[c1]=(unsigned short)(cbase+j+3); c1++; }
  }
  cnt8[(size_t)pn0*NCHG + chunk] = (unsigned char)(c0 > 255 ? 255 : c0);
  cnt8[(size_t)pn1*NCHG + chunk] = (unsigned char)(c1 > 255 ? 255 : c1);
}

// 8 threads per node: sub handles 4 chunks; LDS merge of 8 partial top-9s
__global__ __launch_bounds__(256) void k_refine_glob(const float4* __restrict__ xa,
      const float4* __restrict__ xb, const unsigned char* __restrict__ cnt8,
      const unsigned short* __restrict__ list, int* __restrict__ outl, int* __restrict__ outs){
  __shared__ float sval[32][73];
  __shared__ int   sidx[32][73];
  __shared__ int   sovf[32];
  int slot = threadIdx.x >> 3, sub = threadIdx.x & 7;
  int pn = blockIdx.x*32 + slot;          // < 2*TN; grid = 512
  int prob = blockIdx.x >> 8;             // uniform per block
  int node = pn & (TN-1);
  const float4* x = prob ? xb : xa;
  if(sub==0) sovf[slot]=0;
  __syncthreads();
  float4 xi = x[node]; float sqi = sqnorm(xi);
  float bd[9]; int bi[9];
  #pragma unroll
  for(int q=0;q<9;q++){bd[q]=1e30f; bi[q]=node;}
  bool ovf=false;
  for(int ch=sub*4; ch<sub*4+4; ch++){
    int c = cnt8[(size_t)pn*NCHG + ch];
    if(c > CPCG) ovf=true;
    int n = c < CPCG ? c : CPCG;
    const unsigned short* lst = list + ((size_t)pn*NCHG + ch)*CPCG;
    for(int m=0;m<n;m++){
      int j = lst[m]; float4 v = x[j];
      insert9(bd,bi, pairdist(xi,sqi,v,sqnorm(v)), j);
    }
  }
  if(ovf) sovf[slot]=1;
  #pragma unroll
  for(int q=0;q<9;q++){ sval[slot][sub*9+q]=bd[q]; sidx[slot][sub*9+q]=bi[q]; }
  __syncthreads();
  if(sub==0){
    for(int m=9;m<72;m++) insert9(bd,bi, sval[slot][m], sidx[slot][m]);
    if(sovf[slot]){
      #pragma unroll
      for(int q=0;q<9;q++){bd[q]=1e30f; bi[q]=node;}
      for(int j=0;j<TN;j++){
        float4 v = x[j];
        insert9(bd,bi, pairdist(xi,sqi,v,sqnorm(v)), j);
      }
    }
    int* o = prob ? outs : outl;
    #pragma unroll
    for(int q=0;q<9;q++) o[(size_t)node*9+q]=bi[q];
  }
}

// ---------------- conv1: moment-based BN, fused recompute (no Y materialization) ----------------
__global__ __launch_bounds__(256) void k_mom8(const float4* __restrict__ x,
      const int* __restrict__ idx, float* __restrict__ mpart){
  __shared__ float sa[256][9];
  int t = threadIdx.x;
  int e = blockIdx.x*256 + t;
  int i = e/KNN; int j = idx[e];
  float4 xi = x[i], xj = x[j];
  sa[t][0]=xi.x; sa[t][1]=xi.y; sa[t][2]=xi.z; sa[t][3]=xi.w;
  sa[t][4]=xj.x-xi.x; sa[t][5]=xj.y-xi.y; sa[t][6]=xj.z-xi.z; sa[t][7]=xj.w-xi.w;
  __syncthreads();
  if(t < 44){
    float s=0.f;
    if(t<8){
      for(int e2=0;e2<256;e2++) s += sa[e2][t];
    } else {
      int f=t-8, p=0, q=0, acc=0;
      for(p=0;p<8;p++){ int cnt=8-p; if(f<acc+cnt){ q=p+(f-acc); break;} acc+=cnt; }
      for(int e2=0;e2<256;e2++) s += sa[e2][p]*sa[e2][q];
    }
    mpart[blockIdx.x*44+t]=s;
  }
}

__global__ void k_bn1q(const float* __restrict__ mpart, const float* __restrict__ W1,
      const float* __restrict__ g, const float* __restrict__ be,
      float* __restrict__ scale, float* __restrict__ shift){
  __shared__ double mom[44];
  int t = threadIdx.x;   // 128
  if(t<44){ double s=0; for(int b=0;b<288;b++) s+=(double)mpart[b*44+t]; mom[t]=s; }
  __syncthreads();
  double m[8], w[8];
  #pragma unroll
  for(int p=0;p<8;p++){ m[p]=mom[p]/(double)TK; w[p]=(double)W1[p*128+t]; }
  double q=0.0; int f=8;
  for(int p=0;p<8;p++)
    for(int qq=p;qq<8;qq++){
      double cov = mom[f]/(double)TK - m[p]*m[qq];
      q += (p==qq?1.0:2.0)*w[p]*w[qq]*cov;
      f++;
    }
  if(q<0) q=0;
  double sc = (double)g[t]/sqrt(q+1e-5);
  double mu=0; for(int p=0;p<8;p++) mu += m[p]*w[p];
  scale[t]=(float)sc;
  shift[t]=(float)((double)be[t] - mu*sc);
}

// SYRK v4: 512 blocks x 144 edges (3 passes of 48); aligned stride-132 layout
__global__ __launch_bounds__(256) void k_syrk128(const float4* __restrict__ x,
      const int* __restrict__ idx, const float* __restrict__ W1,
      const float* __restrict__ sc1, const float* __restrict__ sh1,
      float* __restrict__ mpartM){
  __shared__ float sa[48][9];
  __shared__ float sW1[8*128];
  __shared__ float sZ[48*132];
  __shared__ float ssum[128];
  const int tid = threadIdx.x;
  ((float4*)sW1)[tid] = ((const float4*)W1)[tid];
  if(tid<128) ssum[tid]=0.f;
  const int zc4 = tid & 31, ze0 = tid >> 5;     // z-compute mapping
  const int i0 = (tid>>4)*8, j0 = (tid&15)*8;   // syrk mapping
  float acc[8][8];
  #pragma unroll
  for(int a=0;a<8;a++)
    #pragma unroll
    for(int b=0;b<8;b++) acc[a][b]=0.f;
  float ls[4]={0,0,0,0};
  float4 scv = ((const float4*)sc1)[zc4];
  float4 shv = ((const float4*)sh1)[zc4];
  for(int pass=0;pass<3;pass++){
    __syncthreads();
    if(tid<48){
      int e = blockIdx.x*144 + pass*48 + tid;
      int i = e/KNN; int j = idx[e];
      float4 xi = x[i], xj = x[j];
      sa[tid][0]=xi.x; sa[tid][1]=xi.y; sa[tid][2]=xi.z; sa[tid][3]=xi.w;
      sa[tid][4]=xj.x-xi.x; sa[tid][5]=xj.y-xi.y; sa[tid][6]=xj.z-xi.z; sa[tid][7]=xj.w-xi.w;
    }
    __syncthreads();
    for(int e=ze0; e<48; e+=8){
      float4 y = make_float4(0.f,0.f,0.f,0.f);
      #pragma unroll
      for(int k=0;k<8;k++){
        float a = sa[e][k];
        float4 wv = *(const float4*)(sW1 + k*128 + zc4*4);
        y.x=fmaf(a,wv.x,y.x); y.y=fmaf(a,wv.y,y.y);
        y.z=fmaf(a,wv.z,y.z); y.w=fmaf(a,wv.w,y.w);
      }
      float4 z;
      z.x = fmaxf(fmaf(scv.x,y.x,shv.x),0.f);
      z.y = fmaxf(fmaf(scv.y,y.y,shv.y),0.f);
      z.z = fmaxf(fmaf(scv.z,y.z,shv.z),0.f);
      z.w = fmaxf(fmaf(scv.w,y.w,shv.w),0.f);
      *(float4*)(sZ + e*132 + zc4*4) = z;
      ls[0]+=z.x; ls[1]+=z.y; ls[2]+=z.z; ls[3]+=z.w;
    }
    __syncthreads();
    #pragma unroll 2
    for(int e=0;e<48;e++){
      const float* rz = sZ + e*132;
      float4 zi0 = *(const float4*)(rz + i0);
      float4 zi1 = *(const float4*)(rz + i0 + 4);
      float4 zj0 = *(const float4*)(rz + j0);
      float4 zj1 = *(const float4*)(rz + j0 + 4);
      float zi[8] = {zi0.x,zi0.y,zi0.z,zi0.w,zi1.x,zi1.y,zi1.z,zi1.w};
      float zj[8] = {zj0.x,zj0.y,zj0.z,zj0.w,zj1.x,zj1.y,zj1.z,zj1.w};
      #pragma unroll
      for(int a=0;a<8;a++)
        #pragma unroll
        for(int b=0;b<8;b++) acc[a][b]=fmaf(zi[a],zj[b],acc[a][b]);
    }
  }
  #pragma unroll
  for(int c=0;c<4;c++) atomicAdd(&ssum[zc4*4+c], ls[c]);
  float* mp = mpartM + (size_t)blockIdx.x*16512;
  #pragma unroll
  for(int a=0;a<8;a++){
    *(float4*)(mp + (i0+a)*128 + j0)     = make_float4(acc[a][0],acc[a][1],acc[a][2],acc[a][3]);
    *(float4*)(mp + (i0+a)*128 + j0 + 4) = make_float4(acc[a][4],acc[a][5],acc[a][6],acc[a][7]);
  }
  __syncthreads();
  if(tid<128) mp[16384+tid] = ssum[tid];
}

__global__ __launch_bounds__(256) void k_redM(const float* __restrict__ mpartM,
      double* __restrict__ Md){
  int ch = blockIdx.x*256 + threadIdx.x;
  if(ch >= 16512) return;
  double s=0;
  for(int b=0;b<512;b++) s += (double)mpartM[(size_t)b*16512 + ch];
  Md[ch]=s;
}

__global__ void k_bn2q(const double* __restrict__ Md, const float* __restrict__ W2,
      const float* __restrict__ g, const float* __restrict__ be,
      float* __restrict__ scale, float* __restrict__ shift){
  __shared__ double redq[128], redt[128];
  __shared__ float sw[128];
  int c = blockIdx.x, t = threadIdx.x;   // 128 threads
  sw[t] = W2[t*128+c];
  __syncthreads();
  double zb = Md[16384+t]/(double)TK;
  double inner=0;
  for(int j=0;j<128;j++) inner += Md[t*128+j]*(double)sw[j];
  redq[t] = (double)sw[t]*(inner/(double)TK);
  redt[t] = (double)sw[t]*zb;
  __syncthreads();
  for(int s=64;s>0;s>>=1){
    if(t<s){ redq[t]+=redq[t+s]; redt[t]+=redt[t+s]; }
    __syncthreads();
  }
  if(t==0){
    double var = redq[0] - redt[0]*redt[0];
    if(var<0) var=0;
    double sc = (double)g[c]/sqrt(var+1e-5);
    scale[c]=(float)sc;
    shift[c]=(float)((double)be[c] - redt[0]*sc);
  }
}

// fused: gather A (8 nodes, 72 edges) -> z1 recompute -> GEMM x W2 (global, broadcast)
// -> BN2+ReLU -> mean over 9 -> Zb[node][128]
__global__ __launch_bounds__(256) void k_midagg(const float4* __restrict__ x,
      const int* __restrict__ idx, const float* __restrict__ W1,
      const float* __restrict__ sc1, const float* __restrict__ sh1,
      const float* __restrict__ W2, const float* __restrict__ sc2,
      const float* __restrict__ sh2, float* __restrict__ Zb){
  __shared__ float sa[72][9];
  __shared__ float sW1[8*128];
  __shared__ float sZ[72*132];
  const int tid = threadIdx.x;
  const int node0 = blockIdx.x*8;
  if(tid<256) ((float4*)sW1)[tid] = ((const float4*)W1)[tid];
  if(tid<72){
    int e = blockIdx.x*72 + tid;
    int i = e/KNN; int j = idx[e];
    float4 xi = x[i], xj = x[j];
    sa[tid][0]=xi.x; sa[tid][1]=xi.y; sa[tid][2]=xi.z; sa[tid][3]=xi.w;
    sa[tid][4]=xj.x-xi.x; sa[tid][5]=xj.y-xi.y; sa[tid][6]=xj.z-xi.z; sa[tid][7]=xj.w-xi.w;
  }
  __syncthreads();
  for(int f=tid; f<2304; f+=256){
    int e = f>>5, c4 = f&31;
    float4 scv = ((const float4*)sc1)[c4];
    float4 shv = ((const float4*)sh1)[c4];
    float4 y = make_float4(0.f,0.f,0.f,0.f);
    #pragma unroll
    for(int k=0;k<8;k++){
      float a = sa[e][k];
      float4 wv = *(const float4*)(sW1 + k*128 + c4*4);
      y.x=fmaf(a,wv.x,y.x); y.y=fmaf(a,wv.y,y.y);
      y.z=fmaf(a,wv.z,y.z); y.w=fmaf(a,wv.w,y.w);
    }
    float4 z;
    z.x = fmaxf(fmaf(scv.x,y.x,shv.x),0.f);
    z.y = fmaxf(fmaf(scv.y,y.y,shv.y),0.f);
    z.z = fmaxf(fmaf(scv.z,y.z,shv.z),0.f);
    z.w = fmaxf(fmaf(scv.w,y.w,shv.w),0.f);
    *(float4*)(sZ + e*132 + c4*4) = z;
  }
  __syncthreads();
  const int tc = tid & 31, tr = tid >> 5;  // node tr, cols tc*4
  float acc[9][4];
  #pragma unroll
  for(int s=0;s<9;s++)
    #pragma unroll
    for(int e=0;e<4;e++) acc[s][e]=0.f;
  #pragma unroll 2
  for(int k4=0;k4<32;k4++){
    float4 av[9];
    #pragma unroll
    for(int s=0;s<9;s++) av[s] = *(const float4*)(sZ + (tr*9+s)*132 + k4*4);
    #pragma unroll
    for(int kk=0;kk<4;kk++){
      float4 bv = *(const float4*)(W2 + (size_t)(k4*4+kk)*128 + tc*4);
      #pragma unroll
      for(int s=0;s<9;s++){
        float a = (kk==0)?av[s].x:(kk==1)?av[s].y:(kk==2)?av[s].z:av[s].w;
        acc[s][0]=fmaf(a,bv.x,acc[s][0]);
        acc[s][1]=fmaf(a,bv.y,acc[s][1]);
        acc[s][2]=fmaf(a,bv.z,acc[s][2]);
        acc[s][3]=fmaf(a,bv.w,acc[s][3]);
      }
    }
  }
  float4 scv = ((const float4*)sc2)[tc];
  float4 shv = ((const float4*)sh2)[tc];
  float4 sum = make_float4(0.f,0.f,0.f,0.f);
  #pragma unroll
  for(int s=0;s<9;s++){
    sum.x += fmaxf(fmaf(scv.x,acc[s][0],shv.x),0.f);
    sum.y += fmaxf(fmaf(scv.y,acc[s][1],shv.y),0.f);
    sum.z += fmaxf(fmaf(scv.z,acc[s][2],shv.z),0.f);
    sum.w += fmaxf(fmaf(scv.w,acc[s][3],shv.w),0.f);
  }
  sum.x*=(1.f/9.f); sum.y*=(1.f/9.f); sum.z*=(1.f/9.f); sum.w*=(1.f/9.f);
  *(float4*)(Zb + (size_t)(node0+tr)*128 + tc*4) = sum;
}

// plain GEMM x1 = Zb[8192,128] @ W3[128,128] + b3; 32 rows/block, grid 256
__global__ __launch_bounds__(256) void k_gemm128(const float* __restrict__ A,
      const float* __restrict__ W, const float* __restrict__ bias,
      float* __restrict__ out){
  __shared__ float sZ[32*132];
  const int tid = threadIdx.x;
  const int row0 = blockIdx.x*32;
  for(int e=tid; e<32*32; e+=256){
    int r = e>>5, c4 = e&31;
    ((float4*)(sZ + r*132))[c4] = ((const float4*)(A + (size_t)(row0+r)*128))[c4];
  }
  __syncthreads();
  const int tc = tid & 31, tr = tid >> 5;  // cols tc*4, rows tr+rr*8
  float acc[4][4];
  #pragma unroll
  for(int rr=0;rr<4;rr++)
    #pragma unroll
    for(int e=0;e<4;e++) acc[rr][e]=0.f;
  #pragma unroll 4
  for(int k4=0;k4<32;k4++){
    float4 av[4];
    #pragma unroll
    for(int rr=0;rr<4;rr++) av[rr] = *(const float4*)(sZ + (tr+rr*8)*132 + k4*4);
    #pragma unroll
    for(int kk=0;kk<4;kk++){
      float4 bv = *(const float4*)(W + (size_t)(k4*4+kk)*128 + tc*4);
      #pragma unroll
      for(int rr=0;rr<4;rr++){
        float a = (kk==0)?av[rr].x:(kk==1)?av[rr].y:(kk==2)?av[rr].z:av[rr].w;
        acc[rr][0]=fmaf(a,bv.x,acc[rr][0]);
        acc[rr][1]=fmaf(a,bv.y,acc[rr][1]);
        acc[rr][2]=fmaf(a,bv.z,acc[rr][2]);
        acc[rr][3]=fmaf(a,bv.w,acc[rr][3]);
      }
    }
  }
  float4 breg = *(const float4*)(bias + tc*4);
  #pragma unroll
  for(int rr=0;rr<4;rr++){
    int r = row0 + tr + rr*8;
    float4 vals;
    vals.x = acc[rr][0]+breg.x;
    vals.y = acc[rr][1]+breg.y;
    vals.z = acc[rr][2]+breg.z;
    vals.w = acc[rr][3]+breg.w;
    *(float4*)(out + (size_t)r*128 + tc*4) = vals;
  }
}

// ---------------- conv3: moment-based, dual problems ----------------
__global__ __launch_bounds__(256) void k_mom8d(const float4* __restrict__ xa,
      const float4* __restrict__ xb, const int* __restrict__ ia,
      const int* __restrict__ ib, float* __restrict__ mpart){
  __shared__ float sa[256][9];
  const int prob = blockIdx.y;
  const float4* x = prob ? xb : xa;
  const int* idx = prob ? ib : ia;
  int t = threadIdx.x;
  int e = blockIdx.x*256 + t;
  int i = e/KNN; int j = idx[e];
  float4 xi = x[i], xj = x[j];
  sa[t][0]=xi.x; sa[t][1]=xi.y; sa[t][2]=xi.z; sa[t][3]=xi.w;
  sa[t][4]=xj.x-xi.x; sa[t][5]=xj.y-xi.y; sa[t][6]=xj.z-xi.z; sa[t][7]=xj.w-xi.w;
  __syncthreads();
  if(t < 44){
    float s=0.f;
    if(t<8){
      for(int e2=0;e2<256;e2++) s += sa[e2][t];
    } else {
      int f=t-8, p=0, q=0, acc=0;
      for(p=0;p<8;p++){ int cnt=8-p; if(f<acc+cnt){ q=p+(f-acc); break;} acc+=cnt; }
      for(int e2=0;e2<256;e2++) s += sa[e2][p]*sa[e2][q];
    }
    mpart[((size_t)prob*288 + blockIdx.x)*44 + t]=s;
  }
}

// 128 threads = 2 probs x 64 ch; W1 is 8x64
__global__ void k_bn1qd(const float* __restrict__ mpart, const float* __restrict__ W1,
      const float* __restrict__ g, const float* __restrict__ be,
      float* __restrict__ scale, float* __restrict__ shift){
  __shared__ double mom[2][44];
  int t = threadIdx.x;   // 128
  if(t<88){
    int pr=t/44, m=t%44;
    double s=0; for(int b=0;b<288;b++) s+=(double)mpart[((size_t)pr*288+b)*44+m];
    mom[pr][m]=s;
  }
  __syncthreads();
  int prob = t>>6, c = t&63;
  double m[8], w[8];
  #pragma unroll
  for(int p=0;p<8;p++){ m[p]=mom[prob][p]/(double)TK; w[p]=(double)W1[p*64+c]; }
  double q=0.0; int f=8;
  for(int p=0;p<8;p++)
    for(int qq=p;qq<8;qq++){
      double cov = mom[prob][f]/(double)TK - m[p]*m[qq];
      q += (p==qq?1.0:2.0)*w[p]*w[qq]*cov;
      f++;
    }
  if(q<0) q=0;
  double sc = (double)g[c]/sqrt(q+1e-5);
  double mu=0; for(int p=0;p<8;p++) mu += m[p]*w[p];
  scale[prob*64+c]=(float)sc;
  shift[prob*64+c]=(float)((double)be[c] - mu*sc);
}

// SYRK 64-d dual: per block 256 edges (4 passes of 64), M64 + colsum -> mpartM[(prob*288+b)*4160]
__global__ __launch_bounds__(256) void k_syrk64d(const float4* __restrict__ xa,
      const float4* __restrict__ xb, const int* __restrict__ ia,
      const int* __restrict__ ib, const float* __restrict__ W1,
      const float* __restrict__ sc0, const float* __restrict__ sh0,
      float* __restrict__ mpartM){
  __shared__ float sa[64][9];
  __shared__ float sW1[8*64];
  __shared__ float sZ[64*68];
  __shared__ float ssum[64];
  const int prob = blockIdx.y;
  const float4* x = prob ? xb : xa;
  const int* idx = prob ? ib : ia;
  const float* sc1 = sc0 + prob*64;
  const float* sh1 = sh0 + prob*64;
  const int tid = threadIdx.x;
  if(tid<128) ((float4*)sW1)[tid] = ((const float4*)W1)[tid];
  if(tid<64) ssum[tid]=0.f;
  const int zc4 = tid & 15, ze0 = tid >> 4;     // z chunk (16x4=64ch), rows ze0+16k
  const int i0 = (tid>>4)*4, j0 = (tid&15)*4;   // syrk 4x4 tile
  float acc[4][4];
  #pragma unroll
  for(int a=0;a<4;a++)
    #pragma unroll
    for(int b=0;b<4;b++) acc[a][b]=0.f;
  float ls[4]={0,0,0,0};
  float4 scv = ((const float4*)sc1)[zc4];
  float4 shv = ((const float4*)sh1)[zc4];
  for(int pass=0;pass<4;pass++){
    __syncthreads();
    if(tid<64){
      int e = blockIdx.x*256 + pass*64 + tid;
      int i = e/KNN; int j = idx[e];
      float4 xi = x[i], xj = x[j];
      sa[tid][0]=xi.x; sa[tid][1]=xi.y; sa[tid][2]=xi.z; sa[tid][3]=xi.w;
      sa[tid][4]=xj.x-xi.x; sa[tid][5]=xj.y-xi.y; sa[tid][6]=xj.z-xi.z; sa[tid][7]=xj.w-xi.w;
    }
    __syncthreads();
    for(int e=ze0; e<64; e+=16){
      float4 y = make_float4(0.f,0.f,0.f,0.f);
      #pragma unroll
      for(int k=0;k<8;k++){
        float a = sa[e][k];
        float4 wv = *(const float4*)(sW1 + k*64 + zc4*4);
        y.x=fmaf(a,wv.x,y.x); y.y=fmaf(a,wv.y,y.y);
        y.z=fmaf(a,wv.z,y.z); y.w=fmaf(a,wv.w,y.w);
      }
      float4 z;
      z.x = fmaxf(fmaf(scv.x,y.x,shv.x),0.f);
      z.y = fmaxf(fmaf(scv.y,y.y,shv.y),0.f);
      z.z = fmaxf(fmaf(scv.z,y.z,shv.z),0.f);
      z.w = fmaxf(fmaf(scv.w,y.w,shv.w),0.f);
      *(float4*)(sZ + e*68 + zc4*4) = z;
      ls[0]+=z.x; ls[1]+=z.y; ls[2]+=z.z; ls[3]+=z.w;
    }
    __syncthreads();
    #pragma unroll 4
    for(int e=0;e<64;e++){
      const float* rz = sZ + e*68;
      float4 zi4 = *(const float4*)(rz + i0);
      float4 zj4 = *(const float4*)(rz + j0);
      float zi[4]={zi4.x,zi4.y,zi4.z,zi4.w};
      float zj[4]={zj4.x,zj4.y,zj4.z,zj4.w};
      #pragma unroll
      for(int a=0;a<4;a++)
        #pragma unroll
        for(int b=0;b<4;b++) acc[a][b]=fmaf(zi[a],zj[b],acc[a][b]);
    }
  }
  #pragma unroll
  for(int c=0;c<4;c++) atomicAdd(&ssum[zc4*4+c], ls[c]);
  float* mp = mpartM + ((size_t)prob*288 + blockIdx.x)*4160;
  #pragma unroll
  for(int a=0;a<4;a++)
    *(float4*)(mp + (i0+a)*64 + j0) = make_float4(acc[a][0],acc[a][1],acc[a][2],acc[a][3]);
  __syncthreads();
  if(tid<64) mp[4096+tid] = ssum[tid];
}

__global__ __launch_bounds__(256) void k_redMd(const float* __restrict__ mpartM,
      double* __restrict__ Md){
  int ch = blockIdx.x*256 + threadIdx.x;
  if(ch >= 8320) return;
  int prob = ch / 4160, c = ch % 4160;
  double s=0;
  for(int b=0;b<288;b++) s += (double)mpartM[((size_t)prob*288+b)*4160 + c];
  Md[(size_t)prob*4160 + c]=s;
}

// grid (64, 2); 64 threads; W2 is 64x64
__global__ void k_bn2qd(const double* __restrict__ Md, const float* __restrict__ W2,
      const float* __restrict__ g, const float* __restrict__ be,
      float* __restrict__ scale, float* __restrict__ shift){
  __shared__ double redq[64], redt[64];
  __shared__ float sw[64];
  int c = blockIdx.x, prob = blockIdx.y, t = threadIdx.x;   // 64 threads
  const double* md = Md + (size_t)prob*4160;
  sw[t] = W2[t*64+c];
  __syncthreads();
  double zb = md[4096+t]/(double)TK;
  double inner=0;
  for(int j=0;j<64;j++) inner += md[t*64+j]*(double)sw[j];
  redq[t] = (double)sw[t]*(inner/(double)TK);
  redt[t] = (double)sw[t]*zb;
  __syncthreads();
  for(int s=32;s>0;s>>=1){
    if(t<s){ redq[t]+=redq[t+s]; redt[t]+=redt[t+s]; }
    __syncthreads();
  }
  if(t==0){
    double var = redq[0] - redt[0]*redt[0];
    if(var<0) var=0;
    double sc = (double)g[c]/sqrt(var+1e-5);
    scale[prob*64+c]=(float)sc;
    shift[prob*64+c]=(float)((double)be[c] - redt[0]*sc);
  }
}

// fused conv3 mid+agg: 16 nodes / 144 edges per block; grid (512, 2)
__global__ __launch_bounds__(256) void k_midagg64d(const float4* __restrict__ xa,
      const float4* __restrict__ xb, const int* __restrict__ ia,
      const int* __restrict__ ib, const float* __restrict__ W1,
      const float* __restrict__ sc0, const float* __restrict__ sh0,
      const float* __restrict__ W2, const float* __restrict__ sc20,
      const float* __restrict__ sh20, float* __restrict__ Zb64){
  __shared__ float sa[144][9];
  __shared__ float sW1[8*64];
  __shared__ float sZ[144*68];
  const int prob = blockIdx.y;
  const float4* x = prob ? xb : xa;
  const int* idx = prob ? ib : ia;
  const float* sc1 = sc0 + prob*64;
  const float* sh1 = sh0 + prob*64;
  const float* sc2 = sc20 + prob*64;
  const float* sh2 = sh20 + prob*64;
  const int tid = threadIdx.x;
  const int node0 = blockIdx.x*16;
  if(tid<128) ((float4*)sW1)[tid] = ((const float4*)W1)[tid];
  if(tid<144){
    int e = blockIdx.x*144 + tid;
    int i = e/KNN; int j = idx[e];
    float4 xi = x[i], xj = x[j];
    sa[tid][0]=xi.x; sa[tid][1]=xi.y; sa[tid][2]=xi.z; sa[tid][3]=xi.w;
    sa[tid][4]=xj.x-xi.x; sa[tid][5]=xj.y-xi.y; sa[tid][6]=xj.z-xi.z; sa[tid][7]=xj.w-xi.w;
  }
  __syncthreads();
  // z1 recompute: 144 edges x 16 chunks of 4
  for(int f=tid; f<144*16; f+=256){
    int e = f>>4, c4 = f&15;
    float4 scv = ((const float4*)sc1)[c4];
    float4 shv = ((const float4*)sh1)[c4];
    float4 y = make_float4(0.f,0.f,0.f,0.f);
    #pragma unroll
    for(int k=0;k<8;k++){
      float a = sa[e][k];
      float4 wv = *(const float4*)(sW1 + k*64 + c4*4);
      y.x=fmaf(a,wv.x,y.x); y.y=fmaf(a,wv.y,y.y);
      y.z=fmaf(a,wv.z,y.z); y.w=fmaf(a,wv.w,y.w);
    }
    float4 z;
    z.x = fmaxf(fmaf(scv.x,y.x,shv.x),0.f);
    z.y = fmaxf(fmaf(scv.y,y.y,shv.y),0.f);
    z.z = fmaxf(fmaf(scv.z,y.z,shv.z),0.f);
    z.w = fmaxf(fmaf(scv.w,y.w,shv.w),0.f);
    *(float4*)(sZ + e*68 + c4*4) = z;
  }
  __syncthreads();
  // GEMM x W2 + BN2 + ReLU + mean9 -> Zb64
  const int cg = tid & 15, nd = tid >> 4;   // node nd (16), cols cg*4
  float acc[9][4];
  #pragma unroll
  for(int s=0;s<9;s++)
    #pragma unroll
    for(int e=0;e<4;e++) acc[s][e]=0.f;
  #pragma unroll 2
  for(int k4=0;k4<16;k4++){
    float4 av[9];
    #pragma unroll
    for(int s=0;s<9;s++) av[s] = *(const float4*)(sZ + (nd*9+s)*68 + k4*4);
    #pragma unroll
    for(int kk=0;kk<4;kk++){
      float4 bv = *(const float4*)(W2 + (size_t)(k4*4+kk)*64 + cg*4);
      #pragma unroll
      for(int s=0;s<9;s++){
        float a = (kk==0)?av[s].x:(kk==1)?av[s].y:(kk==2)?av[s].z:av[s].w;
        acc[s][0]=fmaf(a,bv.x,acc[s][0]);
        acc[s][1]=fmaf(a,bv.y,acc[s][1]);
        acc[s][2]=fmaf(a,bv.z,acc[s][2]);
        acc[s][3]=fmaf(a,bv.w,acc[s][3]);
      }
    }
  }
  float4 scv = ((const float4*)sc2)[cg];
  float4 shv = ((const float4*)sh2)[cg];
  float4 sum = make_float4(0.f,0.f,0.f,0.f);
  #pragma unroll
  for(int s=0;s<9;s++){
    sum.x += fmaxf(fmaf(scv.x,acc[s][0],shv.x),0.f);
    sum.y += fmaxf(fmaf(scv.y,acc[s][1],shv.y),0.f);
    sum.z += fmaxf(fmaf(scv.z,acc[s][2],shv.z),0.f);
    sum.w += fmaxf(fmaf(scv.w,acc[s][3],shv.w),0.f);
  }
  sum.x*=(1.f/9.f); sum.y*=(1.f/9.f); sum.z*=(1.f/9.f); sum.w*=(1.f/9.f);
  *(float4*)(Zb64 + ((size_t)prob*TN + node0+nd)*64 + cg*4) = sum;
}

// Zb64 @ W3[64,16] + b3 -> xlf/xsf; grid (TN/64, 2)
__global__ __launch_bounds__(256) void k_gemm16d(const float* __restrict__ Zb64,
      const float* __restrict__ W, const float* __restrict__ bias,
      float* __restrict__ outl, float* __restrict__ outs){
  __shared__ float sZ[64*68];
  __shared__ float sW[64*16];
  const int prob = blockIdx.y;
  const float* A = Zb64 + (size_t)prob*TN*64;
  float* out = prob ? outs : outl;
  const int tid = threadIdx.x;
  const int row0 = blockIdx.x*64;
  for(int e=tid; e<64*16; e+=256){
    int r = e>>4, c4 = e&15;
    ((float4*)(sZ + r*68))[c4] = ((const float4*)(A + (size_t)(row0+r)*64))[c4];
  }
  ((float4*)sW)[tid] = ((const float4*)W)[tid];
  __syncthreads();
  const int tc = tid & 15, tr = tid >> 4;   // col tc, rows tr+rr*16
  float acc[4] = {0.f,0.f,0.f,0.f};
  #pragma unroll 4
  for(int k4=0;k4<16;k4++){
    float4 av[4];
    #pragma unroll
    for(int rr=0;rr<4;rr++) av[rr] = *(const float4*)(sZ + (tr+rr*16)*68 + k4*4);
    #pragma unroll
    for(int kk=0;kk<4;kk++){
      float bv = sW[(k4*4+kk)*16 + tc];
      #pragma unroll
      for(int rr=0;rr<4;rr++){
        float a = (kk==0)?av[rr].x:(kk==1)?av[rr].y:(kk==2)?av[rr].z:av[rr].w;
        acc[rr]=fmaf(a,bv,acc[rr]);
      }
    }
  }
  #pragma unroll
  for(int rr=0;rr<4;rr++){
    int r = row0 + tr + rr*16;
    out[(size_t)r*16 + tc] = acc[rr] + bias[tc];
  }
}

// ---------------- head MLP 128->64->32->1, block-tiled (32 rows/block) ----------------
__global__ __launch_bounds__(256) void k_head(const float* __restrict__ x1,
    const float* __restrict__ W1, const float* __restrict__ b1,
    const float* __restrict__ W2, const float* __restrict__ b2,
    const float* __restrict__ W3, const float* __restrict__ b3,
    float* __restrict__ h, float* __restrict__ pstat){
  __shared__ float sA[32*132];
  __shared__ float sW1[128*64];
  __shared__ float o1[32*68];
  __shared__ float sW2[64*32];
  __shared__ float o2[32*33];
  __shared__ float sb1[64], sb2[32], sW3v[32];
  __shared__ float rs[32], rq[32];
  const int tid = threadIdx.x;
  const int row0 = blockIdx.x*32;
  for(int e=tid; e<32*32; e+=256){
    int r = e>>5, c4 = e&31;
    ((float4*)(sA + r*132))[c4] = ((const float4*)(x1 + (size_t)(row0+r)*128))[c4];
  }
  for(int e=tid; e<128*64/4; e+=256) ((float4*)sW1)[e] = ((const float4*)W1)[e];
  for(int e=tid; e<64*32/4; e+=256)  ((float4*)sW2)[e] = ((const float4*)W2)[e];
  if(tid < 64) sb1[tid]=b1[tid];
  if(tid < 32){ sb2[tid]=b2[tid]; sW3v[tid]=W3[tid]; }
  __syncthreads();
  const int tc = tid & 15, tr = tid >> 4;
  float a1[2][4];
  #pragma unroll
  for(int rr=0;rr<2;rr++)
    #pragma unroll
    for(int e=0;e<4;e++) a1[rr][e]=0.f;
  for(int k4=0;k4<32;k4++){
    float4 av0 = *(const float4*)(sA + (tr*2  )*132 + k4*4);
    float4 av1 = *(const float4*)(sA + (tr*2+1)*132 + k4*4);
    #pragma unroll
    for(int kk=0;kk<4;kk++){
      float4 bv = *(const float4*)(sW1 + (k4*4+kk)*64 + tc*4);
      float p0 = (kk==0)?av0.x:(kk==1)?av0.y:(kk==2)?av0.z:av0.w;
      float p1 = (kk==0)?av1.x:(kk==1)?av1.y:(kk==2)?av1.z:av1.w;
      a1[0][0]=fmaf(p0,bv.x,a1[0][0]); a1[0][1]=fmaf(p0,bv.y,a1[0][1]);
      a1[0][2]=fmaf(p0,bv.z,a1[0][2]); a1[0][3]=fmaf(p0,bv.w,a1[0][3]);
      a1[1][0]=fmaf(p1,bv.x,a1[1][0]); a1[1][1]=fmaf(p1,bv.y,a1[1][1]);
      a1[1][2]=fmaf(p1,bv.z,a1[1][2]); a1[1][3]=fmaf(p1,bv.w,a1[1][3]);
    }
  }
  #pragma unroll
  for(int rr=0;rr<2;rr++)
    #pragma unroll
    for(int e=0;e<4;e++)
      o1[(tr*2+rr)*68 + tc*4+e] = fmaxf(a1[rr][e]+sb1[tc*4+e], 0.f);
  __syncthreads();
  float a2[2][2] = {{0.f,0.f},{0.f,0.f}};
  for(int k=0;k<64;k++){
    float w0 = sW2[k*32 + tc*2], w1 = sW2[k*32 + tc*2+1];
    float v0 = o1[(tr*2  )*68 + k];
    float v1 = o1[(tr*2+1)*68 + k];
    a2[0][0]=fmaf(v0,w0,a2[0][0]); a2[0][1]=fmaf(v0,w1,a2[0][1]);
    a2[1][0]=fmaf(v1,w0,a2[1][0]); a2[1][1]=fmaf(v1,w1,a2[1][1]);
  }
  #pragma unroll
  for(int rr=0;rr<2;rr++)
    #pragma unroll
    for(int cc=0;cc<2;cc++)
      o2[(tr*2+rr)*33 + tc*2+cc] = fmaxf(a2[rr][cc]+sb2[tc*2+cc], 0.f);
  __syncthreads();
  if(tid < 32){
    float hv = b3[0];
    #pragma unroll
    for(int k=0;k<32;k++) hv = fmaf(o2[tid*33+k], sW3v[k], hv);
    h[row0+tid]=hv;
    rs[tid]=hv; rq[tid]=hv*hv;
  }
  __syncthreads();
  if(tid==0){
    float S=0.f, Q=0.f;
    #pragma unroll
    for(int i=0;i<32;i++){ S+=rs[i]; Q+=rq[i]; }
    pstat[blockIdx.x*2]=S; pstat[blockIdx.x*2+1]=Q;
  }
}

__global__ __launch_bounds__(256) void k_fin_h(const float* __restrict__ pstat,
      float* __restrict__ hpar){
  __shared__ double sS[256], sQ[256];
  int t = threadIdx.x;
  sS[t] = (double)pstat[2*t]; sQ[t] = (double)pstat[2*t+1];
  __syncthreads();
  for(int s=128;s>0;s>>=1){
    if(t<s){ sS[t]+=sS[t+s]; sQ[t]+=sQ[t+s]; }
    __syncthreads();
  }
  if(t==0){
    double mu = sS[0]/8192.0;
    double var = (sQ[0] - 8192.0*mu*mu)/8191.0;   // ddof=1
    double sd = (var > 0) ? sqrt(var) : 0.0;
    hpar[0]=(float)mu;
    hpar[1]=(float)(1.0/(sd + 1e-5));
  }
}

__global__ __launch_bounds__(256) void k_gate(const float* __restrict__ h,
      const float* __restrict__ hpar, const float4* __restrict__ x,
      float4* __restrict__ xl, float4* __restrict__ xs){
  int i = blockIdx.x*256 + threadIdx.x;
  float z = (h[i]-hpar[0])*hpar[1];
  float o = 1.0f/(1.0f+expf(-z));
  float om = 1.0f - o;
  float4 v = x[i];
  xl[i] = make_float4(o*v.x, o*v.y, o*v.z, o*v.w);
  xs[i] = make_float4(om*v.x, om*v.y, om*v.z, om*v.w);
}

// ---------------- final: per-graph max pool (16ch x 2) + linear [32]->1 ----------------
__global__ __launch_bounds__(256) void k_final(const float* __restrict__ xlf,
      const float* __restrict__ xsf, const float* __restrict__ W,
      const float* __restrict__ b, float* __restrict__ out){
  __shared__ float red[32][8];
  int g = blockIdx.x;
  int c = threadIdx.x & 31;
  int chunk = threadIdx.x >> 5;
  const float* src = (c < 16) ? xlf : xsf;
  int ch = (c < 16) ? c : c-16;
  float m = -1e30f;
  for(int n=chunk*128; n<chunk*128+128; n++)
    m = fmaxf(m, src[((size_t)g*1024+n)*16 + ch]);
  red[c][chunk]=m;
  __syncthreads();
  if(threadIdx.x < 32){
    float mm = red[threadIdx.x][0];
    #pragma unroll
    for(int p=1;p<8;p++) mm = fmaxf(mm, red[threadIdx.x][p]);
    red[threadIdx.x][0]=mm;
  }
  __syncthreads();
  if(threadIdx.x == 0){
    float acc = b[0];
    for(int cc=0;cc<32;cc++) acc = fmaf(red[cc][0], W[cc], acc);
    out[g]=acc;
  }
}

// ---------------- launch ----------------
extern "C" void kernel_launch(void* const* d_in, const int* in_sizes, int n_in,
                              void* d_out, int out_size, void* d_ws, size_t ws_size,
                              hipStream_t stream){
  const float* x    =(const float*)d_in[0];
  const float* c1W1 =(const float*)d_in[1];
  const float* c1g1 =(const float*)d_in[3];
  const float* c1be1=(const float*)d_in[4];
  const float* c1W2 =(const float*)d_in[5];
  const float* c1g2 =(const float*)d_in[7];
  const float* c1be2=(const float*)d_in[8];
  const float* c1W3 =(const float*)d_in[9];
  const float* c1b3 =(const float*)d_in[10];
  const float* c3W1 =(const float*)d_in[11];
  const float* c3g1 =(const float*)d_in[13];
  const float* c3be1=(const float*)d_in[14];
  const float* c3W2 =(const float*)d_in[15];
  const float* c3g2 =(const float*)d_in[17];
  const float* c3be2=(const float*)d_in[18];
  const float* c3W3 =(const float*)d_in[19];
  const float* c3b3 =(const float*)d_in[20];
  const float* hW1  =(const float*)d_in[21];
  const float* hb1  =(const float*)d_in[22];
  const float* hW2  =(const float*)d_in[23];
  const float* hb2  =(const float*)d_in[24];
  const float* hW3  =(const float*)d_in[25];
  const float* hb3  =(const float*)d_in[26];
  const float* l2W  =(const float*)d_in[27];
  const float* l2b  =(const float*)d_in[28];
  (void)in_sizes; (void)n_in; (void)out_size; (void)ws_size;

  char* wsb=(char*)d_ws;
  size_t off=0;
  auto alloc=[&](size_t bytes)->char*{
    char* p = wsb + off;
    off = (off + bytes + 255) & ~(size_t)255;
    return p;
  };
  float* Y    =(float*)alloc((size_t)TK*128*4);   // overlay: lists, mpartM (conv1+conv3)
  float* x1   =(float*)alloc((size_t)TN*128*4);
  float* Zb   =(float*)alloc((size_t)TN*128*4);   // conv1 Zb / conv3 Zb64 (dual)
  int*   idx1 =(int*)  alloc((size_t)TK*4);
  int*   idxl =(int*)  alloc((size_t)TK*4);
  int*   idxs =(int*)  alloc((size_t)TK*4);
  float* pd   =(float*)alloc((size_t)2*TN*72*4);
  float* h    =(float*)alloc((size_t)TN*4);
  float* xl   =(float*)alloc((size_t)TN*16);
  float* xs   =(float*)alloc((size_t)TN*16);
  float* xlf  =(float*)alloc((size_t)TN*16*4);
  float* xsf  =(float*)alloc((size_t)TN*16*4);
  float* pstat=(float*)alloc((size_t)512*4);
  double* Md  =(double*)alloc((size_t)16512*8);
  double* Mdd =(double*)alloc((size_t)8320*8);
  float* mp44 =(float*)alloc((size_t)288*44*4);
  float* mp44d=(float*)alloc((size_t)2*288*44*4);
  float* tl   =(float*)alloc((size_t)TN*4);
  float* tg   =(float*)alloc((size_t)2*TN*4);
  unsigned char* cnt8l=(unsigned char*)alloc((size_t)TN*8);
  unsigned char* cnt8g=(unsigned char*)alloc((size_t)2*TN*NCHG);
  float* bnp  =(float*)alloc(1024*4);
  float* hpar =(float*)alloc(64);

  float* sc1=bnp,      *sh1=bnp+128, *sc2=bnp+256, *sh2=bnp+384;
  float* scA=bnp+512,  *shA=bnp+640, *scB=bnp+768, *shB=bnp+896;  // conv3: [prob][64]
  unsigned short* listl=(unsigned short*)Y;   // Y region dead during kNN phases
  unsigned short* listg=(unsigned short*)Y;
  float* mpartM = Y;                          // conv1 moments overlay (512*16512*4 = 33.8MB <= Y)
  float* mpartMd = Y;                         // conv3 moments overlay (disjoint in time)

  // ---- conv1 kNN (per-graph) ----
  k_part_local  <<<256,256,0,stream>>>((const float4*)x, pd);
  k_thresh_local<<<32, 256,0,stream>>>(pd, tl);
  k_collect_local<<<256,256,0,stream>>>((const float4*)x, tl, cnt8l, listl);
  k_refine_local<<<TN/32,256,0,stream>>>((const float4*)x, cnt8l, listl, idx1);
  // ---- conv1 (moment-based, no Y materialization) ----
  k_mom8<<<288,256,0,stream>>>((const float4*)x, idx1, mp44);
  k_bn1q<<<1,128,0,stream>>>(mp44, c1W1, c1g1, c1be1, sc1, sh1);
  k_syrk128<<<512,256,0,stream>>>((const float4*)x, idx1, c1W1, sc1, sh1, mpartM);
  k_redM<<<65,256,0,stream>>>(mpartM, Md);
  k_bn2q<<<128,128,0,stream>>>(Md, c1W2, c1g2, c1be2, sc2, sh2);
  k_midagg<<<1024,256,0,stream>>>((const float4*)x, idx1, c1W1, sc1, sh1, c1W2, sc2, sh2, Zb);
  k_gemm128<<<TN/32,256,0,stream>>>(Zb, c1W3, c1b3, x1);
  // ---- head + gate ----
  k_head<<<TN/32,256,0,stream>>>(x1,hW1,hb1,hW2,hb2,hW3,hb3,h,pstat);
  k_fin_h<<<1,256,0,stream>>>(pstat,hpar);
  k_gate<<<32,256,0,stream>>>(h,hpar,(const float4*)x,(float4*)xl,(float4*)xs);
  // ---- global kNN for xl & xs ----
  k_part_sub   <<<dim3(256,2),256,0,stream>>>((const float4*)xl,(const float4*)xs,pd);
  k_thresh_sub <<<64,256,0,stream>>>(pd,tg);
  k_collect_glob<<<dim3(512,2),256,0,stream>>>((const float4*)xl,(const float4*)xs,tg,cnt8g,listg);
  k_refine_glob<<<2*TN/32,256,0,stream>>>((const float4*)xl,(const float4*)xs,cnt8g,listg,idxl,idxs);
  // ---- conv3 on xl & xs (moment-based, dual) ----
  k_mom8d<<<dim3(288,2),256,0,stream>>>((const float4*)xl,(const float4*)xs,idxl,idxs,mp44d);
  k_bn1qd<<<1,128,0,stream>>>(mp44d, c3W1, c3g1, c3be1, scA, shA);
  k_syrk64d<<<dim3(288,2),256,0,stream>>>((const float4*)xl,(const float4*)xs,idxl,idxs,c3W1,scA,shA,mpartMd);
  k_redMd<<<33,256,0,stream>>>(mpartMd, Mdd);
  k_bn2qd<<<dim3(64,2),64,0,stream>>>(Mdd, c3W2, c3g2, c3be2, scB, shB);
  k_midagg64d<<<dim3(512,2),256,0,stream>>>((const float4*)xl,(const float4*)xs,idxl,idxs,
      c3W1, scA, shA, c3W2, scB, shB, Zb);
  k_gemm16d<<<dim3(TN/64,2),256,0,stream>>>(Zb, c3W3, c3b3, xlf, xsf);
  // ---- final pooling + linear ----
  k_final<<<8,256,0,stream>>>(xlf,xsf,l2W,l2b,(float*)d_out);
}

// Round 16
// 425.380 us; speedup vs baseline: 1.5926x; 1.0112x over previous
//
#include <hip/hip_runtime.h>
#include <math.h>

#define TN 8192          // total nodes (B*N)
#define KNN 9
#define NPG 1024         // nodes per graph
#define TK (TN*KNN)      // 73728 edge rows
#define CPCL 12          // cap per (node,chunk), local (8 chunks of 128)
#define NCHG 32          // global chunks (of 256 candidates)
#define CPCG 16          // cap per (node,chunk), global
#define NSYB 768         // syrk128 blocks

// ---------------- helpers ----------------
__device__ __forceinline__ float sqnorm(float4 v){
  return fmaf(v.x,v.x,fmaf(v.y,v.y,fmaf(v.z,v.z,v.w*v.w)));
}
__device__ __forceinline__ float pairdist(float4 a, float sqa, float4 b, float sqb){
  float dot = fmaf(a.x,b.x,fmaf(a.y,b.y,fmaf(a.z,b.z,a.w*b.w)));
  return sqa + sqb - 2.0f*dot;
}
__device__ __forceinline__ void chain9(float (&bd)[9], float d){
  float t=d;
  #pragma unroll
  for(int p=0;p<9;p++){
    float lo=fminf(bd[p],t);
    t=fmaxf(bd[p],t);
    bd[p]=lo;
  }
}
__device__ __forceinline__ void insert9(float (&bd)[9], int (&bi)[9], float d, int id){
  if(d < bd[8]){
    float td=d; int ti=id;
    #pragma unroll
    for(int p=0;p<9;p++){
      bool sw = (td < bd[p]);
      float nbd = sw ? td : bd[p];
      int   nbi = sw ? ti : bi[p];
      float ntd = sw ? bd[p] : td;
      int   nti = sw ? bi[p] : ti;
      bd[p]=nbd; bi[p]=nbi; td=ntd; ti=nti;
    }
  }
}

// ---------------- kNN: local (per-graph) ----------------
__global__ __launch_bounds__(256) void k_part_local(const float4* __restrict__ x, float* __restrict__ pd){
  __shared__ float4 sx[128]; __shared__ float ssq[128];
  int nb = blockIdx.x >> 3, chunk = blockIdx.x & 7;
  int g = nb >> 2;
  int cbase = g*NPG + chunk*128;
  if(threadIdx.x < 128){
    float4 v = x[cbase + threadIdx.x];
    sx[threadIdx.x]=v; ssq[threadIdx.x]=sqnorm(v);
  }
  __syncthreads();
  int node = nb*256 + threadIdx.x;
  float4 xi = x[node]; float sqi = sqnorm(xi);
  float bdA[9], bdB[9];
  #pragma unroll
  for(int q=0;q<9;q++){bdA[q]=1e30f;bdB[q]=1e30f;}
  for(int j=0;j<128;j+=2){
    chain9(bdA, pairdist(xi,sqi,sx[j],ssq[j]));
    chain9(bdB, pairdist(xi,sqi,sx[j+1],ssq[j+1]));
  }
  #pragma unroll
  for(int q=0;q<9;q++) chain9(bdA, bdB[q]);
  #pragma unroll
  for(int q=0;q<9;q++) pd[(size_t)(chunk*9+q)*TN + node]=bdA[q];
}

__global__ __launch_bounds__(256) void k_thresh_local(const float* __restrict__ pd,
      float* __restrict__ tl){
  int node = blockIdx.x*256 + threadIdx.x;
  float bd[9];
  #pragma unroll
  for(int q=0;q<9;q++) bd[q]=1e30f;
  for(int m=0;m<72;m++) chain9(bd, pd[(size_t)m*TN + node]);
  float t = bd[8];
  tl[node] = t + fabsf(t)*1e-5f + 1e-12f;
}

__global__ __launch_bounds__(256) void k_collect_local(const float4* __restrict__ x,
      const float* __restrict__ tl, unsigned char* __restrict__ cnt8,
      unsigned short* __restrict__ list){
  __shared__ float4 sx[128]; __shared__ float ssq[128];
  int nb = blockIdx.x >> 3, chunk = blockIdx.x & 7;
  int g = nb >> 2;
  int cbase = g*NPG + chunk*128;
  if(threadIdx.x < 128){
    float4 v = x[cbase + threadIdx.x];
    sx[threadIdx.x]=v; ssq[threadIdx.x]=sqnorm(v);
  }
  __syncthreads();
  int node = nb*256 + threadIdx.x;
  float4 xi = x[node];
  float m2x=-2.0f*xi.x, m2y=-2.0f*xi.y, m2z=-2.0f*xi.z, m2w=-2.0f*xi.w;
  float tadj = tl[node] - sqnorm(xi);
  int cnt = 0;
  unsigned short* lst = list + ((size_t)node*8 + chunk)*CPCL;
  for(int j=0;j<128;j+=4){
    float4 v0=sx[j], v1=sx[j+1], v2=sx[j+2], v3=sx[j+3];
    float q0=ssq[j], q1=ssq[j+1], q2=ssq[j+2], q3=ssq[j+3];
    float s0=fmaf(v0.x,m2x,fmaf(v0.y,m2y,fmaf(v0.z,m2z,fmaf(v0.w,m2w,q0))));
    float s1=fmaf(v1.x,m2x,fmaf(v1.y,m2y,fmaf(v1.z,m2z,fmaf(v1.w,m2w,q1))));
    float s2=fmaf(v2.x,m2x,fmaf(v2.y,m2y,fmaf(v2.z,m2z,fmaf(v2.w,m2w,q2))));
    float s3=fmaf(v3.x,m2x,fmaf(v3.y,m2y,fmaf(v3.z,m2z,fmaf(v3.w,m2w,q3))));
    if(s0<=tadj){ if(cnt<CPCL) lst[cnt]=(unsigned short)(cbase+j  ); cnt++; }
    if(s1<=tadj){ if(cnt<CPCL) lst[cnt]=(unsigned short)(cbase+j+1); cnt++; }
    if(s2<=tadj){ if(cnt<CPCL) lst[cnt]=(unsigned short)(cbase+j+2); cnt++; }
    if(s3<=tadj){ if(cnt<CPCL) lst[cnt]=(unsigned short)(cbase+j+3); cnt++; }
  }
  cnt8[(size_t)node*8 + chunk] = (unsigned char)(cnt > 255 ? 255 : cnt);
}

// 8 threads per node: sub handles 1 chunk; LDS merge of 8 partial top-9s
__global__ __launch_bounds__(256) void k_refine_local(const float4* __restrict__ x,
      const unsigned char* __restrict__ cnt8, const unsigned short* __restrict__ list,
      int* __restrict__ out){
  __shared__ float sval[32][73];
  __shared__ int   sidx[32][73];
  __shared__ int   sovf[32];
  int slot = threadIdx.x >> 3, sub = threadIdx.x & 7;
  int node = blockIdx.x*32 + slot;
  if(sub==0) sovf[slot]=0;
  __syncthreads();
  float4 xi = x[node]; float sqi = sqnorm(xi);
  float bd[9]; int bi[9];
  #pragma unroll
  for(int q=0;q<9;q++){bd[q]=1e30f; bi[q]=node;}
  int ch = sub;
  int c = cnt8[(size_t)node*8 + ch];
  if(c > CPCL) sovf[slot]=1;
  int n = c < CPCL ? c : CPCL;
  const unsigned short* lst = list + ((size_t)node*8 + ch)*CPCL;
  for(int m=0;m<n;m++){
    int j = lst[m]; float4 v = x[j];
    insert9(bd,bi, pairdist(xi,sqi,v,sqnorm(v)), j);
  }
  #pragma unroll
  for(int q=0;q<9;q++){ sval[slot][sub*9+q]=bd[q]; sidx[slot][sub*9+q]=bi[q]; }
  __syncthreads();
  if(sub==0){
    for(int m=9;m<72;m++) insert9(bd,bi, sval[slot][m], sidx[slot][m]);
    if(sovf[slot]){
      #pragma unroll
      for(int q=0;q<9;q++){bd[q]=1e30f; bi[q]=node;}
      int gbase = node & ~(NPG-1);
      for(int j=gbase;j<gbase+NPG;j++){
        float4 v = x[j];
        insert9(bd,bi, pairdist(xi,sqi,v,sqnorm(v)), j);
      }
    }
    #pragma unroll
    for(int q=0;q<9;q++) out[(size_t)node*9+q]=bi[q];
  }
}

// ---------------- kNN: global (two problems: xl, xs) ----------------
__global__ __launch_bounds__(256) void k_part_sub(const float4* __restrict__ xa,
      const float4* __restrict__ xb, float* __restrict__ pd){
  const float4* x = blockIdx.y ? xb : xa;
  __shared__ float4 sx[256]; __shared__ float ssq[256];
  int nb = blockIdx.x >> 3, chunk = blockIdx.x & 7;
  {
    int j = (chunk*256 + threadIdx.x)*4;
    float4 v = x[j];
    sx[threadIdx.x]=v; ssq[threadIdx.x]=sqnorm(v);
  }
  __syncthreads();
  int node = nb*256 + threadIdx.x;
  float4 xi = x[node]; float sqi = sqnorm(xi);
  float bdA[9], bdB[9];
  #pragma unroll
  for(int q=0;q<9;q++){bdA[q]=1e30f;bdB[q]=1e30f;}
  for(int j=0;j<256;j+=2){
    chain9(bdA, pairdist(xi,sqi,sx[j],ssq[j]));
    chain9(bdB, pairdist(xi,sqi,sx[j+1],ssq[j+1]));
  }
  #pragma unroll
  for(int q=0;q<9;q++) chain9(bdA, bdB[q]);
  int pn = blockIdx.y*TN + node;
  #pragma unroll
  for(int q=0;q<9;q++) pd[(size_t)(chunk*9+q)*2*TN + pn]=bdA[q];
}

__global__ __launch_bounds__(256) void k_thresh_sub(const float* __restrict__ pd,
      float* __restrict__ tg){
  int pn = blockIdx.x*256 + threadIdx.x;   // < 2*TN
  float bd[9];
  #pragma unroll
  for(int q=0;q<9;q++) bd[q]=1e30f;
  for(int m=0;m<72;m++) chain9(bd, pd[(size_t)m*2*TN + pn]);
  float t = bd[8];
  tg[pn] = t + fabsf(t)*1e-5f + 1e-12f;
}

// 2 nodes/thread, 32 chunks of 256 cands: grid (16*32, 2) = 1024 blocks
__global__ __launch_bounds__(256) void k_collect_glob(const float4* __restrict__ xa,
      const float4* __restrict__ xb, const float* __restrict__ tg,
      unsigned char* __restrict__ cnt8, unsigned short* __restrict__ list){
  const float4* x = blockIdx.y ? xb : xa;
  __shared__ float4 sx[256];
  __shared__ float4 ssq4[64];
  int nb = blockIdx.x >> 5, chunk = blockIdx.x & 31;
  int cbase = chunk*256;
  {
    float4 v = x[cbase+threadIdx.x];
    sx[threadIdx.x]=v; ((float*)ssq4)[threadIdx.x]=sqnorm(v);
  }
  __syncthreads();
  int node0 = nb*512 + threadIdx.x;
  int node1 = node0 + 256;
  int pn0 = blockIdx.y*TN + node0;
  int pn1 = pn0 + 256;
  float4 xi0 = x[node0], xi1 = x[node1];
  float a0x=-2.0f*xi0.x, a0y=-2.0f*xi0.y, a0z=-2.0f*xi0.z, a0w=-2.0f*xi0.w;
  float a1x=-2.0f*xi1.x, a1y=-2.0f*xi1.y, a1z=-2.0f*xi1.z, a1w=-2.0f*xi1.w;
  float t0 = tg[pn0] - sqnorm(xi0);
  float t1 = tg[pn1] - sqnorm(xi1);
  int c0 = 0, c1 = 0;
  unsigned short* l0 = list + ((size_t)pn0*NCHG + chunk)*CPCG;
  unsigned short* l1 = list + ((size_t)pn1*NCHG + chunk)*CPCG;
  for(int j=0;j<256;j+=4){
    float4 v0=sx[j], v1=sx[j+1], v2=sx[j+2], v3=sx[j+3];
    float4 qv = ssq4[j>>2];
    float s00=fmaf(v0.x,a0x,fmaf(v0.y,a0y,fmaf(v0.z,a0z,fmaf(v0.w,a0w,qv.x))));
    float s01=fmaf(v1.x,a0x,fmaf(v1.y,a0y,fmaf(v1.z,a0z,fmaf(v1.w,a0w,qv.y))));
    float s02=fmaf(v2.x,a0x,fmaf(v2.y,a0y,fmaf(v2.z,a0z,fmaf(v2.w,a0w,qv.z))));
    float s03=fmaf(v3.x,a0x,fmaf(v3.y,a0y,fmaf(v3.z,a0z,fmaf(v3.w,a0w,qv.w))));
    float s10=fmaf(v0.x,a1x,fmaf(v0.y,a1y,fmaf(v0.z,a1z,fmaf(v0.w,a1w,qv.x))));
    float s11=fmaf(v1.x,a1x,fmaf(v1.y,a1y,fmaf(v1.z,a1z,fmaf(v1.w,a1w,qv.y))));
    float s12=fmaf(v2.x,a1x,fmaf(v2.y,a1y,fmaf(v2.z,a1z,fmaf(v2.w,a1w,qv.z))));
    float s13=fmaf(v3.x,a1x,fmaf(v3.y,a1y,fmaf(v3.z,a1z,fmaf(v3.w,a1w,qv.w))));
    if(s00<=t0){ if(c0<CPCG) l0[c0]=(unsigned short)(cbase+j  ); c0++; }
    if(s01<=t0){ if(c0<CPCG) l0[c0]=(unsigned short)(cbase+j+1); c0++; }
    if(s02<=t0){ if(c0<CPCG) l0[c0]=(unsigned short)(cbase+j+2); c0++; }
    if(s03<=t0){ if(c0<CPCG) l0[c0]=(unsigned short)(cbase+j+3); c0++; }
    if(s10<=t1){ if(c1<CPCG) l1[c1]=(unsigned short)(cbase+j  ); c1++; }
    if(s11<=t1){ if(c1<CPCG) l1[c1]=(unsigned short)(cbase+j+1); c1++; }
    if(s12<=t1){ if(c1<CPCG) l1[c1]=(unsigned short)(cbase+j+2); c1++; }
    if(s13<=t1){ if(c1<CPCG) l1[c1]=(unsigned short)(cbase+j+3); c1++; }
  }
  cnt8[(size_t)pn0*NCHG + chunk] = (unsigned char)(c0 > 255 ? 255 : c0);
  cnt8[(size_t)pn1*NCHG + chunk] = (unsigned char)(c1 > 255 ? 255 : c1);
}

// 8 threads per node: sub handles 4 chunks; LDS merge of 8 partial top-9s
__global__ __launch_bounds__(256) void k_refine_glob(const float4* __restrict__ xa,
      const float4* __restrict__ xb, const unsigned char* __restrict__ cnt8,
      const unsigned short* __restrict__ list, int* __restrict__ outl, int* __restrict__ outs){
  __shared__ float sval[32][73];
  __shared__ int   sidx[32][73];
  __shared__ int   sovf[32];
  int slot = threadIdx.x >> 3, sub = threadIdx.x & 7;
  int pn = blockIdx.x*32 + slot;          // < 2*TN; grid = 512
  int prob = blockIdx.x >> 8;             // uniform per block
  int node = pn & (TN-1);
  const float4* x = prob ? xb : xa;
  if(sub==0) sovf[slot]=0;
  __syncthreads();
  float4 xi = x[node]; float sqi = sqnorm(xi);
  float bd[9]; int bi[9];
  #pragma unroll
  for(int q=0;q<9;q++){bd[q]=1e30f; bi[q]=node;}
  bool ovf=false;
  for(int ch=sub*4; ch<sub*4+4; ch++){
    int c = cnt8[(size_t)pn*NCHG + ch];
    if(c > CPCG) ovf=true;
    int n = c < CPCG ? c : CPCG;
    const unsigned short* lst = list + ((size_t)pn*NCHG + ch)*CPCG;
    for(int m=0;m<n;m++){
      int j = lst[m]; float4 v = x[j];
      insert9(bd,bi, pairdist(xi,sqi,v,sqnorm(v)), j);
    }
  }
  if(ovf) sovf[slot]=1;
  #pragma unroll
  for(int q=0;q<9;q++){ sval[slot][sub*9+q]=bd[q]; sidx[slot][sub*9+q]=bi[q]; }
  __syncthreads();
  if(sub==0){
    for(int m=9;m<72;m++) insert9(bd,bi, sval[slot][m], sidx[slot][m]);
    if(sovf[slot]){
      #pragma unroll
      for(int q=0;q<9;q++){bd[q]=1e30f; bi[q]=node;}
      for(int j=0;j<TN;j++){
        float4 v = x[j];
        insert9(bd,bi, pairdist(xi,sqi,v,sqnorm(v)), j);
      }
    }
    int* o = prob ? outs : outl;
    #pragma unroll
    for(int q=0;q<9;q++) o[(size_t)node*9+q]=bi[q];
  }
}

// ---------------- conv1: moment-based BN, fused recompute (no Y materialization) ----------------
__global__ __launch_bounds__(256) void k_mom8(const float4* __restrict__ x,
      const int* __restrict__ idx, float* __restrict__ mpart){
  __shared__ float sa[256][9];
  int t = threadIdx.x;
  int e = blockIdx.x*256 + t;
  int i = e/KNN; int j = idx[e];
  float4 xi = x[i], xj = x[j];
  sa[t][0]=xi.x; sa[t][1]=xi.y; sa[t][2]=xi.z; sa[t][3]=xi.w;
  sa[t][4]=xj.x-xi.x; sa[t][5]=xj.y-xi.y; sa[t][6]=xj.z-xi.z; sa[t][7]=xj.w-xi.w;
  __syncthreads();
  if(t < 44){
    float s=0.f;
    if(t<8){
      for(int e2=0;e2<256;e2++) s += sa[e2][t];
    } else {
      int f=t-8, p=0, q=0, acc=0;
      for(p=0;p<8;p++){ int cnt=8-p; if(f<acc+cnt){ q=p+(f-acc); break;} acc+=cnt; }
      for(int e2=0;e2<256;e2++) s += sa[e2][p]*sa[e2][q];
    }
    mpart[blockIdx.x*44+t]=s;
  }
}

__global__ void k_bn1q(const float* __restrict__ mpart, const float* __restrict__ W1,
      const float* __restrict__ g, const float* __restrict__ be,
      float* __restrict__ scale, float* __restrict__ shift){
  __shared__ double mom[44];
  int t = threadIdx.x;   // 128
  if(t<44){ double s=0; for(int b=0;b<288;b++) s+=(double)mpart[b*44+t]; mom[t]=s; }
  __syncthreads();
  double m[8], w[8];
  #pragma unroll
  for(int p=0;p<8;p++){ m[p]=mom[p]/(double)TK; w[p]=(double)W1[p*128+t]; }
  double q=0.0; int f=8;
  for(int p=0;p<8;p++)
    for(int qq=p;qq<8;qq++){
      double cov = mom[f]/(double)TK - m[p]*m[qq];
      q += (p==qq?1.0:2.0)*w[p]*w[qq]*cov;
      f++;
    }
  if(q<0) q=0;
  double sc = (double)g[t]/sqrt(q+1e-5);
  double mu=0; for(int p=0;p<8;p++) mu += m[p]*w[p];
  scale[t]=(float)sc;
  shift[t]=(float)((double)be[t] - mu*sc);
}

// SYRK v5: 768 blocks x 96 edges (2 passes of 48); aligned stride-132 layout
__global__ __launch_bounds__(256) void k_syrk128(const float4* __restrict__ x,
      const int* __restrict__ idx, const float* __restrict__ W1,
      const float* __restrict__ sc1, const float* __restrict__ sh1,
      float* __restrict__ mpartM){
  __shared__ float sa[48][9];
  __shared__ float sW1[8*128];
  __shared__ float sZ[48*132];
  __shared__ float ssum[128];
  const int tid = threadIdx.x;
  ((float4*)sW1)[tid] = ((const float4*)W1)[tid];
  if(tid<128) ssum[tid]=0.f;
  const int zc4 = tid & 31, ze0 = tid >> 5;     // z-compute mapping
  const int i0 = (tid>>4)*8, j0 = (tid&15)*8;   // syrk mapping
  float acc[8][8];
  #pragma unroll
  for(int a=0;a<8;a++)
    #pragma unroll
    for(int b=0;b<8;b++) acc[a][b]=0.f;
  float ls[4]={0,0,0,0};
  float4 scv = ((const float4*)sc1)[zc4];
  float4 shv = ((const float4*)sh1)[zc4];
  for(int pass=0;pass<2;pass++){
    __syncthreads();
    if(tid<48){
      int e = blockIdx.x*96 + pass*48 + tid;
      int i = e/KNN; int j = idx[e];
      float4 xi = x[i], xj = x[j];
      sa[tid][0]=xi.x; sa[tid][1]=xi.y; sa[tid][2]=xi.z; sa[tid][3]=xi.w;
      sa[tid][4]=xj.x-xi.x; sa[tid][5]=xj.y-xi.y; sa[tid][6]=xj.z-xi.z; sa[tid][7]=xj.w-xi.w;
    }
    __syncthreads();
    for(int e=ze0; e<48; e+=8){
      float4 y = make_float4(0.f,0.f,0.f,0.f);
      #pragma unroll
      for(int k=0;k<8;k++){
        float a = sa[e][k];
        float4 wv = *(const float4*)(sW1 + k*128 + zc4*4);
        y.x=fmaf(a,wv.x,y.x); y.y=fmaf(a,wv.y,y.y);
        y.z=fmaf(a,wv.z,y.z); y.w=fmaf(a,wv.w,y.w);
      }
      float4 z;
      z.x = fmaxf(fmaf(scv.x,y.x,shv.x),0.f);
      z.y = fmaxf(fmaf(scv.y,y.y,shv.y),0.f);
      z.z = fmaxf(fmaf(scv.z,y.z,shv.z),0.f);
      z.w = fmaxf(fmaf(scv.w,y.w,shv.w),0.f);
      *(float4*)(sZ + e*132 + zc4*4) = z;
      ls[0]+=z.x; ls[1]+=z.y; ls[2]+=z.z; ls[3]+=z.w;
    }
    __syncthreads();
    #pragma unroll 2
    for(int e=0;e<48;e++){
      const float* rz = sZ + e*132;
      float4 zi0 = *(const float4*)(rz + i0);
      float4 zi1 = *(const float4*)(rz + i0 + 4);
      float4 zj0 = *(const float4*)(rz + j0);
      float4 zj1 = *(const float4*)(rz + j0 + 4);
      float zi[8] = {zi0.x,zi0.y,zi0.z,zi0.w,zi1.x,zi1.y,zi1.z,zi1.w};
      float zj[8] = {zj0.x,zj0.y,zj0.z,zj0.w,zj1.x,zj1.y,zj1.z,zj1.w};
      #pragma unroll
      for(int a=0;a<8;a++)
        #pragma unroll
        for(int b=0;b<8;b++) acc[a][b]=fmaf(zi[a],zj[b],acc[a][b]);
    }
  }
  #pragma unroll
  for(int c=0;c<4;c++) atomicAdd(&ssum[zc4*4+c], ls[c]);
  float* mp = mpartM + (size_t)blockIdx.x*16512;
  #pragma unroll
  for(int a=0;a<8;a++){
    *(float4*)(mp + (i0+a)*128 + j0)     = make_float4(acc[a][0],acc[a][1],acc[a][2],acc[a][3]);
    *(float4*)(mp + (i0+a)*128 + j0 + 4) = make_float4(acc[a][4],acc[a][5],acc[a][6],acc[a][7]);
  }
  __syncthreads();
  if(tid<128) mp[16384+tid] = ssum[tid];
}

// 2-stage reduce of 768 partials: stage A grid (65,8) sums 96 each; stage B sums 8
__global__ __launch_bounds__(256) void k_redA(const float* __restrict__ mpartM,
      double* __restrict__ pp8){
  int ch = blockIdx.x*256 + threadIdx.x;
  if(ch >= 16512) return;
  int y = blockIdx.y;
  double s=0;
  for(int b=y*96;b<y*96+96;b++) s += (double)mpartM[(size_t)b*16512 + ch];
  pp8[(size_t)y*16512 + ch]=s;
}

__global__ __launch_bounds__(256) void k_redB(const double* __restrict__ pp8,
      double* __restrict__ Md){
  int ch = blockIdx.x*256 + threadIdx.x;
  if(ch >= 16512) return;
  double s=0;
  #pragma unroll
  for(int y=0;y<8;y++) s += pp8[(size_t)y*16512 + ch];
  Md[ch]=s;
}

__global__ void k_bn2q(const double* __restrict__ Md, const float* __restrict__ W2,
      const float* __restrict__ g, const float* __restrict__ be,
      float* __restrict__ scale, float* __restrict__ shift){
  __shared__ double redq[128], redt[128];
  __shared__ float sw[128];
  int c = blockIdx.x, t = threadIdx.x;   // 128 threads
  sw[t] = W2[t*128+c];
  __syncthreads();
  double zb = Md[16384+t]/(double)TK;
  double inner=0;
  for(int j=0;j<128;j++) inner += Md[t*128+j]*(double)sw[j];
  redq[t] = (double)sw[t]*(inner/(double)TK);
  redt[t] = (double)sw[t]*zb;
  __syncthreads();
  for(int s=64;s>0;s>>=1){
    if(t<s){ redq[t]+=redq[t+s]; redt[t]+=redt[t+s]; }
    __syncthreads();
  }
  if(t==0){
    double var = redq[0] - redt[0]*redt[0];
    if(var<0) var=0;
    double sc = (double)g[c]/sqrt(var+1e-5);
    scale[c]=(float)sc;
    shift[c]=(float)((double)be[c] - redt[0]*sc);
  }
}

// fused: gather A (8 nodes, 72 edges) -> z1 recompute -> GEMM x W2 (global, broadcast)
// -> BN2+ReLU -> mean over 9 -> Zb[node][128]
__global__ __launch_bounds__(256) void k_midagg(const float4* __restrict__ x,
      const int* __restrict__ idx, const float* __restrict__ W1,
      const float* __restrict__ sc1, const float* __restrict__ sh1,
      const float* __restrict__ W2, const float* __restrict__ sc2,
      const float* __restrict__ sh2, float* __restrict__ Zb){
  __shared__ float sa[72][9];
  __shared__ float sW1[8*128];
  __shared__ float sZ[72*132];
  const int tid = threadIdx.x;
  const int node0 = blockIdx.x*8;
  if(tid<256) ((float4*)sW1)[tid] = ((const float4*)W1)[tid];
  if(tid<72){
    int e = blockIdx.x*72 + tid;
    int i = e/KNN; int j = idx[e];
    float4 xi = x[i], xj = x[j];
    sa[tid][0]=xi.x; sa[tid][1]=xi.y; sa[tid][2]=xi.z; sa[tid][3]=xi.w;
    sa[tid][4]=xj.x-xi.x; sa[tid][5]=xj.y-xi.y; sa[tid][6]=xj.z-xi.z; sa[tid][7]=xj.w-xi.w;
  }
  __syncthreads();
  for(int f=tid; f<2304; f+=256){
    int e = f>>5, c4 = f&31;
    float4 scv = ((const float4*)sc1)[c4];
    float4 shv = ((const float4*)sh1)[c4];
    float4 y = make_float4(0.f,0.f,0.f,0.f);
    #pragma unroll
    for(int k=0;k<8;k++){
      float a = sa[e][k];
      float4 wv = *(const float4*)(sW1 + k*128 + c4*4);
      y.x=fmaf(a,wv.x,y.x); y.y=fmaf(a,wv.y,y.y);
      y.z=fmaf(a,wv.z,y.z); y.w=fmaf(a,wv.w,y.w);
    }
    float4 z;
    z.x = fmaxf(fmaf(scv.x,y.x,shv.x),0.f);
    z.y = fmaxf(fmaf(scv.y,y.y,shv.y),0.f);
    z.z = fmaxf(fmaf(scv.z,y.z,shv.z),0.f);
    z.w = fmaxf(fmaf(scv.w,y.w,shv.w),0.f);
    *(float4*)(sZ + e*132 + c4*4) = z;
  }
  __syncthreads();
  const int tc = tid & 31, tr = tid >> 5;  // node tr, cols tc*4
  float acc[9][4];
  #pragma unroll
  for(int s=0;s<9;s++)
    #pragma unroll
    for(int e=0;e<4;e++) acc[s][e]=0.f;
  #pragma unroll 2
  for(int k4=0;k4<32;k4++){
    float4 av[9];
    #pragma unroll
    for(int s=0;s<9;s++) av[s] = *(const float4*)(sZ + (tr*9+s)*132 + k4*4);
    #pragma unroll
    for(int kk=0;kk<4;kk++){
      float4 bv = *(const float4*)(W2 + (size_t)(k4*4+kk)*128 + tc*4);
      #pragma unroll
      for(int s=0;s<9;s++){
        float a = (kk==0)?av[s].x:(kk==1)?av[s].y:(kk==2)?av[s].z:av[s].w;
        acc[s][0]=fmaf(a,bv.x,acc[s][0]);
        acc[s][1]=fmaf(a,bv.y,acc[s][1]);
        acc[s][2]=fmaf(a,bv.z,acc[s][2]);
        acc[s][3]=fmaf(a,bv.w,acc[s][3]);
      }
    }
  }
  float4 scv = ((const float4*)sc2)[tc];
  float4 shv = ((const float4*)sh2)[tc];
  float4 sum = make_float4(0.f,0.f,0.f,0.f);
  #pragma unroll
  for(int s=0;s<9;s++){
    sum.x += fmaxf(fmaf(scv.x,acc[s][0],shv.x),0.f);
    sum.y += fmaxf(fmaf(scv.y,acc[s][1],shv.y),0.f);
    sum.z += fmaxf(fmaf(scv.z,acc[s][2],shv.z),0.f);
    sum.w += fmaxf(fmaf(scv.w,acc[s][3],shv.w),0.f);
  }
  sum.x*=(1.f/9.f); sum.y*=(1.f/9.f); sum.z*=(1.f/9.f); sum.w*=(1.f/9.f);
  *(float4*)(Zb + (size_t)(node0+tr)*128 + tc*4) = sum;
}

// plain GEMM x1 = Zb[8192,128] @ W3[128,128] + b3; 32 rows/block, grid 256
__global__ __launch_bounds__(256) void k_gemm128(const float* __restrict__ A,
      const float* __restrict__ W, const float* __restrict__ bias,
      float* __restrict__ out){
  __shared__ float sZ[32*132];
  const int tid = threadIdx.x;
  const int row0 = blockIdx.x*32;
  for(int e=tid; e<32*32; e+=256){
    int r = e>>5, c4 = e&31;
    ((float4*)(sZ + r*132))[c4] = ((const float4*)(A + (size_t)(row0+r)*128))[c4];
  }
  __syncthreads();
  const int tc = tid & 31, tr = tid >> 5;  // cols tc*4, rows tr+rr*8
  float acc[4][4];
  #pragma unroll
  for(int rr=0;rr<4;rr++)
    #pragma unroll
    for(int e=0;e<4;e++) acc[rr][e]=0.f;
  #pragma unroll 4
  for(int k4=0;k4<32;k4++){
    float4 av[4];
    #pragma unroll
    for(int rr=0;rr<4;rr++) av[rr] = *(const float4*)(sZ + (tr+rr*8)*132 + k4*4);
    #pragma unroll
    for(int kk=0;kk<4;kk++){
      float4 bv = *(const float4*)(W + (size_t)(k4*4+kk)*128 + tc*4);
      #pragma unroll
      for(int rr=0;rr<4;rr++){
        float a = (kk==0)?av[rr].x:(kk==1)?av[rr].y:(kk==2)?av[rr].z:av[rr].w;
        acc[rr][0]=fmaf(a,bv.x,acc[rr][0]);
        acc[rr][1]=fmaf(a,bv.y,acc[rr][1]);
        acc[rr][2]=fmaf(a,bv.z,acc[rr][2]);
        acc[rr][3]=fmaf(a,bv.w,acc[rr][3]);
      }
    }
  }
  float4 breg = *(const float4*)(bias + tc*4);
  #pragma unroll
  for(int rr=0;rr<4;rr++){
    int r = row0 + tr + rr*8;
    float4 vals;
    vals.x = acc[rr][0]+breg.x;
    vals.y = acc[rr][1]+breg.y;
    vals.z = acc[rr][2]+breg.z;
    vals.w = acc[rr][3]+breg.w;
    *(float4*)(out + (size_t)r*128 + tc*4) = vals;
  }
}

// ---------------- conv3: moment-based, dual problems ----------------
__global__ __launch_bounds__(256) void k_mom8d(const float4* __restrict__ xa,
      const float4* __restrict__ xb, const int* __restrict__ ia,
      const int* __restrict__ ib, float* __restrict__ mpart){
  __shared__ float sa[256][9];
  const int prob = blockIdx.y;
  const float4* x = prob ? xb : xa;
  const int* idx = prob ? ib : ia;
  int t = threadIdx.x;
  int e = blockIdx.x*256 + t;
  int i = e/KNN; int j = idx[e];
  float4 xi = x[i], xj = x[j];
  sa[t][0]=xi.x; sa[t][1]=xi.y; sa[t][2]=xi.z; sa[t][3]=xi.w;
  sa[t][4]=xj.x-xi.x; sa[t][5]=xj.y-xi.y; sa[t][6]=xj.z-xi.z; sa[t][7]=xj.w-xi.w;
  __syncthreads();
  if(t < 44){
    float s=0.f;
    if(t<8){
      for(int e2=0;e2<256;e2++) s += sa[e2][t];
    } else {
      int f=t-8, p=0, q=0, acc=0;
      for(p=0;p<8;p++){ int cnt=8-p; if(f<acc+cnt){ q=p+(f-acc); break;} acc+=cnt; }
      for(int e2=0;e2<256;e2++) s += sa[e2][p]*sa[e2][q];
    }
    mpart[((size_t)prob*288 + blockIdx.x)*44 + t]=s;
  }
}

// 128 threads = 2 probs x 64 ch; W1 is 8x64
__global__ void k_bn1qd(const float* __restrict__ mpart, const float* __restrict__ W1,
      const float* __restrict__ g, const float* __restrict__ be,
      float* __restrict__ scale, float* __restrict__ shift){
  __shared__ double mom[2][44];
  int t = threadIdx.x;   // 128
  if(t<88){
    int pr=t/44, m=t%44;
    double s=0; for(int b=0;b<288;b++) s+=(double)mpart[((size_t)pr*288+b)*44+m];
    mom[pr][m]=s;
  }
  __syncthreads();
  int prob = t>>6, c = t&63;
  double m[8], w[8];
  #pragma unroll
  for(int p=0;p<8;p++){ m[p]=mom[prob][p]/(double)TK; w[p]=(double)W1[p*64+c]; }
  double q=0.0; int f=8;
  for(int p=0;p<8;p++)
    for(int qq=p;qq<8;qq++){
      double cov = mom[prob][f]/(double)TK - m[p]*m[qq];
      q += (p==qq?1.0:2.0)*w[p]*w[qq]*cov;
      f++;
    }
  if(q<0) q=0;
  double sc = (double)g[c]/sqrt(q+1e-5);
  double mu=0; for(int p=0;p<8;p++) mu += m[p]*w[p];
  scale[prob*64+c]=(float)sc;
  shift[prob*64+c]=(float)((double)be[c] - mu*sc);
}

// SYRK 64-d dual: per block 256 edges (4 passes of 64), M64 + colsum -> mpartM[(prob*288+b)*4160]
__global__ __launch_bounds__(256) void k_syrk64d(const float4* __restrict__ xa,
      const float4* __restrict__ xb, const int* __restrict__ ia,
      const int* __restrict__ ib, const float* __restrict__ W1,
      const float* __restrict__ sc0, const float* __restrict__ sh0,
      float* __restrict__ mpartM){
  __shared__ float sa[64][9];
  __shared__ float sW1[8*64];
  __shared__ float sZ[64*68];
  __shared__ float ssum[64];
  const int prob = blockIdx.y;
  const float4* x = prob ? xb : xa;
  const int* idx = prob ? ib : ia;
  const float* sc1 = sc0 + prob*64;
  const float* sh1 = sh0 + prob*64;
  const int tid = threadIdx.x;
  if(tid<128) ((float4*)sW1)[tid] = ((const float4*)W1)[tid];
  if(tid<64) ssum[tid]=0.f;
  const int zc4 = tid & 15, ze0 = tid >> 4;     // z chunk (16x4=64ch), rows ze0+16k
  const int i0 = (tid>>4)*4, j0 = (tid&15)*4;   // syrk 4x4 tile
  float acc[4][4];
  #pragma unroll
  for(int a=0;a<4;a++)
    #pragma unroll
    for(int b=0;b<4;b++) acc[a][b]=0.f;
  float ls[4]={0,0,0,0};
  float4 scv = ((const float4*)sc1)[zc4];
  float4 shv = ((const float4*)sh1)[zc4];
  for(int pass=0;pass<4;pass++){
    __syncthreads();
    if(tid<64){
      int e = blockIdx.x*256 + pass*64 + tid;
      int i = e/KNN; int j = idx[e];
      float4 xi = x[i], xj = x[j];
      sa[tid][0]=xi.x; sa[tid][1]=xi.y; sa[tid][2]=xi.z; sa[tid][3]=xi.w;
      sa[tid][4]=xj.x-xi.x; sa[tid][5]=xj.y-xi.y; sa[tid][6]=xj.z-xi.z; sa[tid][7]=xj.w-xi.w;
    }
    __syncthreads();
    for(int e=ze0; e<64; e+=16){
      float4 y = make_float4(0.f,0.f,0.f,0.f);
      #pragma unroll
      for(int k=0;k<8;k++){
        float a = sa[e][k];
        float4 wv = *(const float4*)(sW1 + k*64 + zc4*4);
        y.x=fmaf(a,wv.x,y.x); y.y=fmaf(a,wv.y,y.y);
        y.z=fmaf(a,wv.z,y.z); y.w=fmaf(a,wv.w,y.w);
      }
      float4 z;
      z.x = fmaxf(fmaf(scv.x,y.x,shv.x),0.f);
      z.y = fmaxf(fmaf(scv.y,y.y,shv.y),0.f);
      z.z = fmaxf(fmaf(scv.z,y.z,shv.z),0.f);
      z.w = fmaxf(fmaf(scv.w,y.w,shv.w),0.f);
      *(float4*)(sZ + e*68 + zc4*4) = z;
      ls[0]+=z.x; ls[1]+=z.y; ls[2]+=z.z; ls[3]+=z.w;
    }
    __syncthreads();
    #pragma unroll 4
    for(int e=0;e<64;e++){
      const float* rz = sZ + e*68;
      float4 zi4 = *(const float4*)(rz + i0);
      float4 zj4 = *(const float4*)(rz + j0);
      float zi[4]={zi4.x,zi4.y,zi4.z,zi4.w};
      float zj[4]={zj4.x,zj4.y,zj4.z,zj4.w};
      #pragma unroll
      for(int a=0;a<4;a++)
        #pragma unroll
        for(int b=0;b<4;b++) acc[a][b]=fmaf(zi[a],zj[b],acc[a][b]);
    }
  }
  #pragma unroll
  for(int c=0;c<4;c++) atomicAdd(&ssum[zc4*4+c], ls[c]);
  float* mp = mpartM + ((size_t)prob*288 + blockIdx.x)*4160;
  #pragma unroll
  for(int a=0;a<4;a++)
    *(float4*)(mp + (i0+a)*64 + j0) = make_float4(acc[a][0],acc[a][1],acc[a][2],acc[a][3]);
  __syncthreads();
  if(tid<64) mp[4096+tid] = ssum[tid];
}

__global__ __launch_bounds__(256) void k_redMd(const float* __restrict__ mpartM,
      double* __restrict__ Md){
  int ch = blockIdx.x*256 + threadIdx.x;
  if(ch >= 8320) return;
  int prob = ch / 4160, c = ch % 4160;
  double s=0;
  for(int b=0;b<288;b++) s += (double)mpartM[((size_t)prob*288+b)*4160 + c];
  Md[(size_t)prob*4160 + c]=s;
}

// grid (64, 2); 64 threads; W2 is 64x64
__global__ void k_bn2qd(const double* __restrict__ Md, const float* __restrict__ W2,
      const float* __restrict__ g, const float* __restrict__ be,
      float* __restrict__ scale, float* __restrict__ shift){
  __shared__ double redq[64], redt[64];
  __shared__ float sw[64];
  int c = blockIdx.x, prob = blockIdx.y, t = threadIdx.x;   // 64 threads
  const double* md = Md + (size_t)prob*4160;
  sw[t] = W2[t*64+c];
  __syncthreads();
  double zb = md[4096+t]/(double)TK;
  double inner=0;
  for(int j=0;j<64;j++) inner += md[t*64+j]*(double)sw[j];
  redq[t] = (double)sw[t]*(inner/(double)TK);
  redt[t] = (double)sw[t]*zb;
  __syncthreads();
  for(int s=32;s>0;s>>=1){
    if(t<s){ redq[t]+=redq[t+s]; redt[t]+=redt[t+s]; }
    __syncthreads();
  }
  if(t==0){
    double var = redq[0] - redt[0]*redt[0];
    if(var<0) var=0;
    double sc = (double)g[c]/sqrt(var+1e-5);
    scale[prob*64+c]=(float)sc;
    shift[prob*64+c]=(float)((double)be[c] - redt[0]*sc);
  }
}

// fused conv3 mid+agg: 16 nodes / 144 edges per block; grid (512, 2)
__global__ __launch_bounds__(256) void k_midagg64d(const float4* __restrict__ xa,
      const float4* __restrict__ xb, const int* __restrict__ ia,
      const int* __restrict__ ib, const float* __restrict__ W1,
      const float* __restrict__ sc0, const float* __restrict__ sh0,
      const float* __restrict__ W2, const float* __restrict__ sc20,
      const float* __restrict__ sh20, float* __restrict__ Zb64){
  __shared__ float sa[144][9];
  __shared__ float sW1[8*64];
  __shared__ float sZ[144*68];
  const int prob = blockIdx.y;
  const float4* x = prob ? xb : xa;
  const int* idx = prob ? ib : ia;
  const float* sc1 = sc0 + prob*64;
  const float* sh1 = sh0 + prob*64;
  const float* sc2 = sc20 + prob*64;
  const float* sh2 = sh20 + prob*64;
  const int tid = threadIdx.x;
  const int node0 = blockIdx.x*16;
  if(tid<128) ((float4*)sW1)[tid] = ((const float4*)W1)[tid];
  if(tid<144){
    int e = blockIdx.x*144 + tid;
    int i = e/KNN; int j = idx[e];
    float4 xi = x[i], xj = x[j];
    sa[tid][0]=xi.x; sa[tid][1]=xi.y; sa[tid][2]=xi.z; sa[tid][3]=xi.w;
    sa[tid][4]=xj.x-xi.x; sa[tid][5]=xj.y-xi.y; sa[tid][6]=xj.z-xi.z; sa[tid][7]=xj.w-xi.w;
  }
  __syncthreads();
  // z1 recompute: 144 edges x 16 chunks of 4
  for(int f=tid; f<144*16; f+=256){
    int e = f>>4, c4 = f&15;
    float4 scv = ((const float4*)sc1)[c4];
    float4 shv = ((const float4*)sh1)[c4];
    float4 y = make_float4(0.f,0.f,0.f,0.f);
    #pragma unroll
    for(int k=0;k<8;k++){
      float a = sa[e][k];
      float4 wv = *(const float4*)(sW1 + k*64 + c4*4);
      y.x=fmaf(a,wv.x,y.x); y.y=fmaf(a,wv.y,y.y);
      y.z=fmaf(a,wv.z,y.z); y.w=fmaf(a,wv.w,y.w);
    }
    float4 z;
    z.x = fmaxf(fmaf(scv.x,y.x,shv.x),0.f);
    z.y = fmaxf(fmaf(scv.y,y.y,shv.y),0.f);
    z.z = fmaxf(fmaf(scv.z,y.z,shv.z),0.f);
    z.w = fmaxf(fmaf(scv.w,y.w,shv.w),0.f);
    *(float4*)(sZ + e*68 + c4*4) = z;
  }
  __syncthreads();
  // GEMM x W2 + BN2 + ReLU + mean9 -> Zb64
  const int cg = tid & 15, nd = tid >> 4;   // node nd (16), cols cg*4
  float acc[9][4];
  #pragma unroll
  for(int s=0;s<9;s++)
    #pragma unroll
    for(int e=0;e<4;e++) acc[s][e]=0.f;
  #pragma unroll 2
  for(int k4=0;k4<16;k4++){
    float4 av[9];
    #pragma unroll
    for(int s=0;s<9;s++) av[s] = *(const float4*)(sZ + (nd*9+s)*68 + k4*4);
    #pragma unroll
    for(int kk=0;kk<4;kk++){
      float4 bv = *(const float4*)(W2 + (size_t)(k4*4+kk)*64 + cg*4);
      #pragma unroll
      for(int s=0;s<9;s++){
        float a = (kk==0)?av[s].x:(kk==1)?av[s].y:(kk==2)?av[s].z:av[s].w;
        acc[s][0]=fmaf(a,bv.x,acc[s][0]);
        acc[s][1]=fmaf(a,bv.y,acc[s][1]);
        acc[s][2]=fmaf(a,bv.z,acc[s][2]);
        acc[s][3]=fmaf(a,bv.w,acc[s][3]);
      }
    }
  }
  float4 scv = ((const float4*)sc2)[cg];
  float4 shv = ((const float4*)sh2)[cg];
  float4 sum = make_float4(0.f,0.f,0.f,0.f);
  #pragma unroll
  for(int s=0;s<9;s++){
    sum.x += fmaxf(fmaf(scv.x,acc[s][0],shv.x),0.f);
    sum.y += fmaxf(fmaf(scv.y,acc[s][1],shv.y),0.f);
    sum.z += fmaxf(fmaf(scv.z,acc[s][2],shv.z),0.f);
    sum.w += fmaxf(fmaf(scv.w,acc[s][3],shv.w),0.f);
  }
  sum.x*=(1.f/9.f); sum.y*=(1.f/9.f); sum.z*=(1.f/9.f); sum.w*=(1.f/9.f);
  *(float4*)(Zb64 + ((size_t)prob*TN + node0+nd)*64 + cg*4) = sum;
}

// Zb64 @ W3[64,16] + b3 -> xlf/xsf; grid (TN/64, 2)
__global__ __launch_bounds__(256) void k_gemm16d(const float* __restrict__ Zb64,
      const float* __restrict__ W, const float* __restrict__ bias,
      float* __restrict__ outl, float* __restrict__ outs){
  __shared__ float sZ[64*68];
  __shared__ float sW[64*16];
  const int prob = blockIdx.y;
  const float* A = Zb64 + (size_t)prob*TN*64;
  float* out = prob ? outs : outl;
  const int tid = threadIdx.x;
  const int row0 = blockIdx.x*64;
  for(int e=tid; e<64*16; e+=256){
    int r = e>>4, c4 = e&15;
    ((float4*)(sZ + r*68))[c4] = ((const float4*)(A + (size_t)(row0+r)*64))[c4];
  }
  ((float4*)sW)[tid] = ((const float4*)W)[tid];
  __syncthreads();
  const int tc = tid & 15, tr = tid >> 4;   // col tc, rows tr+rr*16
  float acc[4] = {0.f,0.f,0.f,0.f};
  #pragma unroll 4
  for(int k4=0;k4<16;k4++){
    float4 av[4];
    #pragma unroll
    for(int rr=0;rr<4;rr++) av[rr] = *(const float4*)(sZ + (tr+rr*16)*68 + k4*4);
    #pragma unroll
    for(int kk=0;kk<4;kk++){
      float bv = sW[(k4*4+kk)*16 + tc];
      #pragma unroll
      for(int rr=0;rr<4;rr++){
        float a = (kk==0)?av[rr].x:(kk==1)?av[rr].y:(kk==2)?av[rr].z:av[rr].w;
        acc[rr]=fmaf(a,bv,acc[rr]);
      }
    }
  }
  #pragma unroll
  for(int rr=0;rr<4;rr++){
    int r = row0 + tr + rr*16;
    out[(size_t)r*16 + tc] = acc[rr] + bias[tc];
  }
}

// ---------------- head MLP 128->64->32->1, block-tiled (32 rows/block) ----------------
__global__ __launch_bounds__(256) void k_head(const float* __restrict__ x1,
    const float* __restrict__ W1, const float* __restrict__ b1,
    const float* __restrict__ W2, const float* __restrict__ b2,
    const float* __restrict__ W3, const float* __restrict__ b3,
    float* __restrict__ h, float* __restrict__ pstat){
  __shared__ float sA[32*132];
  __shared__ float sW1[128*64];
  __shared__ float o1[32*68];
  __shared__ float sW2[64*32];
  __shared__ float o2[32*33];
  __shared__ float sb1[64], sb2[32], sW3v[32];
  __shared__ float rs[32], rq[32];
  const int tid = threadIdx.x;
  const int row0 = blockIdx.x*32;
  for(int e=tid; e<32*32; e+=256){
    int r = e>>5, c4 = e&31;
    ((float4*)(sA + r*132))[c4] = ((const float4*)(x1 + (size_t)(row0+r)*128))[c4];
  }
  for(int e=tid; e<128*64/4; e+=256) ((float4*)sW1)[e] = ((const float4*)W1)[e];
  for(int e=tid; e<64*32/4; e+=256)  ((float4*)sW2)[e] = ((const float4*)W2)[e];
  if(tid < 64) sb1[tid]=b1[tid];
  if(tid < 32){ sb2[tid]=b2[tid]; sW3v[tid]=W3[tid]; }
  __syncthreads();
  const int tc = tid & 15, tr = tid >> 4;
  float a1[2][4];
  #pragma unroll
  for(int rr=0;rr<2;rr++)
    #pragma unroll
    for(int e=0;e<4;e++) a1[rr][e]=0.f;
  for(int k4=0;k4<32;k4++){
    float4 av0 = *(const float4*)(sA + (tr*2  )*132 + k4*4);
    float4 av1 = *(const float4*)(sA + (tr*2+1)*132 + k4*4);
    #pragma unroll
    for(int kk=0;kk<4;kk++){
      float4 bv = *(const float4*)(sW1 + (k4*4+kk)*64 + tc*4);
      float p0 = (kk==0)?av0.x:(kk==1)?av0.y:(kk==2)?av0.z:av0.w;
      float p1 = (kk==0)?av1.x:(kk==1)?av1.y:(kk==2)?av1.z:av1.w;
      a1[0][0]=fmaf(p0,bv.x,a1[0][0]); a1[0][1]=fmaf(p0,bv.y,a1[0][1]);
      a1[0][2]=fmaf(p0,bv.z,a1[0][2]); a1[0][3]=fmaf(p0,bv.w,a1[0][3]);
      a1[1][0]=fmaf(p1,bv.x,a1[1][0]); a1[1][1]=fmaf(p1,bv.y,a1[1][1]);
      a1[1][2]=fmaf(p1,bv.z,a1[1][2]); a1[1][3]=fmaf(p1,bv.w,a1[1][3]);
    }
  }
  #pragma unroll
  for(int rr=0;rr<2;rr++)
    #pragma unroll
    for(int e=0;e<4;e++)
      o1[(tr*2+rr)*68 + tc*4+e] = fmaxf(a1[rr][e]+sb1[tc*4+e], 0.f);
  __syncthreads();
  float a2[2][2] = {{0.f,0.f},{0.f,0.f}};
  for(int k=0;k<64;k++){
    float w0 = sW2[k*32 + tc*2], w1 = sW2[k*32 + tc*2+1];
    float v0 = o1[(tr*2  )*68 + k];
    float v1 = o1[(tr*2+1)*68 + k];
    a2[0][0]=fmaf(v0,w0,a2[0][0]); a2[0][1]=fmaf(v0,w1,a2[0][1]);
    a2[1][0]=fmaf(v1,w0,a2[1][0]); a2[1][1]=fmaf(v1,w1,a2[1][1]);
  }
  #pragma unroll
  for(int rr=0;rr<2;rr++)
    #pragma unroll
    for(int cc=0;cc<2;cc++)
      o2[(tr*2+rr)*33 + tc*2+cc] = fmaxf(a2[rr][cc]+sb2[tc*2+cc], 0.f);
  __syncthreads();
  if(tid < 32){
    float hv = b3[0];
    #pragma unroll
    for(int k=0;k<32;k++) hv = fmaf(o2[tid*33+k], sW3v[k], hv);
    h[row0+tid]=hv;
    rs[tid]=hv; rq[tid]=hv*hv;
  }
  __syncthreads();
  if(tid==0){
    float S=0.f, Q=0.f;
    #pragma unroll
    for(int i=0;i<32;i++){ S+=rs[i]; Q+=rq[i]; }
    pstat[blockIdx.x*2]=S; pstat[blockIdx.x*2+1]=Q;
  }
}

__global__ __launch_bounds__(256) void k_fin_h(const float* __restrict__ pstat,
      float* __restrict__ hpar){
  __shared__ double sS[256], sQ[256];
  int t = threadIdx.x;
  sS[t] = (double)pstat[2*t]; sQ[t] = (double)pstat[2*t+1];
  __syncthreads();
  for(int s=128;s>0;s>>=1){
    if(t<s){ sS[t]+=sS[t+s]; sQ[t]+=sQ[t+s]; }
    __syncthreads();
  }
  if(t==0){
    double mu = sS[0]/8192.0;
    double var = (sQ[0] - 8192.0*mu*mu)/8191.0;   // ddof=1
    double sd = (var > 0) ? sqrt(var) : 0.0;
    hpar[0]=(float)mu;
    hpar[1]=(float)(1.0/(sd + 1e-5));
  }
}

__global__ __launch_bounds__(256) void k_gate(const float* __restrict__ h,
      const float* __restrict__ hpar, const float4* __restrict__ x,
      float4* __restrict__ xl, float4* __restrict__ xs){
  int i = blockIdx.x*256 + threadIdx.x;
  float z = (h[i]-hpar[0])*hpar[1];
  float o = 1.0f/(1.0f+expf(-z));
  float om = 1.0f - o;
  float4 v = x[i];
  xl[i] = make_float4(o*v.x, o*v.y, o*v.z, o*v.w);
  xs[i] = make_float4(om*v.x, om*v.y, om*v.z, om*v.w);
}

// ---------------- final: per-graph max pool (16ch x 2) + linear [32]->1 ----------------
__global__ __launch_bounds__(256) void k_final(const float* __restrict__ xlf,
      const float* __restrict__ xsf, const float* __restrict__ W,
      const float* __restrict__ b, float* __restrict__ out){
  __shared__ float red[32][8];
  int g = blockIdx.x;
  int c = threadIdx.x & 31;
  int chunk = threadIdx.x >> 5;
  const float* src = (c < 16) ? xlf : xsf;
  int ch = (c < 16) ? c : c-16;
  float m = -1e30f;
  for(int n=chunk*128; n<chunk*128+128; n++)
    m = fmaxf(m, src[((size_t)g*1024+n)*16 + ch]);
  red[c][chunk]=m;
  __syncthreads();
  if(threadIdx.x < 32){
    float mm = red[threadIdx.x][0];
    #pragma unroll
    for(int p=1;p<8;p++) mm = fmaxf(mm, red[threadIdx.x][p]);
    red[threadIdx.x][0]=mm;
  }
  __syncthreads();
  if(threadIdx.x == 0){
    float acc = b[0];
    for(int cc=0;cc<32;cc++) acc = fmaf(red[cc][0], W[cc], acc);
    out[g]=acc;
  }
}

// ---------------- launch ----------------
extern "C" void kernel_launch(void* const* d_in, const int* in_sizes, int n_in,
                              void* d_out, int out_size, void* d_ws, size_t ws_size,
                              hipStream_t stream){
  const float* x    =(const float*)d_in[0];
  const float* c1W1 =(const float*)d_in[1];
  const float* c1g1 =(const float*)d_in[3];
  const float* c1be1=(const float*)d_in[4];
  const float* c1W2 =(const float*)d_in[5];
  const float* c1g2 =(const float*)d_in[7];
  const float* c1be2=(const float*)d_in[8];
  const float* c1W3 =(const float*)d_in[9];
  const float* c1b3 =(const float*)d_in[10];
  const float* c3W1 =(const float*)d_in[11];
  const float* c3g1 =(const float*)d_in[13];
  const float* c3be1=(const float*)d_in[14];
  const float* c3W2 =(const float*)d_in[15];
  const float* c3g2 =(const float*)d_in[17];
  const float* c3be2=(const float*)d_in[18];
  const float* c3W3 =(const float*)d_in[19];
  const float* c3b3 =(const float*)d_in[20];
  const float* hW1  =(const float*)d_in[21];
  const float* hb1  =(const float*)d_in[22];
  const float* hW2  =(const float*)d_in[23];
  const float* hb2  =(const float*)d_in[24];
  const float* hW3  =(const float*)d_in[25];
  const float* hb3  =(const float*)d_in[26];
  const float* l2W  =(const float*)d_in[27];
  const float* l2b  =(const float*)d_in[28];
  (void)in_sizes; (void)n_in; (void)out_size; (void)ws_size;

  char* wsb=(char*)d_ws;
  size_t off=0;
  auto alloc=[&](size_t bytes)->char*{
    char* p = wsb + off;
    off = (off + bytes + 255) & ~(size_t)255;
    return p;
  };
  float* ovl  =(float*)alloc((size_t)NSYB*16512*4);  // overlay: lists / conv1 mpartM / conv3 mpartMd
  float* x1   =(float*)alloc((size_t)TN*128*4);
  float* Zb   =(float*)alloc((size_t)TN*128*4);   // conv1 Zb / conv3 Zb64 (dual)
  int*   idx1 =(int*)  alloc((size_t)TK*4);
  int*   idxl =(int*)  alloc((size_t)TK*4);
  int*   idxs =(int*)  alloc((size_t)TK*4);
  float* pd   =(float*)alloc((size_t)2*TN*72*4);
  float* h    =(float*)alloc((size_t)TN*4);
  float* xl   =(float*)alloc((size_t)TN*16);
  float* xs   =(float*)alloc((size_t)TN*16);
  float* xlf  =(float*)alloc((size_t)TN*16*4);
  float* xsf  =(float*)alloc((size_t)TN*16*4);
  float* pstat=(float*)alloc((size_t)512*4);
  double* Md  =(double*)alloc((size_t)16512*8);
  double* Mdd =(double*)alloc((size_t)8320*8);
  double* pp8 =(double*)alloc((size_t)8*16512*8);
  float* mp44 =(float*)alloc((size_t)288*44*4);
  float* mp44d=(float*)alloc((size_t)2*288*44*4);
  float* tl   =(float*)alloc((size_t)TN*4);
  float* tg   =(float*)alloc((size_t)2*TN*4);
  unsigned char* cnt8l=(unsigned char*)alloc((size_t)TN*8);
  unsigned char* cnt8g=(unsigned char*)alloc((size_t)2*TN*NCHG);
  float* bnp  =(float*)alloc(1024*4);
  float* hpar =(float*)alloc(64);

  float* sc1=bnp,      *sh1=bnp+128, *sc2=bnp+256, *sh2=bnp+384;
  float* scA=bnp+512,  *shA=bnp+640, *scB=bnp+768, *shB=bnp+896;  // conv3: [prob][64]
  unsigned short* listl=(unsigned short*)ovl;   // overlay (disjoint in time)
  unsigned short* listg=(unsigned short*)ovl;
  float* mpartM = ovl;
  float* mpartMd = ovl;

  // ---- conv1 kNN (per-graph) ----
  k_part_local  <<<256,256,0,stream>>>((const float4*)x, pd);
  k_thresh_local<<<32, 256,0,stream>>>(pd, tl);
  k_collect_local<<<256,256,0,stream>>>((const float4*)x, tl, cnt8l, listl);
  k_refine_local<<<TN/32,256,0,stream>>>((const float4*)x, cnt8l, listl, idx1);
  // ---- conv1 (moment-based, no Y materialization) ----
  k_mom8<<<288,256,0,stream>>>((const float4*)x, idx1, mp44);
  k_bn1q<<<1,128,0,stream>>>(mp44, c1W1, c1g1, c1be1, sc1, sh1);
  k_syrk128<<<NSYB,256,0,stream>>>((const float4*)x, idx1, c1W1, sc1, sh1, mpartM);
  k_redA<<<dim3(65,8),256,0,stream>>>(mpartM, pp8);
  k_redB<<<65,256,0,stream>>>(pp8, Md);
  k_bn2q<<<128,128,0,stream>>>(Md, c1W2, c1g2, c1be2, sc2, sh2);
  k_midagg<<<1024,256,0,stream>>>((const float4*)x, idx1, c1W1, sc1, sh1, c1W2, sc2, sh2, Zb);
  k_gemm128<<<TN/32,256,0,stream>>>(Zb, c1W3, c1b3, x1);
  // ---- head + gate ----
  k_head<<<TN/32,256,0,stream>>>(x1,hW1,hb1,hW2,hb2,hW3,hb3,h,pstat);
  k_fin_h<<<1,256,0,stream>>>(pstat,hpar);
  k_gate<<<32,256,0,stream>>>(h,hpar,(const float4*)x,(float4*)xl,(float4*)xs);
  // ---- global kNN for xl & xs ----
  k_part_sub   <<<dim3(256,2),256,0,stream>>>((const float4*)xl,(const float4*)xs,pd);
  k_thresh_sub <<<64,256,0,stream>>>(pd,tg);
  k_collect_glob<<<dim3(512,2),256,0,stream>>>((const float4*)xl,(const float4*)xs,tg,cnt8g,listg);
  k_refine_glob<<<2*TN/32,256,0,stream>>>((const float4*)xl,(const float4*)xs,cnt8g,listg,idxl,idxs);
  // ---- conv3 on xl & xs (moment-based, dual) ----
  k_mom8d<<<dim3(288,2),256,0,stream>>>((const float4*)xl,(const float4*)xs,idxl,idxs,mp44d);
  k_bn1qd<<<1,128,0,stream>>>(mp44d, c3W1, c3g1, c3be1, scA, shA);
  k_syrk64d<<<dim3(288,2),256,0,stream>>>((const float4*)xl,(const float4*)xs,idxl,idxs,c3W1,scA,shA,mpartMd);
  k_redMd<<<33,256,0,stream>>>(mpartMd, Mdd);
  k_bn2qd<<<dim3(64,2),64,0,stream>>>(Mdd, c3W2, c3g2, c3be2, scB, shB);
  k_midagg64d<<<dim3(512,2),256,0,stream>>>((const float4*)xl,(const float4*)xs,idxl,idxs,
      c3W1, scA, shA, c3W2, scB, shB, Zb);
  k_gemm16d<<<dim3(TN/64,2),256,0,stream>>>(Zb, c3W3, c3b3, xlf, xsf);
  // ---- final pooling + linear ----
  k_final<<<8,256,0,stream>>>(xlf,xsf,l2W,l2b,(float*)d_out);
}

// Round 17
// 422.996 us; speedup vs baseline: 1.6015x; 1.0056x over previous
//
#include <hip/hip_runtime.h>
#include <math.h>

#define TN 8192          // total nodes (B*N)
#define KNN 9
#define NPG 1024         // nodes per graph
#define TK (TN*KNN)      // 73728 edge rows
#define CPCL 12          // cap per (node,chunk), local (8 chunks of 128)
#define NCHG 32          // global chunks (of 256 candidates)
#define CPCG 16          // cap per (node,chunk), global
#define NSYB 768         // syrk128 blocks

// ---------------- helpers ----------------
__device__ __forceinline__ float sqnorm(float4 v){
  return fmaf(v.x,v.x,fmaf(v.y,v.y,fmaf(v.z,v.z,v.w*v.w)));
}
__device__ __forceinline__ float pairdist(float4 a, float sqa, float4 b, float sqb){
  float dot = fmaf(a.x,b.x,fmaf(a.y,b.y,fmaf(a.z,b.z,a.w*b.w)));
  return sqa + sqb - 2.0f*dot;
}
__device__ __forceinline__ void chain9(float (&bd)[9], float d){
  float t=d;
  #pragma unroll
  for(int p=0;p<9;p++){
    float lo=fminf(bd[p],t);
    t=fmaxf(bd[p],t);
    bd[p]=lo;
  }
}
__device__ __forceinline__ void insert9(float (&bd)[9], int (&bi)[9], float d, int id){
  if(d < bd[8]){
    float td=d; int ti=id;
    #pragma unroll
    for(int p=0;p<9;p++){
      bool sw = (td < bd[p]);
      float nbd = sw ? td : bd[p];
      int   nbi = sw ? ti : bi[p];
      float ntd = sw ? bd[p] : td;
      int   nti = sw ? bi[p] : ti;
      bd[p]=nbd; bi[p]=nbi; td=ntd; ti=nti;
    }
  }
}

// ---------------- kNN: local (per-graph) ----------------
__global__ __launch_bounds__(256) void k_part_local(const float4* __restrict__ x, float* __restrict__ pd){
  __shared__ float4 sx[128]; __shared__ float ssq[128];
  int nb = blockIdx.x >> 3, chunk = blockIdx.x & 7;
  int g = nb >> 2;
  int cbase = g*NPG + chunk*128;
  if(threadIdx.x < 128){
    float4 v = x[cbase + threadIdx.x];
    sx[threadIdx.x]=v; ssq[threadIdx.x]=sqnorm(v);
  }
  __syncthreads();
  int node = nb*256 + threadIdx.x;
  float4 xi = x[node]; float sqi = sqnorm(xi);
  float bdA[9], bdB[9];
  #pragma unroll
  for(int q=0;q<9;q++){bdA[q]=1e30f;bdB[q]=1e30f;}
  for(int j=0;j<128;j+=2){
    chain9(bdA, pairdist(xi,sqi,sx[j],ssq[j]));
    chain9(bdB, pairdist(xi,sqi,sx[j+1],ssq[j+1]));
  }
  #pragma unroll
  for(int q=0;q<9;q++) chain9(bdA, bdB[q]);
  #pragma unroll
  for(int q=0;q<9;q++) pd[(size_t)(chunk*9+q)*TN + node]=bdA[q];
}

__global__ __launch_bounds__(256) void k_thresh_local(const float* __restrict__ pd,
      float* __restrict__ tl){
  int node = blockIdx.x*256 + threadIdx.x;
  float bd[9];
  #pragma unroll
  for(int q=0;q<9;q++) bd[q]=1e30f;
  for(int m=0;m<72;m++) chain9(bd, pd[(size_t)m*TN + node]);
  float t = bd[8];
  tl[node] = t + fabsf(t)*1e-5f + 1e-12f;
}

__global__ __launch_bounds__(256) void k_collect_local(const float4* __restrict__ x,
      const float* __restrict__ tl, unsigned char* __restrict__ cnt8,
      unsigned short* __restrict__ list){
  __shared__ float4 sx[128]; __shared__ float ssq[128];
  int nb = blockIdx.x >> 3, chunk = blockIdx.x & 7;
  int g = nb >> 2;
  int cbase = g*NPG + chunk*128;
  if(threadIdx.x < 128){
    float4 v = x[cbase + threadIdx.x];
    sx[threadIdx.x]=v; ssq[threadIdx.x]=sqnorm(v);
  }
  __syncthreads();
  int node = nb*256 + threadIdx.x;
  float4 xi = x[node];
  float m2x=-2.0f*xi.x, m2y=-2.0f*xi.y, m2z=-2.0f*xi.z, m2w=-2.0f*xi.w;
  float tadj = tl[node] - sqnorm(xi);
  int cnt = 0;
  unsigned short* lst = list + ((size_t)node*8 + chunk)*CPCL;
  for(int j=0;j<128;j+=4){
    float4 v0=sx[j], v1=sx[j+1], v2=sx[j+2], v3=sx[j+3];
    float q0=ssq[j], q1=ssq[j+1], q2=ssq[j+2], q3=ssq[j+3];
    float s0=fmaf(v0.x,m2x,fmaf(v0.y,m2y,fmaf(v0.z,m2z,fmaf(v0.w,m2w,q0))));
    float s1=fmaf(v1.x,m2x,fmaf(v1.y,m2y,fmaf(v1.z,m2z,fmaf(v1.w,m2w,q1))));
    float s2=fmaf(v2.x,m2x,fmaf(v2.y,m2y,fmaf(v2.z,m2z,fmaf(v2.w,m2w,q2))));
    float s3=fmaf(v3.x,m2x,fmaf(v3.y,m2y,fmaf(v3.z,m2z,fmaf(v3.w,m2w,q3))));
    if(s0<=tadj){ if(cnt<CPCL) lst[cnt]=(unsigned short)(cbase+j  ); cnt++; }
    if(s1<=tadj){ if(cnt<CPCL) lst[cnt]=(unsigned short)(cbase+j+1); cnt++; }
    if(s2<=tadj){ if(cnt<CPCL) lst[cnt]=(unsigned short)(cbase+j+2); cnt++; }
    if(s3<=tadj){ if(cnt<CPCL) lst[cnt]=(unsigned short)(cbase+j+3); cnt++; }
  }
  cnt8[(size_t)node*8 + chunk] = (unsigned char)(cnt > 255 ? 255 : cnt);
}

// 8 threads per node: sub handles 1 chunk; LDS merge of 8 partial top-9s
__global__ __launch_bounds__(256) void k_refine_local(const float4* __restrict__ x,
      const unsigned char* __restrict__ cnt8, const unsigned short* __restrict__ list,
      int* __restrict__ out){
  __shared__ float sval[32][73];
  __shared__ int   sidx[32][73];
  __shared__ int   sovf[32];
  int slot = threadIdx.x >> 3, sub = threadIdx.x & 7;
  int node = blockIdx.x*32 + slot;
  if(sub==0) sovf[slot]=0;
  __syncthreads();
  float4 xi = x[node]; float sqi = sqnorm(xi);
  float bd[9]; int bi[9];
  #pragma unroll
  for(int q=0;q<9;q++){bd[q]=1e30f; bi[q]=node;}
  int ch = sub;
  int c = cnt8[(size_t)node*8 + ch];
  if(c > CPCL) sovf[slot]=1;
  int n = c < CPCL ? c : CPCL;
  const unsigned short* lst = list + ((size_t)node*8 + ch)*CPCL;
  for(int m=0;m<n;m++){
    int j = lst[m]; float4 v = x[j];
    insert9(bd,bi, pairdist(xi,sqi,v,sqnorm(v)), j);
  }
  #pragma unroll
  for(int q=0;q<9;q++){ sval[slot][sub*9+q]=bd[q]; sidx[slot][sub*9+q]=bi[q]; }
  __syncthreads();
  if(sub==0){
    for(int m=9;m<72;m++) insert9(bd,bi, sval[slot][m], sidx[slot][m]);
    if(sovf[slot]){
      #pragma unroll
      for(int q=0;q<9;q++){bd[q]=1e30f; bi[q]=node;}
      int gbase = node & ~(NPG-1);
      for(int j=gbase;j<gbase+NPG;j++){
        float4 v = x[j];
        insert9(bd,bi, pairdist(xi,sqi,v,sqnorm(v)), j);
      }
    }
    #pragma unroll
    for(int q=0;q<9;q++) out[(size_t)node*9+q]=bi[q];
  }
}

// ---------------- kNN: global (two problems: xl, xs) ----------------
__global__ __launch_bounds__(256) void k_part_sub(const float4* __restrict__ xa,
      const float4* __restrict__ xb, float* __restrict__ pd){
  const float4* x = blockIdx.y ? xb : xa;
  __shared__ float4 sx[256]; __shared__ float ssq[256];
  int nb = blockIdx.x >> 3, chunk = blockIdx.x & 7;
  {
    int j = (chunk*256 + threadIdx.x)*4;
    float4 v = x[j];
    sx[threadIdx.x]=v; ssq[threadIdx.x]=sqnorm(v);
  }
  __syncthreads();
  int node = nb*256 + threadIdx.x;
  float4 xi = x[node]; float sqi = sqnorm(xi);
  float bdA[9], bdB[9];
  #pragma unroll
  for(int q=0;q<9;q++){bdA[q]=1e30f;bdB[q]=1e30f;}
  for(int j=0;j<256;j+=2){
    chain9(bdA, pairdist(xi,sqi,sx[j],ssq[j]));
    chain9(bdB, pairdist(xi,sqi,sx[j+1],ssq[j+1]));
  }
  #pragma unroll
  for(int q=0;q<9;q++) chain9(bdA, bdB[q]);
  int pn = blockIdx.y*TN + node;
  #pragma unroll
  for(int q=0;q<9;q++) pd[(size_t)(chunk*9+q)*2*TN + pn]=bdA[q];
}

__global__ __launch_bounds__(256) void k_thresh_sub(const float* __restrict__ pd,
      float* __restrict__ tg){
  int pn = blockIdx.x*256 + threadIdx.x;   // < 2*TN
  float bd[9];
  #pragma unroll
  for(int q=0;q<9;q++) bd[q]=1e30f;
  for(int m=0;m<72;m++) chain9(bd, pd[(size_t)m*2*TN + pn]);
  float t = bd[8];
  tg[pn] = t + fabsf(t)*1e-5f + 1e-12f;
}

// 2 nodes/thread, 32 chunks of 256 cands: grid (16*32, 2) = 1024 blocks
__global__ __launch_bounds__(256) void k_collect_glob(const float4* __restrict__ xa,
      const float4* __restrict__ xb, const float* __restrict__ tg,
      unsigned char* __restrict__ cnt8, unsigned short* __restrict__ list){
  const float4* x = blockIdx.y ? xb : xa;
  __shared__ float4 sx[256];
  __shared__ float4 ssq4[64];
  int nb = blockIdx.x >> 5, chunk = blockIdx.x & 31;
  int cbase = chunk*256;
  {
    float4 v = x[cbase+threadIdx.x];
    sx[threadIdx.x]=v; ((float*)ssq4)[threadIdx.x]=sqnorm(v);
  }
  __syncthreads();
  int node0 = nb*512 + threadIdx.x;
  int node1 = node0 + 256;
  int pn0 = blockIdx.y*TN + node0;
  int pn1 = pn0 + 256;
  float4 xi0 = x[node0], xi1 = x[node1];
  float a0x=-2.0f*xi0.x, a0y=-2.0f*xi0.y, a0z=-2.0f*xi0.z, a0w=-2.0f*xi0.w;
  float a1x=-2.0f*xi1.x, a1y=-2.0f*xi1.y, a1z=-2.0f*xi1.z, a1w=-2.0f*xi1.w;
  float t0 = tg[pn0] - sqnorm(xi0);
  float t1 = tg[pn1] - sqnorm(xi1);
  int c0 = 0, c1 = 0;
  unsigned short* l0 = list + ((size_t)pn0*NCHG + chunk)*CPCG;
  unsigned short* l1 = list + ((size_t)pn1*NCHG + chunk)*CPCG;
  for(int j=0;j<256;j+=4){
    float4 v0=sx[j], v1=sx[j+1], v2=sx[j+2], v3=sx[j+3];
    float4 qv = ssq4[j>>2];
    float s00=fmaf(v0.x,a0x,fmaf(v0.y,a0y,fmaf(v0.z,a0z,fmaf(v0.w,a0w,qv.x))));
    float s01=fmaf(v1.x,a0x,fmaf(v1.y,a0y,fmaf(v1.z,a0z,fmaf(v1.w,a0w,qv.y))));
    float s02=fmaf(v2.x,a0x,fmaf(v2.y,a0y,fmaf(v2.z,a0z,fmaf(v2.w,a0w,qv.z))));
    float s03=fmaf(v3.x,a0x,fmaf(v3.y,a0y,fmaf(v3.z,a0z,fmaf(v3.w,a0w,qv.w))));
    float s10=fmaf(v0.x,a1x,fmaf(v0.y,a1y,fmaf(v0.z,a1z,fmaf(v0.w,a1w,qv.x))));
    float s11=fmaf(v1.x,a1x,fmaf(v1.y,a1y,fmaf(v1.z,a1z,fmaf(v1.w,a1w,qv.y))));
    float s12=fmaf(v2.x,a1x,fmaf(v2.y,a1y,fmaf(v2.z,a1z,fmaf(v2.w,a1w,qv.z))));
    float s13=fmaf(v3.x,a1x,fmaf(v3.y,a1y,fmaf(v3.z,a1z,fmaf(v3.w,a1w,qv.w))));
    if(s00<=t0){ if(c0<CPCG) l0[c0]=(unsigned short)(cbase+j  ); c0++; }
    if(s01<=t0){ if(c0<CPCG) l0[c0]=(unsigned short)(cbase+j+1); c0++; }
    if(s02<=t0){ if(c0<CPCG) l0[c0]=(unsigned short)(cbase+j+2); c0++; }
    if(s03<=t0){ if(c0<CPCG) l0[c0]=(unsigned short)(cbase+j+3); c0++; }
    if(s10<=t1){ if(c1<CPCG) l1[c1]=(unsigned short)(cbase+j  ); c1++; }
    if(s11<=t1){ if(c1<CPCG) l1[c1]=(unsigned short)(cbase+j+1); c1++; }
    if(s12<=t1){ if(c1<CPCG) l1[c1]=(unsigned short)(cbase+j+2); c1++; }
    if(s13<=t1){ if(c1<CPCG) l1[c1]=(unsigned short)(cbase+j+3); c1++; }
  }
  cnt8[(size_t)pn0*NCHG + chunk] = (unsigned char)(c0 > 255 ? 255 : c0);
  cnt8[(size_t)pn1*NCHG + chunk] = (unsigned char)(c1 > 255 ? 255 : c1);
}

// 8 threads per node: sub handles 4 chunks; LDS merge of 8 partial top-9s
__global__ __launch_bounds__(256) void k_refine_glob(const float4* __restrict__ xa,
      const float4* __restrict__ xb, const unsigned char* __restrict__ cnt8,
      const unsigned short* __restrict__ list, int* __restrict__ outl, int* __restrict__ outs){
  __shared__ float sval[32][73];
  __shared__ int   sidx[32][73];
  __shared__ int   sovf[32];
  int slot = threadIdx.x >> 3, sub = threadIdx.x & 7;
  int pn = blockIdx.x*32 + slot;          // < 2*TN; grid = 512
  int prob = blockIdx.x >> 8;             // uniform per block
  int node = pn & (TN-1);
  const float4* x = prob ? xb : xa;
  if(sub==0) sovf[slot]=0;
  __syncthreads();
  float4 xi = x[node]; float sqi = sqnorm(xi);
  float bd[9]; int bi[9];
  #pragma unroll
  for(int q=0;q<9;q++){bd[q]=1e30f; bi[q]=node;}
  bool ovf=false;
  for(int ch=sub*4; ch<sub*4+4; ch++){
    int c = cnt8[(size_t)pn*NCHG + ch];
    if(c > CPCG) ovf=true;
    int n = c < CPCG ? c : CPCG;
    const unsigned short* lst = list + ((size_t)pn*NCHG + ch)*CPCG;
    for(int m=0;m<n;m++){
      int j = lst[m]; float4 v = x[j];
      insert9(bd,bi, pairdist(xi,sqi,v,sqnorm(v)), j);
    }
  }
  if(ovf) sovf[slot]=1;
  #pragma unroll
  for(int q=0;q<9;q++){ sval[slot][sub*9+q]=bd[q]; sidx[slot][sub*9+q]=bi[q]; }
  __syncthreads();
  if(sub==0){
    for(int m=9;m<72;m++) insert9(bd,bi, sval[slot][m], sidx[slot][m]);
    if(sovf[slot]){
      #pragma unroll
      for(int q=0;q<9;q++){bd[q]=1e30f; bi[q]=node;}
      for(int j=0;j<TN;j++){
        float4 v = x[j];
        insert9(bd,bi, pairdist(xi,sqi,v,sqnorm(v)), j);
      }
    }
    int* o = prob ? outs : outl;
    #pragma unroll
    for(int q=0;q<9;q++) o[(size_t)node*9+q]=bi[q];
  }
}

// ---------------- conv1: moment-based BN, fused recompute (no Y materialization) ----------------
__global__ __launch_bounds__(256) void k_mom8(const float4* __restrict__ x,
      const int* __restrict__ idx, float* __restrict__ mpart){
  __shared__ float sa[256][9];
  int t = threadIdx.x;
  int e = blockIdx.x*256 + t;
  int i = e/KNN; int j = idx[e];
  float4 xi = x[i], xj = x[j];
  sa[t][0]=xi.x; sa[t][1]=xi.y; sa[t][2]=xi.z; sa[t][3]=xi.w;
  sa[t][4]=xj.x-xi.x; sa[t][5]=xj.y-xi.y; sa[t][6]=xj.z-xi.z; sa[t][7]=xj.w-xi.w;
  __syncthreads();
  if(t < 44){
    float s=0.f;
    if(t<8){
      for(int e2=0;e2<256;e2++) s += sa[e2][t];
    } else {
      int f=t-8, p=0, q=0, acc=0;
      for(p=0;p<8;p++){ int cnt=8-p; if(f<acc+cnt){ q=p+(f-acc); break;} acc+=cnt; }
      for(int e2=0;e2<256;e2++) s += sa[e2][p]*sa[e2][q];
    }
    mpart[blockIdx.x*44+t]=s;
  }
}

__global__ void k_bn1q(const float* __restrict__ mpart, const float* __restrict__ W1,
      const float* __restrict__ g, const float* __restrict__ be,
      float* __restrict__ scale, float* __restrict__ shift){
  __shared__ double mom[44];
  int t = threadIdx.x;   // 128
  if(t<44){ double s=0; for(int b=0;b<288;b++) s+=(double)mpart[b*44+t]; mom[t]=s; }
  __syncthreads();
  double m[8], w[8];
  #pragma unroll
  for(int p=0;p<8;p++){ m[p]=mom[p]/(double)TK; w[p]=(double)W1[p*128+t]; }
  double q=0.0; int f=8;
  for(int p=0;p<8;p++)
    for(int qq=p;qq<8;qq++){
      double cov = mom[f]/(double)TK - m[p]*m[qq];
      q += (p==qq?1.0:2.0)*w[p]*w[qq]*cov;
      f++;
    }
  if(q<0) q=0;
  double sc = (double)g[t]/sqrt(q+1e-5);
  double mu=0; for(int p=0;p<8;p++) mu += m[p]*w[p];
  scale[t]=(float)sc;
  shift[t]=(float)((double)be[t] - mu*sc);
}

// SYRK v6: 768 blocks x 96 edges (2 passes of 48); split column groups
// thread (gi,gj): rows {gi*4..+3}u{64+gi*4..+3}, cols {gj*4..+3}u{64+gj*4..+3}
// -> zj reads at float offset 4*gj / 64+4*gj: banks 4gj mod 32 = 2-way (free)
__global__ __launch_bounds__(256) void k_syrk128(const float4* __restrict__ x,
      const int* __restrict__ idx, const float* __restrict__ W1,
      const float* __restrict__ sc1, const float* __restrict__ sh1,
      float* __restrict__ mpartM){
  __shared__ float sa[48][9];
  __shared__ float sW1[8*128];
  __shared__ float sZ[48*132];
  __shared__ float ssum[128];
  const int tid = threadIdx.x;
  ((float4*)sW1)[tid] = ((const float4*)W1)[tid];
  if(tid<128) ssum[tid]=0.f;
  const int zc4 = tid & 31, ze0 = tid >> 5;     // z-compute mapping
  const int gi = tid >> 4, gj = tid & 15;       // syrk tile indices (16x16 tiles of 8x8)
  const int ia = gi*4, ib = 64 + gi*4;          // row groups
  const int ja = gj*4, jb = 64 + gj*4;          // col groups
  float acc[8][8];
  #pragma unroll
  for(int a=0;a<8;a++)
    #pragma unroll
    for(int b=0;b<8;b++) acc[a][b]=0.f;
  float ls[4]={0,0,0,0};
  float4 scv = ((const float4*)sc1)[zc4];
  float4 shv = ((const float4*)sh1)[zc4];
  for(int pass=0;pass<2;pass++){
    __syncthreads();
    if(tid<48){
      int e = blockIdx.x*96 + pass*48 + tid;
      int i = e/KNN; int j = idx[e];
      float4 xi = x[i], xj = x[j];
      sa[tid][0]=xi.x; sa[tid][1]=xi.y; sa[tid][2]=xi.z; sa[tid][3]=xi.w;
      sa[tid][4]=xj.x-xi.x; sa[tid][5]=xj.y-xi.y; sa[tid][6]=xj.z-xi.z; sa[tid][7]=xj.w-xi.w;
    }
    __syncthreads();
    for(int e=ze0; e<48; e+=8){
      float4 y = make_float4(0.f,0.f,0.f,0.f);
      #pragma unroll
      for(int k=0;k<8;k++){
        float a = sa[e][k];
        float4 wv = *(const float4*)(sW1 + k*128 + zc4*4);
        y.x=fmaf(a,wv.x,y.x); y.y=fmaf(a,wv.y,y.y);
        y.z=fmaf(a,wv.z,y.z); y.w=fmaf(a,wv.w,y.w);
      }
      float4 z;
      z.x = fmaxf(fmaf(scv.x,y.x,shv.x),0.f);
      z.y = fmaxf(fmaf(scv.y,y.y,shv.y),0.f);
      z.z = fmaxf(fmaf(scv.z,y.z,shv.z),0.f);
      z.w = fmaxf(fmaf(scv.w,y.w,shv.w),0.f);
      *(float4*)(sZ + e*132 + zc4*4) = z;
      ls[0]+=z.x; ls[1]+=z.y; ls[2]+=z.z; ls[3]+=z.w;
    }
    __syncthreads();
    #pragma unroll 2
    for(int e=0;e<48;e++){
      const float* rz = sZ + e*132;
      float4 zi0 = *(const float4*)(rz + ia);
      float4 zi1 = *(const float4*)(rz + ib);
      float4 zj0 = *(const float4*)(rz + ja);
      float4 zj1 = *(const float4*)(rz + jb);
      float zi[8] = {zi0.x,zi0.y,zi0.z,zi0.w,zi1.x,zi1.y,zi1.z,zi1.w};
      float zj[8] = {zj0.x,zj0.y,zj0.z,zj0.w,zj1.x,zj1.y,zj1.z,zj1.w};
      #pragma unroll
      for(int a=0;a<8;a++)
        #pragma unroll
        for(int b=0;b<8;b++) acc[a][b]=fmaf(zi[a],zj[b],acc[a][b]);
    }
  }
  #pragma unroll
  for(int c=0;c<4;c++) atomicAdd(&ssum[zc4*4+c], ls[c]);
  float* mp = mpartM + (size_t)blockIdx.x*16512;
  #pragma unroll
  for(int a=0;a<8;a++){
    int row = (a<4) ? (ia+a) : (ib+a-4);
    *(float4*)(mp + row*128 + ja) = make_float4(acc[a][0],acc[a][1],acc[a][2],acc[a][3]);
    *(float4*)(mp + row*128 + jb) = make_float4(acc[a][4],acc[a][5],acc[a][6],acc[a][7]);
  }
  __syncthreads();
  if(tid<128) mp[16384+tid] = ssum[tid];
}

// 2-stage reduce of 768 partials: stage A grid (65,8) sums 96 each; stage B sums 8
__global__ __launch_bounds__(256) void k_redA(const float* __restrict__ mpartM,
      double* __restrict__ pp8){
  int ch = blockIdx.x*256 + threadIdx.x;
  if(ch >= 16512) return;
  int y = blockIdx.y;
  double s=0;
  for(int b=y*96;b<y*96+96;b++) s += (double)mpartM[(size_t)b*16512 + ch];
  pp8[(size_t)y*16512 + ch]=s;
}

__global__ __launch_bounds__(256) void k_redB(const double* __restrict__ pp8,
      double* __restrict__ Md){
  int ch = blockIdx.x*256 + threadIdx.x;
  if(ch >= 16512) return;
  double s=0;
  #pragma unroll
  for(int y=0;y<8;y++) s += pp8[(size_t)y*16512 + ch];
  Md[ch]=s;
}

__global__ void k_bn2q(const double* __restrict__ Md, const float* __restrict__ W2,
      const float* __restrict__ g, const float* __restrict__ be,
      float* __restrict__ scale, float* __restrict__ shift){
  __shared__ double redq[128], redt[128];
  __shared__ float sw[128];
  int c = blockIdx.x, t = threadIdx.x;   // 128 threads
  sw[t] = W2[t*128+c];
  __syncthreads();
  double zb = Md[16384+t]/(double)TK;
  double inner=0;
  for(int j=0;j<128;j++) inner += Md[t*128+j]*(double)sw[j];
  redq[t] = (double)sw[t]*(inner/(double)TK);
  redt[t] = (double)sw[t]*zb;
  __syncthreads();
  for(int s=64;s>0;s>>=1){
    if(t<s){ redq[t]+=redq[t+s]; redt[t]+=redt[t+s]; }
    __syncthreads();
  }
  if(t==0){
    double var = redq[0] - redt[0]*redt[0];
    if(var<0) var=0;
    double sc = (double)g[c]/sqrt(var+1e-5);
    scale[c]=(float)sc;
    shift[c]=(float)((double)be[c] - redt[0]*sc);
  }
}

// fused: gather A (8 nodes, 72 edges) -> z1 recompute -> GEMM x W2 (global, broadcast)
// -> BN2+ReLU -> mean over 9 -> Zb[node][128]
__global__ __launch_bounds__(256) void k_midagg(const float4* __restrict__ x,
      const int* __restrict__ idx, const float* __restrict__ W1,
      const float* __restrict__ sc1, const float* __restrict__ sh1,
      const float* __restrict__ W2, const float* __restrict__ sc2,
      const float* __restrict__ sh2, float* __restrict__ Zb){
  __shared__ float sa[72][9];
  __shared__ float sW1[8*128];
  __shared__ float sZ[72*132];
  const int tid = threadIdx.x;
  const int node0 = blockIdx.x*8;
  if(tid<256) ((float4*)sW1)[tid] = ((const float4*)W1)[tid];
  if(tid<72){
    int e = blockIdx.x*72 + tid;
    int i = e/KNN; int j = idx[e];
    float4 xi = x[i], xj = x[j];
    sa[tid][0]=xi.x; sa[tid][1]=xi.y; sa[tid][2]=xi.z; sa[tid][3]=xi.w;
    sa[tid][4]=xj.x-xi.x; sa[tid][5]=xj.y-xi.y; sa[tid][6]=xj.z-xi.z; sa[tid][7]=xj.w-xi.w;
  }
  __syncthreads();
  for(int f=tid; f<2304; f+=256){
    int e = f>>5, c4 = f&31;
    float4 scv = ((const float4*)sc1)[c4];
    float4 shv = ((const float4*)sh1)[c4];
    float4 y = make_float4(0.f,0.f,0.f,0.f);
    #pragma unroll
    for(int k=0;k<8;k++){
      float a = sa[e][k];
      float4 wv = *(const float4*)(sW1 + k*128 + c4*4);
      y.x=fmaf(a,wv.x,y.x); y.y=fmaf(a,wv.y,y.y);
      y.z=fmaf(a,wv.z,y.z); y.w=fmaf(a,wv.w,y.w);
    }
    float4 z;
    z.x = fmaxf(fmaf(scv.x,y.x,shv.x),0.f);
    z.y = fmaxf(fmaf(scv.y,y.y,shv.y),0.f);
    z.z = fmaxf(fmaf(scv.z,y.z,shv.z),0.f);
    z.w = fmaxf(fmaf(scv.w,y.w,shv.w),0.f);
    *(float4*)(sZ + e*132 + c4*4) = z;
  }
  __syncthreads();
  const int tc = tid & 31, tr = tid >> 5;  // node tr, cols tc*4
  float acc[9][4];
  #pragma unroll
  for(int s=0;s<9;s++)
    #pragma unroll
    for(int e=0;e<4;e++) acc[s][e]=0.f;
  #pragma unroll 2
  for(int k4=0;k4<32;k4++){
    float4 av[9];
    #pragma unroll
    for(int s=0;s<9;s++) av[s] = *(const float4*)(sZ + (tr*9+s)*132 + k4*4);
    #pragma unroll
    for(int kk=0;kk<4;kk++){
      float4 bv = *(const float4*)(W2 + (size_t)(k4*4+kk)*128 + tc*4);
      #pragma unroll
      for(int s=0;s<9;s++){
        float a = (kk==0)?av[s].x:(kk==1)?av[s].y:(kk==2)?av[s].z:av[s].w;
        acc[s][0]=fmaf(a,bv.x,acc[s][0]);
        acc[s][1]=fmaf(a,bv.y,acc[s][1]);
        acc[s][2]=fmaf(a,bv.z,acc[s][2]);
        acc[s][3]=fmaf(a,bv.w,acc[s][3]);
      }
    }
  }
  float4 scv = ((const float4*)sc2)[tc];
  float4 shv = ((const float4*)sh2)[tc];
  float4 sum = make_float4(0.f,0.f,0.f,0.f);
  #pragma unroll
  for(int s=0;s<9;s++){
    sum.x += fmaxf(fmaf(scv.x,acc[s][0],shv.x),0.f);
    sum.y += fmaxf(fmaf(scv.y,acc[s][1],shv.y),0.f);
    sum.z += fmaxf(fmaf(scv.z,acc[s][2],shv.z),0.f);
    sum.w += fmaxf(fmaf(scv.w,acc[s][3],shv.w),0.f);
  }
  sum.x*=(1.f/9.f); sum.y*=(1.f/9.f); sum.z*=(1.f/9.f); sum.w*=(1.f/9.f);
  *(float4*)(Zb + (size_t)(node0+tr)*128 + tc*4) = sum;
}

// plain GEMM x1 = Zb[8192,128] @ W3[128,128] + b3; 32 rows/block, grid 256
__global__ __launch_bounds__(256) void k_gemm128(const float* __restrict__ A,
      const float* __restrict__ W, const float* __restrict__ bias,
      float* __restrict__ out){
  __shared__ float sZ[32*132];
  const int tid = threadIdx.x;
  const int row0 = blockIdx.x*32;
  for(int e=tid; e<32*32; e+=256){
    int r = e>>5, c4 = e&31;
    ((float4*)(sZ + r*132))[c4] = ((const float4*)(A + (size_t)(row0+r)*128))[c4];
  }
  __syncthreads();
  const int tc = tid & 31, tr = tid >> 5;  // cols tc*4, rows tr+rr*8
  float acc[4][4];
  #pragma unroll
  for(int rr=0;rr<4;rr++)
    #pragma unroll
    for(int e=0;e<4;e++) acc[rr][e]=0.f;
  #pragma unroll 4
  for(int k4=0;k4<32;k4++){
    float4 av[4];
    #pragma unroll
    for(int rr=0;rr<4;rr++) av[rr] = *(const float4*)(sZ + (tr+rr*8)*132 + k4*4);
    #pragma unroll
    for(int kk=0;kk<4;kk++){
      float4 bv = *(const float4*)(W + (size_t)(k4*4+kk)*128 + tc*4);
      #pragma unroll
      for(int rr=0;rr<4;rr++){
        float a = (kk==0)?av[rr].x:(kk==1)?av[rr].y:(kk==2)?av[rr].z:av[rr].w;
        acc[rr][0]=fmaf(a,bv.x,acc[rr][0]);
        acc[rr][1]=fmaf(a,bv.y,acc[rr][1]);
        acc[rr][2]=fmaf(a,bv.z,acc[rr][2]);
        acc[rr][3]=fmaf(a,bv.w,acc[rr][3]);
      }
    }
  }
  float4 breg = *(const float4*)(bias + tc*4);
  #pragma unroll
  for(int rr=0;rr<4;rr++){
    int r = row0 + tr + rr*8;
    float4 vals;
    vals.x = acc[rr][0]+breg.x;
    vals.y = acc[rr][1]+breg.y;
    vals.z = acc[rr][2]+breg.z;
    vals.w = acc[rr][3]+breg.w;
    *(float4*)(out + (size_t)r*128 + tc*4) = vals;
  }
}

// ---------------- conv3: moment-based, dual problems ----------------
__global__ __launch_bounds__(256) void k_mom8d(const float4* __restrict__ xa,
      const float4* __restrict__ xb, const int* __restrict__ ia,
      const int* __restrict__ ib, float* __restrict__ mpart){
  __shared__ float sa[256][9];
  const int prob = blockIdx.y;
  const float4* x = prob ? xb : xa;
  const int* idx = prob ? ib : ia;
  int t = threadIdx.x;
  int e = blockIdx.x*256 + t;
  int i = e/KNN; int j = idx[e];
  float4 xi = x[i], xj = x[j];
  sa[t][0]=xi.x; sa[t][1]=xi.y; sa[t][2]=xi.z; sa[t][3]=xi.w;
  sa[t][4]=xj.x-xi.x; sa[t][5]=xj.y-xi.y; sa[t][6]=xj.z-xi.z; sa[t][7]=xj.w-xi.w;
  __syncthreads();
  if(t < 44){
    float s=0.f;
    if(t<8){
      for(int e2=0;e2<256;e2++) s += sa[e2][t];
    } else {
      int f=t-8, p=0, q=0, acc=0;
      for(p=0;p<8;p++){ int cnt=8-p; if(f<acc+cnt){ q=p+(f-acc); break;} acc+=cnt; }
      for(int e2=0;e2<256;e2++) s += sa[e2][p]*sa[e2][q];
    }
    mpart[((size_t)prob*288 + blockIdx.x)*44 + t]=s;
  }
}

// 128 threads = 2 probs x 64 ch; W1 is 8x64
__global__ void k_bn1qd(const float* __restrict__ mpart, const float* __restrict__ W1,
      const float* __restrict__ g, const float* __restrict__ be,
      float* __restrict__ scale, float* __restrict__ shift){
  __shared__ double mom[2][44];
  int t = threadIdx.x;   // 128
  if(t<88){
    int pr=t/44, m=t%44;
    double s=0; for(int b=0;b<288;b++) s+=(double)mpart[((size_t)pr*288+b)*44+m];
    mom[pr][m]=s;
  }
  __syncthreads();
  int prob = t>>6, c = t&63;
  double m[8], w[8];
  #pragma unroll
  for(int p=0;p<8;p++){ m[p]=mom[prob][p]/(double)TK; w[p]=(double)W1[p*64+c]; }
  double q=0.0; int f=8;
  for(int p=0;p<8;p++)
    for(int qq=p;qq<8;qq++){
      double cov = mom[prob][f]/(double)TK - m[p]*m[qq];
      q += (p==qq?1.0:2.0)*w[p]*w[qq]*cov;
      f++;
    }
  if(q<0) q=0;
  double sc = (double)g[c]/sqrt(q+1e-5);
  double mu=0; for(int p=0;p<8;p++) mu += m[p]*w[p];
  scale[prob*64+c]=(float)sc;
  shift[prob*64+c]=(float)((double)be[c] - mu*sc);
}

// SYRK 64-d dual: per block 256 edges (4 passes of 64), M64 + colsum -> mpartM[(prob*288+b)*4160]
__global__ __launch_bounds__(256) void k_syrk64d(const float4* __restrict__ xa,
      const float4* __restrict__ xb, const int* __restrict__ ia,
      const int* __restrict__ ib, const float* __restrict__ W1,
      const float* __restrict__ sc0, const float* __restrict__ sh0,
      float* __restrict__ mpartM){
  __shared__ float sa[64][9];
  __shared__ float sW1[8*64];
  __shared__ float sZ[64*68];
  __shared__ float ssum[64];
  const int prob = blockIdx.y;
  const float4* x = prob ? xb : xa;
  const int* idx = prob ? ib : ia;
  const float* sc1 = sc0 + prob*64;
  const float* sh1 = sh0 + prob*64;
  const int tid = threadIdx.x;
  if(tid<128) ((float4*)sW1)[tid] = ((const float4*)W1)[tid];
  if(tid<64) ssum[tid]=0.f;
  const int zc4 = tid & 15, ze0 = tid >> 4;     // z chunk (16x4=64ch), rows ze0+16k
  const int i0 = (tid>>4)*4, j0 = (tid&15)*4;   // syrk 4x4 tile
  float acc[4][4];
  #pragma unroll
  for(int a=0;a<4;a++)
    #pragma unroll
    for(int b=0;b<4;b++) acc[a][b]=0.f;
  float ls[4]={0,0,0,0};
  float4 scv = ((const float4*)sc1)[zc4];
  float4 shv = ((const float4*)sh1)[zc4];
  for(int pass=0;pass<4;pass++){
    __syncthreads();
    if(tid<64){
      int e = blockIdx.x*256 + pass*64 + tid;
      int i = e/KNN; int j = idx[e];
      float4 xi = x[i], xj = x[j];
      sa[tid][0]=xi.x; sa[tid][1]=xi.y; sa[tid][2]=xi.z; sa[tid][3]=xi.w;
      sa[tid][4]=xj.x-xi.x; sa[tid][5]=xj.y-xi.y; sa[tid][6]=xj.z-xi.z; sa[tid][7]=xj.w-xi.w;
    }
    __syncthreads();
    for(int e=ze0; e<64; e+=16){
      float4 y = make_float4(0.f,0.f,0.f,0.f);
      #pragma unroll
      for(int k=0;k<8;k++){
        float a = sa[e][k];
        float4 wv = *(const float4*)(sW1 + k*64 + zc4*4);
        y.x=fmaf(a,wv.x,y.x); y.y=fmaf(a,wv.y,y.y);
        y.z=fmaf(a,wv.z,y.z); y.w=fmaf(a,wv.w,y.w);
      }
      float4 z;
      z.x = fmaxf(fmaf(scv.x,y.x,shv.x),0.f);
      z.y = fmaxf(fmaf(scv.y,y.y,shv.y),0.f);
      z.z = fmaxf(fmaf(scv.z,y.z,shv.z),0.f);
      z.w = fmaxf(fmaf(scv.w,y.w,shv.w),0.f);
      *(float4*)(sZ + e*68 + zc4*4) = z;
      ls[0]+=z.x; ls[1]+=z.y; ls[2]+=z.z; ls[3]+=z.w;
    }
    __syncthreads();
    #pragma unroll 4
    for(int e=0;e<64;e++){
      const float* rz = sZ + e*68;
      float4 zi4 = *(const float4*)(rz + i0);
      float4 zj4 = *(const float4*)(rz + j0);
      float zi[4]={zi4.x,zi4.y,zi4.z,zi4.w};
      float zj[4]={zj4.x,zj4.y,zj4.z,zj4.w};
      #pragma unroll
      for(int a=0;a<4;a++)
        #pragma unroll
        for(int b=0;b<4;b++) acc[a][b]=fmaf(zi[a],zj[b],acc[a][b]);
    }
  }
  #pragma unroll
  for(int c=0;c<4;c++) atomicAdd(&ssum[zc4*4+c], ls[c]);
  float* mp = mpartM + ((size_t)prob*288 + blockIdx.x)*4160;
  #pragma unroll
  for(int a=0;a<4;a++)
    *(float4*)(mp + (i0+a)*64 + j0) = make_float4(acc[a][0],acc[a][1],acc[a][2],acc[a][3]);
  __syncthreads();
  if(tid<64) mp[4096+tid] = ssum[tid];
}

__global__ __launch_bounds__(256) void k_redMd(const float* __restrict__ mpartM,
      double* __restrict__ Md){
  int ch = blockIdx.x*256 + threadIdx.x;
  if(ch >= 8320) return;
  int prob = ch / 4160, c = ch % 4160;
  double s=0;
  for(int b=0;b<288;b++) s += (double)mpartM[((size_t)prob*288+b)*4160 + c];
  Md[(size_t)prob*4160 + c]=s;
}

// grid (64, 2); 64 threads; W2 is 64x64
__global__ void k_bn2qd(const double* __restrict__ Md, const float* __restrict__ W2,
      const float* __restrict__ g, const float* __restrict__ be,
      float* __restrict__ scale, float* __restrict__ shift){
  __shared__ double redq[64], redt[64];
  __shared__ float sw[64];
  int c = blockIdx.x, prob = blockIdx.y, t = threadIdx.x;   // 64 threads
  const double* md = Md + (size_t)prob*4160;
  sw[t] = W2[t*64+c];
  __syncthreads();
  double zb = md[4096+t]/(double)TK;
  double inner=0;
  for(int j=0;j<64;j++) inner += md[t*64+j]*(double)sw[j];
  redq[t] = (double)sw[t]*(inner/(double)TK);
  redt[t] = (double)sw[t]*zb;
  __syncthreads();
  for(int s=32;s>0;s>>=1){
    if(t<s){ redq[t]+=redq[t+s]; redt[t]+=redt[t+s]; }
    __syncthreads();
  }
  if(t==0){
    double var = redq[0] - redt[0]*redt[0];
    if(var<0) var=0;
    double sc = (double)g[c]/sqrt(var+1e-5);
    scale[prob*64+c]=(float)sc;
    shift[prob*64+c]=(float)((double)be[c] - redt[0]*sc);
  }
}

// fused conv3 mid+agg: 16 nodes / 144 edges per block; grid (512, 2)
__global__ __launch_bounds__(256) void k_midagg64d(const float4* __restrict__ xa,
      const float4* __restrict__ xb, const int* __restrict__ ia,
      const int* __restrict__ ib, const float* __restrict__ W1,
      const float* __restrict__ sc0, const float* __restrict__ sh0,
      const float* __restrict__ W2, const float* __restrict__ sc20,
      const float* __restrict__ sh20, float* __restrict__ Zb64){
  __shared__ float sa[144][9];
  __shared__ float sW1[8*64];
  __shared__ float sZ[144*68];
  const int prob = blockIdx.y;
  const float4* x = prob ? xb : xa;
  const int* idx = prob ? ib : ia;
  const float* sc1 = sc0 + prob*64;
  const float* sh1 = sh0 + prob*64;
  const float* sc2 = sc20 + prob*64;
  const float* sh2 = sh20 + prob*64;
  const int tid = threadIdx.x;
  const int node0 = blockIdx.x*16;
  if(tid<128) ((float4*)sW1)[tid] = ((const float4*)W1)[tid];
  if(tid<144){
    int e = blockIdx.x*144 + tid;
    int i = e/KNN; int j = idx[e];
    float4 xi = x[i], xj = x[j];
    sa[tid][0]=xi.x; sa[tid][1]=xi.y; sa[tid][2]=xi.z; sa[tid][3]=xi.w;
    sa[tid][4]=xj.x-xi.x; sa[tid][5]=xj.y-xi.y; sa[tid][6]=xj.z-xi.z; sa[tid][7]=xj.w-xi.w;
  }
  __syncthreads();
  // z1 recompute: 144 edges x 16 chunks of 4
  for(int f=tid; f<144*16; f+=256){
    int e = f>>4, c4 = f&15;
    float4 scv = ((const float4*)sc1)[c4];
    float4 shv = ((const float4*)sh1)[c4];
    float4 y = make_float4(0.f,0.f,0.f,0.f);
    #pragma unroll
    for(int k=0;k<8;k++){
      float a = sa[e][k];
      float4 wv = *(const float4*)(sW1 + k*64 + c4*4);
      y.x=fmaf(a,wv.x,y.x); y.y=fmaf(a,wv.y,y.y);
      y.z=fmaf(a,wv.z,y.z); y.w=fmaf(a,wv.w,y.w);
    }
    float4 z;
    z.x = fmaxf(fmaf(scv.x,y.x,shv.x),0.f);
    z.y = fmaxf(fmaf(scv.y,y.y,shv.y),0.f);
    z.z = fmaxf(fmaf(scv.z,y.z,shv.z),0.f);
    z.w = fmaxf(fmaf(scv.w,y.w,shv.w),0.f);
    *(float4*)(sZ + e*68 + c4*4) = z;
  }
  __syncthreads();
  // GEMM x W2 + BN2 + ReLU + mean9 -> Zb64
  const int cg = tid & 15, nd = tid >> 4;   // node nd (16), cols cg*4
  float acc[9][4];
  #pragma unroll
  for(int s=0;s<9;s++)
    #pragma unroll
    for(int e=0;e<4;e++) acc[s][e]=0.f;
  #pragma unroll 2
  for(int k4=0;k4<16;k4++){
    float4 av[9];
    #pragma unroll
    for(int s=0;s<9;s++) av[s] = *(const float4*)(sZ + (nd*9+s)*68 + k4*4);
    #pragma unroll
    for(int kk=0;kk<4;kk++){
      float4 bv = *(const float4*)(W2 + (size_t)(k4*4+kk)*64 + cg*4);
      #pragma unroll
      for(int s=0;s<9;s++){
        float a = (kk==0)?av[s].x:(kk==1)?av[s].y:(kk==2)?av[s].z:av[s].w;
        acc[s][0]=fmaf(a,bv.x,acc[s][0]);
        acc[s][1]=fmaf(a,bv.y,acc[s][1]);
        acc[s][2]=fmaf(a,bv.z,acc[s][2]);
        acc[s][3]=fmaf(a,bv.w,acc[s][3]);
      }
    }
  }
  float4 scv = ((const float4*)sc2)[cg];
  float4 shv = ((const float4*)sh2)[cg];
  float4 sum = make_float4(0.f,0.f,0.f,0.f);
  #pragma unroll
  for(int s=0;s<9;s++){
    sum.x += fmaxf(fmaf(scv.x,acc[s][0],shv.x),0.f);
    sum.y += fmaxf(fmaf(scv.y,acc[s][1],shv.y),0.f);
    sum.z += fmaxf(fmaf(scv.z,acc[s][2],shv.z),0.f);
    sum.w += fmaxf(fmaf(scv.w,acc[s][3],shv.w),0.f);
  }
  sum.x*=(1.f/9.f); sum.y*=(1.f/9.f); sum.z*=(1.f/9.f); sum.w*=(1.f/9.f);
  *(float4*)(Zb64 + ((size_t)prob*TN + node0+nd)*64 + cg*4) = sum;
}

// Zb64 @ W3[64,16] + b3 -> xlf/xsf; grid (TN/64, 2)
__global__ __launch_bounds__(256) void k_gemm16d(const float* __restrict__ Zb64,
      const float* __restrict__ W, const float* __restrict__ bias,
      float* __restrict__ outl, float* __restrict__ outs){
  __shared__ float sZ[64*68];
  __shared__ float sW[64*16];
  const int prob = blockIdx.y;
  const float* A = Zb64 + (size_t)prob*TN*64;
  float* out = prob ? outs : outl;
  const int tid = threadIdx.x;
  const int row0 = blockIdx.x*64;
  for(int e=tid; e<64*16; e+=256){
    int r = e>>4, c4 = e&15;
    ((float4*)(sZ + r*68))[c4] = ((const float4*)(A + (size_t)(row0+r)*64))[c4];
  }
  ((float4*)sW)[tid] = ((const float4*)W)[tid];
  __syncthreads();
  const int tc = tid & 15, tr = tid >> 4;   // col tc, rows tr+rr*16
  float acc[4] = {0.f,0.f,0.f,0.f};
  #pragma unroll 4
  for(int k4=0;k4<16;k4++){
    float4 av[4];
    #pragma unroll
    for(int rr=0;rr<4;rr++) av[rr] = *(const float4*)(sZ + (tr+rr*16)*68 + k4*4);
    #pragma unroll
    for(int kk=0;kk<4;kk++){
      float bv = sW[(k4*4+kk)*16 + tc];
      #pragma unroll
      for(int rr=0;rr<4;rr++){
        float a = (kk==0)?av[rr].x:(kk==1)?av[rr].y:(kk==2)?av[rr].z:av[rr].w;
        acc[rr]=fmaf(a,bv,acc[rr]);
      }
    }
  }
  #pragma unroll
  for(int rr=0;rr<4;rr++){
    int r = row0 + tr + rr*16;
    out[(size_t)r*16 + tc] = acc[rr] + bias[tc];
  }
}

// ---------------- head MLP 128->64->32->1, block-tiled (32 rows/block) ----------------
__global__ __launch_bounds__(256) void k_head(const float* __restrict__ x1,
    const float* __restrict__ W1, const float* __restrict__ b1,
    const float* __restrict__ W2, const float* __restrict__ b2,
    const float* __restrict__ W3, const float* __restrict__ b3,
    float* __restrict__ h, float* __restrict__ pstat){
  __shared__ float sA[32*132];
  __shared__ float sW1[128*64];
  __shared__ float o1[32*68];
  __shared__ float sW2[64*32];
  __shared__ float o2[32*33];
  __shared__ float sb1[64], sb2[32], sW3v[32];
  __shared__ float rs[32], rq[32];
  const int tid = threadIdx.x;
  const int row0 = blockIdx.x*32;
  for(int e=tid; e<32*32; e+=256){
    int r = e>>5, c4 = e&31;
    ((float4*)(sA + r*132))[c4] = ((const float4*)(x1 + (size_t)(row0+r)*128))[c4];
  }
  for(int e=tid; e<128*64/4; e+=256) ((float4*)sW1)[e] = ((const float4*)W1)[e];
  for(int e=tid; e<64*32/4; e+=256)  ((float4*)sW2)[e] = ((const float4*)W2)[e];
  if(tid < 64) sb1[tid]=b1[tid];
  if(tid < 32){ sb2[tid]=b2[tid]; sW3v[tid]=W3[tid]; }
  __syncthreads();
  const int tc = tid & 15, tr = tid >> 4;
  float a1[2][4];
  #pragma unroll
  for(int rr=0;rr<2;rr++)
    #pragma unroll
    for(int e=0;e<4;e++) a1[rr][e]=0.f;
  for(int k4=0;k4<32;k4++){
    float4 av0 = *(const float4*)(sA + (tr*2  )*132 + k4*4);
    float4 av1 = *(const float4*)(sA + (tr*2+1)*132 + k4*4);
    #pragma unroll
    for(int kk=0;kk<4;kk++){
      float4 bv = *(const float4*)(sW1 + (k4*4+kk)*64 + tc*4);
      float p0 = (kk==0)?av0.x:(kk==1)?av0.y:(kk==2)?av0.z:av0.w;
      float p1 = (kk==0)?av1.x:(kk==1)?av1.y:(kk==2)?av1.z:av1.w;
      a1[0][0]=fmaf(p0,bv.x,a1[0][0]); a1[0][1]=fmaf(p0,bv.y,a1[0][1]);
      a1[0][2]=fmaf(p0,bv.z,a1[0][2]); a1[0][3]=fmaf(p0,bv.w,a1[0][3]);
      a1[1][0]=fmaf(p1,bv.x,a1[1][0]); a1[1][1]=fmaf(p1,bv.y,a1[1][1]);
      a1[1][2]=fmaf(p1,bv.z,a1[1][2]); a1[1][3]=fmaf(p1,bv.w,a1[1][3]);
    }
  }
  #pragma unroll
  for(int rr=0;rr<2;rr++)
    #pragma unroll
    for(int e=0;e<4;e++)
      o1[(tr*2+rr)*68 + tc*4+e] = fmaxf(a1[rr][e]+sb1[tc*4+e], 0.f);
  __syncthreads();
  float a2[2][2] = {{0.f,0.f},{0.f,0.f}};
  for(int k=0;k<64;k++){
    float w0 = sW2[k*32 + tc*2], w1 = sW2[k*32 + tc*2+1];
    float v0 = o1[(tr*2  )*68 + k];
    float v1 = o1[(tr*2+1)*68 + k];
    a2[0][0]=fmaf(v0,w0,a2[0][0]); a2[0][1]=fmaf(v0,w1,a2[0][1]);
    a2[1][0]=fmaf(v1,w0,a2[1][0]); a2[1][1]=fmaf(v1,w1,a2[1][1]);
  }
  #pragma unroll
  for(int rr=0;rr<2;rr++)
    #pragma unroll
    for(int cc=0;cc<2;cc++)
      o2[(tr*2+rr)*33 + tc*2+cc] = fmaxf(a2[rr][cc]+sb2[tc*2+cc], 0.f);
  __syncthreads();
  if(tid < 32){
    float hv = b3[0];
    #pragma unroll
    for(int k=0;k<32;k++) hv = fmaf(o2[tid*33+k], sW3v[k], hv);
    h[row0+tid]=hv;
    rs[tid]=hv; rq[tid]=hv*hv;
  }
  __syncthreads();
  if(tid==0){
    float S=0.f, Q=0.f;
    #pragma unroll
    for(int i=0;i<32;i++){ S+=rs[i]; Q+=rq[i]; }
    pstat[blockIdx.x*2]=S; pstat[blockIdx.x*2+1]=Q;
  }
}

__global__ __launch_bounds__(256) void k_fin_h(const float* __restrict__ pstat,
      float* __restrict__ hpar){
  __shared__ double sS[256], sQ[256];
  int t = threadIdx.x;
  sS[t] = (double)pstat[2*t]; sQ[t] = (double)pstat[2*t+1];
  __syncthreads();
  for(int s=128;s>0;s>>=1){
    if(t<s){ sS[t]+=sS[t+s]; sQ[t]+=sQ[t+s]; }
    __syncthreads();
  }
  if(t==0){
    double mu = sS[0]/8192.0;
    double var = (sQ[0] - 8192.0*mu*mu)/8191.0;   // ddof=1
    double sd = (var > 0) ? sqrt(var) : 0.0;
    hpar[0]=(float)mu;
    hpar[1]=(float)(1.0/(sd + 1e-5));
  }
}

__global__ __launch_bounds__(256) void k_gate(const float* __restrict__ h,
      const float* __restrict__ hpar, const float4* __restrict__ x,
      float4* __restrict__ xl, float4* __restrict__ xs){
  int i = blockIdx.x*256 + threadIdx.x;
  float z = (h[i]-hpar[0])*hpar[1];
  float o = 1.0f/(1.0f+expf(-z));
  float om = 1.0f - o;
  float4 v = x[i];
  xl[i] = make_float4(o*v.x, o*v.y, o*v.z, o*v.w);
  xs[i] = make_float4(om*v.x, om*v.y, om*v.z, om*v.w);
}

// ---------------- final: per-graph max pool (16ch x 2) + linear [32]->1 ----------------
__global__ __launch_bounds__(256) void k_final(const float* __restrict__ xlf,
      const float* __restrict__ xsf, const float* __restrict__ W,
      const float* __restrict__ b, float* __restrict__ out){
  __shared__ float red[32][8];
  int g = blockIdx.x;
  int c = threadIdx.x & 31;
  int chunk = threadIdx.x >> 5;
  const float* src = (c < 16) ? xlf : xsf;
  int ch = (c < 16) ? c : c-16;
  float m = -1e30f;
  for(int n=chunk*128; n<chunk*128+128; n++)
    m = fmaxf(m, src[((size_t)g*1024+n)*16 + ch]);
  red[c][chunk]=m;
  __syncthreads();
  if(threadIdx.x < 32){
    float mm = red[threadIdx.x][0];
    #pragma unroll
    for(int p=1;p<8;p++) mm = fmaxf(mm, red[threadIdx.x][p]);
    red[threadIdx.x][0]=mm;
  }
  __syncthreads();
  if(threadIdx.x == 0){
    float acc = b[0];
    for(int cc=0;cc<32;cc++) acc = fmaf(red[cc][0], W[cc], acc);
    out[g]=acc;
  }
}

// ---------------- launch ----------------
extern "C" void kernel_launch(void* const* d_in, const int* in_sizes, int n_in,
                              void* d_out, int out_size, void* d_ws, size_t ws_size,
                              hipStream_t stream){
  const float* x    =(const float*)d_in[0];
  const float* c1W1 =(const float*)d_in[1];
  const float* c1g1 =(const float*)d_in[3];
  const float* c1be1=(const float*)d_in[4];
  const float* c1W2 =(const float*)d_in[5];
  const float* c1g2 =(const float*)d_in[7];
  const float* c1be2=(const float*)d_in[8];
  const float* c1W3 =(const float*)d_in[9];
  const float* c1b3 =(const float*)d_in[10];
  const float* c3W1 =(const float*)d_in[11];
  const float* c3g1 =(const float*)d_in[13];
  const float* c3be1=(const float*)d_in[14];
  const float* c3W2 =(const float*)d_in[15];
  const float* c3g2 =(const float*)d_in[17];
  const float* c3be2=(const float*)d_in[18];
  const float* c3W3 =(const float*)d_in[19];
  const float* c3b3 =(const float*)d_in[20];
  const float* hW1  =(const float*)d_in[21];
  const float* hb1  =(const float*)d_in[22];
  const float* hW2  =(const float*)d_in[23];
  const float* hb2  =(const float*)d_in[24];
  const float* hW3  =(const float*)d_in[25];
  const float* hb3  =(const float*)d_in[26];
  const float* l2W  =(const float*)d_in[27];
  const float* l2b  =(const float*)d_in[28];
  (void)in_sizes; (void)n_in; (void)out_size; (void)ws_size;

  char* wsb=(char*)d_ws;
  size_t off=0;
  auto alloc=[&](size_t bytes)->char*{
    char* p = wsb + off;
    off = (off + bytes + 255) & ~(size_t)255;
    return p;
  };
  float* ovl  =(float*)alloc((size_t)NSYB*16512*4);  // overlay: lists / conv1 mpartM / conv3 mpartMd
  float* x1   =(float*)alloc((size_t)TN*128*4);
  float* Zb   =(float*)alloc((size_t)TN*128*4);   // conv1 Zb / conv3 Zb64 (dual)
  int*   idx1 =(int*)  alloc((size_t)TK*4);
  int*   idxl =(int*)  alloc((size_t)TK*4);
  int*   idxs =(int*)  alloc((size_t)TK*4);
  float* pd   =(float*)alloc((size_t)2*TN*72*4);
  float* h    =(float*)alloc((size_t)TN*4);
  float* xl   =(float*)alloc((size_t)TN*16);
  float* xs   =(float*)alloc((size_t)TN*16);
  float* xlf  =(float*)alloc((size_t)TN*16*4);
  float* xsf  =(float*)alloc((size_t)TN*16*4);
  float* pstat=(float*)alloc((size_t)512*4);
  double* Md  =(double*)alloc((size_t)16512*8);
  double* Mdd =(double*)alloc((size_t)8320*8);
  double* pp8 =(double*)alloc((size_t)8*16512*8);
  float* mp44 =(float*)alloc((size_t)288*44*4);
  float* mp44d=(float*)alloc((size_t)2*288*44*4);
  float* tl   =(float*)alloc((size_t)TN*4);
  float* tg   =(float*)alloc((size_t)2*TN*4);
  unsigned char* cnt8l=(unsigned char*)alloc((size_t)TN*8);
  unsigned char* cnt8g=(unsigned char*)alloc((size_t)2*TN*NCHG);
  float* bnp  =(float*)alloc(1024*4);
  float* hpar =(float*)alloc(64);

  float* sc1=bnp,      *sh1=bnp+128, *sc2=bnp+256, *sh2=bnp+384;
  float* scA=bnp+512,  *shA=bnp+640, *scB=bnp+768, *shB=bnp+896;  // conv3: [prob][64]
  unsigned short* listl=(unsigned short*)ovl;   // overlay (disjoint in time)
  unsigned short* listg=(unsigned short*)ovl;
  float* mpartM = ovl;
  float* mpartMd = ovl;

  // ---- conv1 kNN (per-graph) ----
  k_part_local  <<<256,256,0,stream>>>((const float4*)x, pd);
  k_thresh_local<<<32, 256,0,stream>>>(pd, tl);
  k_collect_local<<<256,256,0,stream>>>((const float4*)x, tl, cnt8l, listl);
  k_refine_local<<<TN/32,256,0,stream>>>((const float4*)x, cnt8l, listl, idx1);
  // ---- conv1 (moment-based, no Y materialization) ----
  k_mom8<<<288,256,0,stream>>>((const float4*)x, idx1, mp44);
  k_bn1q<<<1,128,0,stream>>>(mp44, c1W1, c1g1, c1be1, sc1, sh1);
  k_syrk128<<<NSYB,256,0,stream>>>((const float4*)x, idx1, c1W1, sc1, sh1, mpartM);
  k_redA<<<dim3(65,8),256,0,stream>>>(mpartM, pp8);
  k_redB<<<65,256,0,stream>>>(pp8, Md);
  k_bn2q<<<128,128,0,stream>>>(Md, c1W2, c1g2, c1be2, sc2, sh2);
  k_midagg<<<1024,256,0,stream>>>((const float4*)x, idx1, c1W1, sc1, sh1, c1W2, sc2, sh2, Zb);
  k_gemm128<<<TN/32,256,0,stream>>>(Zb, c1W3, c1b3, x1);
  // ---- head + gate ----
  k_head<<<TN/32,256,0,stream>>>(x1,hW1,hb1,hW2,hb2,hW3,hb3,h,pstat);
  k_fin_h<<<1,256,0,stream>>>(pstat,hpar);
  k_gate<<<32,256,0,stream>>>(h,hpar,(const float4*)x,(float4*)xl,(float4*)xs);
  // ---- global kNN for xl & xs ----
  k_part_sub   <<<dim3(256,2),256,0,stream>>>((const float4*)xl,(const float4*)xs,pd);
  k_thresh_sub <<<64,256,0,stream>>>(pd,tg);
  k_collect_glob<<<dim3(512,2),256,0,stream>>>((const float4*)xl,(const float4*)xs,tg,cnt8g,listg);
  k_refine_glob<<<2*TN/32,256,0,stream>>>((const float4*)xl,(const float4*)xs,cnt8g,listg,idxl,idxs);
  // ---- conv3 on xl & xs (moment-based, dual) ----
  k_mom8d<<<dim3(288,2),256,0,stream>>>((const float4*)xl,(const float4*)xs,idxl,idxs,mp44d);
  k_bn1qd<<<1,128,0,stream>>>(mp44d, c3W1, c3g1, c3be1, scA, shA);
  k_syrk64d<<<dim3(288,2),256,0,stream>>>((const float4*)xl,(const float4*)xs,idxl,idxs,c3W1,scA,shA,mpartMd);
  k_redMd<<<33,256,0,stream>>>(mpartMd, Mdd);
  k_bn2qd<<<dim3(64,2),64,0,stream>>>(Mdd, c3W2, c3g2, c3be2, scB, shB);
  k_midagg64d<<<dim3(512,2),256,0,stream>>>((const float4*)xl,(const float4*)xs,idxl,idxs,
      c3W1, scA, shA, c3W2, scB, shB, Zb);
  k_gemm16d<<<dim3(TN/64,2),256,0,stream>>>(Zb, c3W3, c3b3, xlf, xsf);
  // ---- final pooling + linear ----
  k_final<<<8,256,0,stream>>>(xlf,xsf,l2W,l2b,(float*)d_out);
}

// Round 18
// 406.753 us; speedup vs baseline: 1.6655x; 1.0399x over previous
//
#include <hip/hip_runtime.h>
#include <math.h>

#define TN 8192          // total nodes (B*N)
#define KNN 9
#define NPG 1024         // nodes per graph
#define TK (TN*KNN)      // 73728 edge rows
#define CPCL 12          // cap per (node,chunk), local (8 chunks of 128)
#define NCHG 32          // global chunks (of 256 candidates)
#define CPCG 16          // cap per (node,chunk), global
#define NSYB 768         // syrk128 blocks

// ---------------- helpers ----------------
__device__ __forceinline__ float sqnorm(float4 v){
  return fmaf(v.x,v.x,fmaf(v.y,v.y,fmaf(v.z,v.z,v.w*v.w)));
}
__device__ __forceinline__ float pairdist(float4 a, float sqa, float4 b, float sqb){
  float dot = fmaf(a.x,b.x,fmaf(a.y,b.y,fmaf(a.z,b.z,a.w*b.w)));
  return sqa + sqb - 2.0f*dot;
}
__device__ __forceinline__ void chain9(float (&bd)[9], float d){
  float t=d;
  #pragma unroll
  for(int p=0;p<9;p++){
    float lo=fminf(bd[p],t);
    t=fmaxf(bd[p],t);
    bd[p]=lo;
  }
}
__device__ __forceinline__ void insert9(float (&bd)[9], int (&bi)[9], float d, int id){
  if(d < bd[8]){
    float td=d; int ti=id;
    #pragma unroll
    for(int p=0;p<9;p++){
      bool sw = (td < bd[p]);
      float nbd = sw ? td : bd[p];
      int   nbi = sw ? ti : bi[p];
      float ntd = sw ? bd[p] : td;
      int   nti = sw ? bi[p] : ti;
      bd[p]=nbd; bi[p]=nbi; td=ntd; ti=nti;
    }
  }
}

// ---------------- kNN: local (per-graph) ----------------
__global__ __launch_bounds__(256) void k_part_local(const float4* __restrict__ x, float* __restrict__ pd){
  __shared__ float4 sx[128]; __shared__ float ssq[128];
  int nb = blockIdx.x >> 3, chunk = blockIdx.x & 7;
  int g = nb >> 2;
  int cbase = g*NPG + chunk*128;
  if(threadIdx.x < 128){
    float4 v = x[cbase + threadIdx.x];
    sx[threadIdx.x]=v; ssq[threadIdx.x]=sqnorm(v);
  }
  __syncthreads();
  int node = nb*256 + threadIdx.x;
  float4 xi = x[node]; float sqi = sqnorm(xi);
  float bdA[9], bdB[9];
  #pragma unroll
  for(int q=0;q<9;q++){bdA[q]=1e30f;bdB[q]=1e30f;}
  for(int j=0;j<128;j+=2){
    chain9(bdA, pairdist(xi,sqi,sx[j],ssq[j]));
    chain9(bdB, pairdist(xi,sqi,sx[j+1],ssq[j+1]));
  }
  #pragma unroll
  for(int q=0;q<9;q++) chain9(bdA, bdB[q]);
  #pragma unroll
  for(int q=0;q<9;q++) pd[(size_t)(chunk*9+q)*TN + node]=bdA[q];
}

__global__ __launch_bounds__(256) void k_thresh_local(const float* __restrict__ pd,
      float* __restrict__ tl){
  int node = blockIdx.x*256 + threadIdx.x;
  float bd[9];
  #pragma unroll
  for(int q=0;q<9;q++) bd[q]=1e30f;
  for(int m=0;m<72;m++) chain9(bd, pd[(size_t)m*TN + node]);
  float t = bd[8];
  tl[node] = t + fabsf(t)*1e-5f + 1e-12f;
}

__global__ __launch_bounds__(256) void k_collect_local(const float4* __restrict__ x,
      const float* __restrict__ tl, unsigned char* __restrict__ cnt8,
      unsigned short* __restrict__ list){
  __shared__ float4 sx[128]; __shared__ float ssq[128];
  int nb = blockIdx.x >> 3, chunk = blockIdx.x & 7;
  int g = nb >> 2;
  int cbase = g*NPG + chunk*128;
  if(threadIdx.x < 128){
    float4 v = x[cbase + threadIdx.x];
    sx[threadIdx.x]=v; ssq[threadIdx.x]=sqnorm(v);
  }
  __syncthreads();
  int node = nb*256 + threadIdx.x;
  float4 xi = x[node];
  float m2x=-2.0f*xi.x, m2y=-2.0f*xi.y, m2z=-2.0f*xi.z, m2w=-2.0f*xi.w;
  float tadj = tl[node] - sqnorm(xi);
  int cnt = 0;
  unsigned short* lst = list + ((size_t)node*8 + chunk)*CPCL;
  for(int j=0;j<128;j+=4){
    float4 v0=sx[j], v1=sx[j+1], v2=sx[j+2], v3=sx[j+3];
    float q0=ssq[j], q1=ssq[j+1], q2=ssq[j+2], q3=ssq[j+3];
    float s0=fmaf(v0.x,m2x,fmaf(v0.y,m2y,fmaf(v0.z,m2z,fmaf(v0.w,m2w,q0))));
    float s1=fmaf(v1.x,m2x,fmaf(v1.y,m2y,fmaf(v1.z,m2z,fmaf(v1.w,m2w,q1))));
    float s2=fmaf(v2.x,m2x,fmaf(v2.y,m2y,fmaf(v2.z,m2z,fmaf(v2.w,m2w,q2))));
    float s3=fmaf(v3.x,m2x,fmaf(v3.y,m2y,fmaf(v3.z,m2z,fmaf(v3.w,m2w,q3))));
    if(s0<=tadj){ if(cnt<CPCL) lst[cnt]=(unsigned short)(cbase+j  ); cnt++; }
    if(s1<=tadj){ if(cnt<CPCL) lst[cnt]=(unsigned short)(cbase+j+1); cnt++; }
    if(s2<=tadj){ if(cnt<CPCL) lst[cnt]=(unsigned short)(cbase+j+2); cnt++; }
    if(s3<=tadj){ if(cnt<CPCL) lst[cnt]=(unsigned short)(cbase+j+3); cnt++; }
  }
  cnt8[(size_t)node*8 + chunk] = (unsigned char)(cnt > 255 ? 255 : cnt);
}

// 8 threads per node: sub handles 1 chunk; LDS merge of 8 partial top-9s
__global__ __launch_bounds__(256) void k_refine_local(const float4* __restrict__ x,
      const unsigned char* __restrict__ cnt8, const unsigned short* __restrict__ list,
      int* __restrict__ out){
  __shared__ float sval[32][73];
  __shared__ int   sidx[32][73];
  __shared__ int   sovf[32];
  int slot = threadIdx.x >> 3, sub = threadIdx.x & 7;
  int node = blockIdx.x*32 + slot;
  if(sub==0) sovf[slot]=0;
  __syncthreads();
  float4 xi = x[node]; float sqi = sqnorm(xi);
  float bd[9]; int bi[9];
  #pragma unroll
  for(int q=0;q<9;q++){bd[q]=1e30f; bi[q]=node;}
  int ch = sub;
  int c = cnt8[(size_t)node*8 + ch];
  if(c > CPCL) sovf[slot]=1;
  int n = c < CPCL ? c : CPCL;
  const unsigned short* lst = list + ((size_t)node*8 + ch)*CPCL;
  for(int m=0;m<n;m++){
    int j = lst[m]; float4 v = x[j];
    insert9(bd,bi, pairdist(xi,sqi,v,sqnorm(v)), j);
  }
  #pragma unroll
  for(int q=0;q<9;q++){ sval[slot][sub*9+q]=bd[q]; sidx[slot][sub*9+q]=bi[q]; }
  __syncthreads();
  if(sub==0){
    for(int m=9;m<72;m++) insert9(bd,bi, sval[slot][m], sidx[slot][m]);
    if(sovf[slot]){
      #pragma unroll
      for(int q=0;q<9;q++){bd[q]=1e30f; bi[q]=node;}
      int gbase = node & ~(NPG-1);
      for(int j=gbase;j<gbase+NPG;j++){
        float4 v = x[j];
        insert9(bd,bi, pairdist(xi,sqi,v,sqnorm(v)), j);
      }
    }
    #pragma unroll
    for(int q=0;q<9;q++) out[(size_t)node*9+q]=bi[q];
  }
}

// ---------------- kNN: global (two problems: xl, xs) ----------------
__global__ __launch_bounds__(256) void k_part_sub(const float4* __restrict__ xa,
      const float4* __restrict__ xb, float* __restrict__ pd){
  const float4* x = blockIdx.y ? xb : xa;
  __shared__ float4 sx[256]; __shared__ float ssq[256];
  int nb = blockIdx.x >> 3, chunk = blockIdx.x & 7;
  {
    int j = (chunk*256 + threadIdx.x)*4;
    float4 v = x[j];
    sx[threadIdx.x]=v; ssq[threadIdx.x]=sqnorm(v);
  }
  __syncthreads();
  int node = nb*256 + threadIdx.x;
  float4 xi = x[node]; float sqi = sqnorm(xi);
  float bdA[9], bdB[9];
  #pragma unroll
  for(int q=0;q<9;q++){bdA[q]=1e30f;bdB[q]=1e30f;}
  for(int j=0;j<256;j+=2){
    chain9(bdA, pairdist(xi,sqi,sx[j],ssq[j]));
    chain9(bdB, pairdist(xi,sqi,sx[j+1],ssq[j+1]));
  }
  #pragma unroll
  for(int q=0;q<9;q++) chain9(bdA, bdB[q]);
  int pn = blockIdx.y*TN + node;
  #pragma unroll
  for(int q=0;q<9;q++) pd[(size_t)(chunk*9+q)*2*TN + pn]=bdA[q];
}

__global__ __launch_bounds__(256) void k_thresh_sub(const float* __restrict__ pd,
      float* __restrict__ tg){
  int pn = blockIdx.x*256 + threadIdx.x;   // < 2*TN
  float bd[9];
  #pragma unroll
  for(int q=0;q<9;q++) bd[q]=1e30f;
  for(int m=0;m<72;m++) chain9(bd, pd[(size_t)m*2*TN + pn]);
  float t = bd[8];
  tg[pn] = t + fabsf(t)*1e-5f + 1e-12f;
}

// 2 nodes/thread, 32 chunks of 256 cands: grid (16*32, 2) = 1024 blocks
__global__ __launch_bounds__(256) void k_collect_glob(const float4* __restrict__ xa,
      const float4* __restrict__ xb, const float* __restrict__ tg,
      unsigned char* __restrict__ cnt8, unsigned short* __restrict__ list){
  const float4* x = blockIdx.y ? xb : xa;
  __shared__ float4 sx[256];
  __shared__ float4 ssq4[64];
  int nb = blockIdx.x >> 5, chunk = blockIdx.x & 31;
  int cbase = chunk*256;
  {
    float4 v = x[cbase+threadIdx.x];
    sx[threadIdx.x]=v; ((float*)ssq4)[threadIdx.x]=sqnorm(v);
  }
  __syncthreads();
  int node0 = nb*512 + threadIdx.x;
  int node1 = node0 + 256;
  int pn0 = blockIdx.y*TN + node0;
  int pn1 = pn0 + 256;
  float4 xi0 = x[node0], xi1 = x[node1];
  float a0x=-2.0f*xi0.x, a0y=-2.0f*xi0.y, a0z=-2.0f*xi0.z, a0w=-2.0f*xi0.w;
  float a1x=-2.0f*xi1.x, a1y=-2.0f*xi1.y, a1z=-2.0f*xi1.z, a1w=-2.0f*xi1.w;
  float t0 = tg[pn0] - sqnorm(xi0);
  float t1 = tg[pn1] - sqnorm(xi1);
  int c0 = 0, c1 = 0;
  unsigned short* l0 = list + ((size_t)pn0*NCHG + chunk)*CPCG;
  unsigned short* l1 = list + ((size_t)pn1*NCHG + chunk)*CPCG;
  for(int j=0;j<256;j+=4){
    float4 v0=sx[j], v1=sx[j+1], v2=sx[j+2], v3=sx[j+3];
    float4 qv = ssq4[j>>2];
    float s00=fmaf(v0.x,a0x,fmaf(v0.y,a0y,fmaf(v0.z,a0z,fmaf(v0.w,a0w,qv.x))));
    float s01=fmaf(v1.x,a0x,fmaf(v1.y,a0y,fmaf(v1.z,a0z,fmaf(v1.w,a0w,qv.y))));
    float s02=fmaf(v2.x,a0x,fmaf(v2.y,a0y,fmaf(v2.z,a0z,fmaf(v2.w,a0w,qv.z))));
    float s03=fmaf(v3.x,a0x,fmaf(v3.y,a0y,fmaf(v3.z,a0z,fmaf(v3.w,a0w,qv.w))));
    float s10=fmaf(v0.x,a1x,fmaf(v0.y,a1y,fmaf(v0.z,a1z,fmaf(v0.w,a1w,qv.x))));
    float s11=fmaf(v1.x,a1x,fmaf(v1.y,a1y,fmaf(v1.z,a1z,fmaf(v1.w,a1w,qv.y))));
    float s12=fmaf(v2.x,a1x,fmaf(v2.y,a1y,fmaf(v2.z,a1z,fmaf(v2.w,a1w,qv.z))));
    float s13=fmaf(v3.x,a1x,fmaf(v3.y,a1y,fmaf(v3.z,a1z,fmaf(v3.w,a1w,qv.w))));
    if(s00<=t0){ if(c0<CPCG) l0[c0]=(unsigned short)(cbase+j  ); c0++; }
    if(s01<=t0){ if(c0<CPCG) l0[c0]=(unsigned short)(cbase+j+1); c0++; }
    if(s02<=t0){ if(c0<CPCG) l0[c0]=(unsigned short)(cbase+j+2); c0++; }
    if(s03<=t0){ if(c0<CPCG) l0[c0]=(unsigned short)(cbase+j+3); c0++; }
    if(s10<=t1){ if(c1<CPCG) l1[c1]=(unsigned short)(cbase+j  ); c1++; }
    if(s11<=t1){ if(c1<CPCG) l1[c1]=(unsigned short)(cbase+j+1); c1++; }
    if(s12<=t1){ if(c1<CPCG) l1[c1]=(unsigned short)(cbase+j+2); c1++; }
    if(s13<=t1){ if(c1<CPCG) l1[c1]=(unsigned short)(cbase+j+3); c1++; }
  }
  cnt8[(size_t)pn0*NCHG + chunk] = (unsigned char)(c0 > 255 ? 255 : c0);
  cnt8[(size_t)pn1*NCHG + chunk] = (unsigned char)(c1 > 255 ? 255 : c1);
}

// 8 threads per node: sub handles 4 chunks; LDS merge of 8 partial top-9s
__global__ __launch_bounds__(256) void k_refine_glob(const float4* __restrict__ xa,
      const float4* __restrict__ xb, const unsigned char* __restrict__ cnt8,
      const unsigned short* __restrict__ list, int* __restrict__ outl, int* __restrict__ outs){
  __shared__ float sval[32][73];
  __shared__ int   sidx[32][73];
  __shared__ int   sovf[32];
  int slot = threadIdx.x >> 3, sub = threadIdx.x & 7;
  int pn = blockIdx.x*32 + slot;          // < 2*TN; grid = 512
  int prob = blockIdx.x >> 8;             // uniform per block
  int node = pn & (TN-1);
  const float4* x = prob ? xb : xa;
  if(sub==0) sovf[slot]=0;
  __syncthreads();
  float4 xi = x[node]; float sqi = sqnorm(xi);
  float bd[9]; int bi[9];
  #pragma unroll
  for(int q=0;q<9;q++){bd[q]=1e30f; bi[q]=node;}
  bool ovf=false;
  for(int ch=sub*4; ch<sub*4+4; ch++){
    int c = cnt8[(size_t)pn*NCHG + ch];
    if(c > CPCG) ovf=true;
    int n = c < CPCG ? c : CPCG;
    const unsigned short* lst = list + ((size_t)pn*NCHG + ch)*CPCG;
    for(int m=0;m<n;m++){
      int j = lst[m]; float4 v = x[j];
      insert9(bd,bi, pairdist(xi,sqi,v,sqnorm(v)), j);
    }
  }
  if(ovf) sovf[slot]=1;
  #pragma unroll
  for(int q=0;q<9;q++){ sval[slot][sub*9+q]=bd[q]; sidx[slot][sub*9+q]=bi[q]; }
  __syncthreads();
  if(sub==0){
    for(int m=9;m<72;m++) insert9(bd,bi, sval[slot][m], sidx[slot][m]);
    if(sovf[slot]){
      #pragma unroll
      for(int q=0;q<9;q++){bd[q]=1e30f; bi[q]=node;}
      for(int j=0;j<TN;j++){
        float4 v = x[j];
        insert9(bd,bi, pairdist(xi,sqi,v,sqnorm(v)), j);
      }
    }
    int* o = prob ? outs : outl;
    #pragma unroll
    for(int q=0;q<9;q++) o[(size_t)node*9+q]=bi[q];
  }
}

// ---------------- conv1: moment-based BN, fused recompute (no Y materialization) ----------------
__global__ __launch_bounds__(256) void k_mom8(const float4* __restrict__ x,
      const int* __restrict__ idx, float* __restrict__ mpart){
  __shared__ float sa[256][9];
  int t = threadIdx.x;
  int e = blockIdx.x*256 + t;
  int i = e/KNN; int j = idx[e];
  float4 xi = x[i], xj = x[j];
  sa[t][0]=xi.x; sa[t][1]=xi.y; sa[t][2]=xi.z; sa[t][3]=xi.w;
  sa[t][4]=xj.x-xi.x; sa[t][5]=xj.y-xi.y; sa[t][6]=xj.z-xi.z; sa[t][7]=xj.w-xi.w;
  __syncthreads();
  if(t < 44){
    float s=0.f;
    if(t<8){
      for(int e2=0;e2<256;e2++) s += sa[e2][t];
    } else {
      int f=t-8, p=0, q=0, acc=0;
      for(p=0;p<8;p++){ int cnt=8-p; if(f<acc+cnt){ q=p+(f-acc); break;} acc+=cnt; }
      for(int e2=0;e2<256;e2++) s += sa[e2][p]*sa[e2][q];
    }
    mpart[blockIdx.x*44+t]=s;
  }
}

__global__ void k_bn1q(const float* __restrict__ mpart, const float* __restrict__ W1,
      const float* __restrict__ g, const float* __restrict__ be,
      float* __restrict__ scale, float* __restrict__ shift){
  __shared__ double mom[44];
  int t = threadIdx.x;   // 128
  if(t<44){ double s=0; for(int b=0;b<288;b++) s+=(double)mpart[b*44+t]; mom[t]=s; }
  __syncthreads();
  double m[8], w[8];
  #pragma unroll
  for(int p=0;p<8;p++){ m[p]=mom[p]/(double)TK; w[p]=(double)W1[p*128+t]; }
  double q=0.0; int f=8;
  for(int p=0;p<8;p++)
    for(int qq=p;qq<8;qq++){
      double cov = mom[f]/(double)TK - m[p]*m[qq];
      q += (p==qq?1.0:2.0)*w[p]*w[qq]*cov;
      f++;
    }
  if(q<0) q=0;
  double sc = (double)g[t]/sqrt(q+1e-5);
  double mu=0; for(int p=0;p<8;p++) mu += m[p]*w[p];
  scale[t]=(float)sc;
  shift[t]=(float)((double)be[t] - mu*sc);
}

// SYRK v6: 768 blocks x 96 edges (2 passes of 48); split column groups
__global__ __launch_bounds__(256) void k_syrk128(const float4* __restrict__ x,
      const int* __restrict__ idx, const float* __restrict__ W1,
      const float* __restrict__ sc1, const float* __restrict__ sh1,
      float* __restrict__ mpartM){
  __shared__ float sa[48][9];
  __shared__ float sW1[8*128];
  __shared__ float sZ[48*132];
  __shared__ float ssum[128];
  const int tid = threadIdx.x;
  ((float4*)sW1)[tid] = ((const float4*)W1)[tid];
  if(tid<128) ssum[tid]=0.f;
  const int zc4 = tid & 31, ze0 = tid >> 5;     // z-compute mapping
  const int gi = tid >> 4, gj = tid & 15;       // syrk tile indices
  const int ia = gi*4, ib = 64 + gi*4;          // row groups
  const int ja = gj*4, jb = 64 + gj*4;          // col groups
  float acc[8][8];
  #pragma unroll
  for(int a=0;a<8;a++)
    #pragma unroll
    for(int b=0;b<8;b++) acc[a][b]=0.f;
  float ls[4]={0,0,0,0};
  float4 scv = ((const float4*)sc1)[zc4];
  float4 shv = ((const float4*)sh1)[zc4];
  for(int pass=0;pass<2;pass++){
    __syncthreads();
    if(tid<48){
      int e = blockIdx.x*96 + pass*48 + tid;
      int i = e/KNN; int j = idx[e];
      float4 xi = x[i], xj = x[j];
      sa[tid][0]=xi.x; sa[tid][1]=xi.y; sa[tid][2]=xi.z; sa[tid][3]=xi.w;
      sa[tid][4]=xj.x-xi.x; sa[tid][5]=xj.y-xi.y; sa[tid][6]=xj.z-xi.z; sa[tid][7]=xj.w-xi.w;
    }
    __syncthreads();
    for(int e=ze0; e<48; e+=8){
      float4 y = make_float4(0.f,0.f,0.f,0.f);
      #pragma unroll
      for(int k=0;k<8;k++){
        float a = sa[e][k];
        float4 wv = *(const float4*)(sW1 + k*128 + zc4*4);
        y.x=fmaf(a,wv.x,y.x); y.y=fmaf(a,wv.y,y.y);
        y.z=fmaf(a,wv.z,y.z); y.w=fmaf(a,wv.w,y.w);
      }
      float4 z;
      z.x = fmaxf(fmaf(scv.x,y.x,shv.x),0.f);
      z.y = fmaxf(fmaf(scv.y,y.y,shv.y),0.f);
      z.z = fmaxf(fmaf(scv.z,y.z,shv.z),0.f);
      z.w = fmaxf(fmaf(scv.w,y.w,shv.w),0.f);
      *(float4*)(sZ + e*132 + zc4*4) = z;
      ls[0]+=z.x; ls[1]+=z.y; ls[2]+=z.z; ls[3]+=z.w;
    }
    __syncthreads();
    #pragma unroll 2
    for(int e=0;e<48;e++){
      const float* rz = sZ + e*132;
      float4 zi0 = *(const float4*)(rz + ia);
      float4 zi1 = *(const float4*)(rz + ib);
      float4 zj0 = *(const float4*)(rz + ja);
      float4 zj1 = *(const float4*)(rz + jb);
      float zi[8] = {zi0.x,zi0.y,zi0.z,zi0.w,zi1.x,zi1.y,zi1.z,zi1.w};
      float zj[8] = {zj0.x,zj0.y,zj0.z,zj0.w,zj1.x,zj1.y,zj1.z,zj1.w};
      #pragma unroll
      for(int a=0;a<8;a++)
        #pragma unroll
        for(int b=0;b<8;b++) acc[a][b]=fmaf(zi[a],zj[b],acc[a][b]);
    }
  }
  #pragma unroll
  for(int c=0;c<4;c++) atomicAdd(&ssum[zc4*4+c], ls[c]);
  float* mp = mpartM + (size_t)blockIdx.x*16512;
  #pragma unroll
  for(int a=0;a<8;a++){
    int row = (a<4) ? (ia+a) : (ib+a-4);
    *(float4*)(mp + row*128 + ja) = make_float4(acc[a][0],acc[a][1],acc[a][2],acc[a][3]);
    *(float4*)(mp + row*128 + jb) = make_float4(acc[a][4],acc[a][5],acc[a][6],acc[a][7]);
  }
  __syncthreads();
  if(tid<128) mp[16384+tid] = ssum[tid];
}

// 2-stage reduce of 768 partials: stage A grid (65,8) sums 96 each; stage B sums 8
__global__ __launch_bounds__(256) void k_redA(const float* __restrict__ mpartM,
      double* __restrict__ pp8){
  int ch = blockIdx.x*256 + threadIdx.x;
  if(ch >= 16512) return;
  int y = blockIdx.y;
  double s=0;
  for(int b=y*96;b<y*96+96;b++) s += (double)mpartM[(size_t)b*16512 + ch];
  pp8[(size_t)y*16512 + ch]=s;
}

__global__ __launch_bounds__(256) void k_redB(const double* __restrict__ pp8,
      double* __restrict__ Md){
  int ch = blockIdx.x*256 + threadIdx.x;
  if(ch >= 16512) return;
  double s=0;
  #pragma unroll
  for(int y=0;y<8;y++) s += pp8[(size_t)y*16512 + ch];
  Md[ch]=s;
}

__global__ void k_bn2q(const double* __restrict__ Md, const float* __restrict__ W2,
      const float* __restrict__ g, const float* __restrict__ be,
      float* __restrict__ scale, float* __restrict__ shift){
  __shared__ double redq[128], redt[128];
  __shared__ float sw[128];
  int c = blockIdx.x, t = threadIdx.x;   // 128 threads
  sw[t] = W2[t*128+c];
  __syncthreads();
  double zb = Md[16384+t]/(double)TK;
  double inner=0;
  for(int j=0;j<128;j++) inner += Md[t*128+j]*(double)sw[j];
  redq[t] = (double)sw[t]*(inner/(double)TK);
  redt[t] = (double)sw[t]*zb;
  __syncthreads();
  for(int s=64;s>0;s>>=1){
    if(t<s){ redq[t]+=redq[t+s]; redt[t]+=redt[t+s]; }
    __syncthreads();
  }
  if(t==0){
    double var = redq[0] - redt[0]*redt[0];
    if(var<0) var=0;
    double sc = (double)g[c]/sqrt(var+1e-5);
    scale[c]=(float)sc;
    shift[c]=(float)((double)be[c] - redt[0]*sc);
  }
}

// fused: gather A (8 nodes, 72 edges) -> z1 recompute -> GEMM x W2 (global, broadcast)
// -> BN2+ReLU -> mean over 9 -> Zb (LDS) -> GEMM x W3 + b3 -> x1[node][128]
__global__ __launch_bounds__(256) void k_midagg(const float4* __restrict__ x,
      const int* __restrict__ idx, const float* __restrict__ W1,
      const float* __restrict__ sc1, const float* __restrict__ sh1,
      const float* __restrict__ W2, const float* __restrict__ sc2,
      const float* __restrict__ sh2, const float* __restrict__ W3,
      const float* __restrict__ b3, float* __restrict__ x1){
  __shared__ float sa[72][9];
  __shared__ float sW1[8*128];
  __shared__ float sZ[72*132];
  const int tid = threadIdx.x;
  const int node0 = blockIdx.x*8;
  if(tid<256) ((float4*)sW1)[tid] = ((const float4*)W1)[tid];
  if(tid<72){
    int e = blockIdx.x*72 + tid;
    int i = e/KNN; int j = idx[e];
    float4 xi = x[i], xj = x[j];
    sa[tid][0]=xi.x; sa[tid][1]=xi.y; sa[tid][2]=xi.z; sa[tid][3]=xi.w;
    sa[tid][4]=xj.x-xi.x; sa[tid][5]=xj.y-xi.y; sa[tid][6]=xj.z-xi.z; sa[tid][7]=xj.w-xi.w;
  }
  __syncthreads();
  for(int f=tid; f<2304; f+=256){
    int e = f>>5, c4 = f&31;
    float4 scv = ((const float4*)sc1)[c4];
    float4 shv = ((const float4*)sh1)[c4];
    float4 y = make_float4(0.f,0.f,0.f,0.f);
    #pragma unroll
    for(int k=0;k<8;k++){
      float a = sa[e][k];
      float4 wv = *(const float4*)(sW1 + k*128 + c4*4);
      y.x=fmaf(a,wv.x,y.x); y.y=fmaf(a,wv.y,y.y);
      y.z=fmaf(a,wv.z,y.z); y.w=fmaf(a,wv.w,y.w);
    }
    float4 z;
    z.x = fmaxf(fmaf(scv.x,y.x,shv.x),0.f);
    z.y = fmaxf(fmaf(scv.y,y.y,shv.y),0.f);
    z.z = fmaxf(fmaf(scv.z,y.z,shv.z),0.f);
    z.w = fmaxf(fmaf(scv.w,y.w,shv.w),0.f);
    *(float4*)(sZ + e*132 + c4*4) = z;
  }
  __syncthreads();
  const int tc = tid & 31, tr = tid >> 5;  // node tr, cols tc*4
  float acc[9][4];
  #pragma unroll
  for(int s=0;s<9;s++)
    #pragma unroll
    for(int e=0;e<4;e++) acc[s][e]=0.f;
  #pragma unroll 2
  for(int k4=0;k4<32;k4++){
    float4 av[9];
    #pragma unroll
    for(int s=0;s<9;s++) av[s] = *(const float4*)(sZ + (tr*9+s)*132 + k4*4);
    #pragma unroll
    for(int kk=0;kk<4;kk++){
      float4 bv = *(const float4*)(W2 + (size_t)(k4*4+kk)*128 + tc*4);
      #pragma unroll
      for(int s=0;s<9;s++){
        float a = (kk==0)?av[s].x:(kk==1)?av[s].y:(kk==2)?av[s].z:av[s].w;
        acc[s][0]=fmaf(a,bv.x,acc[s][0]);
        acc[s][1]=fmaf(a,bv.y,acc[s][1]);
        acc[s][2]=fmaf(a,bv.z,acc[s][2]);
        acc[s][3]=fmaf(a,bv.w,acc[s][3]);
      }
    }
  }
  float4 scv = ((const float4*)sc2)[tc];
  float4 shv = ((const float4*)sh2)[tc];
  float4 sum = make_float4(0.f,0.f,0.f,0.f);
  #pragma unroll
  for(int s=0;s<9;s++){
    sum.x += fmaxf(fmaf(scv.x,acc[s][0],shv.x),0.f);
    sum.y += fmaxf(fmaf(scv.y,acc[s][1],shv.y),0.f);
    sum.z += fmaxf(fmaf(scv.z,acc[s][2],shv.z),0.f);
    sum.w += fmaxf(fmaf(scv.w,acc[s][3],shv.w),0.f);
  }
  sum.x*=(1.f/9.f); sum.y*=(1.f/9.f); sum.z*=(1.f/9.f); sum.w*=(1.f/9.f);
  // restage Zb rows (8 x 128) into sZ and apply W3 in-block
  __syncthreads();
  *(float4*)(sZ + tr*132 + tc*4) = sum;
  __syncthreads();
  const float* zr = sZ + tr*132;
  float4 o = make_float4(0.f,0.f,0.f,0.f);
  #pragma unroll 4
  for(int k=0;k<128;k++){
    float a = zr[k];
    float4 bv = *(const float4*)(W3 + (size_t)k*128 + tc*4);
    o.x=fmaf(a,bv.x,o.x); o.y=fmaf(a,bv.y,o.y);
    o.z=fmaf(a,bv.z,o.z); o.w=fmaf(a,bv.w,o.w);
  }
  float4 bb = ((const float4*)b3)[tc];
  o.x+=bb.x; o.y+=bb.y; o.z+=bb.z; o.w+=bb.w;
  *(float4*)(x1 + (size_t)(node0+tr)*128 + tc*4) = o;
}

// ---------------- conv3: moment-based, dual problems ----------------
__global__ __launch_bounds__(256) void k_mom8d(const float4* __restrict__ xa,
      const float4* __restrict__ xb, const int* __restrict__ ia,
      const int* __restrict__ ib, float* __restrict__ mpart){
  __shared__ float sa[256][9];
  const int prob = blockIdx.y;
  const float4* x = prob ? xb : xa;
  const int* idx = prob ? ib : ia;
  int t = threadIdx.x;
  int e = blockIdx.x*256 + t;
  int i = e/KNN; int j = idx[e];
  float4 xi = x[i], xj = x[j];
  sa[t][0]=xi.x; sa[t][1]=xi.y; sa[t][2]=xi.z; sa[t][3]=xi.w;
  sa[t][4]=xj.x-xi.x; sa[t][5]=xj.y-xi.y; sa[t][6]=xj.z-xi.z; sa[t][7]=xj.w-xi.w;
  __syncthreads();
  if(t < 44){
    float s=0.f;
    if(t<8){
      for(int e2=0;e2<256;e2++) s += sa[e2][t];
    } else {
      int f=t-8, p=0, q=0, acc=0;
      for(p=0;p<8;p++){ int cnt=8-p; if(f<acc+cnt){ q=p+(f-acc); break;} acc+=cnt; }
      for(int e2=0;e2<256;e2++) s += sa[e2][p]*sa[e2][q];
    }
    mpart[((size_t)prob*288 + blockIdx.x)*44 + t]=s;
  }
}

// 128 threads = 2 probs x 64 ch; W1 is 8x64
__global__ void k_bn1qd(const float* __restrict__ mpart, const float* __restrict__ W1,
      const float* __restrict__ g, const float* __restrict__ be,
      float* __restrict__ scale, float* __restrict__ shift){
  __shared__ double mom[2][44];
  int t = threadIdx.x;   // 128
  if(t<88){
    int pr=t/44, m=t%44;
    double s=0; for(int b=0;b<288;b++) s+=(double)mpart[((size_t)pr*288+b)*44+m];
    mom[pr][m]=s;
  }
  __syncthreads();
  int prob = t>>6, c = t&63;
  double m[8], w[8];
  #pragma unroll
  for(int p=0;p<8;p++){ m[p]=mom[prob][p]/(double)TK; w[p]=(double)W1[p*64+c]; }
  double q=0.0; int f=8;
  for(int p=0;p<8;p++)
    for(int qq=p;qq<8;qq++){
      double cov = mom[prob][f]/(double)TK - m[p]*m[qq];
      q += (p==qq?1.0:2.0)*w[p]*w[qq]*cov;
      f++;
    }
  if(q<0) q=0;
  double sc = (double)g[c]/sqrt(q+1e-5);
  double mu=0; for(int p=0;p<8;p++) mu += m[p]*w[p];
  scale[prob*64+c]=(float)sc;
  shift[prob*64+c]=(float)((double)be[c] - mu*sc);
}

// SYRK 64-d dual: per block 256 edges (4 passes of 64), M64 + colsum -> mpartM[(prob*288+b)*4160]
__global__ __launch_bounds__(256) void k_syrk64d(const float4* __restrict__ xa,
      const float4* __restrict__ xb, const int* __restrict__ ia,
      const int* __restrict__ ib, const float* __restrict__ W1,
      const float* __restrict__ sc0, const float* __restrict__ sh0,
      float* __restrict__ mpartM){
  __shared__ float sa[64][9];
  __shared__ float sW1[8*64];
  __shared__ float sZ[64*68];
  __shared__ float ssum[64];
  const int prob = blockIdx.y;
  const float4* x = prob ? xb : xa;
  const int* idx = prob ? ib : ia;
  const float* sc1 = sc0 + prob*64;
  const float* sh1 = sh0 + prob*64;
  const int tid = threadIdx.x;
  if(tid<128) ((float4*)sW1)[tid] = ((const float4*)W1)[tid];
  if(tid<64) ssum[tid]=0.f;
  const int zc4 = tid & 15, ze0 = tid >> 4;     // z chunk (16x4=64ch), rows ze0+16k
  const int i0 = (tid>>4)*4, j0 = (tid&15)*4;   // syrk 4x4 tile
  float acc[4][4];
  #pragma unroll
  for(int a=0;a<4;a++)
    #pragma unroll
    for(int b=0;b<4;b++) acc[a][b]=0.f;
  float ls[4]={0,0,0,0};
  float4 scv = ((const float4*)sc1)[zc4];
  float4 shv = ((const float4*)sh1)[zc4];
  for(int pass=0;pass<4;pass++){
    __syncthreads();
    if(tid<64){
      int e = blockIdx.x*256 + pass*64 + tid;
      int i = e/KNN; int j = idx[e];
      float4 xi = x[i], xj = x[j];
      sa[tid][0]=xi.x; sa[tid][1]=xi.y; sa[tid][2]=xi.z; sa[tid][3]=xi.w;
      sa[tid][4]=xj.x-xi.x; sa[tid][5]=xj.y-xi.y; sa[tid][6]=xj.z-xi.z; sa[tid][7]=xj.w-xi.w;
    }
    __syncthreads();
    for(int e=ze0; e<64; e+=16){
      float4 y = make_float4(0.f,0.f,0.f,0.f);
      #pragma unroll
      for(int k=0;k<8;k++){
        float a = sa[e][k];
        float4 wv = *(const float4*)(sW1 + k*64 + zc4*4);
        y.x=fmaf(a,wv.x,y.x); y.y=fmaf(a,wv.y,y.y);
        y.z=fmaf(a,wv.z,y.z); y.w=fmaf(a,wv.w,y.w);
      }
      float4 z;
      z.x = fmaxf(fmaf(scv.x,y.x,shv.x),0.f);
      z.y = fmaxf(fmaf(scv.y,y.y,shv.y),0.f);
      z.z = fmaxf(fmaf(scv.z,y.z,shv.z),0.f);
      z.w = fmaxf(fmaf(scv.w,y.w,shv.w),0.f);
      *(float4*)(sZ + e*68 + zc4*4) = z;
      ls[0]+=z.x; ls[1]+=z.y; ls[2]+=z.z; ls[3]+=z.w;
    }
    __syncthreads();
    #pragma unroll 4
    for(int e=0;e<64;e++){
      const float* rz = sZ + e*68;
      float4 zi4 = *(const float4*)(rz + i0);
      float4 zj4 = *(const float4*)(rz + j0);
      float zi[4]={zi4.x,zi4.y,zi4.z,zi4.w};
      float zj[4]={zj4.x,zj4.y,zj4.z,zj4.w};
      #pragma unroll
      for(int a=0;a<4;a++)
        #pragma unroll
        for(int b=0;b<4;b++) acc[a][b]=fmaf(zi[a],zj[b],acc[a][b]);
    }
  }
  #pragma unroll
  for(int c=0;c<4;c++) atomicAdd(&ssum[zc4*4+c], ls[c]);
  float* mp = mpartM + ((size_t)prob*288 + blockIdx.x)*4160;
  #pragma unroll
  for(int a=0;a<4;a++)
    *(float4*)(mp + (i0+a)*64 + j0) = make_float4(acc[a][0],acc[a][1],acc[a][2],acc[a][3]);
  __syncthreads();
  if(tid<64) mp[4096+tid] = ssum[tid];
}

__global__ __launch_bounds__(256) void k_redMd(const float* __restrict__ mpartM,
      double* __restrict__ Md){
  int ch = blockIdx.x*256 + threadIdx.x;
  if(ch >= 8320) return;
  int prob = ch / 4160, c = ch % 4160;
  double s=0;
  for(int b=0;b<288;b++) s += (double)mpartM[((size_t)prob*288+b)*4160 + c];
  Md[(size_t)prob*4160 + c]=s;
}

// grid (64, 2); 64 threads; W2 is 64x64
__global__ void k_bn2qd(const double* __restrict__ Md, const float* __restrict__ W2,
      const float* __restrict__ g, const float* __restrict__ be,
      float* __restrict__ scale, float* __restrict__ shift){
  __shared__ double redq[64], redt[64];
  __shared__ float sw[64];
  int c = blockIdx.x, prob = blockIdx.y, t = threadIdx.x;   // 64 threads
  const double* md = Md + (size_t)prob*4160;
  sw[t] = W2[t*64+c];
  __syncthreads();
  double zb = md[4096+t]/(double)TK;
  double inner=0;
  for(int j=0;j<64;j++) inner += md[t*64+j]*(double)sw[j];
  redq[t] = (double)sw[t]*(inner/(double)TK);
  redt[t] = (double)sw[t]*zb;
  __syncthreads();
  for(int s=32;s>0;s>>=1){
    if(t<s){ redq[t]+=redq[t+s]; redt[t]+=redt[t+s]; }
    __syncthreads();
  }
  if(t==0){
    double var = redq[0] - redt[0]*redt[0];
    if(var<0) var=0;
    double sc = (double)g[c]/sqrt(var+1e-5);
    scale[prob*64+c]=(float)sc;
    shift[prob*64+c]=(float)((double)be[c] - redt[0]*sc);
  }
}

// fused conv3 mid+agg+W3: 16 nodes / 144 edges per block; grid (512, 2); writes xlf/xsf
__global__ __launch_bounds__(256) void k_midagg64d(const float4* __restrict__ xa,
      const float4* __restrict__ xb, const int* __restrict__ ia,
      const int* __restrict__ ib, const float* __restrict__ W1,
      const float* __restrict__ sc0, const float* __restrict__ sh0,
      const float* __restrict__ W2, const float* __restrict__ sc20,
      const float* __restrict__ sh20, const float* __restrict__ W3,
      const float* __restrict__ b3, float* __restrict__ outl, float* __restrict__ outs){
  __shared__ float sa[144][9];
  __shared__ float sW1[8*64];
  __shared__ float sZ[144*68];
  const int prob = blockIdx.y;
  const float4* x = prob ? xb : xa;
  const int* idx = prob ? ib : ia;
  const float* sc1 = sc0 + prob*64;
  const float* sh1 = sh0 + prob*64;
  const float* sc2 = sc20 + prob*64;
  const float* sh2 = sh20 + prob*64;
  float* out = prob ? outs : outl;
  const int tid = threadIdx.x;
  const int node0 = blockIdx.x*16;
  if(tid<128) ((float4*)sW1)[tid] = ((const float4*)W1)[tid];
  if(tid<144){
    int e = blockIdx.x*144 + tid;
    int i = e/KNN; int j = idx[e];
    float4 xi = x[i], xj = x[j];
    sa[tid][0]=xi.x; sa[tid][1]=xi.y; sa[tid][2]=xi.z; sa[tid][3]=xi.w;
    sa[tid][4]=xj.x-xi.x; sa[tid][5]=xj.y-xi.y; sa[tid][6]=xj.z-xi.z; sa[tid][7]=xj.w-xi.w;
  }
  __syncthreads();
  // z1 recompute: 144 edges x 16 chunks of 4
  for(int f=tid; f<144*16; f+=256){
    int e = f>>4, c4 = f&15;
    float4 scv = ((const float4*)sc1)[c4];
    float4 shv = ((const float4*)sh1)[c4];
    float4 y = make_float4(0.f,0.f,0.f,0.f);
    #pragma unroll
    for(int k=0;k<8;k++){
      float a = sa[e][k];
      float4 wv = *(const float4*)(sW1 + k*64 + c4*4);
      y.x=fmaf(a,wv.x,y.x); y.y=fmaf(a,wv.y,y.y);
      y.z=fmaf(a,wv.z,y.z); y.w=fmaf(a,wv.w,y.w);
    }
    float4 z;
    z.x = fmaxf(fmaf(scv.x,y.x,shv.x),0.f);
    z.y = fmaxf(fmaf(scv.y,y.y,shv.y),0.f);
    z.z = fmaxf(fmaf(scv.z,y.z,shv.z),0.f);
    z.w = fmaxf(fmaf(scv.w,y.w,shv.w),0.f);
    *(float4*)(sZ + e*68 + c4*4) = z;
  }
  __syncthreads();
  // GEMM x W2 + BN2 + ReLU + mean9 -> Zb64 (regs)
  const int cg = tid & 15, nd = tid >> 4;   // node nd (16), cols cg*4
  float acc[9][4];
  #pragma unroll
  for(int s=0;s<9;s++)
    #pragma unroll
    for(int e=0;e<4;e++) acc[s][e]=0.f;
  #pragma unroll 2
  for(int k4=0;k4<16;k4++){
    float4 av[9];
    #pragma unroll
    for(int s=0;s<9;s++) av[s] = *(const float4*)(sZ + (nd*9+s)*68 + k4*4);
    #pragma unroll
    for(int kk=0;kk<4;kk++){
      float4 bv = *(const float4*)(W2 + (size_t)(k4*4+kk)*64 + cg*4);
      #pragma unroll
      for(int s=0;s<9;s++){
        float a = (kk==0)?av[s].x:(kk==1)?av[s].y:(kk==2)?av[s].z:av[s].w;
        acc[s][0]=fmaf(a,bv.x,acc[s][0]);
        acc[s][1]=fmaf(a,bv.y,acc[s][1]);
        acc[s][2]=fmaf(a,bv.z,acc[s][2]);
        acc[s][3]=fmaf(a,bv.w,acc[s][3]);
      }
    }
  }
  float4 scv = ((const float4*)sc2)[cg];
  float4 shv = ((const float4*)sh2)[cg];
  float4 sum = make_float4(0.f,0.f,0.f,0.f);
  #pragma unroll
  for(int s=0;s<9;s++){
    sum.x += fmaxf(fmaf(scv.x,acc[s][0],shv.x),0.f);
    sum.y += fmaxf(fmaf(scv.y,acc[s][1],shv.y),0.f);
    sum.z += fmaxf(fmaf(scv.z,acc[s][2],shv.z),0.f);
    sum.w += fmaxf(fmaf(scv.w,acc[s][3],shv.w),0.f);
  }
  sum.x*=(1.f/9.f); sum.y*=(1.f/9.f); sum.z*=(1.f/9.f); sum.w*=(1.f/9.f);
  // restage Zb64 rows (16 x 64) into sZ and apply W3 (64x16) in-block
  __syncthreads();
  *(float4*)(sZ + nd*68 + cg*4) = sum;
  __syncthreads();
  {
    int node = tid >> 4, col = tid & 15;
    const float* zr = sZ + node*68;
    float o = 0.f;
    #pragma unroll 4
    for(int k=0;k<64;k++) o = fmaf(zr[k], W3[k*16+col], o);
    out[(size_t)(node0+node)*16 + col] = o + b3[col];
  }
}

// ---------------- head MLP 128->64->32->1, block-tiled (32 rows/block) ----------------
__global__ __launch_bounds__(256) void k_head(const float* __restrict__ x1,
    const float* __restrict__ W1, const float* __restrict__ b1,
    const float* __restrict__ W2, const float* __restrict__ b2,
    const float* __restrict__ W3, const float* __restrict__ b3,
    float* __restrict__ h, float* __restrict__ pstat){
  __shared__ float sA[32*132];
  __shared__ float sW1[128*64];
  __shared__ float o1[32*68];
  __shared__ float sW2[64*32];
  __shared__ float o2[32*33];
  __shared__ float sb1[64], sb2[32], sW3v[32];
  __shared__ float rs[32], rq[32];
  const int tid = threadIdx.x;
  const int row0 = blockIdx.x*32;
  for(int e=tid; e<32*32; e+=256){
    int r = e>>5, c4 = e&31;
    ((float4*)(sA + r*132))[c4] = ((const float4*)(x1 + (size_t)(row0+r)*128))[c4];
  }
  for(int e=tid; e<128*64/4; e+=256) ((float4*)sW1)[e] = ((const float4*)W1)[e];
  for(int e=tid; e<64*32/4; e+=256)  ((float4*)sW2)[e] = ((const float4*)W2)[e];
  if(tid < 64) sb1[tid]=b1[tid];
  if(tid < 32){ sb2[tid]=b2[tid]; sW3v[tid]=W3[tid]; }
  __syncthreads();
  const int tc = tid & 15, tr = tid >> 4;
  float a1[2][4];
  #pragma unroll
  for(int rr=0;rr<2;rr++)
    #pragma unroll
    for(int e=0;e<4;e++) a1[rr][e]=0.f;
  for(int k4=0;k4<32;k4++){
    float4 av0 = *(const float4*)(sA + (tr*2  )*132 + k4*4);
    float4 av1 = *(const float4*)(sA + (tr*2+1)*132 + k4*4);
    #pragma unroll
    for(int kk=0;kk<4;kk++){
      float4 bv = *(const float4*)(sW1 + (k4*4+kk)*64 + tc*4);
      float p0 = (kk==0)?av0.x:(kk==1)?av0.y:(kk==2)?av0.z:av0.w;
      float p1 = (kk==0)?av1.x:(kk==1)?av1.y:(kk==2)?av1.z:av1.w;
      a1[0][0]=fmaf(p0,bv.x,a1[0][0]); a1[0][1]=fmaf(p0,bv.y,a1[0][1]);
      a1[0][2]=fmaf(p0,bv.z,a1[0][2]); a1[0][3]=fmaf(p0,bv.w,a1[0][3]);
      a1[1][0]=fmaf(p1,bv.x,a1[1][0]); a1[1][1]=fmaf(p1,bv.y,a1[1][1]);
      a1[1][2]=fmaf(p1,bv.z,a1[1][2]); a1[1][3]=fmaf(p1,bv.w,a1[1][3]);
    }
  }
  #pragma unroll
  for(int rr=0;rr<2;rr++)
    #pragma unroll
    for(int e=0;e<4;e++)
      o1[(tr*2+rr)*68 + tc*4+e] = fmaxf(a1[rr][e]+sb1[tc*4+e], 0.f);
  __syncthreads();
  float a2[2][2] = {{0.f,0.f},{0.f,0.f}};
  for(int k=0;k<64;k++){
    float w0 = sW2[k*32 + tc*2], w1 = sW2[k*32 + tc*2+1];
    float v0 = o1[(tr*2  )*68 + k];
    float v1 = o1[(tr*2+1)*68 + k];
    a2[0][0]=fmaf(v0,w0,a2[0][0]); a2[0][1]=fmaf(v0,w1,a2[0][1]);
    a2[1][0]=fmaf(v1,w0,a2[1][0]); a2[1][1]=fmaf(v1,w1,a2[1][1]);
  }
  #pragma unroll
  for(int rr=0;rr<2;rr++)
    #pragma unroll
    for(int cc=0;cc<2;cc++)
      o2[(tr*2+rr)*33 + tc*2+cc] = fmaxf(a2[rr][cc]+sb2[tc*2+cc], 0.f);
  __syncthreads();
  if(tid < 32){
    float hv = b3[0];
    #pragma unroll
    for(int k=0;k<32;k++) hv = fmaf(o2[tid*33+k], sW3v[k], hv);
    h[row0+tid]=hv;
    rs[tid]=hv; rq[tid]=hv*hv;
  }
  __syncthreads();
  if(tid==0){
    float S=0.f, Q=0.f;
    #pragma unroll
    for(int i=0;i<32;i++){ S+=rs[i]; Q+=rq[i]; }
    pstat[blockIdx.x*2]=S; pstat[blockIdx.x*2+1]=Q;
  }
}

__global__ __launch_bounds__(256) void k_fin_h(const float* __restrict__ pstat,
      float* __restrict__ hpar){
  __shared__ double sS[256], sQ[256];
  int t = threadIdx.x;
  sS[t] = (double)pstat[2*t]; sQ[t] = (double)pstat[2*t+1];
  __syncthreads();
  for(int s=128;s>0;s>>=1){
    if(t<s){ sS[t]+=sS[t+s]; sQ[t]+=sQ[t+s]; }
    __syncthreads();
  }
  if(t==0){
    double mu = sS[0]/8192.0;
    double var = (sQ[0] - 8192.0*mu*mu)/8191.0;   // ddof=1
    double sd = (var > 0) ? sqrt(var) : 0.0;
    hpar[0]=(float)mu;
    hpar[1]=(float)(1.0/(sd + 1e-5));
  }
}

__global__ __launch_bounds__(256) void k_gate(const float* __restrict__ h,
      const float* __restrict__ hpar, const float4* __restrict__ x,
      float4* __restrict__ xl, float4* __restrict__ xs){
  int i = blockIdx.x*256 + threadIdx.x;
  float z = (h[i]-hpar[0])*hpar[1];
  float o = 1.0f/(1.0f+expf(-z));
  float om = 1.0f - o;
  float4 v = x[i];
  xl[i] = make_float4(o*v.x, o*v.y, o*v.z, o*v.w);
  xs[i] = make_float4(om*v.x, om*v.y, om*v.z, om*v.w);
}

// ---------------- final: per-graph max pool (16ch x 2) + linear [32]->1 ----------------
__global__ __launch_bounds__(256) void k_final(const float* __restrict__ xlf,
      const float* __restrict__ xsf, const float* __restrict__ W,
      const float* __restrict__ b, float* __restrict__ out){
  __shared__ float red[32][8];
  int g = blockIdx.x;
  int c = threadIdx.x & 31;
  int chunk = threadIdx.x >> 5;
  const float* src = (c < 16) ? xlf : xsf;
  int ch = (c < 16) ? c : c-16;
  float m = -1e30f;
  for(int n=chunk*128; n<chunk*128+128; n++)
    m = fmaxf(m, src[((size_t)g*1024+n)*16 + ch]);
  red[c][chunk]=m;
  __syncthreads();
  if(threadIdx.x < 32){
    float mm = red[threadIdx.x][0];
    #pragma unroll
    for(int p=1;p<8;p++) mm = fmaxf(mm, red[threadIdx.x][p]);
    red[threadIdx.x][0]=mm;
  }
  __syncthreads();
  if(threadIdx.x == 0){
    float acc = b[0];
    for(int cc=0;cc<32;cc++) acc = fmaf(red[cc][0], W[cc], acc);
    out[g]=acc;
  }
}

// ---------------- launch ----------------
extern "C" void kernel_launch(void* const* d_in, const int* in_sizes, int n_in,
                              void* d_out, int out_size, void* d_ws, size_t ws_size,
                              hipStream_t stream){
  const float* x    =(const float*)d_in[0];
  const float* c1W1 =(const float*)d_in[1];
  const float* c1g1 =(const float*)d_in[3];
  const float* c1be1=(const float*)d_in[4];
  const float* c1W2 =(const float*)d_in[5];
  const float* c1g2 =(const float*)d_in[7];
  const float* c1be2=(const float*)d_in[8];
  const float* c1W3 =(const float*)d_in[9];
  const float* c1b3 =(const float*)d_in[10];
  const float* c3W1 =(const float*)d_in[11];
  const float* c3g1 =(const float*)d_in[13];
  const float* c3be1=(const float*)d_in[14];
  const float* c3W2 =(const float*)d_in[15];
  const float* c3g2 =(const float*)d_in[17];
  const float* c3be2=(const float*)d_in[18];
  const float* c3W3 =(const float*)d_in[19];
  const float* c3b3 =(const float*)d_in[20];
  const float* hW1  =(const float*)d_in[21];
  const float* hb1  =(const float*)d_in[22];
  const float* hW2  =(const float*)d_in[23];
  const float* hb2  =(const float*)d_in[24];
  const float* hW3  =(const float*)d_in[25];
  const float* hb3  =(const float*)d_in[26];
  const float* l2W  =(const float*)d_in[27];
  const float* l2b  =(const float*)d_in[28];
  (void)in_sizes; (void)n_in; (void)out_size; (void)ws_size;

  char* wsb=(char*)d_ws;
  size_t off=0;
  auto alloc=[&](size_t bytes)->char*{
    char* p = wsb + off;
    off = (off + bytes + 255) & ~(size_t)255;
    return p;
  };
  float* ovl  =(float*)alloc((size_t)NSYB*16512*4);  // overlay: lists / conv1 mpartM / conv3 mpartMd
  float* x1   =(float*)alloc((size_t)TN*128*4);
  int*   idx1 =(int*)  alloc((size_t)TK*4);
  int*   idxl =(int*)  alloc((size_t)TK*4);
  int*   idxs =(int*)  alloc((size_t)TK*4);
  float* pd   =(float*)alloc((size_t)2*TN*72*4);
  float* h    =(float*)alloc((size_t)TN*4);
  float* xl   =(float*)alloc((size_t)TN*16);
  float* xs   =(float*)alloc((size_t)TN*16);
  float* xlf  =(float*)alloc((size_t)TN*16*4);
  float* xsf  =(float*)alloc((size_t)TN*16*4);
  float* pstat=(float*)alloc((size_t)512*4);
  double* Md  =(double*)alloc((size_t)16512*8);
  double* Mdd =(double*)alloc((size_t)8320*8);
  double* pp8 =(double*)alloc((size_t)8*16512*8);
  float* mp44 =(float*)alloc((size_t)288*44*4);
  float* mp44d=(float*)alloc((size_t)2*288*44*4);
  float* tl   =(float*)alloc((size_t)TN*4);
  float* tg   =(float*)alloc((size_t)2*TN*4);
  unsigned char* cnt8l=(unsigned char*)alloc((size_t)TN*8);
  unsigned char* cnt8g=(unsigned char*)alloc((size_t)2*TN*NCHG);
  float* bnp  =(float*)alloc(1024*4);
  float* hpar =(float*)alloc(64);

  float* sc1=bnp,      *sh1=bnp+128, *sc2=bnp+256, *sh2=bnp+384;
  float* scA=bnp+512,  *shA=bnp+640, *scB=bnp+768, *shB=bnp+896;  // conv3: [prob][64]
  unsigned short* listl=(unsigned short*)ovl;   // overlay (disjoint in time)
  unsigned short* listg=(unsigned short*)ovl;
  float* mpartM = ovl;
  float* mpartMd = ovl;

  // ---- conv1 kNN (per-graph) ----
  k_part_local  <<<256,256,0,stream>>>((const float4*)x, pd);
  k_thresh_local<<<32, 256,0,stream>>>(pd, tl);
  k_collect_local<<<256,256,0,stream>>>((const float4*)x, tl, cnt8l, listl);
  k_refine_local<<<TN/32,256,0,stream>>>((const float4*)x, cnt8l, listl, idx1);
  // ---- conv1 (moment-based, no Y materialization) ----
  k_mom8<<<288,256,0,stream>>>((const float4*)x, idx1, mp44);
  k_bn1q<<<1,128,0,stream>>>(mp44, c1W1, c1g1, c1be1, sc1, sh1);
  k_syrk128<<<NSYB,256,0,stream>>>((const float4*)x, idx1, c1W1, sc1, sh1, mpartM);
  k_redA<<<dim3(65,8),256,0,stream>>>(mpartM, pp8);
  k_redB<<<65,256,0,stream>>>(pp8, Md);
  k_bn2q<<<128,128,0,stream>>>(Md, c1W2, c1g2, c1be2, sc2, sh2);
  k_midagg<<<1024,256,0,stream>>>((const float4*)x, idx1, c1W1, sc1, sh1, c1W2, sc2, sh2, c1W3, c1b3, x1);
  // ---- head + gate ----
  k_head<<<TN/32,256,0,stream>>>(x1,hW1,hb1,hW2,hb2,hW3,hb3,h,pstat);
  k_fin_h<<<1,256,0,stream>>>(pstat,hpar);
  k_gate<<<32,256,0,stream>>>(h,hpar,(const float4*)x,(float4*)xl,(float4*)xs);
  // ---- global kNN for xl & xs ----
  k_part_sub   <<<dim3(256,2),256,0,stream>>>((const float4*)xl,(const float4*)xs,pd);
  k_thresh_sub <<<64,256,0,stream>>>(pd,tg);
  k_collect_glob<<<dim3(512,2),256,0,stream>>>((const float4*)xl,(const float4*)xs,tg,cnt8g,listg);
  k_refine_glob<<<2*TN/32,256,0,stream>>>((const float4*)xl,(const float4*)xs,cnt8g,listg,idxl,idxs);
  // ---- conv3 on xl & xs (moment-based, dual) ----
  k_mom8d<<<dim3(288,2),256,0,stream>>>((const float4*)xl,(const float4*)xs,idxl,idxs,mp44d);
  k_bn1qd<<<1,128,0,stream>>>(mp44d, c3W1, c3g1, c3be1, scA, shA);
  k_syrk64d<<<dim3(288,2),256,0,stream>>>((const float4*)xl,(const float4*)xs,idxl,idxs,c3W1,scA,shA,mpartMd);
  k_redMd<<<33,256,0,stream>>>(mpartMd, Mdd);
  k_bn2qd<<<dim3(64,2),64,0,stream>>>(Mdd, c3W2, c3g2, c3be2, scB, shB);
  k_midagg64d<<<dim3(512,2),256,0,stream>>>((const float4*)xl,(const float4*)xs,idxl,idxs,
      c3W1, scA, shA, c3W2, scB, shB, c3W3, c3b3, xlf, xsf);
  // ---- final pooling + linear ----
  k_final<<<8,256,0,stream>>>(xlf,xsf,l2W,l2b,(float*)d_out);
}